// Round 7
// baseline (739.457 us; speedup 1.0000x reference)
//
#include <hip/hip_runtime.h>
#include <math.h>

constexpr int NODES = 2048;
constexpr int BG = 8;
constexpr int SG = 256;
constexpr int DIN = 4096;
constexpr int NHEAD = 8;
constexpr int EDGES = 32768;
constexpr int LLAY = 2;
constexpr int ACT_N = 5;
constexpr int H4C = 128;
constexpr int ECAP = 192;   // per-dst edge list capacity (GAT)
constexpr int SCAP = 96;    // per-src dedup'd neighbor capacity (RWSE)
constexpr int QS = 2560;    // merged hidden stride: [xl 512 | xr 512 | qkv 1536]

typedef unsigned short u16;
typedef unsigned int u32;
typedef unsigned long long u64;
typedef short short8 __attribute__((ext_vector_type(8)));
typedef float f32x4 __attribute__((ext_vector_type(4)));

__device__ __forceinline__ float wave_sum(float v) {
#pragma unroll
  for (int o = 32; o; o >>= 1) v += __shfl_xor(v, o);
  return v;
}
__device__ __forceinline__ float wave_max(float v) {
#pragma unroll
  for (int o = 32; o; o >>= 1) v = fmaxf(v, __shfl_xor(v, o));
  return v;
}
__device__ __forceinline__ float blk_sum(float v, float* sh) {
  v = wave_sum(v);
  int nw = blockDim.x >> 6;
  __syncthreads();
  if ((threadIdx.x & 63) == 0) sh[threadIdx.x >> 6] = v;
  __syncthreads();
  float s = 0.f;
  for (int k = 0; k < nw; k++) s += sh[k];
  return s;
}
__device__ __forceinline__ float gelu_f(float x) {
  return 0.5f * x * (1.f + erff(x * 0.70710678118654752f));
}
__device__ __forceinline__ u16 f2bf(float x) {  // round-to-nearest-even bf16
  u32 u = __float_as_uint(x);
  return (u16)((u + 0x7FFFu + ((u >> 16) & 1u)) >> 16);
}
__device__ __forceinline__ float bf2f(u16 h) { return __uint_as_float(((u32)h) << 16); }

// ================= RWSE (sparse path) =================
__global__ void build_csr(const int* __restrict__ ei, u32* __restrict__ bits,
                          int* __restrict__ scnt, int* __restrict__ slist) {
  int e = blockIdx.x * 256 + threadIdx.x;
  if (e < EDGES) {
    int s = ei[e], d = ei[EDGES + e];
    u32 m = 1u << (d & 31);
    u32 old = atomicOr(&bits[s * 64 + (d >> 5)], m);
    if (!(old & m)) {
      int p = atomicAdd(&scnt[s], 1);
      if (p < SCAP) slist[s * SCAP + p] = d;
    }
  }
}

__global__ void diag_T(const u32* __restrict__ bits, const int* __restrict__ scnt,
                       float* __restrict__ rwse) {
  int i = blockIdx.x * 256 + threadIdx.x;
  if (i < NODES) {
    int deg = min(scnt[i], SCAP);
    int self = (bits[i * 64 + (i >> 5)] >> (i & 31)) & 1;
    rwse[(size_t)i * 8 + 0] = (self && deg > 0) ? 1.f / (float)deg : 0.f;
  }
}

__global__ __launch_bounds__(256) void spmm_sq(const int* __restrict__ scnt,
                                               const int* __restrict__ slist,
                                               float* __restrict__ P2) {
  int i = blockIdx.x, t = threadIdx.x;
  __shared__ float row[NODES];
  for (int c = t; c < NODES; c += 256) row[c] = 0.f;
  __syncthreads();
  int di = min(scnt[i], SCAP);
  float wi = di > 0 ? 1.f / (float)di : 0.f;
  for (int jj = 0; jj < di; jj++) {
    int j = slist[i * SCAP + jj];
    int dj = min(scnt[j], SCAP);
    if (dj == 0) continue;
    float w = wi / (float)dj;
    for (int kk = t; kk < dj; kk += 256) atomicAdd(&row[slist[j * SCAP + kk]], w);
  }
  __syncthreads();
  for (int c = t; c < NODES; c += 256) P2[(size_t)i * NODES + c] = row[c];
}

__global__ __launch_bounds__(256) void spmm_gather(const int* __restrict__ scnt,
                                                   const int* __restrict__ slist,
                                                   const float* __restrict__ P,
                                                   float* __restrict__ Q) {
  int i = blockIdx.x, t = threadIdx.x;
  __shared__ int nb[SCAP];
  int di = min(scnt[i], SCAP);
  for (int c = t; c < di; c += 256) nb[c] = slist[i * SCAP + c];
  __syncthreads();
  float wi = di > 0 ? 1.f / (float)di : 0.f;
  for (int c = t; c < NODES; c += 256) {
    float s = 0.f;
    for (int jj = 0; jj < di; jj++) s += P[(size_t)nb[jj] * NODES + c];
    Q[(size_t)i * NODES + c] = s * wi;
  }
}

__global__ void diag_copy(const float* __restrict__ P, float* __restrict__ rwse, int col) {
  int i = blockIdx.x * 256 + threadIdx.x;
  if (i < NODES) rwse[(size_t)i * 8 + col] = P[(size_t)i * (NODES + 1)];
}

// fused diag dots, tiled+coalesced
__global__ __launch_bounds__(256) void diag_tiled(const float* __restrict__ P2,
                                                  const float* __restrict__ P3,
                                                  const float* __restrict__ P4,
                                                  float* __restrict__ pbuf) {
  __shared__ float r2[64][65], r3[64][65], r4[64][65], c3[64][65], c4[64][65];
  __shared__ float red[4][4][64];
  int t = threadIdx.x;
  int i0 = blockIdx.x * 64;
  int js = blockIdx.y;
  int lo = t & 63, hi = t >> 6;
  float d5 = 0, d6 = 0, d7 = 0, d8 = 0;
  for (int jc = 0; jc < 4; jc++) {
    int j0 = js * 256 + jc * 64;
    __syncthreads();
#pragma unroll
    for (int r = 0; r < 16; r++) {
      int a = hi * 16 + r;
      r2[a][lo] = P2[(size_t)(i0 + a) * NODES + j0 + lo];
      r3[a][lo] = P3[(size_t)(i0 + a) * NODES + j0 + lo];
      r4[a][lo] = P4[(size_t)(i0 + a) * NODES + j0 + lo];
      c3[a][lo] = P3[(size_t)(j0 + a) * NODES + i0 + lo];
      c4[a][lo] = P4[(size_t)(j0 + a) * NODES + i0 + lo];
    }
    __syncthreads();
#pragma unroll
    for (int r = 0; r < 16; r++) {
      int jj = hi * 16 + r;
      float p3c = c3[jj][lo], p4c = c4[jj][lo];
      d5 += r2[lo][jj] * p3c;
      d6 += r3[lo][jj] * p3c;
      d7 += r3[lo][jj] * p4c;
      d8 += r4[lo][jj] * p4c;
    }
  }
  red[0][hi][lo] = d5; red[1][hi][lo] = d6; red[2][hi][lo] = d7; red[3][hi][lo] = d8;
  __syncthreads();
  if (hi == 0) {
    int i = i0 + lo;
#pragma unroll
    for (int v = 0; v < 4; v++) {
      float s = red[v][0][lo] + red[v][1][lo] + red[v][2][lo] + red[v][3][lo];
      pbuf[((size_t)js * NODES + i) * 4 + v] = s;
    }
  }
}

__global__ void diag_reduce(const float* __restrict__ pbuf, float* __restrict__ rwse) {
  int i = blockIdx.x * 256 + threadIdx.x;
  if (i >= NODES) return;
#pragma unroll
  for (int v = 0; v < 4; v++) {
    float s = 0.f;
    for (int js = 0; js < 8; js++) s += pbuf[((size_t)js * NODES + i) * 4 + v];
    rwse[(size_t)i * 8 + 4 + v] = s;
  }
}

// ================= weight packing v2: unit-vectorized =================
// element fi = off + (((ktile*gnTot + ntOff + nt)*8 + j*2 + ks)*64 + g*16 + lr)*8 + e
// One thread per unit (8 consecutive e) -> 16B coalesced writes.
struct PackArgs {
  const float* src[13];
  u64 offU[13];   // unit offset (off/8)
  u64 cumU[14];   // cumulative unit counts
  int N[13];
  int srcStride[13];
  int gnTot[13];
  int ntOff[13];
};

__global__ __launch_bounds__(256) void pack_all(PackArgs pa, u16* __restrict__ Bh,
                                                u16* __restrict__ Bl) {
  u64 total = pa.cumU[13];
  for (u64 u = (u64)blockIdx.x * 256 + threadIdx.x; u < total;
       u += (u64)gridDim.x * 256) {
    int s = 0;
    while (u >= pa.cumU[s + 1]) s++;
    u64 ur = u - pa.cumU[s];
    int lr = (int)(ur & 15);
    int g = (int)((ur >> 4) & 3);
    int ks = (int)((ur >> 6) & 1);
    int j = (int)((ur >> 7) & 3);
    u64 rest = ur >> 9;
    int Nseg = pa.N[s] >> 6;
    int nt = (int)(rest % (u32)Nseg);
    int ktile = (int)(rest / (u32)Nseg);
    int k0 = (ktile << 6) | (ks << 5) | (g << 3);
    int n = (nt << 6) | (j << 4) | lr;
    const float* src = pa.src[s];
    int stride = pa.srcStride[s];
    u64 fiU = pa.offU[s] +
              ((((u64)ktile * pa.gnTot[s] + pa.ntOff[s] + nt) * 8 + j * 2 + ks) * 64 +
               g * 16 + lr);
    short8 h8, l8;
#pragma unroll
    for (int e = 0; e < 8; e++) {
      float v = src[(size_t)(k0 + e) * stride + n];
      u16 h = f2bf(v);
      h8[e] = (short)h;
      l8[e] = (short)f2bf(v - bf2f(h));
    }
    *((short8*)Bh + fiU) = h8;
    *((short8*)Bl + fiU) = l8;
  }
}

// ================= split-bf16 MFMA GEMM, fp32 A, optional split-K ==========
__device__ __forceinline__ void splitA8(const float* __restrict__ p, short8& h8,
                                        short8& l8) {
  float4 v0 = *(const float4*)p;
  float4 v1 = *(const float4*)(p + 4);
  float v[8] = {v0.x, v0.y, v0.z, v0.w, v1.x, v1.y, v1.z, v1.w};
#pragma unroll
  for (int i = 0; i < 8; i++) {
    u16 h = f2bf(v[i]);
    h8[i] = (short)h;
    l8[i] = (short)f2bf(v[i] - bf2f(h));
  }
}

__global__ __launch_bounds__(256) void gemm_af(
    const float* __restrict__ A, const float* __restrict__ A2, int Ksplit,
    const u16* __restrict__ Bh, const u16* __restrict__ Bl,
    float* __restrict__ C, const float* __restrict__ bias,
    int M, int K, int N, int act, int Kslice, float* __restrict__ part,
    const int* __restrict__ gbase) {
  __shared__ __align__(16) u16 LA[2][4096];
  __shared__ __align__(16) u16 LB[2][4096];
  int gn = N >> 6;
  int nwg = (M >> 6) * gn;
  int q = nwg >> 3;
  int flat = blockIdx.x;
  int virt = (flat & 7) * q + (flat >> 3);     // bijective XCD-contiguous remap
  int bm = (virt / gn) << 6, bn = (virt % gn) << 6;
  int arb = gbase ? ((gbase[0] >> 8) << 8) : 0;  // graph-base row offset for A
  int kb = blockIdx.y;
  int kstart = kb * Kslice;
  int kend = min(K, kstart + Kslice);
  int t = threadIdx.x;
  int lane = t & 63, w = t >> 6;
  int wm = (w >> 1) << 5, wn = (w & 1) << 5;
  int r0 = t >> 3, r1 = r0 + 32;
  int c8 = (t & 7) << 3;
  int ks_s = (t >> 2) & 1, g_s = t & 3;
  int slotA = (((r0 & 15) + (g_s << 4)) ^ (g_s | (ks_s << 2)));
  int da0 = ((((r0 >> 4) << 1) + ks_s) << 9) + (slotA << 3);
  int da1 = ((((r1 >> 4) << 1) + ks_s) << 9) + (slotA << 3);
  int db0 = t * 8, db1 = (t + 256) * 8;
  int A2stride = K - Ksplit;
  size_t btile = ((size_t)(kstart >> 6) * gn + (bn >> 6)) * 4096;
  size_t bstep = (size_t)gn * 4096;

  short8 pah0, pal0, pah1, pal1, pbh0, pbl0, pbh1, pbl1;
  auto loadA = [&](int kt, int r, short8& h, short8& l) {
    int k = kt + c8;
    int row = arb + bm + r;
    const float* p = (k < Ksplit) ? A + (size_t)row * Ksplit + k
                                  : A2 + (size_t)row * A2stride + (k - Ksplit);
    splitA8(p, h, l);
  };
  loadA(kstart, r0, pah0, pal0);
  loadA(kstart, r1, pah1, pal1);
  pbh0 = *(const short8*)(Bh + btile + db0);
  pbl0 = *(const short8*)(Bl + btile + db0);
  pbh1 = *(const short8*)(Bh + btile + db1);
  pbl1 = *(const short8*)(Bl + btile + db1);

  f32x4 acc[2][2] = {};
  int lr = lane & 15, lg = lane >> 4;
  int rboff = lane << 3;

  for (int kt = kstart; kt < kend; kt += 64) {
    __syncthreads();
    *(short8*)&LA[0][da0] = pah0;
    *(short8*)&LA[1][da0] = pal0;
    *(short8*)&LA[0][da1] = pah1;
    *(short8*)&LA[1][da1] = pal1;
    *(short8*)&LB[0][db0] = pbh0;
    *(short8*)&LB[1][db0] = pbl0;
    *(short8*)&LB[0][db1] = pbh1;
    *(short8*)&LB[1][db1] = pbl1;
    __syncthreads();
    if (kt + 64 < kend) {
      btile += bstep;
      loadA(kt + 64, r0, pah0, pal0);
      loadA(kt + 64, r1, pah1, pal1);
      pbh0 = *(const short8*)(Bh + btile + db0);
      pbl0 = *(const short8*)(Bl + btile + db0);
      pbh1 = *(const short8*)(Bh + btile + db1);
      pbl1 = *(const short8*)(Bl + btile + db1);
    }
#pragma unroll
    for (int ks = 0; ks < 2; ks++) {
      short8 ah[2], al[2], bh[2], bl[2];
      int slr = ((lr + (lg << 4)) ^ (lg | (ks << 2))) << 3;
#pragma unroll
      for (int i = 0; i < 2; i++) {
        int ba = ((((wm >> 4) + i) * 2 + ks) << 9) + slr;
        ah[i] = *(const short8*)&LA[0][ba];
        al[i] = *(const short8*)&LA[1][ba];
        int bb = ((((wn >> 4) + i) * 2 + ks) << 9) + rboff;
        bh[i] = *(const short8*)&LB[0][bb];
        bl[i] = *(const short8*)&LB[1][bb];
      }
#pragma unroll
      for (int i = 0; i < 2; i++)
#pragma unroll
        for (int j = 0; j < 2; j++) {
          acc[i][j] = __builtin_amdgcn_mfma_f32_16x16x32_bf16(ah[i], bh[j], acc[i][j], 0, 0, 0);
          acc[i][j] = __builtin_amdgcn_mfma_f32_16x16x32_bf16(ah[i], bl[j], acc[i][j], 0, 0, 0);
          acc[i][j] = __builtin_amdgcn_mfma_f32_16x16x32_bf16(al[i], bh[j], acc[i][j], 0, 0, 0);
        }
    }
  }
  int row0 = (lane >> 4) * 4;
  if (part) {
    size_t pbase = (size_t)kb * (size_t)M * N;
#pragma unroll
    for (int i = 0; i < 2; i++)
#pragma unroll
      for (int j = 0; j < 2; j++) {
        int n = bn + wn + j * 16 + lr;
#pragma unroll
        for (int r = 0; r < 4; r++) {
          int m = bm + wm + i * 16 + row0 + r;
          part[pbase + (size_t)m * N + n] = acc[i][j][r];
        }
      }
    return;
  }
#pragma unroll
  for (int i = 0; i < 2; i++)
#pragma unroll
    for (int j = 0; j < 2; j++) {
      int n = bn + wn + j * 16 + lr;
      float bv = bias ? bias[n] : 0.f;
#pragma unroll
      for (int r = 0; r < 4; r++) {
        int m = bm + wm + i * 16 + row0 + r;
        float v = acc[i][j][r] + bv;
        if (act) v = gelu_f(v);
        C[(size_t)m * N + n] = v;
      }
    }
}

// ================= small fused kernels =================
__global__ __launch_bounds__(128) void rwse_proj(const float* __restrict__ rwse,
                                                 const float* __restrict__ W,
                                                 const float* __restrict__ bb,
                                                 const float* __restrict__ g,
                                                 const float* __restrict__ bt,
                                                 float* __restrict__ r) {
  int i = blockIdx.x, j = threadIdx.x;
  float s = bb[j];
#pragma unroll
  for (int k = 0; k < 8; k++) s += rwse[(size_t)i * 8 + k] * W[k * H4C + j];
  __shared__ float sh[8];
  float sum = blk_sum(s, sh);
  float mu = sum * (1.f / 128.f);
  float d = s - mu;
  float var = blk_sum(d * d, sh) * (1.f / 128.f);
  r[(size_t)i * H4C + j] = gelu_f(d * rsqrtf(var + 1e-5f) * g[j] + bt[j]);
}

// ln512: reduce SK fp32 partials (+gemm bias) (+residual) -> LN -> (gelu)
// -> optional mix: y = a*mix + (1-a)*LNout, a = sigmoid(ap[l])
__global__ __launch_bounds__(256) void ln512(const float* __restrict__ x, int sk,
                                             const float* __restrict__ gbias,
                                             const float* __restrict__ res,
                                             const float* __restrict__ mix,
                                             const float* __restrict__ ap, int l,
                                             const float* __restrict__ g,
                                             const float* __restrict__ b,
                                             float* __restrict__ y, int do_gelu) {
  const size_t MN = (size_t)NODES * 512;
  int i = blockIdx.x, t = threadIdx.x;
  size_t base = (size_t)i * 512;
  float v0 = x[base + t], v1 = x[base + 256 + t];
  for (int s = 1; s < sk; s++) {
    v0 += x[(size_t)s * MN + base + t];
    v1 += x[(size_t)s * MN + base + 256 + t];
  }
  if (gbias) { v0 += gbias[t]; v1 += gbias[t + 256]; }
  if (res) { v0 += res[base + t]; v1 += res[base + 256 + t]; }
  __shared__ float sh[8];
  float s = blk_sum(v0 + v1, sh);
  float mu = s * (1.f / 512.f);
  float d0 = v0 - mu, d1 = v1 - mu;
  float var = blk_sum(d0 * d0 + d1 * d1, sh) * (1.f / 512.f);
  float rstd = rsqrtf(var + 1e-5f);
  float o0 = d0 * rstd * g[t] + b[t];
  float o1 = d1 * rstd * g[t + 256] + b[t + 256];
  if (do_gelu) { o0 = gelu_f(o0); o1 = gelu_f(o1); }
  if (mix) {
    float a = 1.f / (1.f + expf(-ap[l]));
    o0 = a * mix[base + t] + (1.f - a) * o0;
    o1 = a * mix[base + 256 + t] + (1.f - a) * o1;
  }
  y[base + t] = o0;
  y[base + 256 + t] = o1;
}

__global__ void build_cbias(const float* __restrict__ bl, const float* __restrict__ br,
                            const float* __restrict__ inb, float* __restrict__ cb) {
  int i = blockIdx.x * 256 + threadIdx.x;
  if (i >= QS) return;
  cb[i] = i < 512 ? bl[i] : (i < 1024 ? br[i - 512] : inb[i - 1024]);
}

__global__ void fill_edges(const int* __restrict__ ei, int* __restrict__ cnt,
                           int* __restrict__ elist) {
  int e = blockIdx.x * 256 + threadIdx.x;
  if (e < EDGES + NODES) {
    int d = e < EDGES ? ei[EDGES + e] : e - EDGES;
    int p = atomicAdd(&cnt[d], 1);
    if (p < ECAP) elist[(size_t)d * ECAP + p] = e;
  }
}

__global__ void ea_reduce(const float* __restrict__ ea, float* __restrict__ sums) {
  int tid = blockIdx.x * blockDim.x + threadIdx.x;
  int stride = gridDim.x * blockDim.x;
  float s0 = 0.f, s1 = 0.f;
  for (int e = tid; e < EDGES; e += stride) { s0 += ea[2 * e]; s1 += ea[2 * e + 1]; }
  s0 = wave_sum(s0);
  s1 = wave_sum(s1);
  if ((threadIdx.x & 63) == 0) { atomicAdd(&sums[0], s0); atomicAdd(&sums[1], s1); }
}

// layer-0 GAT: xl/xr in merged buffer at stride QS
__global__ __launch_bounds__(512) void gat_kernel(
    const float* __restrict__ hb,
    const float* __restrict__ eattr, const float* __restrict__ easum,
    const float* __restrict__ We, const float* __restrict__ att,
    const float* __restrict__ bias, const int* __restrict__ cnt,
    const int* __restrict__ elist, const int* __restrict__ ei,
    float* __restrict__ out) {
  int i = blockIdx.x;
  int tid = threadIdx.x;
  int h = tid >> 6, c = tid & 63;
  int m_cnt = cnt[i];
  if (m_cnt > ECAP) m_cnt = ECAP;
  const float inv_e = 1.f / (float)EDGES;
  float we0 = We[tid], we1 = We[512 + tid];
  float attv = att[tid];
  float xrv = hb[(size_t)i * QS + 512 + tid];
  float ea_m0 = easum[0] * inv_e, ea_m1 = easum[1] * inv_e;
  __shared__ float logits[NHEAD][ECAP];
  const int* el = elist + (size_t)i * ECAP;
  for (int e = 0; e < m_cnt; e++) {
    int eid = el[e];
    int s;
    float a0, a1;
    if (eid < EDGES) { s = ei[eid]; a0 = eattr[2 * eid]; a1 = eattr[2 * eid + 1]; }
    else { s = i; a0 = ea_m0; a1 = ea_m1; }
    float mval = hb[(size_t)s * QS + tid] + xrv + a0 * we0 + a1 * we1;
    mval = mval > 0.f ? mval : 0.2f * mval;
    float lg = wave_sum(mval * attv);
    if (c == 0) logits[h][e] = lg;
  }
  float mx = -1e30f;
  for (int e = c; e < m_cnt; e += 64) mx = fmaxf(mx, logits[h][e]);
  mx = wave_max(mx);
  float den = 0.f;
  for (int e = c; e < m_cnt; e += 64) den += expf(logits[h][e] - mx);
  den = wave_sum(den) + 1e-16f;
  float acc = 0.f;
  for (int e = 0; e < m_cnt; e++) {
    int eid = el[e];
    int s = eid < EDGES ? ei[eid] : i;
    float alpha = expf(logits[h][e] - mx) / den;
    acc += alpha * hb[(size_t)s * QS + tid];
  }
  out[(size_t)i * 512 + tid] = acc + bias[tid];
}

// ======= MFMA block-diag MHA (layer 0); qkv = merged buffer+1024, stride QS ==
__global__ __launch_bounds__(256) void mha_mfma(const float* __restrict__ qkv,
                                                float* __restrict__ o) {
  __shared__ __align__(16) u16 Ksh[2][256][72];
  __shared__ __align__(16) u16 Vt[2][64][264];
  int bid = blockIdx.x;
  int qq = bid & 3;
  int h = (bid >> 2) & 7;
  int b = bid >> 5;
  int t = threadIdx.x;
  int lane = t & 63, w = t >> 6;
  int lr = lane & 15, g = lane >> 4, kk = g * 8;
  size_t rowbase = (size_t)(b * SG) * QS;
  const float* Kbase = qkv + rowbase + 512 + h * 64;
  const float* Vbase = qkv + rowbase + 1024 + h * 64;
  for (int idx = t; idx < SG * 64; idx += 256) {
    int j = idx >> 6, c = idx & 63;
    float kv = Kbase[(size_t)j * QS + c];
    u16 khh = f2bf(kv);
    Ksh[0][j][c] = khh;
    Ksh[1][j][c] = f2bf(kv - bf2f(khh));
    float vv = Vbase[(size_t)j * QS + c];
    u16 vhh = f2bf(vv);
    Vt[0][c][j] = vhh;
    Vt[1][c][j] = f2bf(vv - bf2f(vhh));
  }
  const float* Qrow = qkv + rowbase + (size_t)(qq * 64 + w * 16 + lr) * QS + h * 64;
  short8 qh[2], ql[2];
#pragma unroll
  for (int kt = 0; kt < 2; kt++) {
    float qv[8];
    *(float4*)&qv[0] = *(const float4*)&Qrow[kt * 32 + kk];
    *(float4*)&qv[4] = *(const float4*)&Qrow[kt * 32 + kk + 4];
#pragma unroll
    for (int i = 0; i < 8; i++) {
      u16 hh = f2bf(qv[i]);
      qh[kt][i] = hh;
      ql[kt][i] = f2bf(qv[i] - bf2f(hh));
    }
  }
  __syncthreads();
  f32x4 S[16];
#pragma unroll
  for (int j = 0; j < 16; j++) {
    f32x4 acc = {};
#pragma unroll
    for (int kt = 0; kt < 2; kt++) {
      short8 bh = *(const short8*)&Ksh[0][j * 16 + lr][kt * 32 + kk];
      short8 bl = *(const short8*)&Ksh[1][j * 16 + lr][kt * 32 + kk];
      acc = __builtin_amdgcn_mfma_f32_16x16x32_bf16(qh[kt], bh, acc, 0, 0, 0);
      acc = __builtin_amdgcn_mfma_f32_16x16x32_bf16(qh[kt], bl, acc, 0, 0, 0);
      acc = __builtin_amdgcn_mfma_f32_16x16x32_bf16(ql[kt], bh, acc, 0, 0, 0);
    }
    S[j] = acc;
  }
  float mx[4], inv[4];
#pragma unroll
  for (int r = 0; r < 4; r++) {
    float m = S[0][r];
#pragma unroll
    for (int j = 1; j < 16; j++) m = fmaxf(m, S[j][r]);
#pragma unroll
    for (int oo = 1; oo < 16; oo <<= 1) m = fmaxf(m, __shfl_xor(m, oo));
    mx[r] = m;
    float d = 0.f;
#pragma unroll
    for (int j = 0; j < 16; j++) d += __expf((S[j][r] - m) * 0.125f);
#pragma unroll
    for (int oo = 1; oo < 16; oo <<= 1) d += __shfl_xor(d, oo);
    inv[r] = 1.f / d;
  }
  __syncthreads();
  u16* Pb = &Ksh[0][0][0];
  int row0 = w * 16 + g * 4;
#pragma unroll
  for (int j = 0; j < 16; j++) {
    int key = j * 16 + lr;
#pragma unroll
    for (int r = 0; r < 4; r++) {
      float p = __expf((S[j][r] - mx[r]) * 0.125f) * inv[r];
      u16 hh = f2bf(p);
      Pb[(row0 + r) * 264 + key] = hh;
      Pb[16896 + (row0 + r) * 264 + key] = f2bf(p - bf2f(hh));
    }
  }
  __syncthreads();
  f32x4 Oacc[4] = {};
#pragma unroll
  for (int kt = 0; kt < 8; kt++) {
    short8 pah = *(const short8*)&Pb[(w * 16 + lr) * 264 + kt * 32 + kk];
    short8 pal = *(const short8*)&Pb[16896 + (w * 16 + lr) * 264 + kt * 32 + kk];
#pragma unroll
    for (int nf = 0; nf < 4; nf++) {
      short8 vh = *(const short8*)&Vt[0][nf * 16 + lr][kt * 32 + kk];
      short8 vl = *(const short8*)&Vt[1][nf * 16 + lr][kt * 32 + kk];
      Oacc[nf] = __builtin_amdgcn_mfma_f32_16x16x32_bf16(pah, vh, Oacc[nf], 0, 0, 0);
      Oacc[nf] = __builtin_amdgcn_mfma_f32_16x16x32_bf16(pah, vl, Oacc[nf], 0, 0, 0);
      Oacc[nf] = __builtin_amdgcn_mfma_f32_16x16x32_bf16(pal, vh, Oacc[nf], 0, 0, 0);
    }
  }
  float* obase = o + (size_t)(b * SG + qq * 64 + w * 16 + g * 4) * 512 + h * 64;
#pragma unroll
  for (int nf = 0; nf < 4; nf++)
#pragma unroll
    for (int r = 0; r < 4; r++)
      obase[(size_t)r * 512 + nf * 16 + lr] = Oacc[nf][r];
}

// ================= layer-2 pruned path (row cni only) =================
// q/xr row GEMVs: blocks 0-7 -> q (inW cols 0..511, +inb), 8-15 -> xr (Wr, +br)
__global__ __launch_bounds__(64) void l2_qxr(const float* __restrict__ hin,
                                             const int* __restrict__ cni,
                                             const float* __restrict__ inW,
                                             const float* __restrict__ inb,
                                             const float* __restrict__ Wr,
                                             const float* __restrict__ br,
                                             float* __restrict__ qrow,
                                             float* __restrict__ xrrow) {
  __shared__ float hr[512];
  int lane = threadIdx.x;
  const float* h = hin + (size_t)cni[0] * 512;
  for (int k = lane; k < 512; k += 64) hr[k] = h[k];
  __syncthreads();
  int b = blockIdx.x;
  int isq = b < 8;
  int n = (b & 7) * 64 + lane;
  const float* W = isq ? inW : Wr;
  int stride = isq ? 1536 : 512;
  float acc = isq ? inb[n] : br[n];
  for (int k = 0; k < 512; k++) acc += hr[k] * W[(size_t)k * stride + n];
  if (isq) qrow[n] = acc;
  else xrrow[n] = acc;
}

// GAT at node cni, fused LN(n1) -> local_row
__global__ __launch_bounds__(512) void gat_l2(
    const float* __restrict__ xl, const float* __restrict__ xrrow,
    const int* __restrict__ cni,
    const float* __restrict__ eattr, const float* __restrict__ easum,
    const float* __restrict__ We, const float* __restrict__ att,
    const float* __restrict__ bias, const int* __restrict__ cnt,
    const int* __restrict__ elist, const int* __restrict__ ei,
    const float* __restrict__ n1g, const float* __restrict__ n1b,
    float* __restrict__ local_row) {
  int i = cni[0];
  int tid = threadIdx.x;
  int h = tid >> 6, c = tid & 63;
  int m_cnt = cnt[i];
  if (m_cnt > ECAP) m_cnt = ECAP;
  const float inv_e = 1.f / (float)EDGES;
  float we0 = We[tid], we1 = We[512 + tid];
  float attv = att[tid];
  float xrv = xrrow[tid];
  float ea_m0 = easum[0] * inv_e, ea_m1 = easum[1] * inv_e;
  __shared__ float logits[NHEAD][ECAP];
  __shared__ float sh[8];
  const int* el = elist + (size_t)i * ECAP;
  for (int e = 0; e < m_cnt; e++) {
    int eid = el[e];
    int s;
    float a0, a1;
    if (eid < EDGES) { s = ei[eid]; a0 = eattr[2 * eid]; a1 = eattr[2 * eid + 1]; }
    else { s = i; a0 = ea_m0; a1 = ea_m1; }
    float mval = xl[(size_t)s * 512 + tid] + xrv + a0 * we0 + a1 * we1;
    mval = mval > 0.f ? mval : 0.2f * mval;
    float lg = wave_sum(mval * attv);
    if (c == 0) logits[h][e] = lg;
  }
  float mx = -1e30f;
  for (int e = c; e < m_cnt; e += 64) mx = fmaxf(mx, logits[h][e]);
  mx = wave_max(mx);
  float den = 0.f;
  for (int e = c; e < m_cnt; e += 64) den += expf(logits[h][e] - mx);
  den = wave_sum(den) + 1e-16f;
  float acc = 0.f;
  for (int e = 0; e < m_cnt; e++) {
    int eid = el[e];
    int s = eid < EDGES ? ei[eid] : i;
    float alpha = expf(logits[h][e] - mx) / den;
    acc += alpha * xl[(size_t)s * 512 + tid];
  }
  float v = acc + bias[tid];
  // LN(n1) over the 512-wide row
  float mu = blk_sum(v, sh) * (1.f / 512.f);
  float d = v - mu;
  float var = blk_sum(d * d, sh) * (1.f / 512.f);
  local_row[tid] = d * rsqrtf(var + 1e-5f) * n1g[tid] + n1b[tid];
}

// MHA for row cni only: one block per head (64 lanes)
__global__ __launch_bounds__(64) void mha_l2(const float* __restrict__ qrow,
                                             const float* __restrict__ kv,
                                             float* __restrict__ attO_row) {
  __shared__ float q[64];
  __shared__ float p[SG];
  int h = blockIdx.x;
  int c = threadIdx.x;
  q[c] = qrow[h * 64 + c];
  __syncthreads();
  float s[4];
#pragma unroll
  for (int it = 0; it < 4; it++) {
    int j = it * 64 + c;
    const float* kr = kv + (size_t)j * 1024 + h * 64;
    float acc = 0.f;
#pragma unroll 8
    for (int c2 = 0; c2 < 64; c2++) acc += q[c2] * kr[c2];
    s[it] = acc * 0.125f;
  }
  float m = fmaxf(fmaxf(s[0], s[1]), fmaxf(s[2], s[3]));
  m = wave_max(m);
  float den = 0.f;
#pragma unroll
  for (int it = 0; it < 4; it++) {
    float e = __expf(s[it] - m);
    p[it * 64 + c] = e;
    den += e;
  }
  den = wave_sum(den);
  __syncthreads();
  float o = 0.f;
  for (int j = 0; j < SG; j++) o += p[j] * kv[(size_t)j * 1024 + 512 + h * 64 + c];
  attO_row[h * 64 + c] = o / den;
}

// generic 64-thread GEMV block: out[n0+lane] = bias + <inrow, W[:,n]>, opt gelu
__global__ __launch_bounds__(64) void mv64(const float* __restrict__ inrow, int K,
                                           const float* __restrict__ W, int N,
                                           const float* __restrict__ bias,
                                           float* __restrict__ out, int act) {
  __shared__ float xr[2048];
  int lane = threadIdx.x;
  for (int k = lane; k < K; k += 64) xr[k] = inrow[k];
  __syncthreads();
  int n = blockIdx.x * 64 + lane;
  float acc = bias[n];
  for (int k = 0; k < K; k++) acc += xr[k] * W[(size_t)k * N + n];
  if (act) acc = gelu_f(acc);
  out[n] = acc;
}

// comb row: LN(n2)(o_raw) then mix with local_row
__global__ __launch_bounds__(512) void comb_l2(const float* __restrict__ o_raw,
                                               const float* __restrict__ local_row,
                                               const float* __restrict__ ap, int l,
                                               const float* __restrict__ g,
                                               const float* __restrict__ b,
                                               float* __restrict__ comb_row) {
  __shared__ float sh[8];
  int t = threadIdx.x;
  float v = o_raw[t];
  float mu = blk_sum(v, sh) * (1.f / 512.f);
  float d = v - mu;
  float var = blk_sum(d * d, sh) * (1.f / 512.f);
  float o = d * rsqrtf(var + 1e-5f) * g[t] + b[t];
  float a = 1.f / (1.f + expf(-ap[l]));
  comb_row[t] = a * local_row[t] + (1.f - a) * o;
}

// final: LN(n3)(raw512 + comb_row) -> hrow
__global__ __launch_bounds__(512) void final_l2(const float* __restrict__ raw512,
                                                const float* __restrict__ comb_row,
                                                const float* __restrict__ g,
                                                const float* __restrict__ b,
                                                float* __restrict__ hrow) {
  __shared__ float sh[8];
  int t = threadIdx.x;
  float v = raw512[t] + comb_row[t];
  float mu = blk_sum(v, sh) * (1.f / 512.f);
  float d = v - mu;
  float var = blk_sum(d * d, sh) * (1.f / 512.f);
  hrow[t] = d * rsqrtf(var + 1e-5f) * g[t] + b[t];
}

__global__ __launch_bounds__(512) void head_kernel(
    const float* __restrict__ hrow,
    const float* __restrict__ W1, const float* __restrict__ b1,
    const float* __restrict__ g, const float* __restrict__ bt,
    const float* __restrict__ W2, const float* __restrict__ b2,
    float* __restrict__ out) {
  __shared__ float emb[512];
  __shared__ float z[512];
  __shared__ float sh[8];
  __shared__ float lg[ACT_N];
  int t = threadIdx.x;
  emb[t] = hrow[t];
  __syncthreads();
  float s = b1[t];
  for (int k = 0; k < 512; k++) s += emb[k] * W1[(size_t)k * 512 + t];
  float sum = blk_sum(s, sh);
  float mu = sum * (1.f / 512.f);
  float d = s - mu;
  float var = blk_sum(d * d, sh) * (1.f / 512.f);
  z[t] = gelu_f(d * rsqrtf(var + 1e-5f) * g[t] + bt[t]);
  __syncthreads();
  if (t < ACT_N) {
    float l = b2[t];
    for (int k = 0; k < 512; k++) l += z[k] * W2[k * ACT_N + t];
    lg[t] = l;
  }
  __syncthreads();
  if (t == 0) {
    float m2 = lg[0];
    for (int a = 1; a < ACT_N; a++) m2 = fmaxf(m2, lg[a]);
    float den = 0.f;
    float ex[ACT_N];
    for (int a = 0; a < ACT_N; a++) { ex[a] = expf(lg[a] - m2); den += ex[a]; }
    for (int a = 0; a < ACT_N; a++) {
      out[a] = lg[a];
      out[ACT_N + a] = ex[a] / den;
    }
  }
}

extern "C" void kernel_launch(void* const* d_in, const int* in_sizes, int n_in,
                              void* d_out, int out_size, void* d_ws, size_t ws_size,
                              hipStream_t stream) {
  const float* x        = (const float*)d_in[0];
  const float* eattr    = (const float*)d_in[1];
  const float* rwse_W   = (const float*)d_in[2];
  const float* rwse_b   = (const float*)d_in[3];
  const float* rwse_g   = (const float*)d_in[4];
  const float* rwse_bt  = (const float*)d_in[5];
  const float* np_W     = (const float*)d_in[6];
  const float* np_b     = (const float*)d_in[7];
  const float* np_g     = (const float*)d_in[8];
  const float* np_bt    = (const float*)d_in[9];
  const float* gat_Wl   = (const float*)d_in[10];
  const float* gat_bl   = (const float*)d_in[11];
  const float* gat_Wr   = (const float*)d_in[12];
  const float* gat_br   = (const float*)d_in[13];
  const float* gat_We   = (const float*)d_in[14];
  const float* gat_att  = (const float*)d_in[15];
  const float* gat_bias = (const float*)d_in[16];
  const float* n1_g = (const float*)d_in[17];
  const float* n1_b = (const float*)d_in[18];
  const float* mha_inW  = (const float*)d_in[19];
  const float* mha_inb  = (const float*)d_in[20];
  const float* mha_outW = (const float*)d_in[21];
  const float* mha_outb = (const float*)d_in[22];
  const float* alpha_p  = (const float*)d_in[23];
  const float* n2_g = (const float*)d_in[24];
  const float* n2_b = (const float*)d_in[25];
  const float* ffn_W1 = (const float*)d_in[26];
  const float* ffn_b1 = (const float*)d_in[27];
  const float* ffn_W2 = (const float*)d_in[28];
  const float* ffn_b2 = (const float*)d_in[29];
  const float* n3_g = (const float*)d_in[30];
  const float* n3_b = (const float*)d_in[31];
  const float* ah_W1 = (const float*)d_in[32];
  const float* ah_b1 = (const float*)d_in[33];
  const float* ah_g  = (const float*)d_in[34];
  const float* ah_bt = (const float*)d_in[35];
  const float* ah_W2 = (const float*)d_in[36];
  const float* ah_b2 = (const float*)d_in[37];
  const int* edge_index = (const int*)d_in[38];
  const int* cni        = (const int*)d_in[39];
  (void)in_sizes; (void)n_in; (void)out_size; (void)ws_size;

  char* wsp = (char*)d_ws;
  size_t off = 0;
  auto alloc = [&](size_t bytes) -> char* {
    char* p = wsp + off;
    off += (bytes + 255) & ~(size_t)255;
    return p;
  };
  const size_t NNb = (size_t)NODES * NODES * 4;
  char* arena = alloc(3 * NNb);
  float* P2 = (float*)arena;
  float* P3 = (float*)(arena + NNb);
  float* P4 = (float*)(arena + 2 * NNb);
  // post-RWSE arena reuse (disjoint lifetimes):
  //   part/hbig @ arena+0 (np SK8 partials 32MB -> hbig 21MB -> outproj/W2 partials)
  //   ffmid     @ arena+20971520 (16.8MB)
  float* part  = (float*)arena;
  float* hbig  = (float*)arena;
  float* ffmid = (float*)(arena + 20971520);
  // packed weights (u16 units): np | l0 merged/out/W1/W2 | l1 Wl | l1 KV
  const u64 SEG_NP = 2162688ull;
  const u64 SEG_L0 = 3670016ull;
  const u64 L1_OFF = SEG_NP + SEG_L0;          // 5,832,704
  const u64 KV1_OFF = L1_OFF + 262144ull;      // 6,094,848
  const u64 PTOT = KV1_OFF + 524288ull;        // 6,619,136
  u16* Bh = (u16*)alloc(PTOT * 2);
  u16* Bl = (u16*)alloc(PTOT * 2);
  float* rwse = (float*)alloc((size_t)NODES * 8 * 4);
  float* rbuf = (float*)alloc((size_t)NODES * H4C * 4);
  float* h0   = (float*)alloc((size_t)NODES * 512 * 4);
  float* h1   = (float*)alloc((size_t)NODES * 512 * 4);
  float* gout = (float*)alloc((size_t)NODES * 512 * 4);   // l0 gat out; l1 xl buf
  float* attO = (float*)alloc((size_t)NODES * 512 * 4);   // l0 attn out; l1 kv buf
  float* comb = (float*)alloc((size_t)NODES * 512 * 4);
  float* cb   = (float*)alloc((size_t)QS * 4);
  float* rows = (float*)alloc(4096 * 4);  // q|xr|local|attO|o_raw|comb|raw512|hrow
  float* midrow = (float*)alloc(2048 * 4);
  u32* bits  = (u32*)alloc((size_t)NODES * 64 * 4);
  int* scnt  = (int*)alloc((size_t)NODES * 4);
  int* slist = (int*)alloc((size_t)NODES * SCAP * 4);
  int* cnt   = (int*)alloc((size_t)NODES * 4);
  int* elist = (int*)alloc((size_t)NODES * ECAP * 4);
  float* easum = (float*)alloc(8);
  float* pbuf  = (float*)alloc((size_t)8 * NODES * 4 * 4);
  float* qrow = rows, *xrrow = rows + 512, *local_row = rows + 1024;
  float* attO_row = rows + 1536, *o_raw = rows + 2048, *comb_row = rows + 2560;
  float* raw512 = rows + 3072, *hrow = rows + 3584;
  float* kvbuf = attO;   // l1: [256][1024]
  float* xlbuf = gout;   // l1: [2048][512]

  // ---- RWSE sparse path ----
  hipMemsetAsync(bits, 0, (size_t)NODES * 64 * 4, stream);
  hipMemsetAsync(scnt, 0, NODES * 4, stream);
  build_csr<<<EDGES / 256, 256, 0, stream>>>(edge_index, bits, scnt, slist);
  diag_T<<<NODES / 256, 256, 0, stream>>>(bits, scnt, rwse);
  spmm_sq<<<NODES, 256, 0, stream>>>(scnt, slist, P2);
  diag_copy<<<NODES / 256, 256, 0, stream>>>(P2, rwse, 1);
  spmm_gather<<<NODES, 256, 0, stream>>>(scnt, slist, P2, P3);
  diag_copy<<<NODES / 256, 256, 0, stream>>>(P3, rwse, 2);
  spmm_gather<<<NODES, 256, 0, stream>>>(scnt, slist, P3, P4);
  diag_copy<<<NODES / 256, 256, 0, stream>>>(P4, rwse, 3);
  diag_tiled<<<dim3(NODES / 64, 8), 256, 0, stream>>>(P2, P3, P4, pbuf);
  diag_reduce<<<NODES / 256, 256, 0, stream>>>(pbuf, rwse);
  rwse_proj<<<NODES, 128, 0, stream>>>(rwse, rwse_W, rwse_b, rwse_g, rwse_bt, rbuf);

  // ---- pack weights (unit-vectorized) ----
  PackArgs pa;
  u64 uc = 0;
  int si = 0;
  auto seg = [&](const float* src, int K, int N, int stride, u64 offElems,
                 int gnTot, int ntOff) {
    pa.src[si] = src; pa.offU[si] = offElems / 8; pa.cumU[si] = uc;
    pa.N[si] = N; pa.srcStride[si] = stride; pa.gnTot[si] = gnTot;
    pa.ntOff[si] = ntOff;
    uc += (u64)K * N / 8; si++;
  };
  seg(np_W, 4224, 512, 512, 0, 8, 0);
  // layer 0 (full)
  seg(gat_Wl, 512, 512, 512, SEG_NP, 40, 0);
  seg(gat_Wr, 512, 512, 512, SEG_NP, 40, 8);
  seg(mha_inW, 512, 1536, 1536, SEG_NP, 40, 16);
  seg(mha_outW, 512, 512, 512, SEG_NP + 1310720, 8, 0);
  seg(ffn_W1, 512, 2048, 2048, SEG_NP + 1572864, 32, 0);
  seg(ffn_W2, 2048, 512, 512, SEG_NP + 2621440, 8, 0);
  // layer 1 (pruned): Wl full, K/V columns of inW only
  seg(gat_Wl + 512 * 512, 512, 512, 512, L1_OFF, 8, 0);
  seg(mha_inW + 512 * 1536 + 512, 512, 1024, 1536, KV1_OFF, 16, 0);
  for (int s2 = si; s2 <= 13; s2++) pa.cumU[s2] = uc;
  pack_all<<<2048, 256, 0, stream>>>(pa, Bh, Bl);
  build_cbias<<<(QS + 255) / 256, 256, 0, stream>>>(gat_bl, gat_br, mha_inb, cb);

  // ---- np projection: split-K8 partials -> fused reduce+bias+LN+gelu ----
  gemm_af<<<dim3(256, 8), 256, 0, stream>>>(x, rbuf, 4096, Bh, Bl, nullptr, nullptr,
                                            NODES, 4224, 512, 0, 576, part, nullptr);
  ln512<<<NODES, 256, 0, stream>>>(part, 8, np_b, nullptr, nullptr, nullptr, 0,
                                   np_g, np_bt, h1, 1);

  // ---- GAT CSR + edge-attr mean ----
  hipMemsetAsync(cnt, 0, NODES * 4, stream);
  fill_edges<<<(EDGES + NODES) / 256, 256, 0, stream>>>(edge_index, cnt, elist);
  hipMemsetAsync(easum, 0, 8, stream);
  ea_reduce<<<64, 256, 0, stream>>>(eattr, easum);

  // ================= layer 0 (full) =================
  float* hin = h1;
  float* hout = h0;
  {
    const u64 lb = SEG_NP;
    gemm_af<<<dim3(1280), 256, 0, stream>>>(hin, hin, 512, Bh + lb, Bl + lb, hbig,
                                            cb, NODES, 512, QS, 0, 512, nullptr,
                                            nullptr);
    gat_kernel<<<NODES, 512, 0, stream>>>(hbig, eattr, easum, gat_We, gat_att,
                                          gat_bias, cnt, elist, edge_index, gout);
    ln512<<<NODES, 256, 0, stream>>>(gout, 1, nullptr, nullptr, nullptr, nullptr, 0,
                                     n1_g, n1_b, gout, 0);
    mha_mfma<<<BG * NHEAD * 4, 256, 0, stream>>>(hbig + 1024, attO);
    gemm_af<<<dim3(256, 2), 256, 0, stream>>>(attO, attO, 512, Bh + lb + 1310720,
                                              Bl + lb + 1310720, nullptr, nullptr,
                                              NODES, 512, 512, 0, 256, part, nullptr);
    ln512<<<NODES, 256, 0, stream>>>(part, 2, mha_outb, nullptr, gout, alpha_p, 0,
                                     n2_g, n2_b, comb, 0);
    gemm_af<<<dim3(1024), 256, 0, stream>>>(comb, comb, 512, Bh + lb + 1572864,
                                            Bl + lb + 1572864, ffmid, ffn_b1,
                                            NODES, 512, 2048, 1, 512, nullptr,
                                            nullptr);
    gemm_af<<<dim3(256, 4), 256, 0, stream>>>(ffmid, ffmid, 2048, Bh + lb + 2621440,
                                              Bl + lb + 2621440, nullptr, nullptr,
                                              NODES, 2048, 512, 0, 512, part,
                                              nullptr);
    ln512<<<NODES, 256, 0, stream>>>(part, 4, ffn_b2, comb, nullptr, nullptr, 0,
                                     n3_g, n3_b, hout, 0);
    float* tmp = hin; hin = hout; hout = tmp;
  }

  // ================= layer 1 (pruned to row cni) =================
  {
    // xl for all nodes (GAT neighbors are data-dependent)
    gemm_af<<<dim3(256), 256, 0, stream>>>(hin, hin, 512, Bh + L1_OFF, Bl + L1_OFF,
                                           xlbuf, gat_bl + 512, NODES, 512, 512, 0,
                                           512, nullptr, nullptr);
    // K/V for the graph containing cni (256 rows), compact [256][1024]
    gemm_af<<<dim3(64), 256, 0, stream>>>(hin, hin, 512, Bh + KV1_OFF, Bl + KV1_OFF,
                                          kvbuf, mha_inb + 1536 + 512, 256, 512,
                                          1024, 0, 512, nullptr, cni);
    // q and xr rows
    l2_qxr<<<16, 64, 0, stream>>>(hin, cni, mha_inW + 512 * 1536, mha_inb + 1536,
                                  gat_Wr + 512 * 512, gat_br + 512, qrow, xrrow);
    gat_l2<<<1, 512, 0, stream>>>(xlbuf, xrrow, cni, eattr, easum, gat_We + 1024,
                                  gat_att + 512, gat_bias + 512, cnt, elist,
                                  edge_index, n1_g + 512, n1_b + 512, local_row);
    mha_l2<<<8, 64, 0, stream>>>(qrow, kvbuf, attO_row);
    mv64<<<8, 64, 0, stream>>>(attO_row, 512, mha_outW + 512 * 512, 512,
                               mha_outb + 512, o_raw, 0);
    comb_l2<<<1, 512, 0, stream>>>(o_raw, local_row, alpha_p, 1, n2_g + 512,
                                   n2_b + 512, comb_row);
    mv64<<<32, 64, 0, stream>>>(comb_row, 512, ffn_W1 + (size_t)512 * 2048, 2048,
                                ffn_b1 + 2048, midrow, 1);
    mv64<<<8, 64, 0, stream>>>(midrow, 2048, ffn_W2 + (size_t)2048 * 512, 512,
                               ffn_b2 + 512, raw512, 0);
    final_l2<<<1, 512, 0, stream>>>(raw512, comb_row, n3_g + 512, n3_b + 512, hrow);
  }

  head_kernel<<<1, 512, 0, stream>>>(hrow, ah_W1, ah_b1, ah_g, ah_bt, ah_W2,
                                     ah_b2, (float*)d_out);
}

// Round 8
// 509.733 us; speedup vs baseline: 1.4507x; 1.4507x over previous
//
#include <hip/hip_runtime.h>
#include <math.h>

constexpr int NODES = 2048;
constexpr int BG = 8;
constexpr int SG = 256;
constexpr int DIN = 4096;
constexpr int NHEAD = 8;
constexpr int EDGES = 32768;
constexpr int LLAY = 2;
constexpr int ACT_N = 5;
constexpr int H4C = 128;
constexpr int ECAP = 192;   // per-dst edge list capacity (GAT)
constexpr int SCAP = 96;    // per-src dedup'd neighbor capacity (RWSE)
constexpr int QS = 2560;    // merged hidden stride: [xl 512 | xr 512 | qkv 1536]

typedef unsigned short u16;
typedef unsigned int u32;
typedef unsigned long long u64;
typedef short short8 __attribute__((ext_vector_type(8)));
typedef float f32x4 __attribute__((ext_vector_type(4)));

__device__ __forceinline__ float wave_sum(float v) {
#pragma unroll
  for (int o = 32; o; o >>= 1) v += __shfl_xor(v, o);
  return v;
}
__device__ __forceinline__ float wave_max(float v) {
#pragma unroll
  for (int o = 32; o; o >>= 1) v = fmaxf(v, __shfl_xor(v, o));
  return v;
}
__device__ __forceinline__ float blk_sum(float v, float* sh) {
  v = wave_sum(v);
  int nw = blockDim.x >> 6;
  __syncthreads();
  if ((threadIdx.x & 63) == 0) sh[threadIdx.x >> 6] = v;
  __syncthreads();
  float s = 0.f;
  for (int k = 0; k < nw; k++) s += sh[k];
  return s;
}
__device__ __forceinline__ float gelu_f(float x) {
  return 0.5f * x * (1.f + erff(x * 0.70710678118654752f));
}
__device__ __forceinline__ u16 f2bf(float x) {  // round-to-nearest-even bf16
  u32 u = __float_as_uint(x);
  return (u16)((u + 0x7FFFu + ((u >> 16) & 1u)) >> 16);
}
__device__ __forceinline__ float bf2f(u16 h) { return __uint_as_float(((u32)h) << 16); }

// ================= RWSE (sparse path) =================
__global__ void build_csr(const int* __restrict__ ei, u32* __restrict__ bits,
                          int* __restrict__ scnt, int* __restrict__ slist) {
  int e = blockIdx.x * 256 + threadIdx.x;
  if (e < EDGES) {
    int s = ei[e], d = ei[EDGES + e];
    u32 m = 1u << (d & 31);
    u32 old = atomicOr(&bits[s * 64 + (d >> 5)], m);
    if (!(old & m)) {
      int p = atomicAdd(&scnt[s], 1);
      if (p < SCAP) slist[s * SCAP + p] = d;
    }
  }
}

__global__ void diag_T(const u32* __restrict__ bits, const int* __restrict__ scnt,
                       float* __restrict__ rwse) {
  int i = blockIdx.x * 256 + threadIdx.x;
  if (i < NODES) {
    int deg = min(scnt[i], SCAP);
    int self = (bits[i * 64 + (i >> 5)] >> (i & 31)) & 1;
    rwse[(size_t)i * 8 + 0] = (self && deg > 0) ? 1.f / (float)deg : 0.f;
  }
}

__global__ __launch_bounds__(256) void spmm_sq(const int* __restrict__ scnt,
                                               const int* __restrict__ slist,
                                               float* __restrict__ P2) {
  int i = blockIdx.x, t = threadIdx.x;
  __shared__ float row[NODES];
  for (int c = t; c < NODES; c += 256) row[c] = 0.f;
  __syncthreads();
  int di = min(scnt[i], SCAP);
  float wi = di > 0 ? 1.f / (float)di : 0.f;
  for (int jj = 0; jj < di; jj++) {
    int j = slist[i * SCAP + jj];
    int dj = min(scnt[j], SCAP);
    if (dj == 0) continue;
    float w = wi / (float)dj;
    for (int kk = t; kk < dj; kk += 256) atomicAdd(&row[slist[j * SCAP + kk]], w);
  }
  __syncthreads();
  for (int c = t; c < NODES; c += 256) P2[(size_t)i * NODES + c] = row[c];
}

__global__ __launch_bounds__(256) void spmm_gather(const int* __restrict__ scnt,
                                                   const int* __restrict__ slist,
                                                   const float* __restrict__ P,
                                                   float* __restrict__ Q) {
  int i = blockIdx.x, t = threadIdx.x;
  __shared__ int nb[SCAP];
  int di = min(scnt[i], SCAP);
  for (int c = t; c < di; c += 256) nb[c] = slist[i * SCAP + c];
  __syncthreads();
  float wi = di > 0 ? 1.f / (float)di : 0.f;
  for (int c = t; c < NODES; c += 256) {
    float s = 0.f;
    for (int jj = 0; jj < di; jj++) s += P[(size_t)nb[jj] * NODES + c];
    Q[(size_t)i * NODES + c] = s * wi;
  }
}

__global__ void diag_copy(const float* __restrict__ P, float* __restrict__ rwse, int col) {
  int i = blockIdx.x * 256 + threadIdx.x;
  if (i < NODES) rwse[(size_t)i * 8 + col] = P[(size_t)i * (NODES + 1)];
}

// fused diag dots, tiled+coalesced
__global__ __launch_bounds__(256) void diag_tiled(const float* __restrict__ P2,
                                                  const float* __restrict__ P3,
                                                  const float* __restrict__ P4,
                                                  float* __restrict__ pbuf) {
  __shared__ float r2[64][65], r3[64][65], r4[64][65], c3[64][65], c4[64][65];
  __shared__ float red[4][4][64];
  int t = threadIdx.x;
  int i0 = blockIdx.x * 64;
  int js = blockIdx.y;
  int lo = t & 63, hi = t >> 6;
  float d5 = 0, d6 = 0, d7 = 0, d8 = 0;
  for (int jc = 0; jc < 4; jc++) {
    int j0 = js * 256 + jc * 64;
    __syncthreads();
#pragma unroll
    for (int r = 0; r < 16; r++) {
      int a = hi * 16 + r;
      r2[a][lo] = P2[(size_t)(i0 + a) * NODES + j0 + lo];
      r3[a][lo] = P3[(size_t)(i0 + a) * NODES + j0 + lo];
      r4[a][lo] = P4[(size_t)(i0 + a) * NODES + j0 + lo];
      c3[a][lo] = P3[(size_t)(j0 + a) * NODES + i0 + lo];
      c4[a][lo] = P4[(size_t)(j0 + a) * NODES + i0 + lo];
    }
    __syncthreads();
#pragma unroll
    for (int r = 0; r < 16; r++) {
      int jj = hi * 16 + r;
      float p3c = c3[jj][lo], p4c = c4[jj][lo];
      d5 += r2[lo][jj] * p3c;
      d6 += r3[lo][jj] * p3c;
      d7 += r3[lo][jj] * p4c;
      d8 += r4[lo][jj] * p4c;
    }
  }
  red[0][hi][lo] = d5; red[1][hi][lo] = d6; red[2][hi][lo] = d7; red[3][hi][lo] = d8;
  __syncthreads();
  if (hi == 0) {
    int i = i0 + lo;
#pragma unroll
    for (int v = 0; v < 4; v++) {
      float s = red[v][0][lo] + red[v][1][lo] + red[v][2][lo] + red[v][3][lo];
      pbuf[((size_t)js * NODES + i) * 4 + v] = s;
    }
  }
}

__global__ void diag_reduce(const float* __restrict__ pbuf, float* __restrict__ rwse) {
  int i = blockIdx.x * 256 + threadIdx.x;
  if (i >= NODES) return;
#pragma unroll
  for (int v = 0; v < 4; v++) {
    float s = 0.f;
    for (int js = 0; js < 8; js++) s += pbuf[((size_t)js * NODES + i) * 4 + v];
    rwse[(size_t)i * 8 + 4 + v] = s;
  }
}

// ================= weight packing v2: unit-vectorized =================
struct PackArgs {
  const float* src[13];
  u64 offU[13];
  u64 cumU[14];
  int N[13];
  int srcStride[13];
  int gnTot[13];
  int ntOff[13];
};

__global__ __launch_bounds__(256) void pack_all(PackArgs pa, u16* __restrict__ Bh,
                                                u16* __restrict__ Bl) {
  u64 total = pa.cumU[13];
  for (u64 u = (u64)blockIdx.x * 256 + threadIdx.x; u < total;
       u += (u64)gridDim.x * 256) {
    int s = 0;
    while (u >= pa.cumU[s + 1]) s++;
    u64 ur = u - pa.cumU[s];
    int lr = (int)(ur & 15);
    int g = (int)((ur >> 4) & 3);
    int ks = (int)((ur >> 6) & 1);
    int j = (int)((ur >> 7) & 3);
    u64 rest = ur >> 9;
    int Nseg = pa.N[s] >> 6;
    int nt = (int)(rest % (u32)Nseg);
    int ktile = (int)(rest / (u32)Nseg);
    int k0 = (ktile << 6) | (ks << 5) | (g << 3);
    int n = (nt << 6) | (j << 4) | lr;
    const float* src = pa.src[s];
    int stride = pa.srcStride[s];
    u64 fiU = pa.offU[s] +
              ((((u64)ktile * pa.gnTot[s] + pa.ntOff[s] + nt) * 8 + j * 2 + ks) * 64 +
               g * 16 + lr);
    short8 h8, l8;
#pragma unroll
    for (int e = 0; e < 8; e++) {
      float v = src[(size_t)(k0 + e) * stride + n];
      u16 h = f2bf(v);
      h8[e] = (short)h;
      l8[e] = (short)f2bf(v - bf2f(h));
    }
    *((short8*)Bh + fiU) = h8;
    *((short8*)Bl + fiU) = l8;
  }
}

// ================= split-bf16 MFMA GEMM, fp32 A, optional split-K ==========
__device__ __forceinline__ void splitA8(const float* __restrict__ p, short8& h8,
                                        short8& l8) {
  float4 v0 = *(const float4*)p;
  float4 v1 = *(const float4*)(p + 4);
  float v[8] = {v0.x, v0.y, v0.z, v0.w, v1.x, v1.y, v1.z, v1.w};
#pragma unroll
  for (int i = 0; i < 8; i++) {
    u16 h = f2bf(v[i]);
    h8[i] = (short)h;
    l8[i] = (short)f2bf(v[i] - bf2f(h));
  }
}

__global__ __launch_bounds__(256) void gemm_af(
    const float* __restrict__ A, const float* __restrict__ A2, int Ksplit,
    const u16* __restrict__ Bh, const u16* __restrict__ Bl,
    float* __restrict__ C, const float* __restrict__ bias,
    int M, int K, int N, int act, int Kslice, float* __restrict__ part,
    const int* __restrict__ gbase) {
  __shared__ __align__(16) u16 LA[2][4096];
  __shared__ __align__(16) u16 LB[2][4096];
  int gn = N >> 6;
  int nwg = (M >> 6) * gn;
  int q = nwg >> 3;
  int flat = blockIdx.x;
  int virt = (flat & 7) * q + (flat >> 3);     // bijective XCD-contiguous remap
  int bm = (virt / gn) << 6, bn = (virt % gn) << 6;
  int arb = gbase ? ((gbase[0] >> 8) << 8) : 0;  // graph-base row offset for A
  int kb = blockIdx.y;
  int kstart = kb * Kslice;
  int kend = min(K, kstart + Kslice);
  int t = threadIdx.x;
  int lane = t & 63, w = t >> 6;
  int wm = (w >> 1) << 5, wn = (w & 1) << 5;
  int r0 = t >> 3, r1 = r0 + 32;
  int c8 = (t & 7) << 3;
  int ks_s = (t >> 2) & 1, g_s = t & 3;
  int slotA = (((r0 & 15) + (g_s << 4)) ^ (g_s | (ks_s << 2)));
  int da0 = ((((r0 >> 4) << 1) + ks_s) << 9) + (slotA << 3);
  int da1 = ((((r1 >> 4) << 1) + ks_s) << 9) + (slotA << 3);
  int db0 = t * 8, db1 = (t + 256) * 8;
  int A2stride = K - Ksplit;
  size_t btile = ((size_t)(kstart >> 6) * gn + (bn >> 6)) * 4096;
  size_t bstep = (size_t)gn * 4096;

  short8 pah0, pal0, pah1, pal1, pbh0, pbl0, pbh1, pbl1;
  auto loadA = [&](int kt, int r, short8& h, short8& l) {
    int k = kt + c8;
    int row = arb + bm + r;
    const float* p = (k < Ksplit) ? A + (size_t)row * Ksplit + k
                                  : A2 + (size_t)row * A2stride + (k - Ksplit);
    splitA8(p, h, l);
  };
  loadA(kstart, r0, pah0, pal0);
  loadA(kstart, r1, pah1, pal1);
  pbh0 = *(const short8*)(Bh + btile + db0);
  pbl0 = *(const short8*)(Bl + btile + db0);
  pbh1 = *(const short8*)(Bh + btile + db1);
  pbl1 = *(const short8*)(Bl + btile + db1);

  f32x4 acc[2][2] = {};
  int lr = lane & 15, lg = lane >> 4;
  int rboff = lane << 3;

  for (int kt = kstart; kt < kend; kt += 64) {
    __syncthreads();
    *(short8*)&LA[0][da0] = pah0;
    *(short8*)&LA[1][da0] = pal0;
    *(short8*)&LA[0][da1] = pah1;
    *(short8*)&LA[1][da1] = pal1;
    *(short8*)&LB[0][db0] = pbh0;
    *(short8*)&LB[1][db0] = pbl0;
    *(short8*)&LB[0][db1] = pbh1;
    *(short8*)&LB[1][db1] = pbl1;
    __syncthreads();
    if (kt + 64 < kend) {
      btile += bstep;
      loadA(kt + 64, r0, pah0, pal0);
      loadA(kt + 64, r1, pah1, pal1);
      pbh0 = *(const short8*)(Bh + btile + db0);
      pbl0 = *(const short8*)(Bl + btile + db0);
      pbh1 = *(const short8*)(Bh + btile + db1);
      pbl1 = *(const short8*)(Bl + btile + db1);
    }
#pragma unroll
    for (int ks = 0; ks < 2; ks++) {
      short8 ah[2], al[2], bh[2], bl[2];
      int slr = ((lr + (lg << 4)) ^ (lg | (ks << 2))) << 3;
#pragma unroll
      for (int i = 0; i < 2; i++) {
        int ba = ((((wm >> 4) + i) * 2 + ks) << 9) + slr;
        ah[i] = *(const short8*)&LA[0][ba];
        al[i] = *(const short8*)&LA[1][ba];
        int bb = ((((wn >> 4) + i) * 2 + ks) << 9) + rboff;
        bh[i] = *(const short8*)&LB[0][bb];
        bl[i] = *(const short8*)&LB[1][bb];
      }
#pragma unroll
      for (int i = 0; i < 2; i++)
#pragma unroll
        for (int j = 0; j < 2; j++) {
          acc[i][j] = __builtin_amdgcn_mfma_f32_16x16x32_bf16(ah[i], bh[j], acc[i][j], 0, 0, 0);
          acc[i][j] = __builtin_amdgcn_mfma_f32_16x16x32_bf16(ah[i], bl[j], acc[i][j], 0, 0, 0);
          acc[i][j] = __builtin_amdgcn_mfma_f32_16x16x32_bf16(al[i], bh[j], acc[i][j], 0, 0, 0);
        }
    }
  }
  int row0 = (lane >> 4) * 4;
  if (part) {
    size_t pbase = (size_t)kb * (size_t)M * N;
#pragma unroll
    for (int i = 0; i < 2; i++)
#pragma unroll
      for (int j = 0; j < 2; j++) {
        int n = bn + wn + j * 16 + lr;
#pragma unroll
        for (int r = 0; r < 4; r++) {
          int m = bm + wm + i * 16 + row0 + r;
          part[pbase + (size_t)m * N + n] = acc[i][j][r];
        }
      }
    return;
  }
#pragma unroll
  for (int i = 0; i < 2; i++)
#pragma unroll
    for (int j = 0; j < 2; j++) {
      int n = bn + wn + j * 16 + lr;
      float bv = bias ? bias[n] : 0.f;
#pragma unroll
      for (int r = 0; r < 4; r++) {
        int m = bm + wm + i * 16 + row0 + r;
        float v = acc[i][j][r] + bv;
        if (act) v = gelu_f(v);
        C[(size_t)m * N + n] = v;
      }
    }
}

// ================= small fused kernels =================
__global__ __launch_bounds__(128) void rwse_proj(const float* __restrict__ rwse,
                                                 const float* __restrict__ W,
                                                 const float* __restrict__ bb,
                                                 const float* __restrict__ g,
                                                 const float* __restrict__ bt,
                                                 float* __restrict__ r) {
  int i = blockIdx.x, j = threadIdx.x;
  float s = bb[j];
#pragma unroll
  for (int k = 0; k < 8; k++) s += rwse[(size_t)i * 8 + k] * W[k * H4C + j];
  __shared__ float sh[8];
  float sum = blk_sum(s, sh);
  float mu = sum * (1.f / 128.f);
  float d = s - mu;
  float var = blk_sum(d * d, sh) * (1.f / 128.f);
  r[(size_t)i * H4C + j] = gelu_f(d * rsqrtf(var + 1e-5f) * g[j] + bt[j]);
}

__global__ __launch_bounds__(256) void ln512(const float* __restrict__ x, int sk,
                                             const float* __restrict__ gbias,
                                             const float* __restrict__ res,
                                             const float* __restrict__ mix,
                                             const float* __restrict__ ap, int l,
                                             const float* __restrict__ g,
                                             const float* __restrict__ b,
                                             float* __restrict__ y, int do_gelu) {
  const size_t MN = (size_t)NODES * 512;
  int i = blockIdx.x, t = threadIdx.x;
  size_t base = (size_t)i * 512;
  float v0 = x[base + t], v1 = x[base + 256 + t];
  for (int s = 1; s < sk; s++) {
    v0 += x[(size_t)s * MN + base + t];
    v1 += x[(size_t)s * MN + base + 256 + t];
  }
  if (gbias) { v0 += gbias[t]; v1 += gbias[t + 256]; }
  if (res) { v0 += res[base + t]; v1 += res[base + 256 + t]; }
  __shared__ float sh[8];
  float s = blk_sum(v0 + v1, sh);
  float mu = s * (1.f / 512.f);
  float d0 = v0 - mu, d1 = v1 - mu;
  float var = blk_sum(d0 * d0 + d1 * d1, sh) * (1.f / 512.f);
  float rstd = rsqrtf(var + 1e-5f);
  float o0 = d0 * rstd * g[t] + b[t];
  float o1 = d1 * rstd * g[t + 256] + b[t + 256];
  if (do_gelu) { o0 = gelu_f(o0); o1 = gelu_f(o1); }
  if (mix) {
    float a = 1.f / (1.f + expf(-ap[l]));
    o0 = a * mix[base + t] + (1.f - a) * o0;
    o1 = a * mix[base + 256 + t] + (1.f - a) * o1;
  }
  y[base + t] = o0;
  y[base + 256 + t] = o1;
}

__global__ void build_cbias(const float* __restrict__ bl, const float* __restrict__ br,
                            const float* __restrict__ inb, float* __restrict__ cb) {
  int i = blockIdx.x * 256 + threadIdx.x;
  if (i >= QS) return;
  cb[i] = i < 512 ? bl[i] : (i < 1024 ? br[i - 512] : inb[i - 1024]);
}

__global__ void fill_edges(const int* __restrict__ ei, int* __restrict__ cnt,
                           int* __restrict__ elist) {
  int e = blockIdx.x * 256 + threadIdx.x;
  if (e < EDGES + NODES) {
    int d = e < EDGES ? ei[EDGES + e] : e - EDGES;
    int p = atomicAdd(&cnt[d], 1);
    if (p < ECAP) elist[(size_t)d * ECAP + p] = e;
  }
}

__global__ void ea_reduce(const float* __restrict__ ea, float* __restrict__ sums) {
  int tid = blockIdx.x * blockDim.x + threadIdx.x;
  int stride = gridDim.x * blockDim.x;
  float s0 = 0.f, s1 = 0.f;
  for (int e = tid; e < EDGES; e += stride) { s0 += ea[2 * e]; s1 += ea[2 * e + 1]; }
  s0 = wave_sum(s0);
  s1 = wave_sum(s1);
  if ((threadIdx.x & 63) == 0) { atomicAdd(&sums[0], s0); atomicAdd(&sums[1], s1); }
}

// layer-0 GAT: xl/xr in merged buffer at stride QS
__global__ __launch_bounds__(512) void gat_kernel(
    const float* __restrict__ hb,
    const float* __restrict__ eattr, const float* __restrict__ easum,
    const float* __restrict__ We, const float* __restrict__ att,
    const float* __restrict__ bias, const int* __restrict__ cnt,
    const int* __restrict__ elist, const int* __restrict__ ei,
    float* __restrict__ out) {
  int i = blockIdx.x;
  int tid = threadIdx.x;
  int h = tid >> 6, c = tid & 63;
  int m_cnt = cnt[i];
  if (m_cnt > ECAP) m_cnt = ECAP;
  const float inv_e = 1.f / (float)EDGES;
  float we0 = We[tid], we1 = We[512 + tid];
  float attv = att[tid];
  float xrv = hb[(size_t)i * QS + 512 + tid];
  float ea_m0 = easum[0] * inv_e, ea_m1 = easum[1] * inv_e;
  __shared__ float logits[NHEAD][ECAP];
  const int* el = elist + (size_t)i * ECAP;
  for (int e = 0; e < m_cnt; e++) {
    int eid = el[e];
    int s;
    float a0, a1;
    if (eid < EDGES) { s = ei[eid]; a0 = eattr[2 * eid]; a1 = eattr[2 * eid + 1]; }
    else { s = i; a0 = ea_m0; a1 = ea_m1; }
    float mval = hb[(size_t)s * QS + tid] + xrv + a0 * we0 + a1 * we1;
    mval = mval > 0.f ? mval : 0.2f * mval;
    float lg = wave_sum(mval * attv);
    if (c == 0) logits[h][e] = lg;
  }
  float mx = -1e30f;
  for (int e = c; e < m_cnt; e += 64) mx = fmaxf(mx, logits[h][e]);
  mx = wave_max(mx);
  float den = 0.f;
  for (int e = c; e < m_cnt; e += 64) den += expf(logits[h][e] - mx);
  den = wave_sum(den) + 1e-16f;
  float acc = 0.f;
  for (int e = 0; e < m_cnt; e++) {
    int eid = el[e];
    int s = eid < EDGES ? ei[eid] : i;
    float alpha = expf(logits[h][e] - mx) / den;
    acc += alpha * hb[(size_t)s * QS + tid];
  }
  out[(size_t)i * 512 + tid] = acc + bias[tid];
}

// ======= MFMA block-diag MHA (layer 0); qkv = merged buffer+1024, stride QS ==
__global__ __launch_bounds__(256) void mha_mfma(const float* __restrict__ qkv,
                                                float* __restrict__ o) {
  __shared__ __align__(16) u16 Ksh[2][256][72];
  __shared__ __align__(16) u16 Vt[2][64][264];
  int bid = blockIdx.x;
  int qq = bid & 3;
  int h = (bid >> 2) & 7;
  int b = bid >> 5;
  int t = threadIdx.x;
  int lane = t & 63, w = t >> 6;
  int lr = lane & 15, g = lane >> 4, kk = g * 8;
  size_t rowbase = (size_t)(b * SG) * QS;
  const float* Kbase = qkv + rowbase + 512 + h * 64;
  const float* Vbase = qkv + rowbase + 1024 + h * 64;
  for (int idx = t; idx < SG * 64; idx += 256) {
    int j = idx >> 6, c = idx & 63;
    float kv = Kbase[(size_t)j * QS + c];
    u16 khh = f2bf(kv);
    Ksh[0][j][c] = khh;
    Ksh[1][j][c] = f2bf(kv - bf2f(khh));
    float vv = Vbase[(size_t)j * QS + c];
    u16 vhh = f2bf(vv);
    Vt[0][c][j] = vhh;
    Vt[1][c][j] = f2bf(vv - bf2f(vhh));
  }
  const float* Qrow = qkv + rowbase + (size_t)(qq * 64 + w * 16 + lr) * QS + h * 64;
  short8 qh[2], ql[2];
#pragma unroll
  for (int kt = 0; kt < 2; kt++) {
    float qv[8];
    *(float4*)&qv[0] = *(const float4*)&Qrow[kt * 32 + kk];
    *(float4*)&qv[4] = *(const float4*)&Qrow[kt * 32 + kk + 4];
#pragma unroll
    for (int i = 0; i < 8; i++) {
      u16 hh = f2bf(qv[i]);
      qh[kt][i] = hh;
      ql[kt][i] = f2bf(qv[i] - bf2f(hh));
    }
  }
  __syncthreads();
  f32x4 S[16];
#pragma unroll
  for (int j = 0; j < 16; j++) {
    f32x4 acc = {};
#pragma unroll
    for (int kt = 0; kt < 2; kt++) {
      short8 bh = *(const short8*)&Ksh[0][j * 16 + lr][kt * 32 + kk];
      short8 bl = *(const short8*)&Ksh[1][j * 16 + lr][kt * 32 + kk];
      acc = __builtin_amdgcn_mfma_f32_16x16x32_bf16(qh[kt], bh, acc, 0, 0, 0);
      acc = __builtin_amdgcn_mfma_f32_16x16x32_bf16(qh[kt], bl, acc, 0, 0, 0);
      acc = __builtin_amdgcn_mfma_f32_16x16x32_bf16(ql[kt], bh, acc, 0, 0, 0);
    }
    S[j] = acc;
  }
  float mx[4], inv[4];
#pragma unroll
  for (int r = 0; r < 4; r++) {
    float m = S[0][r];
#pragma unroll
    for (int j = 1; j < 16; j++) m = fmaxf(m, S[j][r]);
#pragma unroll
    for (int oo = 1; oo < 16; oo <<= 1) m = fmaxf(m, __shfl_xor(m, oo));
    mx[r] = m;
    float d = 0.f;
#pragma unroll
    for (int j = 0; j < 16; j++) d += __expf((S[j][r] - m) * 0.125f);
#pragma unroll
    for (int oo = 1; oo < 16; oo <<= 1) d += __shfl_xor(d, oo);
    inv[r] = 1.f / d;
  }
  __syncthreads();
  u16* Pb = &Ksh[0][0][0];
  int row0 = w * 16 + g * 4;
#pragma unroll
  for (int j = 0; j < 16; j++) {
    int key = j * 16 + lr;
#pragma unroll
    for (int r = 0; r < 4; r++) {
      float p = __expf((S[j][r] - mx[r]) * 0.125f) * inv[r];
      u16 hh = f2bf(p);
      Pb[(row0 + r) * 264 + key] = hh;
      Pb[16896 + (row0 + r) * 264 + key] = f2bf(p - bf2f(hh));
    }
  }
  __syncthreads();
  f32x4 Oacc[4] = {};
#pragma unroll
  for (int kt = 0; kt < 8; kt++) {
    short8 pah = *(const short8*)&Pb[(w * 16 + lr) * 264 + kt * 32 + kk];
    short8 pal = *(const short8*)&Pb[16896 + (w * 16 + lr) * 264 + kt * 32 + kk];
#pragma unroll
    for (int nf = 0; nf < 4; nf++) {
      short8 vh = *(const short8*)&Vt[0][nf * 16 + lr][kt * 32 + kk];
      short8 vl = *(const short8*)&Vt[1][nf * 16 + lr][kt * 32 + kk];
      Oacc[nf] = __builtin_amdgcn_mfma_f32_16x16x32_bf16(pah, vh, Oacc[nf], 0, 0, 0);
      Oacc[nf] = __builtin_amdgcn_mfma_f32_16x16x32_bf16(pah, vl, Oacc[nf], 0, 0, 0);
      Oacc[nf] = __builtin_amdgcn_mfma_f32_16x16x32_bf16(pal, vh, Oacc[nf], 0, 0, 0);
    }
  }
  float* obase = o + (size_t)(b * SG + qq * 64 + w * 16 + g * 4) * 512 + h * 64;
#pragma unroll
  for (int nf = 0; nf < 4; nf++)
#pragma unroll
    for (int r = 0; r < 4; r++)
      obase[(size_t)r * 512 + nf * 16 + lr] = Oacc[nf][r];
}

// ================= layer-2 pruned path (row cni only) =================
// split-K GEMV: part[kb][n] = sum_{k in 64-slice kb} inrow[k] * W[k*ldW + n]
// grid (N/64, K/64), 256 thr = 4 waves x 16-deep k-subslices, LDS reduce.
__global__ __launch_bounds__(256) void gemv_part(
    const float* __restrict__ inrow, const int* __restrict__ cni, int rowStride,
    const float* __restrict__ W, int ldW, int N, float* __restrict__ part) {
  __shared__ float xv[64];
  __shared__ float red[4][64];
  int t = threadIdx.x;
  int kb = blockIdx.y;
  const float* xr = inrow + (cni ? (size_t)cni[0] * rowStride : 0) + kb * 64;
  if (t < 64) xv[t] = xr[t];
  __syncthreads();
  int nl = t & 63;
  int n = blockIdx.x * 64 + nl;
  int seg = t >> 6;
  float acc = 0.f;
  const float* Wp = W + (size_t)(kb * 64 + seg * 16) * ldW + n;
#pragma unroll
  for (int k = 0; k < 16; k++) acc += xv[seg * 16 + k] * Wp[(size_t)k * ldW];
  red[seg][nl] = acc;
  __syncthreads();
  if (t < 64) {
    part[(size_t)kb * N + blockIdx.x * 64 + t] =
        red[0][t] + red[1][t] + red[2][t] + red[3][t];
  }
}

// out[n] = bias[n] + sum_kb part[kb][n], optional gelu
__global__ void row_reduce(const float* __restrict__ part, int KB, int N,
                           const float* __restrict__ bias,
                           float* __restrict__ out, int act) {
  int n = blockIdx.x * 256 + threadIdx.x;
  if (n >= N) return;
  float s = bias[n];
  for (int k = 0; k < KB; k++) s += part[(size_t)k * N + n];
  if (act) s = gelu_f(s);
  out[n] = s;
}

// GAT at node cni, fused LN(n1) -> local_row
__global__ __launch_bounds__(512) void gat_l2(
    const float* __restrict__ xl, const float* __restrict__ xrrow,
    const int* __restrict__ cni,
    const float* __restrict__ eattr, const float* __restrict__ easum,
    const float* __restrict__ We, const float* __restrict__ att,
    const float* __restrict__ bias, const int* __restrict__ cnt,
    const int* __restrict__ elist, const int* __restrict__ ei,
    const float* __restrict__ n1g, const float* __restrict__ n1b,
    float* __restrict__ local_row) {
  int i = cni[0];
  int tid = threadIdx.x;
  int h = tid >> 6, c = tid & 63;
  int m_cnt = cnt[i];
  if (m_cnt > ECAP) m_cnt = ECAP;
  const float inv_e = 1.f / (float)EDGES;
  float we0 = We[tid], we1 = We[512 + tid];
  float attv = att[tid];
  float xrv = xrrow[tid];
  float ea_m0 = easum[0] * inv_e, ea_m1 = easum[1] * inv_e;
  __shared__ float logits[NHEAD][ECAP];
  __shared__ float sh[8];
  const int* el = elist + (size_t)i * ECAP;
  for (int e = 0; e < m_cnt; e++) {
    int eid = el[e];
    int s;
    float a0, a1;
    if (eid < EDGES) { s = ei[eid]; a0 = eattr[2 * eid]; a1 = eattr[2 * eid + 1]; }
    else { s = i; a0 = ea_m0; a1 = ea_m1; }
    float mval = xl[(size_t)s * 512 + tid] + xrv + a0 * we0 + a1 * we1;
    mval = mval > 0.f ? mval : 0.2f * mval;
    float lg = wave_sum(mval * attv);
    if (c == 0) logits[h][e] = lg;
  }
  float mx = -1e30f;
  for (int e = c; e < m_cnt; e += 64) mx = fmaxf(mx, logits[h][e]);
  mx = wave_max(mx);
  float den = 0.f;
  for (int e = c; e < m_cnt; e += 64) den += expf(logits[h][e] - mx);
  den = wave_sum(den) + 1e-16f;
  float acc = 0.f;
  for (int e = 0; e < m_cnt; e++) {
    int eid = el[e];
    int s = eid < EDGES ? ei[eid] : i;
    float alpha = expf(logits[h][e] - mx) / den;
    acc += alpha * xl[(size_t)s * 512 + tid];
  }
  float v = acc + bias[tid];
  float mu = blk_sum(v, sh) * (1.f / 512.f);
  float d = v - mu;
  float var = blk_sum(d * d, sh) * (1.f / 512.f);
  local_row[tid] = d * rsqrtf(var + 1e-5f) * n1g[tid] + n1b[tid];
}

// MHA for row cni only: one block per (head, 64-key slice): grid 32
__global__ __launch_bounds__(64) void mha_l2(const float* __restrict__ qrow,
                                             const float* __restrict__ kv,
                                             float* __restrict__ pexp,
                                             float* __restrict__ pmax) {
  __shared__ float q[64];
  int h = blockIdx.x & 7;
  int slice = blockIdx.x >> 3;
  int c = threadIdx.x;
  q[c] = qrow[h * 64 + c];
  __syncthreads();
  int j = slice * 64 + c;
  const float* kr = kv + (size_t)j * 1024 + h * 64;
  float acc = 0.f;
#pragma unroll 8
  for (int c2 = 0; c2 < 64; c2++) acc += q[c2] * kr[c2];
  acc *= 0.125f;
  pexp[h * SG + j] = acc;
  float m = wave_max(acc);
  if (c == 0) pmax[blockIdx.x] = m;
}

// finish: softmax over 256 logits + PV for one head; grid 8 x 64 thr
__global__ __launch_bounds__(64) void mha_l2b(const float* __restrict__ pexp,
                                              const float* __restrict__ pmax,
                                              const float* __restrict__ kv,
                                              float* __restrict__ attO_row) {
  __shared__ float p[SG];
  int h = blockIdx.x;
  int c = threadIdx.x;
  float m = fmaxf(fmaxf(pmax[h], pmax[8 + h]), fmaxf(pmax[16 + h], pmax[24 + h]));
  float den = 0.f;
#pragma unroll
  for (int it = 0; it < 4; it++) {
    float e = __expf(pexp[h * SG + it * 64 + c] - m);
    p[it * 64 + c] = e;
    den += e;
  }
  den = wave_sum(den);
  __syncthreads();
  float o = 0.f;
  for (int j = 0; j < SG; j++) o += p[j] * kv[(size_t)j * 1024 + 512 + h * 64 + c];
  attO_row[h * 64 + c] = o / den;
}

// comb row: reduce out-proj partials + bias -> LN(n2) -> mix with local_row
__global__ __launch_bounds__(512) void comb_l2(const float* __restrict__ part, int KB,
                                               const float* __restrict__ bias,
                                               const float* __restrict__ local_row,
                                               const float* __restrict__ ap, int l,
                                               const float* __restrict__ g,
                                               const float* __restrict__ b,
                                               float* __restrict__ comb_row) {
  __shared__ float sh[8];
  int t = threadIdx.x;
  float v = bias[t];
  for (int k = 0; k < KB; k++) v += part[(size_t)k * 512 + t];
  float mu = blk_sum(v, sh) * (1.f / 512.f);
  float d = v - mu;
  float var = blk_sum(d * d, sh) * (1.f / 512.f);
  float o = d * rsqrtf(var + 1e-5f) * g[t] + b[t];
  float a = 1.f / (1.f + expf(-ap[l]));
  comb_row[t] = a * local_row[t] + (1.f - a) * o;
}

// final: reduce W2 partials + bias + residual(comb_row) -> LN(n3) -> hrow
__global__ __launch_bounds__(512) void final_l2(const float* __restrict__ part, int KB,
                                                const float* __restrict__ bias,
                                                const float* __restrict__ comb_row,
                                                const float* __restrict__ g,
                                                const float* __restrict__ b,
                                                float* __restrict__ hrow) {
  __shared__ float sh[8];
  int t = threadIdx.x;
  float v = bias[t] + comb_row[t];
  for (int k = 0; k < KB; k++) v += part[(size_t)k * 512 + t];
  float mu = blk_sum(v, sh) * (1.f / 512.f);
  float d = v - mu;
  float var = blk_sum(d * d, sh) * (1.f / 512.f);
  hrow[t] = d * rsqrtf(var + 1e-5f) * g[t] + b[t];
}

__global__ __launch_bounds__(512) void head_kernel(
    const float* __restrict__ hrow,
    const float* __restrict__ W1, const float* __restrict__ b1,
    const float* __restrict__ g, const float* __restrict__ bt,
    const float* __restrict__ W2, const float* __restrict__ b2,
    float* __restrict__ out) {
  __shared__ float emb[512];
  __shared__ float z[512];
  __shared__ float sh[8];
  __shared__ float lg[ACT_N];
  int t = threadIdx.x;
  emb[t] = hrow[t];
  __syncthreads();
  float s = b1[t];
  for (int k = 0; k < 512; k++) s += emb[k] * W1[(size_t)k * 512 + t];
  float sum = blk_sum(s, sh);
  float mu = sum * (1.f / 512.f);
  float d = s - mu;
  float var = blk_sum(d * d, sh) * (1.f / 512.f);
  z[t] = gelu_f(d * rsqrtf(var + 1e-5f) * g[t] + bt[t]);
  __syncthreads();
  if (t < ACT_N) {
    float l = b2[t];
    for (int k = 0; k < 512; k++) l += z[k] * W2[k * ACT_N + t];
    lg[t] = l;
  }
  __syncthreads();
  if (t == 0) {
    float m2 = lg[0];
    for (int a = 1; a < ACT_N; a++) m2 = fmaxf(m2, lg[a]);
    float den = 0.f;
    float ex[ACT_N];
    for (int a = 0; a < ACT_N; a++) { ex[a] = expf(lg[a] - m2); den += ex[a]; }
    for (int a = 0; a < ACT_N; a++) {
      out[a] = lg[a];
      out[ACT_N + a] = ex[a] / den;
    }
  }
}

extern "C" void kernel_launch(void* const* d_in, const int* in_sizes, int n_in,
                              void* d_out, int out_size, void* d_ws, size_t ws_size,
                              hipStream_t stream) {
  const float* x        = (const float*)d_in[0];
  const float* eattr    = (const float*)d_in[1];
  const float* rwse_W   = (const float*)d_in[2];
  const float* rwse_b   = (const float*)d_in[3];
  const float* rwse_g   = (const float*)d_in[4];
  const float* rwse_bt  = (const float*)d_in[5];
  const float* np_W     = (const float*)d_in[6];
  const float* np_b     = (const float*)d_in[7];
  const float* np_g     = (const float*)d_in[8];
  const float* np_bt    = (const float*)d_in[9];
  const float* gat_Wl   = (const float*)d_in[10];
  const float* gat_bl   = (const float*)d_in[11];
  const float* gat_Wr   = (const float*)d_in[12];
  const float* gat_br   = (const float*)d_in[13];
  const float* gat_We   = (const float*)d_in[14];
  const float* gat_att  = (const float*)d_in[15];
  const float* gat_bias = (const float*)d_in[16];
  const float* n1_g = (const float*)d_in[17];
  const float* n1_b = (const float*)d_in[18];
  const float* mha_inW  = (const float*)d_in[19];
  const float* mha_inb  = (const float*)d_in[20];
  const float* mha_outW = (const float*)d_in[21];
  const float* mha_outb = (const float*)d_in[22];
  const float* alpha_p  = (const float*)d_in[23];
  const float* n2_g = (const float*)d_in[24];
  const float* n2_b = (const float*)d_in[25];
  const float* ffn_W1 = (const float*)d_in[26];
  const float* ffn_b1 = (const float*)d_in[27];
  const float* ffn_W2 = (const float*)d_in[28];
  const float* ffn_b2 = (const float*)d_in[29];
  const float* n3_g = (const float*)d_in[30];
  const float* n3_b = (const float*)d_in[31];
  const float* ah_W1 = (const float*)d_in[32];
  const float* ah_b1 = (const float*)d_in[33];
  const float* ah_g  = (const float*)d_in[34];
  const float* ah_bt = (const float*)d_in[35];
  const float* ah_W2 = (const float*)d_in[36];
  const float* ah_b2 = (const float*)d_in[37];
  const int* edge_index = (const int*)d_in[38];
  const int* cni        = (const int*)d_in[39];
  (void)in_sizes; (void)n_in; (void)out_size; (void)ws_size;

  char* wsp = (char*)d_ws;
  size_t off = 0;
  auto alloc = [&](size_t bytes) -> char* {
    char* p = wsp + off;
    off += (bytes + 255) & ~(size_t)255;
    return p;
  };
  const size_t NNb = (size_t)NODES * NODES * 4;
  char* arena = alloc(3 * NNb);
  float* P2 = (float*)arena;
  float* P3 = (float*)(arena + NNb);
  float* P4 = (float*)(arena + 2 * NNb);
  float* part  = (float*)arena;
  float* hbig  = (float*)arena;
  float* ffmid = (float*)(arena + 20971520);
  const u64 SEG_NP = 2162688ull;
  const u64 SEG_L0 = 3670016ull;
  const u64 L1_OFF = SEG_NP + SEG_L0;
  const u64 KV1_OFF = L1_OFF + 262144ull;
  const u64 PTOT = KV1_OFF + 524288ull;
  u16* Bh = (u16*)alloc(PTOT * 2);
  u16* Bl = (u16*)alloc(PTOT * 2);
  float* rwse = (float*)alloc((size_t)NODES * 8 * 4);
  float* rbuf = (float*)alloc((size_t)NODES * H4C * 4);
  float* h0   = (float*)alloc((size_t)NODES * 512 * 4);
  float* h1   = (float*)alloc((size_t)NODES * 512 * 4);
  float* gout = (float*)alloc((size_t)NODES * 512 * 4);   // l0 gat out; l1 xl buf
  float* attO = (float*)alloc((size_t)NODES * 512 * 4);   // l0 attn out; l1 kv buf
  float* comb = (float*)alloc((size_t)NODES * 512 * 4);
  float* cb   = (float*)alloc((size_t)QS * 4);
  float* rows = (float*)alloc(4096 * 4);
  float* midrow = (float*)alloc(2048 * 4);
  float* pv1 = (float*)alloc((size_t)32 * 2048 * 4);  // gemv partials (q/out/W1/W2)
  float* pv2 = (float*)alloc((size_t)8 * 512 * 4);    // gemv partials (xr)
  float* pse = (float*)alloc((size_t)8 * SG * 4);     // mha_l2 logits
  float* psm = (float*)alloc(32 * 4);                 // mha_l2 slice maxima
  u32* bits  = (u32*)alloc((size_t)NODES * 64 * 4);
  int* scnt  = (int*)alloc((size_t)NODES * 4);
  int* slist = (int*)alloc((size_t)NODES * SCAP * 4);
  int* cnt   = (int*)alloc((size_t)NODES * 4);
  int* elist = (int*)alloc((size_t)NODES * ECAP * 4);
  float* easum = (float*)alloc(8);
  float* pbuf  = (float*)alloc((size_t)8 * NODES * 4 * 4);
  float* qrow = rows, *xrrow = rows + 512, *local_row = rows + 1024;
  float* attO_row = rows + 1536, *comb_row = rows + 2560;
  float* hrow = rows + 3584;
  float* kvbuf = attO;   // l1: [256][1024]
  float* xlbuf = gout;   // l1: [2048][512]

  // ---- RWSE sparse path ----
  hipMemsetAsync(bits, 0, (size_t)NODES * 64 * 4, stream);
  hipMemsetAsync(scnt, 0, NODES * 4, stream);
  build_csr<<<EDGES / 256, 256, 0, stream>>>(edge_index, bits, scnt, slist);
  diag_T<<<NODES / 256, 256, 0, stream>>>(bits, scnt, rwse);
  spmm_sq<<<NODES, 256, 0, stream>>>(scnt, slist, P2);
  diag_copy<<<NODES / 256, 256, 0, stream>>>(P2, rwse, 1);
  spmm_gather<<<NODES, 256, 0, stream>>>(scnt, slist, P2, P3);
  diag_copy<<<NODES / 256, 256, 0, stream>>>(P3, rwse, 2);
  spmm_gather<<<NODES, 256, 0, stream>>>(scnt, slist, P3, P4);
  diag_copy<<<NODES / 256, 256, 0, stream>>>(P4, rwse, 3);
  diag_tiled<<<dim3(NODES / 64, 8), 256, 0, stream>>>(P2, P3, P4, pbuf);
  diag_reduce<<<NODES / 256, 256, 0, stream>>>(pbuf, rwse);
  rwse_proj<<<NODES, 128, 0, stream>>>(rwse, rwse_W, rwse_b, rwse_g, rwse_bt, rbuf);

  // ---- pack weights ----
  PackArgs pa;
  u64 uc = 0;
  int si = 0;
  auto seg = [&](const float* src, int K, int N, int stride, u64 offElems,
                 int gnTot, int ntOff) {
    pa.src[si] = src; pa.offU[si] = offElems / 8; pa.cumU[si] = uc;
    pa.N[si] = N; pa.srcStride[si] = stride; pa.gnTot[si] = gnTot;
    pa.ntOff[si] = ntOff;
    uc += (u64)K * N / 8; si++;
  };
  seg(np_W, 4224, 512, 512, 0, 8, 0);
  seg(gat_Wl, 512, 512, 512, SEG_NP, 40, 0);
  seg(gat_Wr, 512, 512, 512, SEG_NP, 40, 8);
  seg(mha_inW, 512, 1536, 1536, SEG_NP, 40, 16);
  seg(mha_outW, 512, 512, 512, SEG_NP + 1310720, 8, 0);
  seg(ffn_W1, 512, 2048, 2048, SEG_NP + 1572864, 32, 0);
  seg(ffn_W2, 2048, 512, 512, SEG_NP + 2621440, 8, 0);
  seg(gat_Wl + 512 * 512, 512, 512, 512, L1_OFF, 8, 0);
  seg(mha_inW + 512 * 1536 + 512, 512, 1024, 1536, KV1_OFF, 16, 0);
  for (int s2 = si; s2 <= 13; s2++) pa.cumU[s2] = uc;
  pack_all<<<2048, 256, 0, stream>>>(pa, Bh, Bl);
  build_cbias<<<(QS + 255) / 256, 256, 0, stream>>>(gat_bl, gat_br, mha_inb, cb);

  // ---- np projection: split-K8 partials -> fused reduce+bias+LN+gelu ----
  gemm_af<<<dim3(256, 8), 256, 0, stream>>>(x, rbuf, 4096, Bh, Bl, nullptr, nullptr,
                                            NODES, 4224, 512, 0, 576, part, nullptr);
  ln512<<<NODES, 256, 0, stream>>>(part, 8, np_b, nullptr, nullptr, nullptr, 0,
                                   np_g, np_bt, h1, 1);

  // ---- GAT CSR + edge-attr mean ----
  hipMemsetAsync(cnt, 0, NODES * 4, stream);
  fill_edges<<<(EDGES + NODES) / 256, 256, 0, stream>>>(edge_index, cnt, elist);
  hipMemsetAsync(easum, 0, 8, stream);
  ea_reduce<<<64, 256, 0, stream>>>(eattr, easum);

  // ================= layer 0 (full) =================
  float* hin = h1;
  float* hout = h0;
  {
    const u64 lb = SEG_NP;
    gemm_af<<<dim3(1280), 256, 0, stream>>>(hin, hin, 512, Bh + lb, Bl + lb, hbig,
                                            cb, NODES, 512, QS, 0, 512, nullptr,
                                            nullptr);
    gat_kernel<<<NODES, 512, 0, stream>>>(hbig, eattr, easum, gat_We, gat_att,
                                          gat_bias, cnt, elist, edge_index, gout);
    ln512<<<NODES, 256, 0, stream>>>(gout, 1, nullptr, nullptr, nullptr, nullptr, 0,
                                     n1_g, n1_b, gout, 0);
    mha_mfma<<<BG * NHEAD * 4, 256, 0, stream>>>(hbig + 1024, attO);
    gemm_af<<<dim3(256, 2), 256, 0, stream>>>(attO, attO, 512, Bh + lb + 1310720,
                                              Bl + lb + 1310720, nullptr, nullptr,
                                              NODES, 512, 512, 0, 256, part, nullptr);
    ln512<<<NODES, 256, 0, stream>>>(part, 2, mha_outb, nullptr, gout, alpha_p, 0,
                                     n2_g, n2_b, comb, 0);
    gemm_af<<<dim3(1024), 256, 0, stream>>>(comb, comb, 512, Bh + lb + 1572864,
                                            Bl + lb + 1572864, ffmid, ffn_b1,
                                            NODES, 512, 2048, 1, 512, nullptr,
                                            nullptr);
    gemm_af<<<dim3(256, 4), 256, 0, stream>>>(ffmid, ffmid, 2048, Bh + lb + 2621440,
                                              Bl + lb + 2621440, nullptr, nullptr,
                                              NODES, 2048, 512, 0, 512, part,
                                              nullptr);
    ln512<<<NODES, 256, 0, stream>>>(part, 4, ffn_b2, comb, nullptr, nullptr, 0,
                                     n3_g, n3_b, hout, 0);
    float* tmp = hin; hin = hout; hout = tmp;
  }

  // ================= layer 1 (pruned to row cni) =================
  {
    // xl for all nodes (GAT neighbors are data-dependent)
    gemm_af<<<dim3(256), 256, 0, stream>>>(hin, hin, 512, Bh + L1_OFF, Bl + L1_OFF,
                                           xlbuf, gat_bl + 512, NODES, 512, 512, 0,
                                           512, nullptr, nullptr);
    // K/V for the graph containing cni (256 rows), compact [256][1024]
    gemm_af<<<dim3(64), 256, 0, stream>>>(hin, hin, 512, Bh + KV1_OFF, Bl + KV1_OFF,
                                          kvbuf, mha_inb + 1536 + 512, 256, 512,
                                          1024, 0, 512, nullptr, cni);
    // q and xr rows via split-K GEMV
    gemv_part<<<dim3(8, 8), 256, 0, stream>>>(hin, cni, 512,
                                              mha_inW + 512 * 1536, 1536, 512, pv1);
    gemv_part<<<dim3(8, 8), 256, 0, stream>>>(hin, cni, 512,
                                              gat_Wr + 512 * 512, 512, 512, pv2);
    row_reduce<<<2, 256, 0, stream>>>(pv1, 8, 512, mha_inb + 1536, qrow, 0);
    row_reduce<<<2, 256, 0, stream>>>(pv2, 8, 512, gat_br + 512, xrrow, 0);
    gat_l2<<<1, 512, 0, stream>>>(xlbuf, xrrow, cni, eattr, easum, gat_We + 1024,
                                  gat_att + 512, gat_bias + 512, cnt, elist,
                                  edge_index, n1_g + 512, n1_b + 512, local_row);
    mha_l2<<<32, 64, 0, stream>>>(qrow, kvbuf, pse, psm);
    mha_l2b<<<8, 64, 0, stream>>>(pse, psm, kvbuf, attO_row);
    gemv_part<<<dim3(8, 8), 256, 0, stream>>>(attO_row, nullptr, 0,
                                              mha_outW + 512 * 512, 512, 512, pv1);
    comb_l2<<<1, 512, 0, stream>>>(pv1, 8, mha_outb + 512, local_row, alpha_p, 1,
                                   n2_g + 512, n2_b + 512, comb_row);
    gemv_part<<<dim3(32, 8), 256, 0, stream>>>(comb_row, nullptr, 0,
                                               ffn_W1 + (size_t)512 * 2048, 2048,
                                               2048, pv1);
    row_reduce<<<8, 256, 0, stream>>>(pv1, 8, 2048, ffn_b1 + 2048, midrow, 1);
    gemv_part<<<dim3(8, 32), 256, 0, stream>>>(midrow, nullptr, 0,
                                               ffn_W2 + (size_t)2048 * 512, 512,
                                               512, pv1);
    final_l2<<<1, 512, 0, stream>>>(pv1, 32, ffn_b2 + 512, comb_row, n3_g + 512,
                                    n3_b + 512, hrow);
  }

  head_kernel<<<1, 512, 0, stream>>>(hrow, ah_W1, ah_b1, ah_g, ah_bt, ah_W2,
                                     ah_b2, (float*)d_out);
}

// Round 9
// 465.752 us; speedup vs baseline: 1.5877x; 1.0944x over previous
//
#include <hip/hip_runtime.h>
#include <math.h>

constexpr int NODES = 2048;
constexpr int BG = 8;
constexpr int SG = 256;
constexpr int DIN = 4096;
constexpr int NHEAD = 8;
constexpr int EDGES = 32768;
constexpr int LLAY = 2;
constexpr int ACT_N = 5;
constexpr int H4C = 128;
constexpr int ECAP = 192;   // per-dst edge list capacity (GAT)
constexpr int SCAP = 96;    // per-src dedup'd neighbor capacity (RWSE)
constexpr int QS = 2560;    // merged hidden stride: [xl 512 | xr 512 | qkv 1536]
constexpr int NC = 512;     // compact row count (256 graph + 192 nbrs + pad)

typedef unsigned short u16;
typedef unsigned int u32;
typedef unsigned long long u64;
typedef short short8 __attribute__((ext_vector_type(8)));
typedef float f32x4 __attribute__((ext_vector_type(4)));

__device__ __forceinline__ float wave_sum(float v) {
#pragma unroll
  for (int o = 32; o; o >>= 1) v += __shfl_xor(v, o);
  return v;
}
__device__ __forceinline__ float wave_max(float v) {
#pragma unroll
  for (int o = 32; o; o >>= 1) v = fmaxf(v, __shfl_xor(v, o));
  return v;
}
__device__ __forceinline__ float blk_sum(float v, float* sh) {
  v = wave_sum(v);
  int nw = blockDim.x >> 6;
  __syncthreads();
  if ((threadIdx.x & 63) == 0) sh[threadIdx.x >> 6] = v;
  __syncthreads();
  float s = 0.f;
  for (int k = 0; k < nw; k++) s += sh[k];
  return s;
}
__device__ __forceinline__ float blk_max(float v, float* sh) {
  v = wave_max(v);
  int nw = blockDim.x >> 6;
  __syncthreads();
  if ((threadIdx.x & 63) == 0) sh[threadIdx.x >> 6] = v;
  __syncthreads();
  float m = sh[0];
  for (int k = 1; k < nw; k++) m = fmaxf(m, sh[k]);
  return m;
}
__device__ __forceinline__ float gelu_f(float x) {
  return 0.5f * x * (1.f + erff(x * 0.70710678118654752f));
}
__device__ __forceinline__ u16 f2bf(float x) {  // round-to-nearest-even bf16
  u32 u = __float_as_uint(x);
  return (u16)((u + 0x7FFFu + ((u >> 16) & 1u)) >> 16);
}
__device__ __forceinline__ float bf2f(u16 h) { return __uint_as_float(((u32)h) << 16); }

// ================= RWSE (sparse path) =================
__global__ void build_csr(const int* __restrict__ ei, u32* __restrict__ bits,
                          int* __restrict__ scnt, int* __restrict__ slist) {
  int e = blockIdx.x * 256 + threadIdx.x;
  if (e < EDGES) {
    int s = ei[e], d = ei[EDGES + e];
    u32 m = 1u << (d & 31);
    u32 old = atomicOr(&bits[s * 64 + (d >> 5)], m);
    if (!(old & m)) {
      int p = atomicAdd(&scnt[s], 1);
      if (p < SCAP) slist[s * SCAP + p] = d;
    }
  }
}

__global__ void diag_T(const u32* __restrict__ bits, const int* __restrict__ scnt,
                       float* __restrict__ rwse) {
  int i = blockIdx.x * 256 + threadIdx.x;
  if (i < NODES) {
    int deg = min(scnt[i], SCAP);
    int self = (bits[i * 64 + (i >> 5)] >> (i & 31)) & 1;
    rwse[(size_t)i * 8 + 0] = (self && deg > 0) ? 1.f / (float)deg : 0.f;
  }
}

__global__ __launch_bounds__(256) void spmm_sq(const int* __restrict__ scnt,
                                               const int* __restrict__ slist,
                                               float* __restrict__ P2) {
  int i = blockIdx.x, t = threadIdx.x;
  __shared__ float row[NODES];
  for (int c = t; c < NODES; c += 256) row[c] = 0.f;
  __syncthreads();
  int di = min(scnt[i], SCAP);
  float wi = di > 0 ? 1.f / (float)di : 0.f;
  for (int jj = 0; jj < di; jj++) {
    int j = slist[i * SCAP + jj];
    int dj = min(scnt[j], SCAP);
    if (dj == 0) continue;
    float w = wi / (float)dj;
    for (int kk = t; kk < dj; kk += 256) atomicAdd(&row[slist[j * SCAP + kk]], w);
  }
  __syncthreads();
  for (int c = t; c < NODES; c += 256) P2[(size_t)i * NODES + c] = row[c];
}

__global__ __launch_bounds__(256) void spmm_gather(const int* __restrict__ scnt,
                                                   const int* __restrict__ slist,
                                                   const float* __restrict__ P,
                                                   float* __restrict__ Q) {
  int i = blockIdx.x, t = threadIdx.x;
  __shared__ int nb[SCAP];
  int di = min(scnt[i], SCAP);
  for (int c = t; c < di; c += 256) nb[c] = slist[i * SCAP + c];
  __syncthreads();
  float wi = di > 0 ? 1.f / (float)di : 0.f;
  for (int c = t; c < NODES; c += 256) {
    float s = 0.f;
    for (int jj = 0; jj < di; jj++) s += P[(size_t)nb[jj] * NODES + c];
    Q[(size_t)i * NODES + c] = s * wi;
  }
}

__global__ void diag_copy(const float* __restrict__ P, float* __restrict__ rwse, int col) {
  int i = blockIdx.x * 256 + threadIdx.x;
  if (i < NODES) rwse[(size_t)i * 8 + col] = P[(size_t)i * (NODES + 1)];
}

// fused diag dots, tiled+coalesced
__global__ __launch_bounds__(256) void diag_tiled(const float* __restrict__ P2,
                                                  const float* __restrict__ P3,
                                                  const float* __restrict__ P4,
                                                  float* __restrict__ pbuf) {
  __shared__ float r2[64][65], r3[64][65], r4[64][65], c3[64][65], c4[64][65];
  __shared__ float red[4][4][64];
  int t = threadIdx.x;
  int i0 = blockIdx.x * 64;
  int js = blockIdx.y;
  int lo = t & 63, hi = t >> 6;
  float d5 = 0, d6 = 0, d7 = 0, d8 = 0;
  for (int jc = 0; jc < 4; jc++) {
    int j0 = js * 256 + jc * 64;
    __syncthreads();
#pragma unroll
    for (int r = 0; r < 16; r++) {
      int a = hi * 16 + r;
      r2[a][lo] = P2[(size_t)(i0 + a) * NODES + j0 + lo];
      r3[a][lo] = P3[(size_t)(i0 + a) * NODES + j0 + lo];
      r4[a][lo] = P4[(size_t)(i0 + a) * NODES + j0 + lo];
      c3[a][lo] = P3[(size_t)(j0 + a) * NODES + i0 + lo];
      c4[a][lo] = P4[(size_t)(j0 + a) * NODES + i0 + lo];
    }
    __syncthreads();
#pragma unroll
    for (int r = 0; r < 16; r++) {
      int jj = hi * 16 + r;
      float p3c = c3[jj][lo], p4c = c4[jj][lo];
      d5 += r2[lo][jj] * p3c;
      d6 += r3[lo][jj] * p3c;
      d7 += r3[lo][jj] * p4c;
      d8 += r4[lo][jj] * p4c;
    }
  }
  red[0][hi][lo] = d5; red[1][hi][lo] = d6; red[2][hi][lo] = d7; red[3][hi][lo] = d8;
  __syncthreads();
  if (hi == 0) {
    int i = i0 + lo;
#pragma unroll
    for (int v = 0; v < 4; v++) {
      float s = red[v][0][lo] + red[v][1][lo] + red[v][2][lo] + red[v][3][lo];
      pbuf[((size_t)js * NODES + i) * 4 + v] = s;
    }
  }
}

__global__ void diag_reduce(const float* __restrict__ pbuf, float* __restrict__ rwse) {
  int i = blockIdx.x * 256 + threadIdx.x;
  if (i >= NODES) return;
#pragma unroll
  for (int v = 0; v < 4; v++) {
    float s = 0.f;
    for (int js = 0; js < 8; js++) s += pbuf[((size_t)js * NODES + i) * 4 + v];
    rwse[(size_t)i * 8 + 4 + v] = s;
  }
}

// ================= weight packing v2: unit-vectorized =================
struct PackArgs {
  const float* src[13];
  u64 offU[13];
  u64 cumU[14];
  int N[13];
  int srcStride[13];
  int gnTot[13];
  int ntOff[13];
};

__global__ __launch_bounds__(256) void pack_all(PackArgs pa, u16* __restrict__ Bh,
                                                u16* __restrict__ Bl) {
  u64 total = pa.cumU[13];
  for (u64 u = (u64)blockIdx.x * 256 + threadIdx.x; u < total;
       u += (u64)gridDim.x * 256) {
    int s = 0;
    while (u >= pa.cumU[s + 1]) s++;
    u64 ur = u - pa.cumU[s];
    int lr = (int)(ur & 15);
    int g = (int)((ur >> 4) & 3);
    int ks = (int)((ur >> 6) & 1);
    int j = (int)((ur >> 7) & 3);
    u64 rest = ur >> 9;
    int Nseg = pa.N[s] >> 6;
    int nt = (int)(rest % (u32)Nseg);
    int ktile = (int)(rest / (u32)Nseg);
    int k0 = (ktile << 6) | (ks << 5) | (g << 3);
    int n = (nt << 6) | (j << 4) | lr;
    const float* src = pa.src[s];
    int stride = pa.srcStride[s];
    u64 fiU = pa.offU[s] +
              ((((u64)ktile * pa.gnTot[s] + pa.ntOff[s] + nt) * 8 + j * 2 + ks) * 64 +
               g * 16 + lr);
    short8 h8, l8;
#pragma unroll
    for (int e = 0; e < 8; e++) {
      float v = src[(size_t)(k0 + e) * stride + n];
      u16 h = f2bf(v);
      h8[e] = (short)h;
      l8[e] = (short)f2bf(v - bf2f(h));
    }
    *((short8*)Bh + fiU) = h8;
    *((short8*)Bl + fiU) = l8;
  }
}

// ================= split-bf16 MFMA GEMM, fp32 A, split-K, row gather =======
__device__ __forceinline__ void splitA8(const float* __restrict__ p, short8& h8,
                                        short8& l8) {
  float4 v0 = *(const float4*)p;
  float4 v1 = *(const float4*)(p + 4);
  float v[8] = {v0.x, v0.y, v0.z, v0.w, v1.x, v1.y, v1.z, v1.w};
#pragma unroll
  for (int i = 0; i < 8; i++) {
    u16 h = f2bf(v[i]);
    h8[i] = (short)h;
    l8[i] = (short)f2bf(v[i] - bf2f(h));
  }
}

__global__ __launch_bounds__(256) void gemm_af(
    const float* __restrict__ A, const float* __restrict__ A2, int Ksplit,
    const u16* __restrict__ Bh, const u16* __restrict__ Bl,
    float* __restrict__ C, const float* __restrict__ bias,
    int M, int K, int N, int act, int Kslice, float* __restrict__ part,
    const int* __restrict__ rowmap) {
  __shared__ __align__(16) u16 LA[2][4096];
  __shared__ __align__(16) u16 LB[2][4096];
  int gn = N >> 6;
  int nwg = (M >> 6) * gn;
  int q = nwg >> 3;
  int flat = blockIdx.x;
  int virt = (flat & 7) * q + (flat >> 3);     // bijective XCD-contiguous remap
  int bm = (virt / gn) << 6, bn = (virt % gn) << 6;
  int kb = blockIdx.y;
  int kstart = kb * Kslice;
  int kend = min(K, kstart + Kslice);
  int t = threadIdx.x;
  int lane = t & 63, w = t >> 6;
  int wm = (w >> 1) << 5, wn = (w & 1) << 5;
  int r0 = t >> 3, r1 = r0 + 32;
  int c8 = (t & 7) << 3;
  int ks_s = (t >> 2) & 1, g_s = t & 3;
  int slotA = (((r0 & 15) + (g_s << 4)) ^ (g_s | (ks_s << 2)));
  int da0 = ((((r0 >> 4) << 1) + ks_s) << 9) + (slotA << 3);
  int da1 = ((((r1 >> 4) << 1) + ks_s) << 9) + (slotA << 3);
  int db0 = t * 8, db1 = (t + 256) * 8;
  int A2stride = K - Ksplit;
  size_t btile = ((size_t)(kstart >> 6) * gn + (bn >> 6)) * 4096;
  size_t bstep = (size_t)gn * 4096;

  int rrow0 = bm + r0, rrow1 = bm + r1;
  if (rowmap) { rrow0 = rowmap[rrow0]; rrow1 = rowmap[rrow1]; }

  short8 pah0, pal0, pah1, pal1, pbh0, pbl0, pbh1, pbl1;
  auto loadA = [&](int kt, int row, short8& h, short8& l) {
    int k = kt + c8;
    const float* p = (k < Ksplit) ? A + (size_t)row * Ksplit + k
                                  : A2 + (size_t)row * A2stride + (k - Ksplit);
    splitA8(p, h, l);
  };
  loadA(kstart, rrow0, pah0, pal0);
  loadA(kstart, rrow1, pah1, pal1);
  pbh0 = *(const short8*)(Bh + btile + db0);
  pbl0 = *(const short8*)(Bl + btile + db0);
  pbh1 = *(const short8*)(Bh + btile + db1);
  pbl1 = *(const short8*)(Bl + btile + db1);

  f32x4 acc[2][2] = {};
  int lr = lane & 15, lg = lane >> 4;
  int rboff = lane << 3;

  for (int kt = kstart; kt < kend; kt += 64) {
    __syncthreads();
    *(short8*)&LA[0][da0] = pah0;
    *(short8*)&LA[1][da0] = pal0;
    *(short8*)&LA[0][da1] = pah1;
    *(short8*)&LA[1][da1] = pal1;
    *(short8*)&LB[0][db0] = pbh0;
    *(short8*)&LB[1][db0] = pbl0;
    *(short8*)&LB[0][db1] = pbh1;
    *(short8*)&LB[1][db1] = pbl1;
    __syncthreads();
    if (kt + 64 < kend) {
      btile += bstep;
      loadA(kt + 64, rrow0, pah0, pal0);
      loadA(kt + 64, rrow1, pah1, pal1);
      pbh0 = *(const short8*)(Bh + btile + db0);
      pbl0 = *(const short8*)(Bl + btile + db0);
      pbh1 = *(const short8*)(Bh + btile + db1);
      pbl1 = *(const short8*)(Bl + btile + db1);
    }
#pragma unroll
    for (int ks = 0; ks < 2; ks++) {
      short8 ah[2], al[2], bh[2], bl[2];
      int slr = ((lr + (lg << 4)) ^ (lg | (ks << 2))) << 3;
#pragma unroll
      for (int i = 0; i < 2; i++) {
        int ba = ((((wm >> 4) + i) * 2 + ks) << 9) + slr;
        ah[i] = *(const short8*)&LA[0][ba];
        al[i] = *(const short8*)&LA[1][ba];
        int bb = ((((wn >> 4) + i) * 2 + ks) << 9) + rboff;
        bh[i] = *(const short8*)&LB[0][bb];
        bl[i] = *(const short8*)&LB[1][bb];
      }
#pragma unroll
      for (int i = 0; i < 2; i++)
#pragma unroll
        for (int j = 0; j < 2; j++) {
          acc[i][j] = __builtin_amdgcn_mfma_f32_16x16x32_bf16(ah[i], bh[j], acc[i][j], 0, 0, 0);
          acc[i][j] = __builtin_amdgcn_mfma_f32_16x16x32_bf16(ah[i], bl[j], acc[i][j], 0, 0, 0);
          acc[i][j] = __builtin_amdgcn_mfma_f32_16x16x32_bf16(al[i], bh[j], acc[i][j], 0, 0, 0);
        }
    }
  }
  int row0 = (lane >> 4) * 4;
  if (part) {
    size_t pbase = (size_t)kb * (size_t)M * N;
#pragma unroll
    for (int i = 0; i < 2; i++)
#pragma unroll
      for (int j = 0; j < 2; j++) {
        int n = bn + wn + j * 16 + lr;
#pragma unroll
        for (int r = 0; r < 4; r++) {
          int m = bm + wm + i * 16 + row0 + r;
          part[pbase + (size_t)m * N + n] = acc[i][j][r];
        }
      }
    return;
  }
#pragma unroll
  for (int i = 0; i < 2; i++)
#pragma unroll
    for (int j = 0; j < 2; j++) {
      int n = bn + wn + j * 16 + lr;
      float bv = bias ? bias[n] : 0.f;
#pragma unroll
      for (int r = 0; r < 4; r++) {
        int m = bm + wm + i * 16 + row0 + r;
        float v = acc[i][j][r] + bv;
        if (act) v = gelu_f(v);
        C[(size_t)m * N + n] = v;
      }
    }
}

// ================= small fused kernels =================
__global__ __launch_bounds__(128) void rwse_proj(const float* __restrict__ rwse,
                                                 const float* __restrict__ W,
                                                 const float* __restrict__ bb,
                                                 const float* __restrict__ g,
                                                 const float* __restrict__ bt,
                                                 float* __restrict__ r) {
  int i = blockIdx.x, j = threadIdx.x;
  float s = bb[j];
#pragma unroll
  for (int k = 0; k < 8; k++) s += rwse[(size_t)i * 8 + k] * W[k * H4C + j];
  __shared__ float sh[8];
  float sum = blk_sum(s, sh);
  float mu = sum * (1.f / 128.f);
  float d = s - mu;
  float var = blk_sum(d * d, sh) * (1.f / 128.f);
  r[(size_t)i * H4C + j] = gelu_f(d * rsqrtf(var + 1e-5f) * g[j] + bt[j]);
}

// ln512: reduce SK fp32 partials of an [sk][M][512] buffer (+bias)(+res)->LN
__global__ __launch_bounds__(256) void ln512(const float* __restrict__ x, int sk,
                                             int M,
                                             const float* __restrict__ gbias,
                                             const float* __restrict__ res,
                                             const float* __restrict__ mix,
                                             const float* __restrict__ ap, int l,
                                             const float* __restrict__ g,
                                             const float* __restrict__ b,
                                             float* __restrict__ y, int do_gelu) {
  const size_t MN = (size_t)M * 512;
  int i = blockIdx.x, t = threadIdx.x;
  size_t base = (size_t)i * 512;
  float v0 = x[base + t], v1 = x[base + 256 + t];
  for (int s = 1; s < sk; s++) {
    v0 += x[(size_t)s * MN + base + t];
    v1 += x[(size_t)s * MN + base + 256 + t];
  }
  if (gbias) { v0 += gbias[t]; v1 += gbias[t + 256]; }
  if (res) { v0 += res[base + t]; v1 += res[base + 256 + t]; }
  __shared__ float sh[8];
  float s = blk_sum(v0 + v1, sh);
  float mu = s * (1.f / 512.f);
  float d0 = v0 - mu, d1 = v1 - mu;
  float var = blk_sum(d0 * d0 + d1 * d1, sh) * (1.f / 512.f);
  float rstd = rsqrtf(var + 1e-5f);
  float o0 = d0 * rstd * g[t] + b[t];
  float o1 = d1 * rstd * g[t + 256] + b[t + 256];
  if (do_gelu) { o0 = gelu_f(o0); o1 = gelu_f(o1); }
  if (mix) {
    float a = 1.f / (1.f + expf(-ap[l]));
    o0 = a * mix[base + t] + (1.f - a) * o0;
    o1 = a * mix[base + 256 + t] + (1.f - a) * o1;
  }
  y[base + t] = o0;
  y[base + 256 + t] = o1;
}

__global__ void build_cbias(const float* __restrict__ bl, const float* __restrict__ br,
                            const float* __restrict__ inb, float* __restrict__ cb) {
  int i = blockIdx.x * 256 + threadIdx.x;
  if (i >= QS) return;
  cb[i] = i < 512 ? bl[i] : (i < 1024 ? br[i - 512] : inb[i - 1024]);
}

__global__ void fill_edges(const int* __restrict__ ei, int* __restrict__ cnt,
                           int* __restrict__ elist) {
  int e = blockIdx.x * 256 + threadIdx.x;
  if (e < EDGES + NODES) {
    int d = e < EDGES ? ei[EDGES + e] : e - EDGES;
    int p = atomicAdd(&cnt[d], 1);
    if (p < ECAP) elist[(size_t)d * ECAP + p] = e;
  }
}

// rowmap: [0..255] = cni's graph rows; [256+p] = src of elist[cni][p]; pad row 0
__global__ void build_rowmap(const int* __restrict__ cni, const int* __restrict__ cnt,
                             const int* __restrict__ elist, const int* __restrict__ ei,
                             int* __restrict__ rowmap) {
  int t = blockIdx.x * 256 + threadIdx.x;
  if (t >= NC) return;
  int i = cni[0];
  if (t < 256) {
    rowmap[t] = ((i >> 8) << 8) + t;
  } else {
    int p = t - 256;
    int m = min(cnt[i], ECAP);
    int v = 0;
    if (p < m) {
      int eid = elist[(size_t)i * ECAP + p];
      v = eid < EDGES ? ei[eid] : i;
    }
    rowmap[t] = v;
  }
}

__global__ void ea_reduce(const float* __restrict__ ea, float* __restrict__ sums) {
  int tid = blockIdx.x * blockDim.x + threadIdx.x;
  int stride = gridDim.x * blockDim.x;
  float s0 = 0.f, s1 = 0.f;
  for (int e = tid; e < EDGES; e += stride) { s0 += ea[2 * e]; s1 += ea[2 * e + 1]; }
  s0 = wave_sum(s0);
  s1 = wave_sum(s1);
  if ((threadIdx.x & 63) == 0) { atomicAdd(&sums[0], s0); atomicAdd(&sums[1], s1); }
}

// layer-0 GAT at rowmap'd dst nodes; xl/xr from merged buffer (full rows)
__global__ __launch_bounds__(512) void gat_kernel(
    const float* __restrict__ hb, const int* __restrict__ rowmap,
    const float* __restrict__ eattr, const float* __restrict__ easum,
    const float* __restrict__ We, const float* __restrict__ att,
    const float* __restrict__ bias, const int* __restrict__ cnt,
    const int* __restrict__ elist, const int* __restrict__ ei,
    float* __restrict__ out) {
  int i = rowmap[blockIdx.x];
  int tid = threadIdx.x;
  int h = tid >> 6, c = tid & 63;
  int m_cnt = cnt[i];
  if (m_cnt > ECAP) m_cnt = ECAP;
  const float inv_e = 1.f / (float)EDGES;
  float we0 = We[tid], we1 = We[512 + tid];
  float attv = att[tid];
  float xrv = hb[(size_t)i * QS + 512 + tid];
  float ea_m0 = easum[0] * inv_e, ea_m1 = easum[1] * inv_e;
  __shared__ float logits[NHEAD][ECAP];
  const int* el = elist + (size_t)i * ECAP;
  for (int e = 0; e < m_cnt; e++) {
    int eid = el[e];
    int s;
    float a0, a1;
    if (eid < EDGES) { s = ei[eid]; a0 = eattr[2 * eid]; a1 = eattr[2 * eid + 1]; }
    else { s = i; a0 = ea_m0; a1 = ea_m1; }
    float mval = hb[(size_t)s * QS + tid] + xrv + a0 * we0 + a1 * we1;
    mval = mval > 0.f ? mval : 0.2f * mval;
    float lg = wave_sum(mval * attv);
    if (c == 0) logits[h][e] = lg;
  }
  float mx = -1e30f;
  for (int e = c; e < m_cnt; e += 64) mx = fmaxf(mx, logits[h][e]);
  mx = wave_max(mx);
  float den = 0.f;
  for (int e = c; e < m_cnt; e += 64) den += expf(logits[h][e] - mx);
  den = wave_sum(den) + 1e-16f;
  float acc = 0.f;
  for (int e = 0; e < m_cnt; e++) {
    int eid = el[e];
    int s = eid < EDGES ? ei[eid] : i;
    float alpha = expf(logits[h][e] - mx) / den;
    acc += alpha * hb[(size_t)s * QS + tid];
  }
  out[(size_t)blockIdx.x * 512 + tid] = acc + bias[tid];
}

// ======= MFMA block-diag MHA (layer 0); qkv = merged buffer+1024, stride QS ==
__global__ __launch_bounds__(256) void mha_mfma(const float* __restrict__ qkv,
                                                float* __restrict__ o) {
  __shared__ __align__(16) u16 Ksh[2][256][72];
  __shared__ __align__(16) u16 Vt[2][64][264];
  int bid = blockIdx.x;
  int qq = bid & 3;
  int h = (bid >> 2) & 7;
  int b = bid >> 5;
  int t = threadIdx.x;
  int lane = t & 63, w = t >> 6;
  int lr = lane & 15, g = lane >> 4, kk = g * 8;
  size_t rowbase = (size_t)(b * SG) * QS;
  const float* Kbase = qkv + rowbase + 512 + h * 64;
  const float* Vbase = qkv + rowbase + 1024 + h * 64;
  for (int idx = t; idx < SG * 64; idx += 256) {
    int j = idx >> 6, c = idx & 63;
    float kv = Kbase[(size_t)j * QS + c];
    u16 khh = f2bf(kv);
    Ksh[0][j][c] = khh;
    Ksh[1][j][c] = f2bf(kv - bf2f(khh));
    float vv = Vbase[(size_t)j * QS + c];
    u16 vhh = f2bf(vv);
    Vt[0][c][j] = vhh;
    Vt[1][c][j] = f2bf(vv - bf2f(vhh));
  }
  const float* Qrow = qkv + rowbase + (size_t)(qq * 64 + w * 16 + lr) * QS + h * 64;
  short8 qh[2], ql[2];
#pragma unroll
  for (int kt = 0; kt < 2; kt++) {
    float qv[8];
    *(float4*)&qv[0] = *(const float4*)&Qrow[kt * 32 + kk];
    *(float4*)&qv[4] = *(const float4*)&Qrow[kt * 32 + kk + 4];
#pragma unroll
    for (int i = 0; i < 8; i++) {
      u16 hh = f2bf(qv[i]);
      qh[kt][i] = hh;
      ql[kt][i] = f2bf(qv[i] - bf2f(hh));
    }
  }
  __syncthreads();
  f32x4 S[16];
#pragma unroll
  for (int j = 0; j < 16; j++) {
    f32x4 acc = {};
#pragma unroll
    for (int kt = 0; kt < 2; kt++) {
      short8 bh = *(const short8*)&Ksh[0][j * 16 + lr][kt * 32 + kk];
      short8 bl = *(const short8*)&Ksh[1][j * 16 + lr][kt * 32 + kk];
      acc = __builtin_amdgcn_mfma_f32_16x16x32_bf16(qh[kt], bh, acc, 0, 0, 0);
      acc = __builtin_amdgcn_mfma_f32_16x16x32_bf16(qh[kt], bl, acc, 0, 0, 0);
      acc = __builtin_amdgcn_mfma_f32_16x16x32_bf16(ql[kt], bh, acc, 0, 0, 0);
    }
    S[j] = acc;
  }
  float mx[4], inv[4];
#pragma unroll
  for (int r = 0; r < 4; r++) {
    float m = S[0][r];
#pragma unroll
    for (int j = 1; j < 16; j++) m = fmaxf(m, S[j][r]);
#pragma unroll
    for (int oo = 1; oo < 16; oo <<= 1) m = fmaxf(m, __shfl_xor(m, oo));
    mx[r] = m;
    float d = 0.f;
#pragma unroll
    for (int j = 0; j < 16; j++) d += __expf((S[j][r] - m) * 0.125f);
#pragma unroll
    for (int oo = 1; oo < 16; oo <<= 1) d += __shfl_xor(d, oo);
    inv[r] = 1.f / d;
  }
  __syncthreads();
  u16* Pb = &Ksh[0][0][0];
  int row0 = w * 16 + g * 4;
#pragma unroll
  for (int j = 0; j < 16; j++) {
    int key = j * 16 + lr;
#pragma unroll
    for (int r = 0; r < 4; r++) {
      float p = __expf((S[j][r] - mx[r]) * 0.125f) * inv[r];
      u16 hh = f2bf(p);
      Pb[(row0 + r) * 264 + key] = hh;
      Pb[16896 + (row0 + r) * 264 + key] = f2bf(p - bf2f(hh));
    }
  }
  __syncthreads();
  f32x4 Oacc[4] = {};
#pragma unroll
  for (int kt = 0; kt < 8; kt++) {
    short8 pah = *(const short8*)&Pb[(w * 16 + lr) * 264 + kt * 32 + kk];
    short8 pal = *(const short8*)&Pb[16896 + (w * 16 + lr) * 264 + kt * 32 + kk];
#pragma unroll
    for (int nf = 0; nf < 4; nf++) {
      short8 vh = *(const short8*)&Vt[0][nf * 16 + lr][kt * 32 + kk];
      short8 vl = *(const short8*)&Vt[1][nf * 16 + lr][kt * 32 + kk];
      Oacc[nf] = __builtin_amdgcn_mfma_f32_16x16x32_bf16(pah, vh, Oacc[nf], 0, 0, 0);
      Oacc[nf] = __builtin_amdgcn_mfma_f32_16x16x32_bf16(pah, vl, Oacc[nf], 0, 0, 0);
      Oacc[nf] = __builtin_amdgcn_mfma_f32_16x16x32_bf16(pal, vh, Oacc[nf], 0, 0, 0);
    }
  }
  float* obase = o + (size_t)(b * SG + qq * 64 + w * 16 + g * 4) * 512 + h * 64;
#pragma unroll
  for (int nf = 0; nf < 4; nf++)
#pragma unroll
    for (int r = 0; r < 4; r++)
      obase[(size_t)r * 512 + nf * 16 + lr] = Oacc[nf][r];
}

// ================= layer-2 pruned path (row cni only) =================
__global__ __launch_bounds__(256) void gemv_part(
    const float* __restrict__ inrow, const int* __restrict__ cni, int rowMask,
    int rowStride, const float* __restrict__ W, int ldW, int N,
    float* __restrict__ part) {
  __shared__ float xv[64];
  __shared__ float red[4][64];
  int t = threadIdx.x;
  int kb = blockIdx.y;
  const float* xr = inrow + (cni ? (size_t)(cni[0] & rowMask) * rowStride : 0) + kb * 64;
  if (t < 64) xv[t] = xr[t];
  __syncthreads();
  int nl = t & 63;
  int n = blockIdx.x * 64 + nl;
  int seg = t >> 6;
  float acc = 0.f;
  const float* Wp = W + (size_t)(kb * 64 + seg * 16) * ldW + n;
#pragma unroll
  for (int k = 0; k < 16; k++) acc += xv[seg * 16 + k] * Wp[(size_t)k * ldW];
  red[seg][nl] = acc;
  __syncthreads();
  if (t < 64) {
    part[(size_t)kb * N + blockIdx.x * 64 + t] =
        red[0][t] + red[1][t] + red[2][t] + red[3][t];
  }
}

__global__ void row_reduce(const float* __restrict__ part, int KB, int N,
                           const float* __restrict__ bias,
                           float* __restrict__ out, int act) {
  int n = blockIdx.x * 256 + threadIdx.x;
  if (n >= N) return;
  float s = bias[n];
  for (int k = 0; k < KB; k++) s += part[(size_t)k * N + n];
  if (act) s = gelu_f(s);
  out[n] = s;
}

// GAT at node cni, xl from COMPACT buffer (edge p -> row 256+p), fused LN(n1)
__global__ __launch_bounds__(512) void gat_l2(
    const float* __restrict__ xlc, const float* __restrict__ xrrow,
    const int* __restrict__ cni,
    const float* __restrict__ eattr, const float* __restrict__ easum,
    const float* __restrict__ We, const float* __restrict__ att,
    const float* __restrict__ bias, const int* __restrict__ cnt,
    const int* __restrict__ elist,
    const float* __restrict__ n1g, const float* __restrict__ n1b,
    float* __restrict__ local_row) {
  int i = cni[0];
  int tid = threadIdx.x;
  int h = tid >> 6, c = tid & 63;
  int m_cnt = cnt[i];
  if (m_cnt > ECAP) m_cnt = ECAP;
  const float inv_e = 1.f / (float)EDGES;
  float we0 = We[tid], we1 = We[512 + tid];
  float attv = att[tid];
  float xrv = xrrow[tid];
  float ea_m0 = easum[0] * inv_e, ea_m1 = easum[1] * inv_e;
  __shared__ float logits[NHEAD][ECAP];
  __shared__ float sh[8];
  const int* el = elist + (size_t)i * ECAP;
  for (int e = 0; e < m_cnt; e++) {
    int eid = el[e];
    float a0, a1;
    if (eid < EDGES) { a0 = eattr[2 * eid]; a1 = eattr[2 * eid + 1]; }
    else { a0 = ea_m0; a1 = ea_m1; }
    float mval = xlc[(size_t)(256 + e) * 512 + tid] + xrv + a0 * we0 + a1 * we1;
    mval = mval > 0.f ? mval : 0.2f * mval;
    float lg = wave_sum(mval * attv);
    if (c == 0) logits[h][e] = lg;
  }
  float mx = -1e30f;
  for (int e = c; e < m_cnt; e += 64) mx = fmaxf(mx, logits[h][e]);
  mx = wave_max(mx);
  float den = 0.f;
  for (int e = c; e < m_cnt; e += 64) den += expf(logits[h][e] - mx);
  den = wave_sum(den) + 1e-16f;
  float acc = 0.f;
  for (int e = 0; e < m_cnt; e++) {
    float alpha = expf(logits[h][e] - mx) / den;
    acc += alpha * xlc[(size_t)(256 + e) * 512 + tid];
  }
  float v = acc + bias[tid];
  float mu = blk_sum(v, sh) * (1.f / 512.f);
  float d = v - mu;
  float var = blk_sum(d * d, sh) * (1.f / 512.f);
  local_row[tid] = d * rsqrtf(var + 1e-5f) * n1g[tid] + n1b[tid];
}

// fused MHA for row cni: one block per head, 256 thr (thread = key)
__global__ __launch_bounds__(256) void mha_row(const float* __restrict__ qrow,
                                               const float* __restrict__ kv,
                                               float* __restrict__ attO_row) {
  __shared__ float q[64];
  __shared__ float p[SG];
  __shared__ float sh[8];
  __shared__ float red[4][64];
  int h = blockIdx.x, t = threadIdx.x;
  if (t < 64) q[t] = qrow[h * 64 + t];
  __syncthreads();
  const float* kr = kv + (size_t)t * 1024 + h * 64;
  float s = 0.f;
#pragma unroll 8
  for (int c2 = 0; c2 < 64; c2++) s += q[c2] * kr[c2];
  s *= 0.125f;
  float m = blk_max(s, sh);
  float e = __expf(s - m);
  p[t] = e;
  float den = blk_sum(e, sh);
  int c = t & 63, seg = t >> 6;
  float o = 0.f;
  for (int j = seg * 64; j < seg * 64 + 64; j++)
    o += p[j] * kv[(size_t)j * 1024 + 512 + h * 64 + c];
  red[seg][c] = o;
  __syncthreads();
  if (t < 64)
    attO_row[h * 64 + t] = (red[0][t] + red[1][t] + red[2][t] + red[3][t]) / den;
}

__global__ __launch_bounds__(512) void comb_l2(const float* __restrict__ part, int KB,
                                               const float* __restrict__ bias,
                                               const float* __restrict__ local_row,
                                               const float* __restrict__ ap, int l,
                                               const float* __restrict__ g,
                                               const float* __restrict__ b,
                                               float* __restrict__ comb_row) {
  __shared__ float sh[8];
  int t = threadIdx.x;
  float v = bias[t];
  for (int k = 0; k < KB; k++) v += part[(size_t)k * 512 + t];
  float mu = blk_sum(v, sh) * (1.f / 512.f);
  float d = v - mu;
  float var = blk_sum(d * d, sh) * (1.f / 512.f);
  float o = d * rsqrtf(var + 1e-5f) * g[t] + b[t];
  float a = 1.f / (1.f + expf(-ap[l]));
  comb_row[t] = a * local_row[t] + (1.f - a) * o;
}

__global__ __launch_bounds__(512) void final_l2(const float* __restrict__ part, int KB,
                                                const float* __restrict__ bias,
                                                const float* __restrict__ comb_row,
                                                const float* __restrict__ g,
                                                const float* __restrict__ b,
                                                float* __restrict__ hrow) {
  __shared__ float sh[8];
  int t = threadIdx.x;
  float v = bias[t] + comb_row[t];
  for (int k = 0; k < KB; k++) v += part[(size_t)k * 512 + t];
  float mu = blk_sum(v, sh) * (1.f / 512.f);
  float d = v - mu;
  float var = blk_sum(d * d, sh) * (1.f / 512.f);
  hrow[t] = d * rsqrtf(var + 1e-5f) * g[t] + b[t];
}

__global__ __launch_bounds__(512) void head_kernel(
    const float* __restrict__ hrow,
    const float* __restrict__ W1, const float* __restrict__ b1,
    const float* __restrict__ g, const float* __restrict__ bt,
    const float* __restrict__ W2, const float* __restrict__ b2,
    float* __restrict__ out) {
  __shared__ float emb[512];
  __shared__ float z[512];
  __shared__ float sh[8];
  __shared__ float lg[ACT_N];
  int t = threadIdx.x;
  emb[t] = hrow[t];
  __syncthreads();
  float s = b1[t];
  for (int k = 0; k < 512; k++) s += emb[k] * W1[(size_t)k * 512 + t];
  float sum = blk_sum(s, sh);
  float mu = sum * (1.f / 512.f);
  float d = s - mu;
  float var = blk_sum(d * d, sh) * (1.f / 512.f);
  z[t] = gelu_f(d * rsqrtf(var + 1e-5f) * g[t] + bt[t]);
  __syncthreads();
  if (t < ACT_N) {
    float l = b2[t];
    for (int k = 0; k < 512; k++) l += z[k] * W2[k * ACT_N + t];
    lg[t] = l;
  }
  __syncthreads();
  if (t == 0) {
    float m2 = lg[0];
    for (int a = 1; a < ACT_N; a++) m2 = fmaxf(m2, lg[a]);
    float den = 0.f;
    float ex[ACT_N];
    for (int a = 0; a < ACT_N; a++) { ex[a] = expf(lg[a] - m2); den += ex[a]; }
    for (int a = 0; a < ACT_N; a++) {
      out[a] = lg[a];
      out[ACT_N + a] = ex[a] / den;
    }
  }
}

extern "C" void kernel_launch(void* const* d_in, const int* in_sizes, int n_in,
                              void* d_out, int out_size, void* d_ws, size_t ws_size,
                              hipStream_t stream) {
  const float* x        = (const float*)d_in[0];
  const float* eattr    = (const float*)d_in[1];
  const float* rwse_W   = (const float*)d_in[2];
  const float* rwse_b   = (const float*)d_in[3];
  const float* rwse_g   = (const float*)d_in[4];
  const float* rwse_bt  = (const float*)d_in[5];
  const float* np_W     = (const float*)d_in[6];
  const float* np_b     = (const float*)d_in[7];
  const float* np_g     = (const float*)d_in[8];
  const float* np_bt    = (const float*)d_in[9];
  const float* gat_Wl   = (const float*)d_in[10];
  const float* gat_bl   = (const float*)d_in[11];
  const float* gat_Wr   = (const float*)d_in[12];
  const float* gat_br   = (const float*)d_in[13];
  const float* gat_We   = (const float*)d_in[14];
  const float* gat_att  = (const float*)d_in[15];
  const float* gat_bias = (const float*)d_in[16];
  const float* n1_g = (const float*)d_in[17];
  const float* n1_b = (const float*)d_in[18];
  const float* mha_inW  = (const float*)d_in[19];
  const float* mha_inb  = (const float*)d_in[20];
  const float* mha_outW = (const float*)d_in[21];
  const float* mha_outb = (const float*)d_in[22];
  const float* alpha_p  = (const float*)d_in[23];
  const float* n2_g = (const float*)d_in[24];
  const float* n2_b = (const float*)d_in[25];
  const float* ffn_W1 = (const float*)d_in[26];
  const float* ffn_b1 = (const float*)d_in[27];
  const float* ffn_W2 = (const float*)d_in[28];
  const float* ffn_b2 = (const float*)d_in[29];
  const float* n3_g = (const float*)d_in[30];
  const float* n3_b = (const float*)d_in[31];
  const float* ah_W1 = (const float*)d_in[32];
  const float* ah_b1 = (const float*)d_in[33];
  const float* ah_g  = (const float*)d_in[34];
  const float* ah_bt = (const float*)d_in[35];
  const float* ah_W2 = (const float*)d_in[36];
  const float* ah_b2 = (const float*)d_in[37];
  const int* edge_index = (const int*)d_in[38];
  const int* cni        = (const int*)d_in[39];
  (void)in_sizes; (void)n_in; (void)out_size; (void)ws_size;

  char* wsp = (char*)d_ws;
  size_t off = 0;
  auto alloc = [&](size_t bytes) -> char* {
    char* p = wsp + off;
    off += (bytes + 255) & ~(size_t)255;
    return p;
  };
  const size_t NNb = (size_t)NODES * NODES * 4;
  char* arena = alloc(3 * NNb);
  float* P2 = (float*)arena;
  float* P3 = (float*)(arena + NNb);
  float* P4 = (float*)(arena + 2 * NNb);
  // post-RWSE: part (np SK8 32MB) -> hbig (21MB) -> small compact partials
  float* part  = (float*)arena;
  float* hbig  = (float*)arena;
  float* ffmid = (float*)(arena + 20971520);  // compact 512x2048 = 4MB
  const u64 SEG_NP = 2162688ull;
  const u64 SEG_L0 = 3670016ull;
  const u64 L1_OFF = SEG_NP + SEG_L0;
  const u64 KV1_OFF = L1_OFF + 262144ull;
  const u64 PTOT = KV1_OFF + 524288ull;
  u16* Bh = (u16*)alloc(PTOT * 2);
  u16* Bl = (u16*)alloc(PTOT * 2);
  float* rwse = (float*)alloc((size_t)NODES * 8 * 4);
  float* rbuf = (float*)alloc((size_t)NODES * H4C * 4);
  float* h1   = (float*)alloc((size_t)NODES * 512 * 4);   // full h after np
  float* h1c  = (float*)alloc((size_t)NC * 512 * 4);      // compact layer-0 out
  float* gout = (float*)alloc((size_t)NC * 512 * 4);      // compact gat/local; l1 xl
  float* attO = (float*)alloc((size_t)NODES * 512 * 4);   // l0 attn out (full); l1 kv
  float* comb = (float*)alloc((size_t)NC * 512 * 4);
  float* cb   = (float*)alloc((size_t)QS * 4);
  float* rows = (float*)alloc(4096 * 4);
  float* midrow = (float*)alloc(2048 * 4);
  float* pv1 = (float*)alloc((size_t)32 * 2048 * 4);
  float* pv2 = (float*)alloc((size_t)8 * 512 * 4);
  u32* bits  = (u32*)alloc((size_t)NODES * 64 * 4);
  int* scnt  = (int*)alloc((size_t)NODES * 4);
  int* slist = (int*)alloc((size_t)NODES * SCAP * 4);
  int* cnt   = (int*)alloc((size_t)NODES * 4);
  int* elist = (int*)alloc((size_t)NODES * ECAP * 4);
  int* rmap  = (int*)alloc((size_t)NC * 4);
  float* easum = (float*)alloc(8);
  float* pbuf  = (float*)alloc((size_t)8 * NODES * 4 * 4);
  float* qrow = rows, *xrrow = rows + 512, *local_row = rows + 1024;
  float* attO_row = rows + 1536, *comb_row = rows + 2560;
  float* hrow = rows + 3584;
  float* kvbuf = attO;   // l1: [256][1024]
  float* xlc = gout;     // l1: compact [NC][512]

  // ---- RWSE sparse path ----
  hipMemsetAsync(bits, 0, (size_t)NODES * 64 * 4, stream);
  hipMemsetAsync(scnt, 0, NODES * 4, stream);
  build_csr<<<EDGES / 256, 256, 0, stream>>>(edge_index, bits, scnt, slist);
  diag_T<<<NODES / 256, 256, 0, stream>>>(bits, scnt, rwse);
  spmm_sq<<<NODES, 256, 0, stream>>>(scnt, slist, P2);
  diag_copy<<<NODES / 256, 256, 0, stream>>>(P2, rwse, 1);
  spmm_gather<<<NODES, 256, 0, stream>>>(scnt, slist, P2, P3);
  diag_copy<<<NODES / 256, 256, 0, stream>>>(P3, rwse, 2);
  spmm_gather<<<NODES, 256, 0, stream>>>(scnt, slist, P3, P4);
  diag_copy<<<NODES / 256, 256, 0, stream>>>(P4, rwse, 3);
  diag_tiled<<<dim3(NODES / 64, 8), 256, 0, stream>>>(P2, P3, P4, pbuf);
  diag_reduce<<<NODES / 256, 256, 0, stream>>>(pbuf, rwse);
  rwse_proj<<<NODES, 128, 0, stream>>>(rwse, rwse_W, rwse_b, rwse_g, rwse_bt, rbuf);

  // ---- pack weights ----
  PackArgs pa;
  u64 uc = 0;
  int si = 0;
  auto seg = [&](const float* src, int K, int N, int stride, u64 offElems,
                 int gnTot, int ntOff) {
    pa.src[si] = src; pa.offU[si] = offElems / 8; pa.cumU[si] = uc;
    pa.N[si] = N; pa.srcStride[si] = stride; pa.gnTot[si] = gnTot;
    pa.ntOff[si] = ntOff;
    uc += (u64)K * N / 8; si++;
  };
  seg(np_W, 4224, 512, 512, 0, 8, 0);
  seg(gat_Wl, 512, 512, 512, SEG_NP, 40, 0);
  seg(gat_Wr, 512, 512, 512, SEG_NP, 40, 8);
  seg(mha_inW, 512, 1536, 1536, SEG_NP, 40, 16);
  seg(mha_outW, 512, 512, 512, SEG_NP + 1310720, 8, 0);
  seg(ffn_W1, 512, 2048, 2048, SEG_NP + 1572864, 32, 0);
  seg(ffn_W2, 2048, 512, 512, SEG_NP + 2621440, 8, 0);
  seg(gat_Wl + 512 * 512, 512, 512, 512, L1_OFF, 8, 0);
  seg(mha_inW + 512 * 1536 + 512, 512, 1024, 1536, KV1_OFF, 16, 0);
  for (int s2 = si; s2 <= 13; s2++) pa.cumU[s2] = uc;
  pack_all<<<2048, 256, 0, stream>>>(pa, Bh, Bl);
  build_cbias<<<(QS + 255) / 256, 256, 0, stream>>>(gat_bl, gat_br, mha_inb, cb);

  // ---- GAT CSR + edge-attr mean + rowmap ----
  hipMemsetAsync(cnt, 0, NODES * 4, stream);
  fill_edges<<<(EDGES + NODES) / 256, 256, 0, stream>>>(edge_index, cnt, elist);
  hipMemsetAsync(easum, 0, 8, stream);
  ea_reduce<<<64, 256, 0, stream>>>(eattr, easum);
  build_rowmap<<<2, 256, 0, stream>>>(cni, cnt, elist, edge_index, rmap);

  // ---- np projection: split-K8 partials -> fused reduce+bias+LN+gelu ----
  gemm_af<<<dim3(256, 8), 256, 0, stream>>>(x, rbuf, 4096, Bh, Bl, nullptr, nullptr,
                                            NODES, 4224, 512, 0, 576, part, nullptr);
  ln512<<<NODES, 256, 0, stream>>>(part, 8, NODES, np_b, nullptr, nullptr, nullptr,
                                   0, np_g, np_bt, h1, 1);

  // ================= layer 0 (outputs pruned to NC compact rows) ===========
  {
    const u64 lb = SEG_NP;
    // merged [xl|xr|QKV] for ALL rows (xl/K/V feed every node's GAT/MHA)
    gemm_af<<<dim3(1280), 256, 0, stream>>>(h1, h1, 512, Bh + lb, Bl + lb, hbig,
                                            cb, NODES, 512, QS, 0, 512, nullptr,
                                            nullptr);
    gat_kernel<<<NC, 512, 0, stream>>>(hbig, rmap, eattr, easum, gat_We, gat_att,
                                       gat_bias, cnt, elist, edge_index, gout);
    ln512<<<NC, 256, 0, stream>>>(gout, 1, NC, nullptr, nullptr, nullptr, nullptr,
                                  0, n1_g, n1_b, gout, 0);
    mha_mfma<<<BG * NHEAD * 4, 256, 0, stream>>>(hbig + 1024, attO);
    // out-proj at compact rows (rowmap A-gather), split-K2
    gemm_af<<<dim3(64, 2), 256, 0, stream>>>(attO, attO, 512, Bh + lb + 1310720,
                                             Bl + lb + 1310720, nullptr, nullptr,
                                             NC, 512, 512, 0, 256, part, rmap);
    ln512<<<NC, 256, 0, stream>>>(part, 2, NC, mha_outb, nullptr, gout, alpha_p, 0,
                                  n2_g, n2_b, comb, 0);
    // FFN at compact rows
    gemm_af<<<dim3(256), 256, 0, stream>>>(comb, comb, 512, Bh + lb + 1572864,
                                           Bl + lb + 1572864, ffmid, ffn_b1,
                                           NC, 512, 2048, 1, 512, nullptr, nullptr);
    gemm_af<<<dim3(64, 4), 256, 0, stream>>>(ffmid, ffmid, 2048, Bh + lb + 2621440,
                                             Bl + lb + 2621440, nullptr, nullptr,
                                             NC, 2048, 512, 0, 512, part, nullptr);
    ln512<<<NC, 256, 0, stream>>>(part, 4, NC, ffn_b2, comb, nullptr, nullptr, 0,
                                  n3_g, n3_b, h1c, 0);
  }

  // ================= layer 1 (row cni; inputs from compact h1c) ============
  {
    // xl for compact rows (only slots 256+p are consumed by gat_l2)
    gemm_af<<<dim3(64), 256, 0, stream>>>(h1c, h1c, 512, Bh + L1_OFF, Bl + L1_OFF,
                                          xlc, gat_bl + 512, NC, 512, 512, 0,
                                          512, nullptr, nullptr);
    // K/V for cni's graph = compact rows 0..255
    gemm_af<<<dim3(64), 256, 0, stream>>>(h1c, h1c, 512, Bh + KV1_OFF, Bl + KV1_OFF,
                                          kvbuf, mha_inb + 1536 + 512, 256, 512,
                                          1024, 0, 512, nullptr, nullptr);
    // q and xr rows from h1c[cni & 255]
    gemv_part<<<dim3(8, 8), 256, 0, stream>>>(h1c, cni, 255, 512,
                                              mha_inW + 512 * 1536, 1536, 512, pv1);
    gemv_part<<<dim3(8, 8), 256, 0, stream>>>(h1c, cni, 255, 512,
                                              gat_Wr + 512 * 512, 512, 512, pv2);
    row_reduce<<<2, 256, 0, stream>>>(pv1, 8, 512, mha_inb + 1536, qrow, 0);
    row_reduce<<<2, 256, 0, stream>>>(pv2, 8, 512, gat_br + 512, xrrow, 0);
    gat_l2<<<1, 512, 0, stream>>>(xlc, xrrow, cni, eattr, easum, gat_We + 1024,
                                  gat_att + 512, gat_bias + 512, cnt, elist,
                                  n1_g + 512, n1_b + 512, local_row);
    mha_row<<<8, 256, 0, stream>>>(qrow, kvbuf, attO_row);
    gemv_part<<<dim3(8, 8), 256, 0, stream>>>(attO_row, nullptr, 0, 0,
                                              mha_outW + 512 * 512, 512, 512, pv1);
    comb_l2<<<1, 512, 0, stream>>>(pv1, 8, mha_outb + 512, local_row, alpha_p, 1,
                                   n2_g + 512, n2_b + 512, comb_row);
    gemv_part<<<dim3(32, 8), 256, 0, stream>>>(comb_row, nullptr, 0, 0,
                                               ffn_W1 + (size_t)512 * 2048, 2048,
                                               2048, pv1);
    row_reduce<<<8, 256, 0, stream>>>(pv1, 8, 2048, ffn_b1 + 2048, midrow, 1);
    gemv_part<<<dim3(8, 32), 256, 0, stream>>>(midrow, nullptr, 0, 0,
                                               ffn_W2 + (size_t)2048 * 512, 512,
                                               512, pv1);
    final_l2<<<1, 512, 0, stream>>>(pv1, 32, ffn_b2 + 512, comb_row, n3_g + 512,
                                    n3_b + 512, hrow);
  }

  head_kernel<<<1, 512, 0, stream>>>(hrow, ah_W1, ah_b1, ah_g, ah_bt, ah_W2,
                                     ah_b2, (float*)d_out);
}

// Round 10
// 450.320 us; speedup vs baseline: 1.6421x; 1.0343x over previous
//
#include <hip/hip_runtime.h>
#include <math.h>

constexpr int NODES = 2048;
constexpr int BG = 8;
constexpr int SG = 256;
constexpr int DIN = 4096;
constexpr int NHEAD = 8;
constexpr int EDGES = 32768;
constexpr int ACT_N = 5;
constexpr int H4C = 128;
constexpr int ECAP = 192;   // per-dst edge list capacity (GAT)
constexpr int SCAP = 96;    // per-src dedup'd neighbor capacity (RWSE)
constexpr int QS = 2560;    // merged hidden stride: [xl 512 | xr 512 | qkv 1536]
constexpr int NC = 512;     // compact row count (256 graph + 192 nbrs + pad)

typedef unsigned short u16;
typedef unsigned int u32;
typedef unsigned long long u64;
typedef short short8 __attribute__((ext_vector_type(8)));
typedef float f32x4 __attribute__((ext_vector_type(4)));

__device__ __forceinline__ float wave_sum(float v) {
#pragma unroll
  for (int o = 32; o; o >>= 1) v += __shfl_xor(v, o);
  return v;
}
__device__ __forceinline__ float wave_max(float v) {
#pragma unroll
  for (int o = 32; o; o >>= 1) v = fmaxf(v, __shfl_xor(v, o));
  return v;
}
__device__ __forceinline__ float blk_sum(float v, float* sh) {
  v = wave_sum(v);
  int nw = blockDim.x >> 6;
  __syncthreads();
  if ((threadIdx.x & 63) == 0) sh[threadIdx.x >> 6] = v;
  __syncthreads();
  float s = 0.f;
  for (int k = 0; k < nw; k++) s += sh[k];
  return s;
}
__device__ __forceinline__ float blk_max(float v, float* sh) {
  v = wave_max(v);
  int nw = blockDim.x >> 6;
  __syncthreads();
  if ((threadIdx.x & 63) == 0) sh[threadIdx.x >> 6] = v;
  __syncthreads();
  float m = sh[0];
  for (int k = 1; k < nw; k++) m = fmaxf(m, sh[k]);
  return m;
}
__device__ __forceinline__ float gelu_f(float x) {
  return 0.5f * x * (1.f + erff(x * 0.70710678118654752f));
}
__device__ __forceinline__ u16 f2bf(float x) {  // round-to-nearest-even bf16
  u32 u = __float_as_uint(x);
  return (u16)((u + 0x7FFFu + ((u >> 16) & 1u)) >> 16);
}
__device__ __forceinline__ float bf2f(u16 h) { return __uint_as_float(((u32)h) << 16); }
__device__ __forceinline__ void split2(float v, u16* ph, u16* pl) {
  u16 h = f2bf(v);
  *ph = h;
  *pl = f2bf(v - bf2f(h));
}

// ================= RWSE (sparse path) =================
__global__ void build_csr(const int* __restrict__ ei, u32* __restrict__ bits,
                          int* __restrict__ scnt, int* __restrict__ slist) {
  int e = blockIdx.x * 256 + threadIdx.x;
  if (e < EDGES) {
    int s = ei[e], d = ei[EDGES + e];
    u32 m = 1u << (d & 31);
    u32 old = atomicOr(&bits[s * 64 + (d >> 5)], m);
    if (!(old & m)) {
      int p = atomicAdd(&scnt[s], 1);
      if (p < SCAP) slist[s * SCAP + p] = d;
    }
  }
}

__global__ void diag_T(const u32* __restrict__ bits, const int* __restrict__ scnt,
                       float* __restrict__ rwse) {
  int i = blockIdx.x * 256 + threadIdx.x;
  if (i < NODES) {
    int deg = min(scnt[i], SCAP);
    int self = (bits[i * 64 + (i >> 5)] >> (i & 31)) & 1;
    rwse[(size_t)i * 8 + 0] = (self && deg > 0) ? 1.f / (float)deg : 0.f;
  }
}

__global__ __launch_bounds__(256) void spmm_sq(const int* __restrict__ scnt,
                                               const int* __restrict__ slist,
                                               float* __restrict__ P2) {
  int i = blockIdx.x, t = threadIdx.x;
  __shared__ float row[NODES];
  for (int c = t; c < NODES; c += 256) row[c] = 0.f;
  __syncthreads();
  int di = min(scnt[i], SCAP);
  float wi = di > 0 ? 1.f / (float)di : 0.f;
  for (int jj = 0; jj < di; jj++) {
    int j = slist[i * SCAP + jj];
    int dj = min(scnt[j], SCAP);
    if (dj == 0) continue;
    float w = wi / (float)dj;
    for (int kk = t; kk < dj; kk += 256) atomicAdd(&row[slist[j * SCAP + kk]], w);
  }
  __syncthreads();
  for (int c = t; c < NODES; c += 256) P2[(size_t)i * NODES + c] = row[c];
}

__global__ __launch_bounds__(256) void spmm_gather(const int* __restrict__ scnt,
                                                   const int* __restrict__ slist,
                                                   const float* __restrict__ P,
                                                   float* __restrict__ Q) {
  int i = blockIdx.x, t = threadIdx.x;
  __shared__ int nb[SCAP];
  int di = min(scnt[i], SCAP);
  for (int c = t; c < di; c += 256) nb[c] = slist[i * SCAP + c];
  __syncthreads();
  float wi = di > 0 ? 1.f / (float)di : 0.f;
  for (int c = t; c < NODES; c += 256) {
    float s = 0.f;
    for (int jj = 0; jj < di; jj++) s += P[(size_t)nb[jj] * NODES + c];
    Q[(size_t)i * NODES + c] = s * wi;
  }
}

__global__ void diag_copy(const float* __restrict__ P, float* __restrict__ rwse, int col) {
  int i = blockIdx.x * 256 + threadIdx.x;
  if (i < NODES) rwse[(size_t)i * 8 + col] = P[(size_t)i * (NODES + 1)];
}

// fused diag dots, tiled+coalesced
__global__ __launch_bounds__(256) void diag_tiled(const float* __restrict__ P2,
                                                  const float* __restrict__ P3,
                                                  const float* __restrict__ P4,
                                                  float* __restrict__ pbuf) {
  __shared__ float r2[64][65], r3[64][65], r4[64][65], c3[64][65], c4[64][65];
  __shared__ float red[4][4][64];
  int t = threadIdx.x;
  int i0 = blockIdx.x * 64;
  int js = blockIdx.y;
  int lo = t & 63, hi = t >> 6;
  float d5 = 0, d6 = 0, d7 = 0, d8 = 0;
  for (int jc = 0; jc < 4; jc++) {
    int j0 = js * 256 + jc * 64;
    __syncthreads();
#pragma unroll
    for (int r = 0; r < 16; r++) {
      int a = hi * 16 + r;
      r2[a][lo] = P2[(size_t)(i0 + a) * NODES + j0 + lo];
      r3[a][lo] = P3[(size_t)(i0 + a) * NODES + j0 + lo];
      r4[a][lo] = P4[(size_t)(i0 + a) * NODES + j0 + lo];
      c3[a][lo] = P3[(size_t)(j0 + a) * NODES + i0 + lo];
      c4[a][lo] = P4[(size_t)(j0 + a) * NODES + i0 + lo];
    }
    __syncthreads();
#pragma unroll
    for (int r = 0; r < 16; r++) {
      int jj = hi * 16 + r;
      float p3c = c3[jj][lo], p4c = c4[jj][lo];
      d5 += r2[lo][jj] * p3c;
      d6 += r3[lo][jj] * p3c;
      d7 += r3[lo][jj] * p4c;
      d8 += r4[lo][jj] * p4c;
    }
  }
  red[0][hi][lo] = d5; red[1][hi][lo] = d6; red[2][hi][lo] = d7; red[3][hi][lo] = d8;
  __syncthreads();
  if (hi == 0) {
    int i = i0 + lo;
#pragma unroll
    for (int v = 0; v < 4; v++) {
      float s = red[v][0][lo] + red[v][1][lo] + red[v][2][lo] + red[v][3][lo];
      pbuf[((size_t)js * NODES + i) * 4 + v] = s;
    }
  }
}

__global__ void diag_reduce(const float* __restrict__ pbuf, float* __restrict__ rwse) {
  int i = blockIdx.x * 256 + threadIdx.x;
  if (i >= NODES) return;
#pragma unroll
  for (int v = 0; v < 4; v++) {
    float s = 0.f;
    for (int js = 0; js < 8; js++) s += pbuf[((size_t)js * NODES + i) * 4 + v];
    rwse[(size_t)i * 8 + 4 + v] = s;
  }
}

// ================= fp32 -> split-bf16 helpers =================
__device__ __forceinline__ void splitA8(const float* __restrict__ p, short8& h8,
                                        short8& l8) {
  float4 v0 = *(const float4*)p;
  float4 v1 = *(const float4*)(p + 4);
  float v[8] = {v0.x, v0.y, v0.z, v0.w, v1.x, v1.y, v1.z, v1.w};
#pragma unroll
  for (int i = 0; i < 8; i++) {
    u16 h = f2bf(v[i]);
    h8[i] = (short)h;
    l8[i] = (short)f2bf(v[i] - bf2f(h));
  }
}

// split src [M][Ksrc] fp32 -> Ah/Al u16 [M][dstStride] @ colOff (8 elems/thread)
__global__ void conv_split(const float* __restrict__ src, u16* __restrict__ Ah,
                           u16* __restrict__ Al, int total8, int Ksrc,
                           int dstStride, int colOff) {
  int u = blockIdx.x * 256 + threadIdx.x;
  if (u >= total8) return;
  int idx = u * 8;
  int m = idx / Ksrc, k = idx - m * Ksrc;
  short8 h8, l8;
  splitA8(src + idx, h8, l8);
  size_t o = (size_t)m * dstStride + colOff + k;
  *(short8*)(Ah + o) = h8;
  *(short8*)(Al + o) = l8;
}

// ================= weight packing: unit-vectorized =================
struct PackArgs {
  const float* src[13];
  u64 offU[13];
  u64 cumU[14];
  int N[13];
  int srcStride[13];
  int gnTot[13];
  int ntOff[13];
};

__global__ __launch_bounds__(256) void pack_all(PackArgs pa, u16* __restrict__ Bh,
                                                u16* __restrict__ Bl) {
  u64 total = pa.cumU[13];
  for (u64 u = (u64)blockIdx.x * 256 + threadIdx.x; u < total;
       u += (u64)gridDim.x * 256) {
    int s = 0;
    while (u >= pa.cumU[s + 1]) s++;
    u64 ur = u - pa.cumU[s];
    int lr = (int)(ur & 15);
    int g = (int)((ur >> 4) & 3);
    int ks = (int)((ur >> 6) & 1);
    int j = (int)((ur >> 7) & 3);
    u64 rest = ur >> 9;
    int Nseg = pa.N[s] >> 6;
    int nt = (int)(rest % (u32)Nseg);
    int ktile = (int)(rest / (u32)Nseg);
    int k0 = (ktile << 6) | (ks << 5) | (g << 3);
    int n = (nt << 6) | (j << 4) | lr;
    const float* src = pa.src[s];
    int stride = pa.srcStride[s];
    u64 fiU = pa.offU[s] +
              ((((u64)ktile * pa.gnTot[s] + pa.ntOff[s] + nt) * 8 + j * 2 + ks) * 64 +
               g * 16 + lr);
    short8 h8, l8;
#pragma unroll
    for (int e = 0; e < 8; e++) {
      float v = src[(size_t)(k0 + e) * stride + n];
      u16 h = f2bf(v);
      h8[e] = (short)h;
      l8[e] = (short)f2bf(v - bf2f(h));
    }
    *((short8*)Bh + fiU) = h8;
    *((short8*)Bl + fiU) = l8;
  }
}

// ========== split-bf16 MFMA GEMM, pre-split u16 A, split-K, row gather =====
__global__ __launch_bounds__(256) void gemm_s(
    const u16* __restrict__ Ahg, const u16* __restrict__ Alg, int lda,
    const u16* __restrict__ Bh, const u16* __restrict__ Bl,
    float* __restrict__ C, u16* __restrict__ Ch, u16* __restrict__ Cl,
    const float* __restrict__ bias,
    int M, int K, int N, int act, int Kslice, float* __restrict__ part,
    const int* __restrict__ rowmap) {
  __shared__ __align__(16) u16 LA[2][4096];
  __shared__ __align__(16) u16 LB[2][4096];
  int gn = N >> 6;
  int nwg = (M >> 6) * gn;
  int q = nwg >> 3;
  int flat = blockIdx.x;
  int virt = (flat & 7) * q + (flat >> 3);     // bijective XCD-contiguous remap
  int bm = (virt / gn) << 6, bn = (virt % gn) << 6;
  int kb = blockIdx.y;
  int kstart = kb * Kslice;
  int kend = min(K, kstart + Kslice);
  int t = threadIdx.x;
  int lane = t & 63, w = t >> 6;
  int wm = (w >> 1) << 5, wn = (w & 1) << 5;
  int r0 = t >> 3, r1 = r0 + 32;
  int c8 = (t & 7) << 3;
  int ks_s = (t >> 2) & 1, g_s = t & 3;
  int slotA = (((r0 & 15) + (g_s << 4)) ^ (g_s | (ks_s << 2)));
  int da0 = ((((r0 >> 4) << 1) + ks_s) << 9) + (slotA << 3);
  int da1 = ((((r1 >> 4) << 1) + ks_s) << 9) + (slotA << 3);
  int db0 = t * 8, db1 = (t + 256) * 8;
  size_t btile = ((size_t)(kstart >> 6) * gn + (bn >> 6)) * 4096;
  size_t bstep = (size_t)gn * 4096;

  int rrow0 = bm + r0, rrow1 = bm + r1;
  if (rowmap) { rrow0 = rowmap[rrow0]; rrow1 = rowmap[rrow1]; }
  size_t aoff0 = (size_t)rrow0 * lda + c8;
  size_t aoff1 = (size_t)rrow1 * lda + c8;

  short8 pah0, pal0, pah1, pal1, pbh0, pbl0, pbh1, pbl1;
  pah0 = *(const short8*)(Ahg + aoff0 + kstart);
  pal0 = *(const short8*)(Alg + aoff0 + kstart);
  pah1 = *(const short8*)(Ahg + aoff1 + kstart);
  pal1 = *(const short8*)(Alg + aoff1 + kstart);
  pbh0 = *(const short8*)(Bh + btile + db0);
  pbl0 = *(const short8*)(Bl + btile + db0);
  pbh1 = *(const short8*)(Bh + btile + db1);
  pbl1 = *(const short8*)(Bl + btile + db1);

  f32x4 acc[2][2] = {};
  int lr = lane & 15, lg = lane >> 4;
  int rboff = lane << 3;

  for (int kt = kstart; kt < kend; kt += 64) {
    __syncthreads();
    *(short8*)&LA[0][da0] = pah0;
    *(short8*)&LA[1][da0] = pal0;
    *(short8*)&LA[0][da1] = pah1;
    *(short8*)&LA[1][da1] = pal1;
    *(short8*)&LB[0][db0] = pbh0;
    *(short8*)&LB[1][db0] = pbl0;
    *(short8*)&LB[0][db1] = pbh1;
    *(short8*)&LB[1][db1] = pbl1;
    __syncthreads();
    if (kt + 64 < kend) {
      btile += bstep;
      int kn = kt + 64;
      pah0 = *(const short8*)(Ahg + aoff0 + kn);
      pal0 = *(const short8*)(Alg + aoff0 + kn);
      pah1 = *(const short8*)(Ahg + aoff1 + kn);
      pal1 = *(const short8*)(Alg + aoff1 + kn);
      pbh0 = *(const short8*)(Bh + btile + db0);
      pbl0 = *(const short8*)(Bl + btile + db0);
      pbh1 = *(const short8*)(Bh + btile + db1);
      pbl1 = *(const short8*)(Bl + btile + db1);
    }
#pragma unroll
    for (int ks = 0; ks < 2; ks++) {
      short8 ah[2], al[2], bh[2], bl[2];
      int slr = ((lr + (lg << 4)) ^ (lg | (ks << 2))) << 3;
#pragma unroll
      for (int i = 0; i < 2; i++) {
        int ba = ((((wm >> 4) + i) * 2 + ks) << 9) + slr;
        ah[i] = *(const short8*)&LA[0][ba];
        al[i] = *(const short8*)&LA[1][ba];
        int bb = ((((wn >> 4) + i) * 2 + ks) << 9) + rboff;
        bh[i] = *(const short8*)&LB[0][bb];
        bl[i] = *(const short8*)&LB[1][bb];
      }
#pragma unroll
      for (int i = 0; i < 2; i++)
#pragma unroll
        for (int j = 0; j < 2; j++) {
          acc[i][j] = __builtin_amdgcn_mfma_f32_16x16x32_bf16(ah[i], bh[j], acc[i][j], 0, 0, 0);
          acc[i][j] = __builtin_amdgcn_mfma_f32_16x16x32_bf16(ah[i], bl[j], acc[i][j], 0, 0, 0);
          acc[i][j] = __builtin_amdgcn_mfma_f32_16x16x32_bf16(al[i], bh[j], acc[i][j], 0, 0, 0);
        }
    }
  }
  int row0 = (lane >> 4) * 4;
  if (part) {
    size_t pbase = (size_t)kb * (size_t)M * N;
#pragma unroll
    for (int i = 0; i < 2; i++)
#pragma unroll
      for (int j = 0; j < 2; j++) {
        int n = bn + wn + j * 16 + lr;
#pragma unroll
        for (int r = 0; r < 4; r++) {
          int m = bm + wm + i * 16 + row0 + r;
          part[pbase + (size_t)m * N + n] = acc[i][j][r];
        }
      }
    return;
  }
#pragma unroll
  for (int i = 0; i < 2; i++)
#pragma unroll
    for (int j = 0; j < 2; j++) {
      int n = bn + wn + j * 16 + lr;
      float bv = bias ? bias[n] : 0.f;
#pragma unroll
      for (int r = 0; r < 4; r++) {
        int m = bm + wm + i * 16 + row0 + r;
        float v = acc[i][j][r] + bv;
        if (act) v = gelu_f(v);
        size_t o = (size_t)m * N + n;
        if (Ch) {
          split2(v, Ch + o, Cl + o);
          if (C) C[o] = v;
        } else {
          C[o] = v;
        }
      }
    }
}

// ================= small fused kernels =================
// rwse projection -> split u16 directly into A-panel cols [4096..4224)
__global__ __launch_bounds__(128) void rwse_proj(const float* __restrict__ rwse,
                                                 const float* __restrict__ W,
                                                 const float* __restrict__ bb,
                                                 const float* __restrict__ g,
                                                 const float* __restrict__ bt,
                                                 u16* __restrict__ Axh,
                                                 u16* __restrict__ Axl) {
  int i = blockIdx.x, j = threadIdx.x;
  float s = bb[j];
#pragma unroll
  for (int k = 0; k < 8; k++) s += rwse[(size_t)i * 8 + k] * W[k * H4C + j];
  __shared__ float sh[8];
  float sum = blk_sum(s, sh);
  float mu = sum * (1.f / 128.f);
  float d = s - mu;
  float var = blk_sum(d * d, sh) * (1.f / 128.f);
  float val = gelu_f(d * rsqrtf(var + 1e-5f) * g[j] + bt[j]);
  size_t o = (size_t)i * 4224 + 4096 + j;
  split2(val, Axh + o, Axl + o);
}

// ln512: reduce SK fp32 partials of [sk][M][512] (+bias)(+res)->LN->(gelu)
// ->(mix) ; outputs: fp32 y (opt) and/or split u16 yh/yl (opt)
__global__ __launch_bounds__(256) void ln512(const float* __restrict__ x, int sk,
                                             int M,
                                             const float* __restrict__ gbias,
                                             const float* __restrict__ res,
                                             const float* __restrict__ mix,
                                             const float* __restrict__ ap, int l,
                                             const float* __restrict__ g,
                                             const float* __restrict__ b,
                                             float* __restrict__ y,
                                             u16* __restrict__ yh,
                                             u16* __restrict__ yl, int do_gelu) {
  const size_t MN = (size_t)M * 512;
  int i = blockIdx.x, t = threadIdx.x;
  size_t base = (size_t)i * 512;
  float v0 = x[base + t], v1 = x[base + 256 + t];
  for (int s = 1; s < sk; s++) {
    v0 += x[(size_t)s * MN + base + t];
    v1 += x[(size_t)s * MN + base + 256 + t];
  }
  if (gbias) { v0 += gbias[t]; v1 += gbias[t + 256]; }
  if (res) { v0 += res[base + t]; v1 += res[base + 256 + t]; }
  __shared__ float sh[8];
  float s = blk_sum(v0 + v1, sh);
  float mu = s * (1.f / 512.f);
  float d0 = v0 - mu, d1 = v1 - mu;
  float var = blk_sum(d0 * d0 + d1 * d1, sh) * (1.f / 512.f);
  float rstd = rsqrtf(var + 1e-5f);
  float o0 = d0 * rstd * g[t] + b[t];
  float o1 = d1 * rstd * g[t + 256] + b[t + 256];
  if (do_gelu) { o0 = gelu_f(o0); o1 = gelu_f(o1); }
  if (mix) {
    float a = 1.f / (1.f + expf(-ap[l]));
    o0 = a * mix[base + t] + (1.f - a) * o0;
    o1 = a * mix[base + 256 + t] + (1.f - a) * o1;
  }
  if (y) { y[base + t] = o0; y[base + 256 + t] = o1; }
  if (yh) {
    split2(o0, yh + base + t, yl + base + t);
    split2(o1, yh + base + 256 + t, yl + base + 256 + t);
  }
}

__global__ void build_cbias(const float* __restrict__ bl, const float* __restrict__ br,
                            const float* __restrict__ inb, float* __restrict__ cb) {
  int i = blockIdx.x * 256 + threadIdx.x;
  if (i >= QS) return;
  cb[i] = i < 512 ? bl[i] : (i < 1024 ? br[i - 512] : inb[i - 1024]);
}

__global__ void fill_edges(const int* __restrict__ ei, int* __restrict__ cnt,
                           int* __restrict__ elist) {
  int e = blockIdx.x * 256 + threadIdx.x;
  if (e < EDGES + NODES) {
    int d = e < EDGES ? ei[EDGES + e] : e - EDGES;
    int p = atomicAdd(&cnt[d], 1);
    if (p < ECAP) elist[(size_t)d * ECAP + p] = e;
  }
}

// rowmap: [0..255] = cni's graph rows; [256+p] = src of elist[cni][p]; pad row 0
__global__ void build_rowmap(const int* __restrict__ cni, const int* __restrict__ cnt,
                             const int* __restrict__ elist, const int* __restrict__ ei,
                             int* __restrict__ rowmap) {
  int t = blockIdx.x * 256 + threadIdx.x;
  if (t >= NC) return;
  int i = cni[0];
  if (t < 256) {
    rowmap[t] = ((i >> 8) << 8) + t;
  } else {
    int p = t - 256;
    int m = min(cnt[i], ECAP);
    int v = 0;
    if (p < m) {
      int eid = elist[(size_t)i * ECAP + p];
      v = eid < EDGES ? ei[eid] : i;
    }
    rowmap[t] = v;
  }
}

__global__ void ea_reduce(const float* __restrict__ ea, float* __restrict__ sums) {
  int tid = blockIdx.x * blockDim.x + threadIdx.x;
  int stride = gridDim.x * blockDim.x;
  float s0 = 0.f, s1 = 0.f;
  for (int e = tid; e < EDGES; e += stride) { s0 += ea[2 * e]; s1 += ea[2 * e + 1]; }
  s0 = wave_sum(s0);
  s1 = wave_sum(s1);
  if ((threadIdx.x & 63) == 0) { atomicAdd(&sums[0], s0); atomicAdd(&sums[1], s1); }
}

// layer-0 GAT at rowmap'd dst nodes; xl/xr from merged buffer (full rows)
__global__ __launch_bounds__(512) void gat_kernel(
    const float* __restrict__ hb, const int* __restrict__ rowmap,
    const float* __restrict__ eattr, const float* __restrict__ easum,
    const float* __restrict__ We, const float* __restrict__ att,
    const float* __restrict__ bias, const int* __restrict__ cnt,
    const int* __restrict__ elist, const int* __restrict__ ei,
    float* __restrict__ out) {
  int i = rowmap[blockIdx.x];
  int tid = threadIdx.x;
  int h = tid >> 6, c = tid & 63;
  int m_cnt = cnt[i];
  if (m_cnt > ECAP) m_cnt = ECAP;
  const float inv_e = 1.f / (float)EDGES;
  float we0 = We[tid], we1 = We[512 + tid];
  float attv = att[tid];
  float xrv = hb[(size_t)i * QS + 512 + tid];
  float ea_m0 = easum[0] * inv_e, ea_m1 = easum[1] * inv_e;
  __shared__ float logits[NHEAD][ECAP];
  const int* el = elist + (size_t)i * ECAP;
  for (int e = 0; e < m_cnt; e++) {
    int eid = el[e];
    int s;
    float a0, a1;
    if (eid < EDGES) { s = ei[eid]; a0 = eattr[2 * eid]; a1 = eattr[2 * eid + 1]; }
    else { s = i; a0 = ea_m0; a1 = ea_m1; }
    float mval = hb[(size_t)s * QS + tid] + xrv + a0 * we0 + a1 * we1;
    mval = mval > 0.f ? mval : 0.2f * mval;
    float lg = wave_sum(mval * attv);
    if (c == 0) logits[h][e] = lg;
  }
  float mx = -1e30f;
  for (int e = c; e < m_cnt; e += 64) mx = fmaxf(mx, logits[h][e]);
  mx = wave_max(mx);
  float den = 0.f;
  for (int e = c; e < m_cnt; e += 64) den += expf(logits[h][e] - mx);
  den = wave_sum(den) + 1e-16f;
  float acc = 0.f;
  for (int e = 0; e < m_cnt; e++) {
    int eid = el[e];
    int s = eid < EDGES ? ei[eid] : i;
    float alpha = expf(logits[h][e] - mx) / den;
    acc += alpha * hb[(size_t)s * QS + tid];
  }
  out[(size_t)blockIdx.x * 512 + tid] = acc + bias[tid];
}

// ======= MFMA block-diag MHA (layer 0); outputs split u16 =======
__global__ __launch_bounds__(256) void mha_mfma(const float* __restrict__ qkv,
                                                u16* __restrict__ attOh,
                                                u16* __restrict__ attOl) {
  __shared__ __align__(16) u16 Ksh[2][256][72];
  __shared__ __align__(16) u16 Vt[2][64][264];
  int bid = blockIdx.x;
  int qq = bid & 3;
  int h = (bid >> 2) & 7;
  int b = bid >> 5;
  int t = threadIdx.x;
  int lane = t & 63, w = t >> 6;
  int lr = lane & 15, g = lane >> 4, kk = g * 8;
  size_t rowbase = (size_t)(b * SG) * QS;
  const float* Kbase = qkv + rowbase + 512 + h * 64;
  const float* Vbase = qkv + rowbase + 1024 + h * 64;
  for (int idx = t; idx < SG * 64; idx += 256) {
    int j = idx >> 6, c = idx & 63;
    float kv = Kbase[(size_t)j * QS + c];
    u16 khh = f2bf(kv);
    Ksh[0][j][c] = khh;
    Ksh[1][j][c] = f2bf(kv - bf2f(khh));
    float vv = Vbase[(size_t)j * QS + c];
    u16 vhh = f2bf(vv);
    Vt[0][c][j] = vhh;
    Vt[1][c][j] = f2bf(vv - bf2f(vhh));
  }
  const float* Qrow = qkv + rowbase + (size_t)(qq * 64 + w * 16 + lr) * QS + h * 64;
  short8 qh[2], ql[2];
#pragma unroll
  for (int kt = 0; kt < 2; kt++) {
    float qv[8];
    *(float4*)&qv[0] = *(const float4*)&Qrow[kt * 32 + kk];
    *(float4*)&qv[4] = *(const float4*)&Qrow[kt * 32 + kk + 4];
#pragma unroll
    for (int i = 0; i < 8; i++) {
      u16 hh = f2bf(qv[i]);
      qh[kt][i] = hh;
      ql[kt][i] = f2bf(qv[i] - bf2f(hh));
    }
  }
  __syncthreads();
  f32x4 S[16];
#pragma unroll
  for (int j = 0; j < 16; j++) {
    f32x4 acc = {};
#pragma unroll
    for (int kt = 0; kt < 2; kt++) {
      short8 bh = *(const short8*)&Ksh[0][j * 16 + lr][kt * 32 + kk];
      short8 bl = *(const short8*)&Ksh[1][j * 16 + lr][kt * 32 + kk];
      acc = __builtin_amdgcn_mfma_f32_16x16x32_bf16(qh[kt], bh, acc, 0, 0, 0);
      acc = __builtin_amdgcn_mfma_f32_16x16x32_bf16(qh[kt], bl, acc, 0, 0, 0);
      acc = __builtin_amdgcn_mfma_f32_16x16x32_bf16(ql[kt], bh, acc, 0, 0, 0);
    }
    S[j] = acc;
  }
  float mx[4], inv[4];
#pragma unroll
  for (int r = 0; r < 4; r++) {
    float m = S[0][r];
#pragma unroll
    for (int j = 1; j < 16; j++) m = fmaxf(m, S[j][r]);
#pragma unroll
    for (int oo = 1; oo < 16; oo <<= 1) m = fmaxf(m, __shfl_xor(m, oo));
    mx[r] = m;
    float d = 0.f;
#pragma unroll
    for (int j = 0; j < 16; j++) d += __expf((S[j][r] - m) * 0.125f);
#pragma unroll
    for (int oo = 1; oo < 16; oo <<= 1) d += __shfl_xor(d, oo);
    inv[r] = 1.f / d;
  }
  __syncthreads();
  u16* Pb = &Ksh[0][0][0];
  int row0 = w * 16 + g * 4;
#pragma unroll
  for (int j = 0; j < 16; j++) {
    int key = j * 16 + lr;
#pragma unroll
    for (int r = 0; r < 4; r++) {
      float p = __expf((S[j][r] - mx[r]) * 0.125f) * inv[r];
      u16 hh = f2bf(p);
      Pb[(row0 + r) * 264 + key] = hh;
      Pb[16896 + (row0 + r) * 264 + key] = f2bf(p - bf2f(hh));
    }
  }
  __syncthreads();
  f32x4 Oacc[4] = {};
#pragma unroll
  for (int kt = 0; kt < 8; kt++) {
    short8 pah = *(const short8*)&Pb[(w * 16 + lr) * 264 + kt * 32 + kk];
    short8 pal = *(const short8*)&Pb[16896 + (w * 16 + lr) * 264 + kt * 32 + kk];
#pragma unroll
    for (int nf = 0; nf < 4; nf++) {
      short8 vh = *(const short8*)&Vt[0][nf * 16 + lr][kt * 32 + kk];
      short8 vl = *(const short8*)&Vt[1][nf * 16 + lr][kt * 32 + kk];
      Oacc[nf] = __builtin_amdgcn_mfma_f32_16x16x32_bf16(pah, vh, Oacc[nf], 0, 0, 0);
      Oacc[nf] = __builtin_amdgcn_mfma_f32_16x16x32_bf16(pah, vl, Oacc[nf], 0, 0, 0);
      Oacc[nf] = __builtin_amdgcn_mfma_f32_16x16x32_bf16(pal, vh, Oacc[nf], 0, 0, 0);
    }
  }
  size_t obase = (size_t)(b * SG + qq * 64 + w * 16 + g * 4) * 512 + h * 64;
#pragma unroll
  for (int nf = 0; nf < 4; nf++)
#pragma unroll
    for (int r = 0; r < 4; r++) {
      size_t o = obase + (size_t)r * 512 + nf * 16 + lr;
      split2(Oacc[nf][r], attOh + o, attOl + o);
    }
}

// ================= layer-2 pruned path (row cni only) =================
__global__ __launch_bounds__(256) void gemv_part(
    const float* __restrict__ inrow, const int* __restrict__ cni, int rowMask,
    int rowStride, const float* __restrict__ W, int ldW, int N,
    float* __restrict__ part) {
  __shared__ float xv[64];
  __shared__ float red[4][64];
  int t = threadIdx.x;
  int kb = blockIdx.y;
  const float* xr = inrow + (cni ? (size_t)(cni[0] & rowMask) * rowStride : 0) + kb * 64;
  if (t < 64) xv[t] = xr[t];
  __syncthreads();
  int nl = t & 63;
  int n = blockIdx.x * 64 + nl;
  int seg = t >> 6;
  float acc = 0.f;
  const float* Wp = W + (size_t)(kb * 64 + seg * 16) * ldW + n;
#pragma unroll
  for (int k = 0; k < 16; k++) acc += xv[seg * 16 + k] * Wp[(size_t)k * ldW];
  red[seg][nl] = acc;
  __syncthreads();
  if (t < 64) {
    part[(size_t)kb * N + blockIdx.x * 64 + t] =
        red[0][t] + red[1][t] + red[2][t] + red[3][t];
  }
}

__global__ void row_reduce(const float* __restrict__ part, int KB, int N,
                           const float* __restrict__ bias,
                           float* __restrict__ out, int act) {
  int n = blockIdx.x * 256 + threadIdx.x;
  if (n >= N) return;
  float s = bias[n];
  for (int k = 0; k < KB; k++) s += part[(size_t)k * N + n];
  if (act) s = gelu_f(s);
  out[n] = s;
}

// GAT at node cni, xl from COMPACT buffer (edge p -> row 256+p), fused LN(n1)
__global__ __launch_bounds__(512) void gat_l2(
    const float* __restrict__ xlc, const float* __restrict__ xrrow,
    const int* __restrict__ cni,
    const float* __restrict__ eattr, const float* __restrict__ easum,
    const float* __restrict__ We, const float* __restrict__ att,
    const float* __restrict__ bias, const int* __restrict__ cnt,
    const int* __restrict__ elist,
    const float* __restrict__ n1g, const float* __restrict__ n1b,
    float* __restrict__ local_row) {
  int i = cni[0];
  int tid = threadIdx.x;
  int h = tid >> 6, c = tid & 63;
  int m_cnt = cnt[i];
  if (m_cnt > ECAP) m_cnt = ECAP;
  const float inv_e = 1.f / (float)EDGES;
  float we0 = We[tid], we1 = We[512 + tid];
  float attv = att[tid];
  float xrv = xrrow[tid];
  float ea_m0 = easum[0] * inv_e, ea_m1 = easum[1] * inv_e;
  __shared__ float logits[NHEAD][ECAP];
  __shared__ float sh[8];
  const int* el = elist + (size_t)i * ECAP;
  for (int e = 0; e < m_cnt; e++) {
    int eid = el[e];
    float a0, a1;
    if (eid < EDGES) { a0 = eattr[2 * eid]; a1 = eattr[2 * eid + 1]; }
    else { a0 = ea_m0; a1 = ea_m1; }
    float mval = xlc[(size_t)(256 + e) * 512 + tid] + xrv + a0 * we0 + a1 * we1;
    mval = mval > 0.f ? mval : 0.2f * mval;
    float lg = wave_sum(mval * attv);
    if (c == 0) logits[h][e] = lg;
  }
  float mx = -1e30f;
  for (int e = c; e < m_cnt; e += 64) mx = fmaxf(mx, logits[h][e]);
  mx = wave_max(mx);
  float den = 0.f;
  for (int e = c; e < m_cnt; e += 64) den += expf(logits[h][e] - mx);
  den = wave_sum(den) + 1e-16f;
  float acc = 0.f;
  for (int e = 0; e < m_cnt; e++) {
    float alpha = expf(logits[h][e] - mx) / den;
    acc += alpha * xlc[(size_t)(256 + e) * 512 + tid];
  }
  float v = acc + bias[tid];
  float mu = blk_sum(v, sh) * (1.f / 512.f);
  float d = v - mu;
  float var = blk_sum(d * d, sh) * (1.f / 512.f);
  local_row[tid] = d * rsqrtf(var + 1e-5f) * n1g[tid] + n1b[tid];
}

// fused MHA for row cni: one block per head, 256 thr (thread = key)
__global__ __launch_bounds__(256) void mha_row(const float* __restrict__ qrow,
                                               const float* __restrict__ kv,
                                               float* __restrict__ attO_row) {
  __shared__ float q[64];
  __shared__ float p[SG];
  __shared__ float sh[8];
  __shared__ float red[4][64];
  int h = blockIdx.x, t = threadIdx.x;
  if (t < 64) q[t] = qrow[h * 64 + t];
  __syncthreads();
  const float* kr = kv + (size_t)t * 1024 + h * 64;
  float s = 0.f;
#pragma unroll 8
  for (int c2 = 0; c2 < 64; c2++) s += q[c2] * kr[c2];
  s *= 0.125f;
  float m = blk_max(s, sh);
  float e = __expf(s - m);
  p[t] = e;
  float den = blk_sum(e, sh);
  int c = t & 63, seg = t >> 6;
  float o = 0.f;
  for (int j = seg * 64; j < seg * 64 + 64; j++)
    o += p[j] * kv[(size_t)j * 1024 + 512 + h * 64 + c];
  red[seg][c] = o;
  __syncthreads();
  if (t < 64)
    attO_row[h * 64 + t] = (red[0][t] + red[1][t] + red[2][t] + red[3][t]) / den;
}

__global__ __launch_bounds__(512) void comb_l2(const float* __restrict__ part, int KB,
                                               const float* __restrict__ bias,
                                               const float* __restrict__ local_row,
                                               const float* __restrict__ ap, int l,
                                               const float* __restrict__ g,
                                               const float* __restrict__ b,
                                               float* __restrict__ comb_row) {
  __shared__ float sh[8];
  int t = threadIdx.x;
  float v = bias[t];
  for (int k = 0; k < KB; k++) v += part[(size_t)k * 512 + t];
  float mu = blk_sum(v, sh) * (1.f / 512.f);
  float d = v - mu;
  float var = blk_sum(d * d, sh) * (1.f / 512.f);
  float o = d * rsqrtf(var + 1e-5f) * g[t] + b[t];
  float a = 1.f / (1.f + expf(-ap[l]));
  comb_row[t] = a * local_row[t] + (1.f - a) * o;
}

__global__ __launch_bounds__(512) void final_l2(const float* __restrict__ part, int KB,
                                                const float* __restrict__ bias,
                                                const float* __restrict__ comb_row,
                                                const float* __restrict__ g,
                                                const float* __restrict__ b,
                                                float* __restrict__ hrow) {
  __shared__ float sh[8];
  int t = threadIdx.x;
  float v = bias[t] + comb_row[t];
  for (int k = 0; k < KB; k++) v += part[(size_t)k * 512 + t];
  float mu = blk_sum(v, sh) * (1.f / 512.f);
  float d = v - mu;
  float var = blk_sum(d * d, sh) * (1.f / 512.f);
  hrow[t] = d * rsqrtf(var + 1e-5f) * g[t] + b[t];
}

__global__ __launch_bounds__(512) void head_kernel(
    const float* __restrict__ hrow,
    const float* __restrict__ W1, const float* __restrict__ b1,
    const float* __restrict__ g, const float* __restrict__ bt,
    const float* __restrict__ W2, const float* __restrict__ b2,
    float* __restrict__ out) {
  __shared__ float emb[512];
  __shared__ float z[512];
  __shared__ float sh[8];
  __shared__ float lg[ACT_N];
  int t = threadIdx.x;
  emb[t] = hrow[t];
  __syncthreads();
  float s = b1[t];
  for (int k = 0; k < 512; k++) s += emb[k] * W1[(size_t)k * 512 + t];
  float sum = blk_sum(s, sh);
  float mu = sum * (1.f / 512.f);
  float d = s - mu;
  float var = blk_sum(d * d, sh) * (1.f / 512.f);
  z[t] = gelu_f(d * rsqrtf(var + 1e-5f) * g[t] + bt[t]);
  __syncthreads();
  if (t < ACT_N) {
    float l = b2[t];
    for (int k = 0; k < 512; k++) l += z[k] * W2[k * ACT_N + t];
    lg[t] = l;
  }
  __syncthreads();
  if (t == 0) {
    float m2 = lg[0];
    for (int a = 1; a < ACT_N; a++) m2 = fmaxf(m2, lg[a]);
    float den = 0.f;
    float ex[ACT_N];
    for (int a = 0; a < ACT_N; a++) { ex[a] = expf(lg[a] - m2); den += ex[a]; }
    for (int a = 0; a < ACT_N; a++) {
      out[a] = lg[a];
      out[ACT_N + a] = ex[a] / den;
    }
  }
}

extern "C" void kernel_launch(void* const* d_in, const int* in_sizes, int n_in,
                              void* d_out, int out_size, void* d_ws, size_t ws_size,
                              hipStream_t stream) {
  const float* x        = (const float*)d_in[0];
  const float* eattr    = (const float*)d_in[1];
  const float* rwse_W   = (const float*)d_in[2];
  const float* rwse_b   = (const float*)d_in[3];
  const float* rwse_g   = (const float*)d_in[4];
  const float* rwse_bt  = (const float*)d_in[5];
  const float* np_W     = (const float*)d_in[6];
  const float* np_b     = (const float*)d_in[7];
  const float* np_g     = (const float*)d_in[8];
  const float* np_bt    = (const float*)d_in[9];
  const float* gat_Wl   = (const float*)d_in[10];
  const float* gat_bl   = (const float*)d_in[11];
  const float* gat_Wr   = (const float*)d_in[12];
  const float* gat_br   = (const float*)d_in[13];
  const float* gat_We   = (const float*)d_in[14];
  const float* gat_att  = (const float*)d_in[15];
  const float* gat_bias = (const float*)d_in[16];
  const float* n1_g = (const float*)d_in[17];
  const float* n1_b = (const float*)d_in[18];
  const float* mha_inW  = (const float*)d_in[19];
  const float* mha_inb  = (const float*)d_in[20];
  const float* mha_outW = (const float*)d_in[21];
  const float* mha_outb = (const float*)d_in[22];
  const float* alpha_p  = (const float*)d_in[23];
  const float* n2_g = (const float*)d_in[24];
  const float* n2_b = (const float*)d_in[25];
  const float* ffn_W1 = (const float*)d_in[26];
  const float* ffn_b1 = (const float*)d_in[27];
  const float* ffn_W2 = (const float*)d_in[28];
  const float* ffn_b2 = (const float*)d_in[29];
  const float* n3_g = (const float*)d_in[30];
  const float* n3_b = (const float*)d_in[31];
  const float* ah_W1 = (const float*)d_in[32];
  const float* ah_b1 = (const float*)d_in[33];
  const float* ah_g  = (const float*)d_in[34];
  const float* ah_bt = (const float*)d_in[35];
  const float* ah_W2 = (const float*)d_in[36];
  const float* ah_b2 = (const float*)d_in[37];
  const int* edge_index = (const int*)d_in[38];
  const int* cni        = (const int*)d_in[39];
  (void)in_sizes; (void)n_in; (void)out_size; (void)ws_size;

  char* wsp = (char*)d_ws;
  size_t off = 0;
  auto alloc = [&](size_t bytes) -> char* {
    char* p = wsp + off;
    off += (bytes + 255) & ~(size_t)255;
    return p;
  };
  const size_t NNb = (size_t)NODES * NODES * 4;
  char* arena = alloc(3 * NNb);
  // phase A (RWSE): P2 | P3 | P4
  float* P2 = (float*)arena;
  float* P3 = (float*)(arena + NNb);
  float* P4 = (float*)(arena + 2 * NNb);
  // phase B (np): Axh@0 (17.3MB), Axl@17.3MB, partNP@34.6MB (SK3, 12.6MB)
  u16* Axh = (u16*)arena;
  u16* Axl = (u16*)(arena + 17301504);
  float* partNP = (float*)(arena + 34603008);
  // phase C (layer0): hbig@0 (21MB), partC@21MB-offset (4MB)
  float* hbig = (float*)arena;
  float* partC = (float*)(arena + 22020096);
  const u64 SEG_NP = 2162688ull;
  const u64 SEG_L0 = 3670016ull;
  const u64 L1_OFF = SEG_NP + SEG_L0;
  const u64 KV1_OFF = L1_OFF + 262144ull;
  const u64 PTOT = KV1_OFF + 524288ull;
  u16* Bh = (u16*)alloc(PTOT * 2);
  u16* Bl = (u16*)alloc(PTOT * 2);
  float* rwse = (float*)alloc((size_t)NODES * 8 * 4);
  u16* h1h = (u16*)alloc((size_t)NODES * 512 * 2);
  u16* h1l = (u16*)alloc((size_t)NODES * 512 * 2);
  u16* attOh = (u16*)alloc((size_t)NODES * 512 * 2);
  u16* attOl = (u16*)alloc((size_t)NODES * 512 * 2);
  u16* combh = (u16*)alloc((size_t)NC * 512 * 2);
  u16* combl = (u16*)alloc((size_t)NC * 512 * 2);
  u16* ffmh = (u16*)alloc((size_t)NC * 2048 * 2);
  u16* ffml = (u16*)alloc((size_t)NC * 2048 * 2);
  u16* h1ch = (u16*)alloc((size_t)NC * 512 * 2);
  u16* h1cl = (u16*)alloc((size_t)NC * 512 * 2);
  float* h1c  = (float*)alloc((size_t)NC * 512 * 4);
  float* gout = (float*)alloc((size_t)NC * 512 * 4);     // l0 gat/local; l1 xl
  float* comb = (float*)alloc((size_t)NC * 512 * 4);
  float* kvbuf = (float*)alloc((size_t)256 * 1024 * 4);
  float* cb   = (float*)alloc((size_t)QS * 4);
  float* rows = (float*)alloc(4096 * 4);
  float* midrow = (float*)alloc(2048 * 4);
  float* pv1 = (float*)alloc((size_t)32 * 2048 * 4);
  float* pv2 = (float*)alloc((size_t)8 * 512 * 4);
  u32* bits  = (u32*)alloc((size_t)NODES * 64 * 4);
  int* scnt  = (int*)alloc((size_t)NODES * 4);
  int* slist = (int*)alloc((size_t)NODES * SCAP * 4);
  int* cnt   = (int*)alloc((size_t)NODES * 4);
  int* elist = (int*)alloc((size_t)NODES * ECAP * 4);
  int* rmap  = (int*)alloc((size_t)NC * 4);
  float* easum = (float*)alloc(8);
  float* pbuf  = (float*)alloc((size_t)8 * NODES * 4 * 4);
  float* qrow = rows, *xrrow = rows + 512, *local_row = rows + 1024;
  float* attO_row = rows + 1536, *comb_row = rows + 2560;
  float* hrow = rows + 3584;
  float* xlc = gout;     // l1: compact [NC][512]

  // ---- RWSE sparse path ----
  hipMemsetAsync(bits, 0, (size_t)NODES * 64 * 4, stream);
  hipMemsetAsync(scnt, 0, NODES * 4, stream);
  build_csr<<<EDGES / 256, 256, 0, stream>>>(edge_index, bits, scnt, slist);
  diag_T<<<NODES / 256, 256, 0, stream>>>(bits, scnt, rwse);
  spmm_sq<<<NODES, 256, 0, stream>>>(scnt, slist, P2);
  diag_copy<<<NODES / 256, 256, 0, stream>>>(P2, rwse, 1);
  spmm_gather<<<NODES, 256, 0, stream>>>(scnt, slist, P2, P3);
  diag_copy<<<NODES / 256, 256, 0, stream>>>(P3, rwse, 2);
  spmm_gather<<<NODES, 256, 0, stream>>>(scnt, slist, P3, P4);
  diag_copy<<<NODES / 256, 256, 0, stream>>>(P4, rwse, 3);
  diag_tiled<<<dim3(NODES / 64, 8), 256, 0, stream>>>(P2, P3, P4, pbuf);
  diag_reduce<<<NODES / 256, 256, 0, stream>>>(pbuf, rwse);
  // arena now free: build split A-panel [x | rwse_proj] in u16
  conv_split<<<NODES * DIN / 8 / 256, 256, 0, stream>>>(x, Axh, Axl,
                                                        NODES * DIN / 8, DIN, 4224, 0);
  rwse_proj<<<NODES, 128, 0, stream>>>(rwse, rwse_W, rwse_b, rwse_g, rwse_bt,
                                       Axh, Axl);

  // ---- pack weights ----
  PackArgs pa;
  u64 uc = 0;
  int si = 0;
  auto seg = [&](const float* src, int K, int N, int stride, u64 offElems,
                 int gnTot, int ntOff) {
    pa.src[si] = src; pa.offU[si] = offElems / 8; pa.cumU[si] = uc;
    pa.N[si] = N; pa.srcStride[si] = stride; pa.gnTot[si] = gnTot;
    pa.ntOff[si] = ntOff;
    uc += (u64)K * N / 8; si++;
  };
  seg(np_W, 4224, 512, 512, 0, 8, 0);
  seg(gat_Wl, 512, 512, 512, SEG_NP, 40, 0);
  seg(gat_Wr, 512, 512, 512, SEG_NP, 40, 8);
  seg(mha_inW, 512, 1536, 1536, SEG_NP, 40, 16);
  seg(mha_outW, 512, 512, 512, SEG_NP + 1310720, 8, 0);
  seg(ffn_W1, 512, 2048, 2048, SEG_NP + 1572864, 32, 0);
  seg(ffn_W2, 2048, 512, 512, SEG_NP + 2621440, 8, 0);
  seg(gat_Wl + 512 * 512, 512, 512, 512, L1_OFF, 8, 0);
  seg(mha_inW + 512 * 1536 + 512, 512, 1024, 1536, KV1_OFF, 16, 0);
  for (int s2 = si; s2 <= 13; s2++) pa.cumU[s2] = uc;
  pack_all<<<2048, 256, 0, stream>>>(pa, Bh, Bl);
  build_cbias<<<(QS + 255) / 256, 256, 0, stream>>>(gat_bl, gat_br, mha_inb, cb);

  // ---- GAT CSR + edge-attr mean + rowmap ----
  hipMemsetAsync(cnt, 0, NODES * 4, stream);
  fill_edges<<<(EDGES + NODES) / 256, 256, 0, stream>>>(edge_index, cnt, elist);
  hipMemsetAsync(easum, 0, 8, stream);
  ea_reduce<<<64, 256, 0, stream>>>(eattr, easum);
  build_rowmap<<<2, 256, 0, stream>>>(cni, cnt, elist, edge_index, rmap);

  // ---- np projection: split-K3 partials -> reduce+bias+LN+gelu -> split h1 --
  gemm_s<<<dim3(256, 3), 256, 0, stream>>>(Axh, Axl, 4224, Bh, Bl,
                                           nullptr, nullptr, nullptr, nullptr,
                                           NODES, 4224, 512, 0, 1408, partNP,
                                           nullptr);
  ln512<<<NODES, 256, 0, stream>>>(partNP, 3, NODES, np_b, nullptr, nullptr,
                                   nullptr, 0, np_g, np_bt, nullptr, h1h, h1l, 1);

  // ================= layer 0 (outputs pruned to NC compact rows) ===========
  {
    const u64 lb = SEG_NP;
    // merged [xl|xr|QKV] for ALL rows
    gemm_s<<<dim3(1280), 256, 0, stream>>>(h1h, h1l, 512, Bh + lb, Bl + lb,
                                           hbig, nullptr, nullptr, cb,
                                           NODES, 512, QS, 0, 512, nullptr,
                                           nullptr);
    gat_kernel<<<NC, 512, 0, stream>>>(hbig, rmap, eattr, easum, gat_We, gat_att,
                                       gat_bias, cnt, elist, edge_index, gout);
    ln512<<<NC, 256, 0, stream>>>(gout, 1, NC, nullptr, nullptr, nullptr, nullptr,
                                  0, n1_g, n1_b, gout, nullptr, nullptr, 0);
    mha_mfma<<<BG * NHEAD * 4, 256, 0, stream>>>(hbig + 1024, attOh, attOl);
    // out-proj at compact rows (rowmap A-gather), split-K2
    gemm_s<<<dim3(64, 2), 256, 0, stream>>>(attOh, attOl, 512, Bh + lb + 1310720,
                                            Bl + lb + 1310720, nullptr, nullptr,
                                            nullptr, nullptr, NC, 512, 512, 0, 256,
                                            partC, rmap);
    ln512<<<NC, 256, 0, stream>>>(partC, 2, NC, mha_outb, nullptr, gout, alpha_p,
                                  0, n2_g, n2_b, comb, combh, combl, 0);
    // FFN at compact rows; W1 emits split directly
    gemm_s<<<dim3(256), 256, 0, stream>>>(combh, combl, 512, Bh + lb + 1572864,
                                          Bl + lb + 1572864, nullptr, ffmh, ffml,
                                          ffn_b1, NC, 512, 2048, 1, 512, nullptr,
                                          nullptr);
    gemm_s<<<dim3(64, 4), 256, 0, stream>>>(ffmh, ffml, 2048, Bh + lb + 2621440,
                                            Bl + lb + 2621440, nullptr, nullptr,
                                            nullptr, nullptr, NC, 2048, 512, 0,
                                            512, partC, nullptr);
    ln512<<<NC, 256, 0, stream>>>(partC, 4, NC, ffn_b2, comb, nullptr, nullptr, 0,
                                  n3_g, n3_b, h1c, h1ch, h1cl, 0);
  }

  // ================= layer 1 (row cni; inputs from compact h1c) ============
  {
    // xl for compact rows
    gemm_s<<<dim3(64), 256, 0, stream>>>(h1ch, h1cl, 512, Bh + L1_OFF, Bl + L1_OFF,
                                         xlc, nullptr, nullptr, gat_bl + 512,
                                         NC, 512, 512, 0, 512, nullptr, nullptr);
    // K/V for cni's graph = compact rows 0..255
    gemm_s<<<dim3(64), 256, 0, stream>>>(h1ch, h1cl, 512, Bh + KV1_OFF, Bl + KV1_OFF,
                                         kvbuf, nullptr, nullptr,
                                         mha_inb + 1536 + 512, 256, 512, 1024, 0,
                                         512, nullptr, nullptr);
    // q and xr rows from h1c[cni & 255]
    gemv_part<<<dim3(8, 8), 256, 0, stream>>>(h1c, cni, 255, 512,
                                              mha_inW + 512 * 1536, 1536, 512, pv1);
    gemv_part<<<dim3(8, 8), 256, 0, stream>>>(h1c, cni, 255, 512,
                                              gat_Wr + 512 * 512, 512, 512, pv2);
    row_reduce<<<2, 256, 0, stream>>>(pv1, 8, 512, mha_inb + 1536, qrow, 0);
    row_reduce<<<2, 256, 0, stream>>>(pv2, 8, 512, gat_br + 512, xrrow, 0);
    gat_l2<<<1, 512, 0, stream>>>(xlc, xrrow, cni, eattr, easum, gat_We + 1024,
                                  gat_att + 512, gat_bias + 512, cnt, elist,
                                  n1_g + 512, n1_b + 512, local_row);
    mha_row<<<8, 256, 0, stream>>>(qrow, kvbuf, attO_row);
    gemv_part<<<dim3(8, 8), 256, 0, stream>>>(attO_row, nullptr, 0, 0,
                                              mha_outW + 512 * 512, 512, 512, pv1);
    comb_l2<<<1, 512, 0, stream>>>(pv1, 8, mha_outb + 512, local_row, alpha_p, 1,
                                   n2_g + 512, n2_b + 512, comb_row);
    gemv_part<<<dim3(32, 8), 256, 0, stream>>>(comb_row, nullptr, 0, 0,
                                               ffn_W1 + (size_t)512 * 2048, 2048,
                                               2048, pv1);
    row_reduce<<<8, 256, 0, stream>>>(pv1, 8, 2048, ffn_b1 + 2048, midrow, 1);
    gemv_part<<<dim3(8, 32), 256, 0, stream>>>(midrow, nullptr, 0, 0,
                                               ffn_W2 + (size_t)2048 * 512, 512,
                                               512, pv1);
    final_l2<<<1, 512, 0, stream>>>(pv1, 32, ffn_b2 + 512, comb_row, n3_g + 512,
                                    n3_b + 512, hrow);
  }

  head_kernel<<<1, 512, 0, stream>>>(hrow, ah_W1, ah_b1, ah_g, ah_bt, ah_W2,
                                     ah_b2, (float*)d_out);
}

// Round 11
// 424.651 us; speedup vs baseline: 1.7413x; 1.0604x over previous
//
#include <hip/hip_runtime.h>
#include <math.h>

constexpr int NODES = 2048;
constexpr int BG = 8;
constexpr int SG = 256;
constexpr int DIN = 4096;
constexpr int NHEAD = 8;
constexpr int EDGES = 32768;
constexpr int ACT_N = 5;
constexpr int H4C = 128;
constexpr int ECAP = 192;   // per-dst edge list capacity (GAT)
constexpr int SCAP = 96;    // per-src dedup'd neighbor capacity (RWSE)
constexpr int QS = 2560;    // merged hidden stride: [xl 512 | xr 512 | qkv 1536]
constexpr int NC = 512;     // compact row count (256 graph + 192 nbrs + pad)

typedef unsigned short u16;
typedef unsigned int u32;
typedef unsigned long long u64;
typedef short short8 __attribute__((ext_vector_type(8)));
typedef float f32x4 __attribute__((ext_vector_type(4)));

__device__ __forceinline__ float wave_sum(float v) {
#pragma unroll
  for (int o = 32; o; o >>= 1) v += __shfl_xor(v, o);
  return v;
}
__device__ __forceinline__ float wave_max(float v) {
#pragma unroll
  for (int o = 32; o; o >>= 1) v = fmaxf(v, __shfl_xor(v, o));
  return v;
}
__device__ __forceinline__ float blk_sum(float v, float* sh) {
  v = wave_sum(v);
  int nw = blockDim.x >> 6;
  __syncthreads();
  if ((threadIdx.x & 63) == 0) sh[threadIdx.x >> 6] = v;
  __syncthreads();
  float s = 0.f;
  for (int k = 0; k < nw; k++) s += sh[k];
  return s;
}
__device__ __forceinline__ float blk_max(float v, float* sh) {
  v = wave_max(v);
  int nw = blockDim.x >> 6;
  __syncthreads();
  if ((threadIdx.x & 63) == 0) sh[threadIdx.x >> 6] = v;
  __syncthreads();
  float m = sh[0];
  for (int k = 1; k < nw; k++) m = fmaxf(m, sh[k]);
  return m;
}
__device__ __forceinline__ float gelu_f(float x) {
  return 0.5f * x * (1.f + erff(x * 0.70710678118654752f));
}
__device__ __forceinline__ u16 f2bf(float x) {  // round-to-nearest-even bf16
  u32 u = __float_as_uint(x);
  return (u16)((u + 0x7FFFu + ((u >> 16) & 1u)) >> 16);
}
__device__ __forceinline__ float bf2f(u16 h) { return __uint_as_float(((u32)h) << 16); }
__device__ __forceinline__ void split2(float v, u16* ph, u16* pl) {
  u16 h = f2bf(v);
  *ph = h;
  *pl = f2bf(v - bf2f(h));
}

// ================= RWSE (sparse path) =================
__global__ void build_csr(const int* __restrict__ ei, u32* __restrict__ bits,
                          int* __restrict__ scnt, int* __restrict__ slist) {
  int e = blockIdx.x * 256 + threadIdx.x;
  if (e < EDGES) {
    int s = ei[e], d = ei[EDGES + e];
    u32 m = 1u << (d & 31);
    u32 old = atomicOr(&bits[s * 64 + (d >> 5)], m);
    if (!(old & m)) {
      int p = atomicAdd(&scnt[s], 1);
      if (p < SCAP) slist[s * SCAP + p] = d;
    }
  }
}

__global__ void diag_T(const u32* __restrict__ bits, const int* __restrict__ scnt,
                       float* __restrict__ rwse) {
  int i = blockIdx.x * 256 + threadIdx.x;
  if (i < NODES) {
    int deg = min(scnt[i], SCAP);
    int self = (bits[i * 64 + (i >> 5)] >> (i & 31)) & 1;
    rwse[(size_t)i * 8 + 0] = (self && deg > 0) ? 1.f / (float)deg : 0.f;
  }
}

__global__ __launch_bounds__(256) void spmm_sq(const int* __restrict__ scnt,
                                               const int* __restrict__ slist,
                                               float* __restrict__ P2) {
  int i = blockIdx.x, t = threadIdx.x;
  __shared__ float row[NODES];
  for (int c = t; c < NODES; c += 256) row[c] = 0.f;
  __syncthreads();
  int di = min(scnt[i], SCAP);
  float wi = di > 0 ? 1.f / (float)di : 0.f;
  for (int jj = 0; jj < di; jj++) {
    int j = slist[i * SCAP + jj];
    int dj = min(scnt[j], SCAP);
    if (dj == 0) continue;
    float w = wi / (float)dj;
    for (int kk = t; kk < dj; kk += 256) atomicAdd(&row[slist[j * SCAP + kk]], w);
  }
  __syncthreads();
  for (int c = t; c < NODES; c += 256) P2[(size_t)i * NODES + c] = row[c];
}

__global__ __launch_bounds__(256) void spmm_gather(const int* __restrict__ scnt,
                                                   const int* __restrict__ slist,
                                                   const float* __restrict__ P,
                                                   float* __restrict__ Q) {
  int i = blockIdx.x, t = threadIdx.x;
  __shared__ int nb[SCAP];
  int di = min(scnt[i], SCAP);
  for (int c = t; c < di; c += 256) nb[c] = slist[i * SCAP + c];
  __syncthreads();
  float wi = di > 0 ? 1.f / (float)di : 0.f;
  for (int c = t; c < NODES; c += 256) {
    float s = 0.f;
    for (int jj = 0; jj < di; jj++) s += P[(size_t)nb[jj] * NODES + c];
    Q[(size_t)i * NODES + c] = s * wi;
  }
}

__global__ void diag_copy(const float* __restrict__ P, float* __restrict__ rwse, int col) {
  int i = blockIdx.x * 256 + threadIdx.x;
  if (i < NODES) rwse[(size_t)i * 8 + col] = P[(size_t)i * (NODES + 1)];
}

// fused diag dots, tiled+coalesced
__global__ __launch_bounds__(256) void diag_tiled(const float* __restrict__ P2,
                                                  const float* __restrict__ P3,
                                                  const float* __restrict__ P4,
                                                  float* __restrict__ pbuf) {
  __shared__ float r2[64][65], r3[64][65], r4[64][65], c3[64][65], c4[64][65];
  __shared__ float red[4][4][64];
  int t = threadIdx.x;
  int i0 = blockIdx.x * 64;
  int js = blockIdx.y;
  int lo = t & 63, hi = t >> 6;
  float d5 = 0, d6 = 0, d7 = 0, d8 = 0;
  for (int jc = 0; jc < 4; jc++) {
    int j0 = js * 256 + jc * 64;
    __syncthreads();
#pragma unroll
    for (int r = 0; r < 16; r++) {
      int a = hi * 16 + r;
      r2[a][lo] = P2[(size_t)(i0 + a) * NODES + j0 + lo];
      r3[a][lo] = P3[(size_t)(i0 + a) * NODES + j0 + lo];
      r4[a][lo] = P4[(size_t)(i0 + a) * NODES + j0 + lo];
      c3[a][lo] = P3[(size_t)(j0 + a) * NODES + i0 + lo];
      c4[a][lo] = P4[(size_t)(j0 + a) * NODES + i0 + lo];
    }
    __syncthreads();
#pragma unroll
    for (int r = 0; r < 16; r++) {
      int jj = hi * 16 + r;
      float p3c = c3[jj][lo], p4c = c4[jj][lo];
      d5 += r2[lo][jj] * p3c;
      d6 += r3[lo][jj] * p3c;
      d7 += r3[lo][jj] * p4c;
      d8 += r4[lo][jj] * p4c;
    }
  }
  red[0][hi][lo] = d5; red[1][hi][lo] = d6; red[2][hi][lo] = d7; red[3][hi][lo] = d8;
  __syncthreads();
  if (hi == 0) {
    int i = i0 + lo;
#pragma unroll
    for (int v = 0; v < 4; v++) {
      float s = red[v][0][lo] + red[v][1][lo] + red[v][2][lo] + red[v][3][lo];
      pbuf[((size_t)js * NODES + i) * 4 + v] = s;
    }
  }
}

__global__ void diag_reduce(const float* __restrict__ pbuf, float* __restrict__ rwse) {
  int i = blockIdx.x * 256 + threadIdx.x;
  if (i >= NODES) return;
#pragma unroll
  for (int v = 0; v < 4; v++) {
    float s = 0.f;
    for (int js = 0; js < 8; js++) s += pbuf[((size_t)js * NODES + i) * 4 + v];
    rwse[(size_t)i * 8 + 4 + v] = s;
  }
}

// ================= fp32 -> split-bf16 helpers =================
__device__ __forceinline__ void splitA8(const float* __restrict__ p, short8& h8,
                                        short8& l8) {
  float4 v0 = *(const float4*)p;
  float4 v1 = *(const float4*)(p + 4);
  float v[8] = {v0.x, v0.y, v0.z, v0.w, v1.x, v1.y, v1.z, v1.w};
#pragma unroll
  for (int i = 0; i < 8; i++) {
    u16 h = f2bf(v[i]);
    h8[i] = (short)h;
    l8[i] = (short)f2bf(v[i] - bf2f(h));
  }
}

__global__ void conv_split(const float* __restrict__ src, u16* __restrict__ Ah,
                           u16* __restrict__ Al, int total8, int Ksrc,
                           int dstStride, int colOff) {
  int u = blockIdx.x * 256 + threadIdx.x;
  if (u >= total8) return;
  int idx = u * 8;
  int m = idx / Ksrc, k = idx - m * Ksrc;
  short8 h8, l8;
  splitA8(src + idx, h8, l8);
  size_t o = (size_t)m * dstStride + colOff + k;
  *(short8*)(Ah + o) = h8;
  *(short8*)(Al + o) = l8;
}

// ================= weight packing: unit-vectorized =================
struct PackArgs {
  const float* src[13];
  u64 offU[13];
  u64 cumU[14];
  int N[13];
  int srcStride[13];
  int gnTot[13];
  int ntOff[13];
};

__global__ __launch_bounds__(256) void pack_all(PackArgs pa, u16* __restrict__ Bh,
                                                u16* __restrict__ Bl) {
  u64 total = pa.cumU[13];
  for (u64 u = (u64)blockIdx.x * 256 + threadIdx.x; u < total;
       u += (u64)gridDim.x * 256) {
    int s = 0;
    while (u >= pa.cumU[s + 1]) s++;
    u64 ur = u - pa.cumU[s];
    int lr = (int)(ur & 15);
    int g = (int)((ur >> 4) & 3);
    int ks = (int)((ur >> 6) & 1);
    int j = (int)((ur >> 7) & 3);
    u64 rest = ur >> 9;
    int Nseg = pa.N[s] >> 6;
    int nt = (int)(rest % (u32)Nseg);
    int ktile = (int)(rest / (u32)Nseg);
    int k0 = (ktile << 6) | (ks << 5) | (g << 3);
    int n = (nt << 6) | (j << 4) | lr;
    const float* src = pa.src[s];
    int stride = pa.srcStride[s];
    u64 fiU = pa.offU[s] +
              ((((u64)ktile * pa.gnTot[s] + pa.ntOff[s] + nt) * 8 + j * 2 + ks) * 64 +
               g * 16 + lr);
    short8 h8, l8;
#pragma unroll
    for (int e = 0; e < 8; e++) {
      float v = src[(size_t)(k0 + e) * stride + n];
      u16 h = f2bf(v);
      h8[e] = (short)h;
      l8[e] = (short)f2bf(v - bf2f(h));
    }
    *((short8*)Bh + fiU) = h8;
    *((short8*)Bl + fiU) = l8;
  }
}

// ========== split-bf16 MFMA GEMM, pre-split u16 A, split-K, row gather =====
__global__ __launch_bounds__(256) void gemm_s(
    const u16* __restrict__ Ahg, const u16* __restrict__ Alg, int lda,
    const u16* __restrict__ Bh, const u16* __restrict__ Bl,
    float* __restrict__ C, u16* __restrict__ Ch, u16* __restrict__ Cl,
    const float* __restrict__ bias,
    int M, int K, int N, int act, int Kslice, float* __restrict__ part,
    const int* __restrict__ rowmap) {
  __shared__ __align__(16) u16 LA[2][4096];
  __shared__ __align__(16) u16 LB[2][4096];
  int gn = N >> 6;
  int nwg = (M >> 6) * gn;
  int q = nwg >> 3;
  int flat = blockIdx.x;
  int virt = (flat & 7) * q + (flat >> 3);     // bijective XCD-contiguous remap
  int bm = (virt / gn) << 6, bn = (virt % gn) << 6;
  int kb = blockIdx.y;
  int kstart = kb * Kslice;
  int kend = min(K, kstart + Kslice);
  int t = threadIdx.x;
  int lane = t & 63, w = t >> 6;
  int wm = (w >> 1) << 5, wn = (w & 1) << 5;
  int r0 = t >> 3, r1 = r0 + 32;
  int c8 = (t & 7) << 3;
  int ks_s = (t >> 2) & 1, g_s = t & 3;
  int slotA = (((r0 & 15) + (g_s << 4)) ^ (g_s | (ks_s << 2)));
  int da0 = ((((r0 >> 4) << 1) + ks_s) << 9) + (slotA << 3);
  int da1 = ((((r1 >> 4) << 1) + ks_s) << 9) + (slotA << 3);
  int db0 = t * 8, db1 = (t + 256) * 8;
  size_t btile = ((size_t)(kstart >> 6) * gn + (bn >> 6)) * 4096;
  size_t bstep = (size_t)gn * 4096;

  int rrow0 = bm + r0, rrow1 = bm + r1;
  if (rowmap) { rrow0 = rowmap[rrow0]; rrow1 = rowmap[rrow1]; }
  size_t aoff0 = (size_t)rrow0 * lda + c8;
  size_t aoff1 = (size_t)rrow1 * lda + c8;

  short8 pah0, pal0, pah1, pal1, pbh0, pbl0, pbh1, pbl1;
  pah0 = *(const short8*)(Ahg + aoff0 + kstart);
  pal0 = *(const short8*)(Alg + aoff0 + kstart);
  pah1 = *(const short8*)(Ahg + aoff1 + kstart);
  pal1 = *(const short8*)(Alg + aoff1 + kstart);
  pbh0 = *(const short8*)(Bh + btile + db0);
  pbl0 = *(const short8*)(Bl + btile + db0);
  pbh1 = *(const short8*)(Bh + btile + db1);
  pbl1 = *(const short8*)(Bl + btile + db1);

  f32x4 acc[2][2] = {};
  int lr = lane & 15, lg = lane >> 4;
  int rboff = lane << 3;

  for (int kt = kstart; kt < kend; kt += 64) {
    __syncthreads();
    *(short8*)&LA[0][da0] = pah0;
    *(short8*)&LA[1][da0] = pal0;
    *(short8*)&LA[0][da1] = pah1;
    *(short8*)&LA[1][da1] = pal1;
    *(short8*)&LB[0][db0] = pbh0;
    *(short8*)&LB[1][db0] = pbl0;
    *(short8*)&LB[0][db1] = pbh1;
    *(short8*)&LB[1][db1] = pbl1;
    __syncthreads();
    if (kt + 64 < kend) {
      btile += bstep;
      int kn = kt + 64;
      pah0 = *(const short8*)(Ahg + aoff0 + kn);
      pal0 = *(const short8*)(Alg + aoff0 + kn);
      pah1 = *(const short8*)(Ahg + aoff1 + kn);
      pal1 = *(const short8*)(Alg + aoff1 + kn);
      pbh0 = *(const short8*)(Bh + btile + db0);
      pbl0 = *(const short8*)(Bl + btile + db0);
      pbh1 = *(const short8*)(Bh + btile + db1);
      pbl1 = *(const short8*)(Bl + btile + db1);
    }
#pragma unroll
    for (int ks = 0; ks < 2; ks++) {
      short8 ah[2], al[2], bh[2], bl[2];
      int slr = ((lr + (lg << 4)) ^ (lg | (ks << 2))) << 3;
#pragma unroll
      for (int i = 0; i < 2; i++) {
        int ba = ((((wm >> 4) + i) * 2 + ks) << 9) + slr;
        ah[i] = *(const short8*)&LA[0][ba];
        al[i] = *(const short8*)&LA[1][ba];
        int bb = ((((wn >> 4) + i) * 2 + ks) << 9) + rboff;
        bh[i] = *(const short8*)&LB[0][bb];
        bl[i] = *(const short8*)&LB[1][bb];
      }
#pragma unroll
      for (int i = 0; i < 2; i++)
#pragma unroll
        for (int j = 0; j < 2; j++) {
          acc[i][j] = __builtin_amdgcn_mfma_f32_16x16x32_bf16(ah[i], bh[j], acc[i][j], 0, 0, 0);
          acc[i][j] = __builtin_amdgcn_mfma_f32_16x16x32_bf16(ah[i], bl[j], acc[i][j], 0, 0, 0);
          acc[i][j] = __builtin_amdgcn_mfma_f32_16x16x32_bf16(al[i], bh[j], acc[i][j], 0, 0, 0);
        }
    }
  }
  int row0 = (lane >> 4) * 4;
  if (part) {
    size_t pbase = (size_t)kb * (size_t)M * N;
#pragma unroll
    for (int i = 0; i < 2; i++)
#pragma unroll
      for (int j = 0; j < 2; j++) {
        int n = bn + wn + j * 16 + lr;
#pragma unroll
        for (int r = 0; r < 4; r++) {
          int m = bm + wm + i * 16 + row0 + r;
          part[pbase + (size_t)m * N + n] = acc[i][j][r];
        }
      }
    return;
  }
#pragma unroll
  for (int i = 0; i < 2; i++)
#pragma unroll
    for (int j = 0; j < 2; j++) {
      int n = bn + wn + j * 16 + lr;
      float bv = bias ? bias[n] : 0.f;
#pragma unroll
      for (int r = 0; r < 4; r++) {
        int m = bm + wm + i * 16 + row0 + r;
        float v = acc[i][j][r] + bv;
        if (act) v = gelu_f(v);
        size_t o = (size_t)m * N + n;
        if (Ch) {
          split2(v, Ch + o, Cl + o);
          if (C) C[o] = v;
        } else {
          C[o] = v;
        }
      }
    }
}

// ================= small fused kernels =================
__global__ __launch_bounds__(128) void rwse_proj(const float* __restrict__ rwse,
                                                 const float* __restrict__ W,
                                                 const float* __restrict__ bb,
                                                 const float* __restrict__ g,
                                                 const float* __restrict__ bt,
                                                 u16* __restrict__ Axh,
                                                 u16* __restrict__ Axl) {
  int i = blockIdx.x, j = threadIdx.x;
  float s = bb[j];
#pragma unroll
  for (int k = 0; k < 8; k++) s += rwse[(size_t)i * 8 + k] * W[k * H4C + j];
  __shared__ float sh[8];
  float sum = blk_sum(s, sh);
  float mu = sum * (1.f / 128.f);
  float d = s - mu;
  float var = blk_sum(d * d, sh) * (1.f / 128.f);
  float val = gelu_f(d * rsqrtf(var + 1e-5f) * g[j] + bt[j]);
  size_t o = (size_t)i * 4224 + 4096 + j;
  split2(val, Axh + o, Axl + o);
}

__global__ __launch_bounds__(256) void ln512(const float* __restrict__ x, int sk,
                                             int M,
                                             const float* __restrict__ gbias,
                                             const float* __restrict__ res,
                                             const float* __restrict__ mix,
                                             const float* __restrict__ ap, int l,
                                             const float* __restrict__ g,
                                             const float* __restrict__ b,
                                             float* __restrict__ y,
                                             u16* __restrict__ yh,
                                             u16* __restrict__ yl, int do_gelu) {
  const size_t MN = (size_t)M * 512;
  int i = blockIdx.x, t = threadIdx.x;
  size_t base = (size_t)i * 512;
  float v0 = x[base + t], v1 = x[base + 256 + t];
  for (int s = 1; s < sk; s++) {
    v0 += x[(size_t)s * MN + base + t];
    v1 += x[(size_t)s * MN + base + 256 + t];
  }
  if (gbias) { v0 += gbias[t]; v1 += gbias[t + 256]; }
  if (res) { v0 += res[base + t]; v1 += res[base + 256 + t]; }
  __shared__ float sh[8];
  float s = blk_sum(v0 + v1, sh);
  float mu = s * (1.f / 512.f);
  float d0 = v0 - mu, d1 = v1 - mu;
  float var = blk_sum(d0 * d0 + d1 * d1, sh) * (1.f / 512.f);
  float rstd = rsqrtf(var + 1e-5f);
  float o0 = d0 * rstd * g[t] + b[t];
  float o1 = d1 * rstd * g[t + 256] + b[t + 256];
  if (do_gelu) { o0 = gelu_f(o0); o1 = gelu_f(o1); }
  if (mix) {
    float a = 1.f / (1.f + expf(-ap[l]));
    o0 = a * mix[base + t] + (1.f - a) * o0;
    o1 = a * mix[base + 256 + t] + (1.f - a) * o1;
  }
  if (y) { y[base + t] = o0; y[base + 256 + t] = o1; }
  if (yh) {
    split2(o0, yh + base + t, yl + base + t);
    split2(o1, yh + base + 256 + t, yl + base + 256 + t);
  }
}

__global__ void build_cbias(const float* __restrict__ bl, const float* __restrict__ br,
                            const float* __restrict__ inb, float* __restrict__ cb) {
  int i = blockIdx.x * 256 + threadIdx.x;
  if (i >= QS) return;
  cb[i] = i < 512 ? bl[i] : (i < 1024 ? br[i - 512] : inb[i - 1024]);
}

__global__ void fill_edges(const int* __restrict__ ei, int* __restrict__ cnt,
                           int* __restrict__ elist) {
  int e = blockIdx.x * 256 + threadIdx.x;
  if (e < EDGES + NODES) {
    int d = e < EDGES ? ei[EDGES + e] : e - EDGES;
    int p = atomicAdd(&cnt[d], 1);
    if (p < ECAP) elist[(size_t)d * ECAP + p] = e;
  }
}

__global__ void build_rowmap(const int* __restrict__ cni, const int* __restrict__ cnt,
                             const int* __restrict__ elist, const int* __restrict__ ei,
                             int* __restrict__ rowmap) {
  int t = blockIdx.x * 256 + threadIdx.x;
  if (t >= NC) return;
  int i = cni[0];
  if (t < 256) {
    rowmap[t] = ((i >> 8) << 8) + t;
  } else {
    int p = t - 256;
    int m = min(cnt[i], ECAP);
    int v = 0;
    if (p < m) {
      int eid = elist[(size_t)i * ECAP + p];
      v = eid < EDGES ? ei[eid] : i;
    }
    rowmap[t] = v;
  }
}

__global__ void ea_reduce(const float* __restrict__ ea, float* __restrict__ sums) {
  int tid = blockIdx.x * blockDim.x + threadIdx.x;
  int stride = gridDim.x * blockDim.x;
  float s0 = 0.f, s1 = 0.f;
  for (int e = tid; e < EDGES; e += stride) { s0 += ea[2 * e]; s1 += ea[2 * e + 1]; }
  s0 = wave_sum(s0);
  s1 = wave_sum(s1);
  if ((threadIdx.x & 63) == 0) { atomicAdd(&sums[0], s0); atomicAdd(&sums[1], s1); }
}

// layer-0 GAT at rowmap'd dst nodes; xl/xr from merged buffer (full rows)
__global__ __launch_bounds__(512) void gat_kernel(
    const float* __restrict__ hb, const int* __restrict__ rowmap,
    const float* __restrict__ eattr, const float* __restrict__ easum,
    const float* __restrict__ We, const float* __restrict__ att,
    const float* __restrict__ bias, const int* __restrict__ cnt,
    const int* __restrict__ elist, const int* __restrict__ ei,
    float* __restrict__ out) {
  int i = rowmap[blockIdx.x];
  int tid = threadIdx.x;
  int h = tid >> 6, c = tid & 63;
  int m_cnt = cnt[i];
  if (m_cnt > ECAP) m_cnt = ECAP;
  const float inv_e = 1.f / (float)EDGES;
  float we0 = We[tid], we1 = We[512 + tid];
  float attv = att[tid];
  float xrv = hb[(size_t)i * QS + 512 + tid];
  float ea_m0 = easum[0] * inv_e, ea_m1 = easum[1] * inv_e;
  __shared__ float logits[NHEAD][ECAP];
  const int* el = elist + (size_t)i * ECAP;
  for (int e = 0; e < m_cnt; e++) {
    int eid = el[e];
    int s;
    float a0, a1;
    if (eid < EDGES) { s = ei[eid]; a0 = eattr[2 * eid]; a1 = eattr[2 * eid + 1]; }
    else { s = i; a0 = ea_m0; a1 = ea_m1; }
    float mval = hb[(size_t)s * QS + tid] + xrv + a0 * we0 + a1 * we1;
    mval = mval > 0.f ? mval : 0.2f * mval;
    float lg = wave_sum(mval * attv);
    if (c == 0) logits[h][e] = lg;
  }
  float mx = -1e30f;
  for (int e = c; e < m_cnt; e += 64) mx = fmaxf(mx, logits[h][e]);
  mx = wave_max(mx);
  float den = 0.f;
  for (int e = c; e < m_cnt; e += 64) den += expf(logits[h][e] - mx);
  den = wave_sum(den) + 1e-16f;
  float acc = 0.f;
  for (int e = 0; e < m_cnt; e++) {
    int eid = el[e];
    int s = eid < EDGES ? ei[eid] : i;
    float alpha = expf(logits[h][e] - mx) / den;
    acc += alpha * hb[(size_t)s * QS + tid];
  }
  out[(size_t)blockIdx.x * 512 + tid] = acc + bias[tid];
}

// ======= MFMA block-diag MHA (layer 0); outputs split u16 =======
__global__ __launch_bounds__(256) void mha_mfma(const float* __restrict__ qkv,
                                                u16* __restrict__ attOh,
                                                u16* __restrict__ attOl) {
  __shared__ __align__(16) u16 Ksh[2][256][72];
  __shared__ __align__(16) u16 Vt[2][64][264];
  int bid = blockIdx.x;
  int qq = bid & 3;
  int h = (bid >> 2) & 7;
  int b = bid >> 5;
  int t = threadIdx.x;
  int lane = t & 63, w = t >> 6;
  int lr = lane & 15, g = lane >> 4, kk = g * 8;
  size_t rowbase = (size_t)(b * SG) * QS;
  const float* Kbase = qkv + rowbase + 512 + h * 64;
  const float* Vbase = qkv + rowbase + 1024 + h * 64;
  for (int idx = t; idx < SG * 64; idx += 256) {
    int j = idx >> 6, c = idx & 63;
    float kv = Kbase[(size_t)j * QS + c];
    u16 khh = f2bf(kv);
    Ksh[0][j][c] = khh;
    Ksh[1][j][c] = f2bf(kv - bf2f(khh));
    float vv = Vbase[(size_t)j * QS + c];
    u16 vhh = f2bf(vv);
    Vt[0][c][j] = vhh;
    Vt[1][c][j] = f2bf(vv - bf2f(vhh));
  }
  const float* Qrow = qkv + rowbase + (size_t)(qq * 64 + w * 16 + lr) * QS + h * 64;
  short8 qh[2], ql[2];
#pragma unroll
  for (int kt = 0; kt < 2; kt++) {
    float qv[8];
    *(float4*)&qv[0] = *(const float4*)&Qrow[kt * 32 + kk];
    *(float4*)&qv[4] = *(const float4*)&Qrow[kt * 32 + kk + 4];
#pragma unroll
    for (int i = 0; i < 8; i++) {
      u16 hh = f2bf(qv[i]);
      qh[kt][i] = hh;
      ql[kt][i] = f2bf(qv[i] - bf2f(hh));
    }
  }
  __syncthreads();
  f32x4 S[16];
#pragma unroll
  for (int j = 0; j < 16; j++) {
    f32x4 acc = {};
#pragma unroll
    for (int kt = 0; kt < 2; kt++) {
      short8 bh = *(const short8*)&Ksh[0][j * 16 + lr][kt * 32 + kk];
      short8 bl = *(const short8*)&Ksh[1][j * 16 + lr][kt * 32 + kk];
      acc = __builtin_amdgcn_mfma_f32_16x16x32_bf16(qh[kt], bh, acc, 0, 0, 0);
      acc = __builtin_amdgcn_mfma_f32_16x16x32_bf16(qh[kt], bl, acc, 0, 0, 0);
      acc = __builtin_amdgcn_mfma_f32_16x16x32_bf16(ql[kt], bh, acc, 0, 0, 0);
    }
    S[j] = acc;
  }
  float mx[4], inv[4];
#pragma unroll
  for (int r = 0; r < 4; r++) {
    float m = S[0][r];
#pragma unroll
    for (int j = 1; j < 16; j++) m = fmaxf(m, S[j][r]);
#pragma unroll
    for (int oo = 1; oo < 16; oo <<= 1) m = fmaxf(m, __shfl_xor(m, oo));
    mx[r] = m;
    float d = 0.f;
#pragma unroll
    for (int j = 0; j < 16; j++) d += __expf((S[j][r] - m) * 0.125f);
#pragma unroll
    for (int oo = 1; oo < 16; oo <<= 1) d += __shfl_xor(d, oo);
    inv[r] = 1.f / d;
  }
  __syncthreads();
  u16* Pb = &Ksh[0][0][0];
  int row0 = w * 16 + g * 4;
#pragma unroll
  for (int j = 0; j < 16; j++) {
    int key = j * 16 + lr;
#pragma unroll
    for (int r = 0; r < 4; r++) {
      float p = __expf((S[j][r] - mx[r]) * 0.125f) * inv[r];
      u16 hh = f2bf(p);
      Pb[(row0 + r) * 264 + key] = hh;
      Pb[16896 + (row0 + r) * 264 + key] = f2bf(p - bf2f(hh));
    }
  }
  __syncthreads();
  f32x4 Oacc[4] = {};
#pragma unroll
  for (int kt = 0; kt < 8; kt++) {
    short8 pah = *(const short8*)&Pb[(w * 16 + lr) * 264 + kt * 32 + kk];
    short8 pal = *(const short8*)&Pb[16896 + (w * 16 + lr) * 264 + kt * 32 + kk];
#pragma unroll
    for (int nf = 0; nf < 4; nf++) {
      short8 vh = *(const short8*)&Vt[0][nf * 16 + lr][kt * 32 + kk];
      short8 vl = *(const short8*)&Vt[1][nf * 16 + lr][kt * 32 + kk];
      Oacc[nf] = __builtin_amdgcn_mfma_f32_16x16x32_bf16(pah, vh, Oacc[nf], 0, 0, 0);
      Oacc[nf] = __builtin_amdgcn_mfma_f32_16x16x32_bf16(pah, vl, Oacc[nf], 0, 0, 0);
      Oacc[nf] = __builtin_amdgcn_mfma_f32_16x16x32_bf16(pal, vh, Oacc[nf], 0, 0, 0);
    }
  }
  size_t obase = (size_t)(b * SG + qq * 64 + w * 16 + g * 4) * 512 + h * 64;
#pragma unroll
  for (int nf = 0; nf < 4; nf++)
#pragma unroll
    for (int r = 0; r < 4; r++) {
      size_t o = obase + (size_t)r * 512 + nf * 16 + lr;
      split2(Oacc[nf][r], attOh + o, attOl + o);
    }
}

// ================= layer-2 pruned path (row cni only) =================
__global__ __launch_bounds__(256) void gemv_part(
    const float* __restrict__ inrow, const int* __restrict__ cni, int rowMask,
    int rowStride, const float* __restrict__ W, int ldW, int N,
    float* __restrict__ part) {
  __shared__ float xv[64];
  __shared__ float red[4][64];
  int t = threadIdx.x;
  int kb = blockIdx.y;
  const float* xr = inrow + (cni ? (size_t)(cni[0] & rowMask) * rowStride : 0) + kb * 64;
  if (t < 64) xv[t] = xr[t];
  __syncthreads();
  int nl = t & 63;
  int n = blockIdx.x * 64 + nl;
  int seg = t >> 6;
  float acc = 0.f;
  const float* Wp = W + (size_t)(kb * 64 + seg * 16) * ldW + n;
#pragma unroll
  for (int k = 0; k < 16; k++) acc += xv[seg * 16 + k] * Wp[(size_t)k * ldW];
  red[seg][nl] = acc;
  __syncthreads();
  if (t < 64) {
    part[(size_t)kb * N + blockIdx.x * 64 + t] =
        red[0][t] + red[1][t] + red[2][t] + red[3][t];
  }
}

__global__ void row_reduce(const float* __restrict__ part, int KB, int N,
                           const float* __restrict__ bias,
                           float* __restrict__ out, int act) {
  int n = blockIdx.x * 256 + threadIdx.x;
  if (n >= N) return;
  float s = bias[n];
  for (int k = 0; k < KB; k++) s += part[(size_t)k * N + n];
  if (act) s = gelu_f(s);
  out[n] = s;
}

// GAT at node cni, xl from COMPACT buffer (edge p -> row 256+p), fused LN(n1)
__global__ __launch_bounds__(512) void gat_l2(
    const float* __restrict__ xlc, const float* __restrict__ xrrow,
    const int* __restrict__ cni,
    const float* __restrict__ eattr, const float* __restrict__ easum,
    const float* __restrict__ We, const float* __restrict__ att,
    const float* __restrict__ bias, const int* __restrict__ cnt,
    const int* __restrict__ elist,
    const float* __restrict__ n1g, const float* __restrict__ n1b,
    float* __restrict__ local_row) {
  int i = cni[0];
  int tid = threadIdx.x;
  int h = tid >> 6, c = tid & 63;
  int m_cnt = cnt[i];
  if (m_cnt > ECAP) m_cnt = ECAP;
  const float inv_e = 1.f / (float)EDGES;
  float we0 = We[tid], we1 = We[512 + tid];
  float attv = att[tid];
  float xrv = xrrow[tid];
  float ea_m0 = easum[0] * inv_e, ea_m1 = easum[1] * inv_e;
  __shared__ float logits[NHEAD][ECAP];
  __shared__ float sh[8];
  const int* el = elist + (size_t)i * ECAP;
  for (int e = 0; e < m_cnt; e++) {
    int eid = el[e];
    float a0, a1;
    if (eid < EDGES) { a0 = eattr[2 * eid]; a1 = eattr[2 * eid + 1]; }
    else { a0 = ea_m0; a1 = ea_m1; }
    float mval = xlc[(size_t)(256 + e) * 512 + tid] + xrv + a0 * we0 + a1 * we1;
    mval = mval > 0.f ? mval : 0.2f * mval;
    float lg = wave_sum(mval * attv);
    if (c == 0) logits[h][e] = lg;
  }
  float mx = -1e30f;
  for (int e = c; e < m_cnt; e += 64) mx = fmaxf(mx, logits[h][e]);
  mx = wave_max(mx);
  float den = 0.f;
  for (int e = c; e < m_cnt; e += 64) den += expf(logits[h][e] - mx);
  den = wave_sum(den) + 1e-16f;
  float acc = 0.f;
  for (int e = 0; e < m_cnt; e++) {
    float alpha = expf(logits[h][e] - mx) / den;
    acc += alpha * xlc[(size_t)(256 + e) * 512 + tid];
  }
  float v = acc + bias[tid];
  float mu = blk_sum(v, sh) * (1.f / 512.f);
  float d = v - mu;
  float var = blk_sum(d * d, sh) * (1.f / 512.f);
  local_row[tid] = d * rsqrtf(var + 1e-5f) * n1g[tid] + n1b[tid];
}

// fused MHA for row cni: one block per head, 256 thr (thread = key)
__global__ __launch_bounds__(256) void mha_row(const float* __restrict__ qrow,
                                               const float* __restrict__ kv,
                                               float* __restrict__ attO_row) {
  __shared__ float q[64];
  __shared__ float p[SG];
  __shared__ float sh[8];
  __shared__ float red[4][64];
  int h = blockIdx.x, t = threadIdx.x;
  if (t < 64) q[t] = qrow[h * 64 + t];
  __syncthreads();
  const float* kr = kv + (size_t)t * 1024 + h * 64;
  float s = 0.f;
#pragma unroll 8
  for (int c2 = 0; c2 < 64; c2++) s += q[c2] * kr[c2];
  s *= 0.125f;
  float m = blk_max(s, sh);
  float e = __expf(s - m);
  p[t] = e;
  float den = blk_sum(e, sh);
  int c = t & 63, seg = t >> 6;
  float o = 0.f;
  for (int j = seg * 64; j < seg * 64 + 64; j++)
    o += p[j] * kv[(size_t)j * 1024 + 512 + h * 64 + c];
  red[seg][c] = o;
  __syncthreads();
  if (t < 64)
    attO_row[h * 64 + t] = (red[0][t] + red[1][t] + red[2][t] + red[3][t]) / den;
}

__global__ __launch_bounds__(512) void comb_l2(const float* __restrict__ part, int KB,
                                               const float* __restrict__ bias,
                                               const float* __restrict__ local_row,
                                               const float* __restrict__ ap, int l,
                                               const float* __restrict__ g,
                                               const float* __restrict__ b,
                                               float* __restrict__ comb_row) {
  __shared__ float sh[8];
  int t = threadIdx.x;
  float v = bias[t];
  for (int k = 0; k < KB; k++) v += part[(size_t)k * 512 + t];
  float mu = blk_sum(v, sh) * (1.f / 512.f);
  float d = v - mu;
  float var = blk_sum(d * d, sh) * (1.f / 512.f);
  float o = d * rsqrtf(var + 1e-5f) * g[t] + b[t];
  float a = 1.f / (1.f + expf(-ap[l]));
  comb_row[t] = a * local_row[t] + (1.f - a) * o;
}

__global__ __launch_bounds__(512) void final_l2(const float* __restrict__ part, int KB,
                                                const float* __restrict__ bias,
                                                const float* __restrict__ comb_row,
                                                const float* __restrict__ g,
                                                const float* __restrict__ b,
                                                float* __restrict__ hrow) {
  __shared__ float sh[8];
  int t = threadIdx.x;
  float v = bias[t] + comb_row[t];
  for (int k = 0; k < KB; k++) v += part[(size_t)k * 512 + t];
  float mu = blk_sum(v, sh) * (1.f / 512.f);
  float d = v - mu;
  float var = blk_sum(d * d, sh) * (1.f / 512.f);
  hrow[t] = d * rsqrtf(var + 1e-5f) * g[t] + b[t];
}

// head finish: reduce W1 partials + b1 -> LN -> gelu -> z; logits via 5
// block-reductions over z*W2; softmax; write [logits | probs]
__global__ __launch_bounds__(512) void head_finish(
    const float* __restrict__ part, int KB,
    const float* __restrict__ b1,
    const float* __restrict__ g, const float* __restrict__ bt,
    const float* __restrict__ W2, const float* __restrict__ b2,
    float* __restrict__ out) {
  __shared__ float sh[8];
  __shared__ float lg[ACT_N];
  int t = threadIdx.x;
  float v = b1[t];
  for (int k = 0; k < KB; k++) v += part[(size_t)k * 512 + t];
  float mu = blk_sum(v, sh) * (1.f / 512.f);
  float d = v - mu;
  float var = blk_sum(d * d, sh) * (1.f / 512.f);
  float z = gelu_f(d * rsqrtf(var + 1e-5f) * g[t] + bt[t]);
  for (int a = 0; a < ACT_N; a++) {
    float s = blk_sum(z * W2[t * ACT_N + a], sh);
    if (t == 0) lg[a] = s + b2[a];
  }
  __syncthreads();
  if (t == 0) {
    float m2 = lg[0];
    for (int a = 1; a < ACT_N; a++) m2 = fmaxf(m2, lg[a]);
    float den = 0.f;
    float ex[ACT_N];
    for (int a = 0; a < ACT_N; a++) { ex[a] = expf(lg[a] - m2); den += ex[a]; }
    for (int a = 0; a < ACT_N; a++) {
      out[a] = lg[a];
      out[ACT_N + a] = ex[a] / den;
    }
  }
}

extern "C" void kernel_launch(void* const* d_in, const int* in_sizes, int n_in,
                              void* d_out, int out_size, void* d_ws, size_t ws_size,
                              hipStream_t stream) {
  const float* x        = (const float*)d_in[0];
  const float* eattr    = (const float*)d_in[1];
  const float* rwse_W   = (const float*)d_in[2];
  const float* rwse_b   = (const float*)d_in[3];
  const float* rwse_g   = (const float*)d_in[4];
  const float* rwse_bt  = (const float*)d_in[5];
  const float* np_W     = (const float*)d_in[6];
  const float* np_b     = (const float*)d_in[7];
  const float* np_g     = (const float*)d_in[8];
  const float* np_bt    = (const float*)d_in[9];
  const float* gat_Wl   = (const float*)d_in[10];
  const float* gat_bl   = (const float*)d_in[11];
  const float* gat_Wr   = (const float*)d_in[12];
  const float* gat_br   = (const float*)d_in[13];
  const float* gat_We   = (const float*)d_in[14];
  const float* gat_att  = (const float*)d_in[15];
  const float* gat_bias = (const float*)d_in[16];
  const float* n1_g = (const float*)d_in[17];
  const float* n1_b = (const float*)d_in[18];
  const float* mha_inW  = (const float*)d_in[19];
  const float* mha_inb  = (const float*)d_in[20];
  const float* mha_outW = (const float*)d_in[21];
  const float* mha_outb = (const float*)d_in[22];
  const float* alpha_p  = (const float*)d_in[23];
  const float* n2_g = (const float*)d_in[24];
  const float* n2_b = (const float*)d_in[25];
  const float* ffn_W1 = (const float*)d_in[26];
  const float* ffn_b1 = (const float*)d_in[27];
  const float* ffn_W2 = (const float*)d_in[28];
  const float* ffn_b2 = (const float*)d_in[29];
  const float* n3_g = (const float*)d_in[30];
  const float* n3_b = (const float*)d_in[31];
  const float* ah_W1 = (const float*)d_in[32];
  const float* ah_b1 = (const float*)d_in[33];
  const float* ah_g  = (const float*)d_in[34];
  const float* ah_bt = (const float*)d_in[35];
  const float* ah_W2 = (const float*)d_in[36];
  const float* ah_b2 = (const float*)d_in[37];
  const int* edge_index = (const int*)d_in[38];
  const int* cni        = (const int*)d_in[39];
  (void)in_sizes; (void)n_in; (void)out_size; (void)ws_size;

  char* wsp = (char*)d_ws;
  size_t off = 0;
  auto alloc = [&](size_t bytes) -> char* {
    char* p = wsp + off;
    off += (bytes + 255) & ~(size_t)255;
    return p;
  };
  const size_t NNb = (size_t)NODES * NODES * 4;
  char* arena = alloc(3 * NNb);
  float* P2 = (float*)arena;
  float* P3 = (float*)(arena + NNb);
  float* P4 = (float*)(arena + 2 * NNb);
  u16* Axh = (u16*)arena;
  u16* Axl = (u16*)(arena + 17301504);
  float* partNP = (float*)(arena + 34603008);
  float* hbig = (float*)arena;
  float* partC = (float*)(arena + 22020096);
  const u64 SEG_NP = 2162688ull;
  const u64 SEG_L0 = 3670016ull;
  const u64 L1_OFF = SEG_NP + SEG_L0;
  const u64 KV1_OFF = L1_OFF + 262144ull;
  const u64 PTOT = KV1_OFF + 524288ull;
  u16* Bh = (u16*)alloc(PTOT * 2);
  u16* Bl = (u16*)alloc(PTOT * 2);
  float* rwse = (float*)alloc((size_t)NODES * 8 * 4);
  u16* h1h = (u16*)alloc((size_t)NODES * 512 * 2);
  u16* h1l = (u16*)alloc((size_t)NODES * 512 * 2);
  u16* attOh = (u16*)alloc((size_t)NODES * 512 * 2);
  u16* attOl = (u16*)alloc((size_t)NODES * 512 * 2);
  u16* combh = (u16*)alloc((size_t)NC * 512 * 2);
  u16* combl = (u16*)alloc((size_t)NC * 512 * 2);
  u16* ffmh = (u16*)alloc((size_t)NC * 2048 * 2);
  u16* ffml = (u16*)alloc((size_t)NC * 2048 * 2);
  u16* h1ch = (u16*)alloc((size_t)NC * 512 * 2);
  u16* h1cl = (u16*)alloc((size_t)NC * 512 * 2);
  float* h1c  = (float*)alloc((size_t)NC * 512 * 4);
  float* gout = (float*)alloc((size_t)NC * 512 * 4);     // l0 gat/local; l1 xl
  float* comb = (float*)alloc((size_t)NC * 512 * 4);
  float* kvbuf = (float*)alloc((size_t)256 * 1024 * 4);
  float* cb   = (float*)alloc((size_t)QS * 4);
  float* rows = (float*)alloc(4096 * 4);
  float* midrow = (float*)alloc(2048 * 4);
  float* pv1 = (float*)alloc((size_t)32 * 2048 * 4);
  float* pv2 = (float*)alloc((size_t)8 * 512 * 4);
  u32* bits  = (u32*)alloc((size_t)NODES * 64 * 4);
  int* scnt  = (int*)alloc((size_t)NODES * 4);
  int* slist = (int*)alloc((size_t)NODES * SCAP * 4);
  int* cnt   = (int*)alloc((size_t)NODES * 4);
  int* elist = (int*)alloc((size_t)NODES * ECAP * 4);
  int* rmap  = (int*)alloc((size_t)NC * 4);
  float* easum = (float*)alloc(8);
  float* pbuf  = (float*)alloc((size_t)8 * NODES * 4 * 4);
  float* qrow = rows, *xrrow = rows + 512, *local_row = rows + 1024;
  float* attO_row = rows + 1536, *comb_row = rows + 2560;
  float* hrow = rows + 3584;
  float* xlc = gout;

  // ---- RWSE sparse path ----
  hipMemsetAsync(bits, 0, (size_t)NODES * 64 * 4, stream);
  hipMemsetAsync(scnt, 0, NODES * 4, stream);
  build_csr<<<EDGES / 256, 256, 0, stream>>>(edge_index, bits, scnt, slist);
  diag_T<<<NODES / 256, 256, 0, stream>>>(bits, scnt, rwse);
  spmm_sq<<<NODES, 256, 0, stream>>>(scnt, slist, P2);
  diag_copy<<<NODES / 256, 256, 0, stream>>>(P2, rwse, 1);
  spmm_gather<<<NODES, 256, 0, stream>>>(scnt, slist, P2, P3);
  diag_copy<<<NODES / 256, 256, 0, stream>>>(P3, rwse, 2);
  spmm_gather<<<NODES, 256, 0, stream>>>(scnt, slist, P3, P4);
  diag_copy<<<NODES / 256, 256, 0, stream>>>(P4, rwse, 3);
  diag_tiled<<<dim3(NODES / 64, 8), 256, 0, stream>>>(P2, P3, P4, pbuf);
  diag_reduce<<<NODES / 256, 256, 0, stream>>>(pbuf, rwse);
  conv_split<<<NODES * DIN / 8 / 256, 256, 0, stream>>>(x, Axh, Axl,
                                                        NODES * DIN / 8, DIN, 4224, 0);
  rwse_proj<<<NODES, 128, 0, stream>>>(rwse, rwse_W, rwse_b, rwse_g, rwse_bt,
                                       Axh, Axl);

  // ---- pack weights ----
  PackArgs pa;
  u64 uc = 0;
  int si = 0;
  auto seg = [&](const float* src, int K, int N, int stride, u64 offElems,
                 int gnTot, int ntOff) {
    pa.src[si] = src; pa.offU[si] = offElems / 8; pa.cumU[si] = uc;
    pa.N[si] = N; pa.srcStride[si] = stride; pa.gnTot[si] = gnTot;
    pa.ntOff[si] = ntOff;
    uc += (u64)K * N / 8; si++;
  };
  seg(np_W, 4224, 512, 512, 0, 8, 0);
  seg(gat_Wl, 512, 512, 512, SEG_NP, 40, 0);
  seg(gat_Wr, 512, 512, 512, SEG_NP, 40, 8);
  seg(mha_inW, 512, 1536, 1536, SEG_NP, 40, 16);
  seg(mha_outW, 512, 512, 512, SEG_NP + 1310720, 8, 0);
  seg(ffn_W1, 512, 2048, 2048, SEG_NP + 1572864, 32, 0);
  seg(ffn_W2, 2048, 512, 512, SEG_NP + 2621440, 8, 0);
  seg(gat_Wl + 512 * 512, 512, 512, 512, L1_OFF, 8, 0);
  seg(mha_inW + 512 * 1536 + 512, 512, 1024, 1536, KV1_OFF, 16, 0);
  for (int s2 = si; s2 <= 13; s2++) pa.cumU[s2] = uc;
  pack_all<<<2048, 256, 0, stream>>>(pa, Bh, Bl);
  build_cbias<<<(QS + 255) / 256, 256, 0, stream>>>(gat_bl, gat_br, mha_inb, cb);

  // ---- GAT CSR + edge-attr mean + rowmap ----
  hipMemsetAsync(cnt, 0, NODES * 4, stream);
  fill_edges<<<(EDGES + NODES) / 256, 256, 0, stream>>>(edge_index, cnt, elist);
  hipMemsetAsync(easum, 0, 8, stream);
  ea_reduce<<<64, 256, 0, stream>>>(eattr, easum);
  build_rowmap<<<2, 256, 0, stream>>>(cni, cnt, elist, edge_index, rmap);

  // ---- np projection ----
  gemm_s<<<dim3(256, 3), 256, 0, stream>>>(Axh, Axl, 4224, Bh, Bl,
                                           nullptr, nullptr, nullptr, nullptr,
                                           NODES, 4224, 512, 0, 1408, partNP,
                                           nullptr);
  ln512<<<NODES, 256, 0, stream>>>(partNP, 3, NODES, np_b, nullptr, nullptr,
                                   nullptr, 0, np_g, np_bt, nullptr, h1h, h1l, 1);

  // ================= layer 0 (outputs pruned to NC compact rows) ===========
  {
    const u64 lb = SEG_NP;
    gemm_s<<<dim3(1280), 256, 0, stream>>>(h1h, h1l, 512, Bh + lb, Bl + lb,
                                           hbig, nullptr, nullptr, cb,
                                           NODES, 512, QS, 0, 512, nullptr,
                                           nullptr);
    gat_kernel<<<NC, 512, 0, stream>>>(hbig, rmap, eattr, easum, gat_We, gat_att,
                                       gat_bias, cnt, elist, edge_index, gout);
    ln512<<<NC, 256, 0, stream>>>(gout, 1, NC, nullptr, nullptr, nullptr, nullptr,
                                  0, n1_g, n1_b, gout, nullptr, nullptr, 0);
    mha_mfma<<<BG * NHEAD * 4, 256, 0, stream>>>(hbig + 1024, attOh, attOl);
    gemm_s<<<dim3(64, 2), 256, 0, stream>>>(attOh, attOl, 512, Bh + lb + 1310720,
                                            Bl + lb + 1310720, nullptr, nullptr,
                                            nullptr, nullptr, NC, 512, 512, 0, 256,
                                            partC, rmap);
    ln512<<<NC, 256, 0, stream>>>(partC, 2, NC, mha_outb, nullptr, gout, alpha_p,
                                  0, n2_g, n2_b, comb, combh, combl, 0);
    gemm_s<<<dim3(256), 256, 0, stream>>>(combh, combl, 512, Bh + lb + 1572864,
                                          Bl + lb + 1572864, nullptr, ffmh, ffml,
                                          ffn_b1, NC, 512, 2048, 1, 512, nullptr,
                                          nullptr);
    gemm_s<<<dim3(64, 4), 256, 0, stream>>>(ffmh, ffml, 2048, Bh + lb + 2621440,
                                            Bl + lb + 2621440, nullptr, nullptr,
                                            nullptr, nullptr, NC, 2048, 512, 0,
                                            512, partC, nullptr);
    ln512<<<NC, 256, 0, stream>>>(partC, 4, NC, ffn_b2, comb, nullptr, nullptr, 0,
                                  n3_g, n3_b, h1c, h1ch, h1cl, 0);
  }

  // ================= layer 1 (row cni; inputs from compact h1c) ============
  {
    gemm_s<<<dim3(64), 256, 0, stream>>>(h1ch, h1cl, 512, Bh + L1_OFF, Bl + L1_OFF,
                                         xlc, nullptr, nullptr, gat_bl + 512,
                                         NC, 512, 512, 0, 512, nullptr, nullptr);
    gemm_s<<<dim3(64), 256, 0, stream>>>(h1ch, h1cl, 512, Bh + KV1_OFF, Bl + KV1_OFF,
                                         kvbuf, nullptr, nullptr,
                                         mha_inb + 1536 + 512, 256, 512, 1024, 0,
                                         512, nullptr, nullptr);
    gemv_part<<<dim3(8, 8), 256, 0, stream>>>(h1c, cni, 255, 512,
                                              mha_inW + 512 * 1536, 1536, 512, pv1);
    gemv_part<<<dim3(8, 8), 256, 0, stream>>>(h1c, cni, 255, 512,
                                              gat_Wr + 512 * 512, 512, 512, pv2);
    row_reduce<<<2, 256, 0, stream>>>(pv1, 8, 512, mha_inb + 1536, qrow, 0);
    row_reduce<<<2, 256, 0, stream>>>(pv2, 8, 512, gat_br + 512, xrrow, 0);
    gat_l2<<<1, 512, 0, stream>>>(xlc, xrrow, cni, eattr, easum, gat_We + 1024,
                                  gat_att + 512, gat_bias + 512, cnt, elist,
                                  n1_g + 512, n1_b + 512, local_row);
    mha_row<<<8, 256, 0, stream>>>(qrow, kvbuf, attO_row);
    gemv_part<<<dim3(8, 8), 256, 0, stream>>>(attO_row, nullptr, 0, 0,
                                              mha_outW + 512 * 512, 512, 512, pv1);
    comb_l2<<<1, 512, 0, stream>>>(pv1, 8, mha_outb + 512, local_row, alpha_p, 1,
                                   n2_g + 512, n2_b + 512, comb_row);
    gemv_part<<<dim3(32, 8), 256, 0, stream>>>(comb_row, nullptr, 0, 0,
                                               ffn_W1 + (size_t)512 * 2048, 2048,
                                               2048, pv1);
    row_reduce<<<8, 256, 0, stream>>>(pv1, 8, 2048, ffn_b1 + 2048, midrow, 1);
    gemv_part<<<dim3(8, 32), 256, 0, stream>>>(midrow, nullptr, 0, 0,
                                               ffn_W2 + (size_t)2048 * 512, 512,
                                               512, pv1);
    final_l2<<<1, 512, 0, stream>>>(pv1, 32, ffn_b2 + 512, comb_row, n3_g + 512,
                                    n3_b + 512, hrow);
  }

  // ---- action head: split-K GEMV + fused finish ----
  gemv_part<<<dim3(8, 8), 256, 0, stream>>>(hrow, nullptr, 0, 0, ah_W1, 512, 512,
                                            pv1);
  head_finish<<<1, 512, 0, stream>>>(pv1, 8, ah_b1, ah_g, ah_bt, ah_W2, ah_b2,
                                     (float*)d_out);
}

// Round 12
// 400.767 us; speedup vs baseline: 1.8451x; 1.0596x over previous
//
#include <hip/hip_runtime.h>
#include <math.h>

constexpr int NODES = 2048;
constexpr int BG = 8;
constexpr int SG = 256;
constexpr int DIN = 4096;
constexpr int NHEAD = 8;
constexpr int EDGES = 32768;
constexpr int ACT_N = 5;
constexpr int H4C = 128;
constexpr int ECAP = 192;   // per-dst edge list capacity (GAT)
constexpr int SCAP = 96;    // per-src dedup'd neighbor capacity (RWSE)
constexpr int QS = 2560;    // merged hidden stride: [xl 512 | xr 512 | qkv 1536]
constexpr int NC = 512;     // compact row count (256 graph + 192 nbrs + pad)

typedef unsigned short u16;
typedef unsigned int u32;
typedef unsigned long long u64;
typedef short short8 __attribute__((ext_vector_type(8)));
typedef float f32x4 __attribute__((ext_vector_type(4)));

__device__ __forceinline__ float wave_sum(float v) {
#pragma unroll
  for (int o = 32; o; o >>= 1) v += __shfl_xor(v, o);
  return v;
}
__device__ __forceinline__ float wave_max(float v) {
#pragma unroll
  for (int o = 32; o; o >>= 1) v = fmaxf(v, __shfl_xor(v, o));
  return v;
}
__device__ __forceinline__ float blk_sum(float v, float* sh) {
  v = wave_sum(v);
  int nw = blockDim.x >> 6;
  __syncthreads();
  if ((threadIdx.x & 63) == 0) sh[threadIdx.x >> 6] = v;
  __syncthreads();
  float s = 0.f;
  for (int k = 0; k < nw; k++) s += sh[k];
  return s;
}
__device__ __forceinline__ float blk_max(float v, float* sh) {
  v = wave_max(v);
  int nw = blockDim.x >> 6;
  __syncthreads();
  if ((threadIdx.x & 63) == 0) sh[threadIdx.x >> 6] = v;
  __syncthreads();
  float m = sh[0];
  for (int k = 1; k < nw; k++) m = fmaxf(m, sh[k]);
  return m;
}
__device__ __forceinline__ float gelu_f(float x) {
  return 0.5f * x * (1.f + erff(x * 0.70710678118654752f));
}
__device__ __forceinline__ u16 f2bf(float x) {  // round-to-nearest-even bf16
  u32 u = __float_as_uint(x);
  return (u16)((u + 0x7FFFu + ((u >> 16) & 1u)) >> 16);
}
__device__ __forceinline__ float bf2f(u16 h) { return __uint_as_float(((u32)h) << 16); }
__device__ __forceinline__ void split2(float v, u16* ph, u16* pl) {
  u16 h = f2bf(v);
  *ph = h;
  *pl = f2bf(v - bf2f(h));
}

// ================= graph build (merged RWSE-CSR + GAT edge lists) =========
__global__ void build_graph(const int* __restrict__ ei, u32* __restrict__ bits,
                            int* __restrict__ scnt, int* __restrict__ slist,
                            int* __restrict__ cnt, int* __restrict__ elist) {
  int e = blockIdx.x * 256 + threadIdx.x;
  if (e < EDGES) {
    int s = ei[e], d = ei[EDGES + e];
    u32 m = 1u << (d & 31);
    u32 old = atomicOr(&bits[s * 64 + (d >> 5)], m);
    if (!(old & m)) {
      int p = atomicAdd(&scnt[s], 1);
      if (p < SCAP) slist[s * SCAP + p] = d;
    }
    int p2 = atomicAdd(&cnt[d], 1);
    if (p2 < ECAP) elist[(size_t)d * ECAP + p2] = e;
  } else if (e < EDGES + NODES) {
    int d = e - EDGES;
    int p = atomicAdd(&cnt[d], 1);
    if (p < ECAP) elist[(size_t)d * ECAP + p] = e;
  }
}

// ================= RWSE (sparse path) =================
// P2 = T@T; also extracts diag(P2) -> rwse col 1
__global__ __launch_bounds__(256) void spmm_sq(const int* __restrict__ scnt,
                                               const int* __restrict__ slist,
                                               float* __restrict__ P2,
                                               float* __restrict__ rwse) {
  int i = blockIdx.x, t = threadIdx.x;
  __shared__ float row[NODES];
  for (int c = t; c < NODES; c += 256) row[c] = 0.f;
  __syncthreads();
  int di = min(scnt[i], SCAP);
  float wi = di > 0 ? 1.f / (float)di : 0.f;
  for (int jj = 0; jj < di; jj++) {
    int j = slist[i * SCAP + jj];
    int dj = min(scnt[j], SCAP);
    if (dj == 0) continue;
    float w = wi / (float)dj;
    for (int kk = t; kk < dj; kk += 256) atomicAdd(&row[slist[j * SCAP + kk]], w);
  }
  __syncthreads();
  for (int c = t; c < NODES; c += 256) {
    float v = row[c];
    P2[(size_t)i * NODES + c] = v;
    if (c == i) rwse[(size_t)i * 8 + 1] = v;
  }
}

// Q = T @ P; also extracts diag(Q) -> rwse col
__global__ __launch_bounds__(256) void spmm_gather(const int* __restrict__ scnt,
                                                   const int* __restrict__ slist,
                                                   const float* __restrict__ P,
                                                   float* __restrict__ Q,
                                                   float* __restrict__ rwse, int col) {
  int i = blockIdx.x, t = threadIdx.x;
  __shared__ int nb[SCAP];
  int di = min(scnt[i], SCAP);
  for (int c = t; c < di; c += 256) nb[c] = slist[i * SCAP + c];
  __syncthreads();
  float wi = di > 0 ? 1.f / (float)di : 0.f;
  for (int c = t; c < NODES; c += 256) {
    float s = 0.f;
    for (int jj = 0; jj < di; jj++) s += P[(size_t)nb[jj] * NODES + c];
    float v = s * wi;
    Q[(size_t)i * NODES + c] = v;
    if (c == i) rwse[(size_t)i * 8 + col] = v;
  }
}

// fused diag dots, tiled+coalesced
__global__ __launch_bounds__(256) void diag_tiled(const float* __restrict__ P2,
                                                  const float* __restrict__ P3,
                                                  const float* __restrict__ P4,
                                                  float* __restrict__ pbuf) {
  __shared__ float r2[64][65], r3[64][65], r4[64][65], c3[64][65], c4[64][65];
  __shared__ float red[4][4][64];
  int t = threadIdx.x;
  int i0 = blockIdx.x * 64;
  int js = blockIdx.y;
  int lo = t & 63, hi = t >> 6;
  float d5 = 0, d6 = 0, d7 = 0, d8 = 0;
  for (int jc = 0; jc < 4; jc++) {
    int j0 = js * 256 + jc * 64;
    __syncthreads();
#pragma unroll
    for (int r = 0; r < 16; r++) {
      int a = hi * 16 + r;
      r2[a][lo] = P2[(size_t)(i0 + a) * NODES + j0 + lo];
      r3[a][lo] = P3[(size_t)(i0 + a) * NODES + j0 + lo];
      r4[a][lo] = P4[(size_t)(i0 + a) * NODES + j0 + lo];
      c3[a][lo] = P3[(size_t)(j0 + a) * NODES + i0 + lo];
      c4[a][lo] = P4[(size_t)(j0 + a) * NODES + i0 + lo];
    }
    __syncthreads();
#pragma unroll
    for (int r = 0; r < 16; r++) {
      int jj = hi * 16 + r;
      float p3c = c3[jj][lo], p4c = c4[jj][lo];
      d5 += r2[lo][jj] * p3c;
      d6 += r3[lo][jj] * p3c;
      d7 += r3[lo][jj] * p4c;
      d8 += r4[lo][jj] * p4c;
    }
  }
  red[0][hi][lo] = d5; red[1][hi][lo] = d6; red[2][hi][lo] = d7; red[3][hi][lo] = d8;
  __syncthreads();
  if (hi == 0) {
    int i = i0 + lo;
#pragma unroll
    for (int v = 0; v < 4; v++) {
      float s = red[v][0][lo] + red[v][1][lo] + red[v][2][lo] + red[v][3][lo];
      pbuf[((size_t)js * NODES + i) * 4 + v] = s;
    }
  }
}

// reduce diag-dot partials -> rwse cols 4..7; also diag(T) -> col 0
__global__ void diag_reduce(const float* __restrict__ pbuf,
                            const u32* __restrict__ bits,
                            const int* __restrict__ scnt,
                            float* __restrict__ rwse) {
  int i = blockIdx.x * 256 + threadIdx.x;
  if (i >= NODES) return;
  int deg = min(scnt[i], SCAP);
  int self = (bits[i * 64 + (i >> 5)] >> (i & 31)) & 1;
  rwse[(size_t)i * 8 + 0] = (self && deg > 0) ? 1.f / (float)deg : 0.f;
#pragma unroll
  for (int v = 0; v < 4; v++) {
    float s = 0.f;
    for (int js = 0; js < 8; js++) s += pbuf[((size_t)js * NODES + i) * 4 + v];
    rwse[(size_t)i * 8 + 4 + v] = s;
  }
}

// ================= fp32 -> split-bf16 helpers =================
__device__ __forceinline__ void splitA8(const float* __restrict__ p, short8& h8,
                                        short8& l8) {
  float4 v0 = *(const float4*)p;
  float4 v1 = *(const float4*)(p + 4);
  float v[8] = {v0.x, v0.y, v0.z, v0.w, v1.x, v1.y, v1.z, v1.w};
#pragma unroll
  for (int i = 0; i < 8; i++) {
    u16 h = f2bf(v[i]);
    h8[i] = (short)h;
    l8[i] = (short)f2bf(v[i] - bf2f(h));
  }
}

__global__ void conv_split(const float* __restrict__ src, u16* __restrict__ Ah,
                           u16* __restrict__ Al, int total8, int Ksrc,
                           int dstStride, int colOff) {
  int u = blockIdx.x * 256 + threadIdx.x;
  if (u >= total8) return;
  int idx = u * 8;
  int m = idx / Ksrc, k = idx - m * Ksrc;
  short8 h8, l8;
  splitA8(src + idx, h8, l8);
  size_t o = (size_t)m * dstStride + colOff + k;
  *(short8*)(Ah + o) = h8;
  *(short8*)(Al + o) = l8;
}

// ================= weight packing: unit-vectorized =================
struct PackArgs {
  const float* src[13];
  u64 offU[13];
  u64 cumU[14];
  int N[13];
  int srcStride[13];
  int gnTot[13];
  int ntOff[13];
};

__global__ __launch_bounds__(256) void pack_all(PackArgs pa, u16* __restrict__ Bh,
                                                u16* __restrict__ Bl) {
  u64 total = pa.cumU[13];
  for (u64 u = (u64)blockIdx.x * 256 + threadIdx.x; u < total;
       u += (u64)gridDim.x * 256) {
    int s = 0;
    while (u >= pa.cumU[s + 1]) s++;
    u64 ur = u - pa.cumU[s];
    int lr = (int)(ur & 15);
    int g = (int)((ur >> 4) & 3);
    int ks = (int)((ur >> 6) & 1);
    int j = (int)((ur >> 7) & 3);
    u64 rest = ur >> 9;
    int Nseg = pa.N[s] >> 6;
    int nt = (int)(rest % (u32)Nseg);
    int ktile = (int)(rest / (u32)Nseg);
    int k0 = (ktile << 6) | (ks << 5) | (g << 3);
    int n = (nt << 6) | (j << 4) | lr;
    const float* src = pa.src[s];
    int stride = pa.srcStride[s];
    u64 fiU = pa.offU[s] +
              ((((u64)ktile * pa.gnTot[s] + pa.ntOff[s] + nt) * 8 + j * 2 + ks) * 64 +
               g * 16 + lr);
    short8 h8, l8;
#pragma unroll
    for (int e = 0; e < 8; e++) {
      float v = src[(size_t)(k0 + e) * stride + n];
      u16 h = f2bf(v);
      h8[e] = (short)h;
      l8[e] = (short)f2bf(v - bf2f(h));
    }
    *((short8*)Bh + fiU) = h8;
    *((short8*)Bl + fiU) = l8;
  }
}

// ========== split-bf16 MFMA GEMM, pre-split u16 A, split-K, row gather =====
__global__ __launch_bounds__(256) void gemm_s(
    const u16* __restrict__ Ahg, const u16* __restrict__ Alg, int lda,
    const u16* __restrict__ Bh, const u16* __restrict__ Bl,
    float* __restrict__ C, u16* __restrict__ Ch, u16* __restrict__ Cl,
    const float* __restrict__ bias,
    int M, int K, int N, int act, int Kslice, float* __restrict__ part,
    const int* __restrict__ rowmap) {
  __shared__ __align__(16) u16 LA[2][4096];
  __shared__ __align__(16) u16 LB[2][4096];
  int gn = N >> 6;
  int nwg = (M >> 6) * gn;
  int q = nwg >> 3;
  int flat = blockIdx.x;
  int virt = (flat & 7) * q + (flat >> 3);     // bijective XCD-contiguous remap
  int bm = (virt / gn) << 6, bn = (virt % gn) << 6;
  int kb = blockIdx.y;
  int kstart = kb * Kslice;
  int kend = min(K, kstart + Kslice);
  int t = threadIdx.x;
  int lane = t & 63, w = t >> 6;
  int wm = (w >> 1) << 5, wn = (w & 1) << 5;
  int r0 = t >> 3, r1 = r0 + 32;
  int c8 = (t & 7) << 3;
  int ks_s = (t >> 2) & 1, g_s = t & 3;
  int slotA = (((r0 & 15) + (g_s << 4)) ^ (g_s | (ks_s << 2)));
  int da0 = ((((r0 >> 4) << 1) + ks_s) << 9) + (slotA << 3);
  int da1 = ((((r1 >> 4) << 1) + ks_s) << 9) + (slotA << 3);
  int db0 = t * 8, db1 = (t + 256) * 8;
  size_t btile = ((size_t)(kstart >> 6) * gn + (bn >> 6)) * 4096;
  size_t bstep = (size_t)gn * 4096;

  int rrow0 = bm + r0, rrow1 = bm + r1;
  if (rowmap) { rrow0 = rowmap[rrow0]; rrow1 = rowmap[rrow1]; }
  size_t aoff0 = (size_t)rrow0 * lda + c8;
  size_t aoff1 = (size_t)rrow1 * lda + c8;

  short8 pah0, pal0, pah1, pal1, pbh0, pbl0, pbh1, pbl1;
  pah0 = *(const short8*)(Ahg + aoff0 + kstart);
  pal0 = *(const short8*)(Alg + aoff0 + kstart);
  pah1 = *(const short8*)(Ahg + aoff1 + kstart);
  pal1 = *(const short8*)(Alg + aoff1 + kstart);
  pbh0 = *(const short8*)(Bh + btile + db0);
  pbl0 = *(const short8*)(Bl + btile + db0);
  pbh1 = *(const short8*)(Bh + btile + db1);
  pbl1 = *(const short8*)(Bl + btile + db1);

  f32x4 acc[2][2] = {};
  int lr = lane & 15, lg = lane >> 4;
  int rboff = lane << 3;

  for (int kt = kstart; kt < kend; kt += 64) {
    __syncthreads();
    *(short8*)&LA[0][da0] = pah0;
    *(short8*)&LA[1][da0] = pal0;
    *(short8*)&LA[0][da1] = pah1;
    *(short8*)&LA[1][da1] = pal1;
    *(short8*)&LB[0][db0] = pbh0;
    *(short8*)&LB[1][db0] = pbl0;
    *(short8*)&LB[0][db1] = pbh1;
    *(short8*)&LB[1][db1] = pbl1;
    __syncthreads();
    if (kt + 64 < kend) {
      btile += bstep;
      int kn = kt + 64;
      pah0 = *(const short8*)(Ahg + aoff0 + kn);
      pal0 = *(const short8*)(Alg + aoff0 + kn);
      pah1 = *(const short8*)(Ahg + aoff1 + kn);
      pal1 = *(const short8*)(Alg + aoff1 + kn);
      pbh0 = *(const short8*)(Bh + btile + db0);
      pbl0 = *(const short8*)(Bl + btile + db0);
      pbh1 = *(const short8*)(Bh + btile + db1);
      pbl1 = *(const short8*)(Bl + btile + db1);
    }
#pragma unroll
    for (int ks = 0; ks < 2; ks++) {
      short8 ah[2], al[2], bh[2], bl[2];
      int slr = ((lr + (lg << 4)) ^ (lg | (ks << 2))) << 3;
#pragma unroll
      for (int i = 0; i < 2; i++) {
        int ba = ((((wm >> 4) + i) * 2 + ks) << 9) + slr;
        ah[i] = *(const short8*)&LA[0][ba];
        al[i] = *(const short8*)&LA[1][ba];
        int bb = ((((wn >> 4) + i) * 2 + ks) << 9) + rboff;
        bh[i] = *(const short8*)&LB[0][bb];
        bl[i] = *(const short8*)&LB[1][bb];
      }
#pragma unroll
      for (int i = 0; i < 2; i++)
#pragma unroll
        for (int j = 0; j < 2; j++) {
          acc[i][j] = __builtin_amdgcn_mfma_f32_16x16x32_bf16(ah[i], bh[j], acc[i][j], 0, 0, 0);
          acc[i][j] = __builtin_amdgcn_mfma_f32_16x16x32_bf16(ah[i], bl[j], acc[i][j], 0, 0, 0);
          acc[i][j] = __builtin_amdgcn_mfma_f32_16x16x32_bf16(al[i], bh[j], acc[i][j], 0, 0, 0);
        }
    }
  }
  int row0 = (lane >> 4) * 4;
  if (part) {
    size_t pbase = (size_t)kb * (size_t)M * N;
#pragma unroll
    for (int i = 0; i < 2; i++)
#pragma unroll
      for (int j = 0; j < 2; j++) {
        int n = bn + wn + j * 16 + lr;
#pragma unroll
        for (int r = 0; r < 4; r++) {
          int m = bm + wm + i * 16 + row0 + r;
          part[pbase + (size_t)m * N + n] = acc[i][j][r];
        }
      }
    return;
  }
#pragma unroll
  for (int i = 0; i < 2; i++)
#pragma unroll
    for (int j = 0; j < 2; j++) {
      int n = bn + wn + j * 16 + lr;
      float bv = bias ? bias[n] : 0.f;
#pragma unroll
      for (int r = 0; r < 4; r++) {
        int m = bm + wm + i * 16 + row0 + r;
        float v = acc[i][j][r] + bv;
        if (act) v = gelu_f(v);
        size_t o = (size_t)m * N + n;
        if (Ch) {
          split2(v, Ch + o, Cl + o);
          if (C) C[o] = v;
        } else {
          C[o] = v;
        }
      }
    }
}

// ================= small fused kernels =================
__global__ __launch_bounds__(128) void rwse_proj(const float* __restrict__ rwse,
                                                 const float* __restrict__ W,
                                                 const float* __restrict__ bb,
                                                 const float* __restrict__ g,
                                                 const float* __restrict__ bt,
                                                 u16* __restrict__ Axh,
                                                 u16* __restrict__ Axl) {
  int i = blockIdx.x, j = threadIdx.x;
  float s = bb[j];
#pragma unroll
  for (int k = 0; k < 8; k++) s += rwse[(size_t)i * 8 + k] * W[k * H4C + j];
  __shared__ float sh[8];
  float sum = blk_sum(s, sh);
  float mu = sum * (1.f / 128.f);
  float d = s - mu;
  float var = blk_sum(d * d, sh) * (1.f / 128.f);
  float val = gelu_f(d * rsqrtf(var + 1e-5f) * g[j] + bt[j]);
  size_t o = (size_t)i * 4224 + 4096 + j;
  split2(val, Axh + o, Axl + o);
}

__global__ __launch_bounds__(256) void ln512(const float* __restrict__ x, int sk,
                                             int M,
                                             const float* __restrict__ gbias,
                                             const float* __restrict__ res,
                                             const float* __restrict__ mix,
                                             const float* __restrict__ ap, int l,
                                             const float* __restrict__ g,
                                             const float* __restrict__ b,
                                             float* __restrict__ y,
                                             u16* __restrict__ yh,
                                             u16* __restrict__ yl, int do_gelu) {
  const size_t MN = (size_t)M * 512;
  int i = blockIdx.x, t = threadIdx.x;
  size_t base = (size_t)i * 512;
  float v0 = x[base + t], v1 = x[base + 256 + t];
  for (int s = 1; s < sk; s++) {
    v0 += x[(size_t)s * MN + base + t];
    v1 += x[(size_t)s * MN + base + 256 + t];
  }
  if (gbias) { v0 += gbias[t]; v1 += gbias[t + 256]; }
  if (res) { v0 += res[base + t]; v1 += res[base + 256 + t]; }
  __shared__ float sh[8];
  float s = blk_sum(v0 + v1, sh);
  float mu = s * (1.f / 512.f);
  float d0 = v0 - mu, d1 = v1 - mu;
  float var = blk_sum(d0 * d0 + d1 * d1, sh) * (1.f / 512.f);
  float rstd = rsqrtf(var + 1e-5f);
  float o0 = d0 * rstd * g[t] + b[t];
  float o1 = d1 * rstd * g[t + 256] + b[t + 256];
  if (do_gelu) { o0 = gelu_f(o0); o1 = gelu_f(o1); }
  if (mix) {
    float a = 1.f / (1.f + expf(-ap[l]));
    o0 = a * mix[base + t] + (1.f - a) * o0;
    o1 = a * mix[base + 256 + t] + (1.f - a) * o1;
  }
  if (y) { y[base + t] = o0; y[base + 256 + t] = o1; }
  if (yh) {
    split2(o0, yh + base + t, yl + base + t);
    split2(o1, yh + base + 256 + t, yl + base + 256 + t);
  }
}

__global__ void build_cbias(const float* __restrict__ bl, const float* __restrict__ br,
                            const float* __restrict__ inb, float* __restrict__ cb) {
  int i = blockIdx.x * 256 + threadIdx.x;
  if (i >= QS) return;
  cb[i] = i < 512 ? bl[i] : (i < 1024 ? br[i - 512] : inb[i - 1024]);
}

__global__ void build_rowmap(const int* __restrict__ cni, const int* __restrict__ cnt,
                             const int* __restrict__ elist, const int* __restrict__ ei,
                             int* __restrict__ rowmap) {
  int t = blockIdx.x * 256 + threadIdx.x;
  if (t >= NC) return;
  int i = cni[0];
  if (t < 256) {
    rowmap[t] = ((i >> 8) << 8) + t;
  } else {
    int p = t - 256;
    int m = min(cnt[i], ECAP);
    int v = 0;
    if (p < m) {
      int eid = elist[(size_t)i * ECAP + p];
      v = eid < EDGES ? ei[eid] : i;
    }
    rowmap[t] = v;
  }
}

__global__ void ea_reduce(const float* __restrict__ ea, float* __restrict__ sums) {
  int tid = blockIdx.x * blockDim.x + threadIdx.x;
  int stride = gridDim.x * blockDim.x;
  float s0 = 0.f, s1 = 0.f;
  for (int e = tid; e < EDGES; e += stride) { s0 += ea[2 * e]; s1 += ea[2 * e + 1]; }
  s0 = wave_sum(s0);
  s1 = wave_sum(s1);
  if ((threadIdx.x & 63) == 0) { atomicAdd(&sums[0], s0); atomicAdd(&sums[1], s1); }
}

// layer-0 GAT at rowmap'd dst nodes, fused LN(n1)
__global__ __launch_bounds__(512) void gat_kernel(
    const float* __restrict__ hb, const int* __restrict__ rowmap,
    const float* __restrict__ eattr, const float* __restrict__ easum,
    const float* __restrict__ We, const float* __restrict__ att,
    const float* __restrict__ bias, const int* __restrict__ cnt,
    const int* __restrict__ elist, const int* __restrict__ ei,
    const float* __restrict__ n1g, const float* __restrict__ n1b,
    float* __restrict__ out) {
  int i = rowmap[blockIdx.x];
  int tid = threadIdx.x;
  int h = tid >> 6, c = tid & 63;
  int m_cnt = cnt[i];
  if (m_cnt > ECAP) m_cnt = ECAP;
  const float inv_e = 1.f / (float)EDGES;
  float we0 = We[tid], we1 = We[512 + tid];
  float attv = att[tid];
  float xrv = hb[(size_t)i * QS + 512 + tid];
  float ea_m0 = easum[0] * inv_e, ea_m1 = easum[1] * inv_e;
  __shared__ float logits[NHEAD][ECAP];
  __shared__ float sh[8];
  const int* el = elist + (size_t)i * ECAP;
  for (int e = 0; e < m_cnt; e++) {
    int eid = el[e];
    int s;
    float a0, a1;
    if (eid < EDGES) { s = ei[eid]; a0 = eattr[2 * eid]; a1 = eattr[2 * eid + 1]; }
    else { s = i; a0 = ea_m0; a1 = ea_m1; }
    float mval = hb[(size_t)s * QS + tid] + xrv + a0 * we0 + a1 * we1;
    mval = mval > 0.f ? mval : 0.2f * mval;
    float lg = wave_sum(mval * attv);
    if (c == 0) logits[h][e] = lg;
  }
  float mx = -1e30f;
  for (int e = c; e < m_cnt; e += 64) mx = fmaxf(mx, logits[h][e]);
  mx = wave_max(mx);
  float den = 0.f;
  for (int e = c; e < m_cnt; e += 64) den += expf(logits[h][e] - mx);
  den = wave_sum(den) + 1e-16f;
  float acc = 0.f;
  for (int e = 0; e < m_cnt; e++) {
    int eid = el[e];
    int s = eid < EDGES ? ei[eid] : i;
    float alpha = expf(logits[h][e] - mx) / den;
    acc += alpha * hb[(size_t)s * QS + tid];
  }
  float v = acc + bias[tid];
  float mu = blk_sum(v, sh) * (1.f / 512.f);
  float d = v - mu;
  float var = blk_sum(d * d, sh) * (1.f / 512.f);
  out[(size_t)blockIdx.x * 512 + tid] = d * rsqrtf(var + 1e-5f) * n1g[tid] + n1b[tid];
}

// ======= MFMA block-diag MHA (layer 0); outputs split u16 =======
__global__ __launch_bounds__(256) void mha_mfma(const float* __restrict__ qkv,
                                                u16* __restrict__ attOh,
                                                u16* __restrict__ attOl) {
  __shared__ __align__(16) u16 Ksh[2][256][72];
  __shared__ __align__(16) u16 Vt[2][64][264];
  int bid = blockIdx.x;
  int qq = bid & 3;
  int h = (bid >> 2) & 7;
  int b = bid >> 5;
  int t = threadIdx.x;
  int lane = t & 63, w = t >> 6;
  int lr = lane & 15, g = lane >> 4, kk = g * 8;
  size_t rowbase = (size_t)(b * SG) * QS;
  const float* Kbase = qkv + rowbase + 512 + h * 64;
  const float* Vbase = qkv + rowbase + 1024 + h * 64;
  for (int idx = t; idx < SG * 64; idx += 256) {
    int j = idx >> 6, c = idx & 63;
    float kv = Kbase[(size_t)j * QS + c];
    u16 khh = f2bf(kv);
    Ksh[0][j][c] = khh;
    Ksh[1][j][c] = f2bf(kv - bf2f(khh));
    float vv = Vbase[(size_t)j * QS + c];
    u16 vhh = f2bf(vv);
    Vt[0][c][j] = vhh;
    Vt[1][c][j] = f2bf(vv - bf2f(vhh));
  }
  const float* Qrow = qkv + rowbase + (size_t)(qq * 64 + w * 16 + lr) * QS + h * 64;
  short8 qh[2], ql[2];
#pragma unroll
  for (int kt = 0; kt < 2; kt++) {
    float qv[8];
    *(float4*)&qv[0] = *(const float4*)&Qrow[kt * 32 + kk];
    *(float4*)&qv[4] = *(const float4*)&Qrow[kt * 32 + kk + 4];
#pragma unroll
    for (int i = 0; i < 8; i++) {
      u16 hh = f2bf(qv[i]);
      qh[kt][i] = hh;
      ql[kt][i] = f2bf(qv[i] - bf2f(hh));
    }
  }
  __syncthreads();
  f32x4 S[16];
#pragma unroll
  for (int j = 0; j < 16; j++) {
    f32x4 acc = {};
#pragma unroll
    for (int kt = 0; kt < 2; kt++) {
      short8 bh = *(const short8*)&Ksh[0][j * 16 + lr][kt * 32 + kk];
      short8 bl = *(const short8*)&Ksh[1][j * 16 + lr][kt * 32 + kk];
      acc = __builtin_amdgcn_mfma_f32_16x16x32_bf16(qh[kt], bh, acc, 0, 0, 0);
      acc = __builtin_amdgcn_mfma_f32_16x16x32_bf16(qh[kt], bl, acc, 0, 0, 0);
      acc = __builtin_amdgcn_mfma_f32_16x16x32_bf16(ql[kt], bh, acc, 0, 0, 0);
    }
    S[j] = acc;
  }
  float mx[4], inv[4];
#pragma unroll
  for (int r = 0; r < 4; r++) {
    float m = S[0][r];
#pragma unroll
    for (int j = 1; j < 16; j++) m = fmaxf(m, S[j][r]);
#pragma unroll
    for (int oo = 1; oo < 16; oo <<= 1) m = fmaxf(m, __shfl_xor(m, oo));
    mx[r] = m;
    float d = 0.f;
#pragma unroll
    for (int j = 0; j < 16; j++) d += __expf((S[j][r] - m) * 0.125f);
#pragma unroll
    for (int oo = 1; oo < 16; oo <<= 1) d += __shfl_xor(d, oo);
    inv[r] = 1.f / d;
  }
  __syncthreads();
  u16* Pb = &Ksh[0][0][0];
  int row0 = w * 16 + g * 4;
#pragma unroll
  for (int j = 0; j < 16; j++) {
    int key = j * 16 + lr;
#pragma unroll
    for (int r = 0; r < 4; r++) {
      float p = __expf((S[j][r] - mx[r]) * 0.125f) * inv[r];
      u16 hh = f2bf(p);
      Pb[(row0 + r) * 264 + key] = hh;
      Pb[16896 + (row0 + r) * 264 + key] = f2bf(p - bf2f(hh));
    }
  }
  __syncthreads();
  f32x4 Oacc[4] = {};
#pragma unroll
  for (int kt = 0; kt < 8; kt++) {
    short8 pah = *(const short8*)&Pb[(w * 16 + lr) * 264 + kt * 32 + kk];
    short8 pal = *(const short8*)&Pb[16896 + (w * 16 + lr) * 264 + kt * 32 + kk];
#pragma unroll
    for (int nf = 0; nf < 4; nf++) {
      short8 vh = *(const short8*)&Vt[0][nf * 16 + lr][kt * 32 + kk];
      short8 vl = *(const short8*)&Vt[1][nf * 16 + lr][kt * 32 + kk];
      Oacc[nf] = __builtin_amdgcn_mfma_f32_16x16x32_bf16(pah, vh, Oacc[nf], 0, 0, 0);
      Oacc[nf] = __builtin_amdgcn_mfma_f32_16x16x32_bf16(pah, vl, Oacc[nf], 0, 0, 0);
      Oacc[nf] = __builtin_amdgcn_mfma_f32_16x16x32_bf16(pal, vh, Oacc[nf], 0, 0, 0);
    }
  }
  size_t obase = (size_t)(b * SG + qq * 64 + w * 16 + g * 4) * 512 + h * 64;
#pragma unroll
  for (int nf = 0; nf < 4; nf++)
#pragma unroll
    for (int r = 0; r < 4; r++) {
      size_t o = obase + (size_t)r * 512 + nf * 16 + lr;
      split2(Oacc[nf][r], attOh + o, attOl + o);
    }
}

// ================= layer-2 pruned path (row cni only) =================
__global__ __launch_bounds__(256) void gemv_part(
    const float* __restrict__ inrow, const int* __restrict__ cni, int rowMask,
    int rowStride, const float* __restrict__ W, int ldW, int N,
    float* __restrict__ part) {
  __shared__ float xv[64];
  __shared__ float red[4][64];
  int t = threadIdx.x;
  int kb = blockIdx.y;
  const float* xr = inrow + (cni ? (size_t)(cni[0] & rowMask) * rowStride : 0) + kb * 64;
  if (t < 64) xv[t] = xr[t];
  __syncthreads();
  int nl = t & 63;
  int n = blockIdx.x * 64 + nl;
  int seg = t >> 6;
  float acc = 0.f;
  const float* Wp = W + (size_t)(kb * 64 + seg * 16) * ldW + n;
#pragma unroll
  for (int k = 0; k < 16; k++) acc += xv[seg * 16 + k] * Wp[(size_t)k * ldW];
  red[seg][nl] = acc;
  __syncthreads();
  if (t < 64) {
    part[(size_t)kb * N + blockIdx.x * 64 + t] =
        red[0][t] + red[1][t] + red[2][t] + red[3][t];
  }
}

// merged q/xr GEMV: blocks 0-7 -> q cols (inW, ld 1536), 8-15 -> xr (Wr, ld 512)
// part layout: [kb][1024] with q at 0..511, xr at 512..1023
__global__ __launch_bounds__(256) void gemv_qxr(
    const float* __restrict__ h1c, const int* __restrict__ cni,
    const float* __restrict__ inW, const float* __restrict__ Wr,
    float* __restrict__ part) {
  __shared__ float xv[64];
  __shared__ float red[4][64];
  int t = threadIdx.x;
  int kb = blockIdx.y;
  const float* xr = h1c + (size_t)(cni[0] & 255) * 512 + kb * 64;
  if (t < 64) xv[t] = xr[t];
  __syncthreads();
  int b = blockIdx.x;
  int isq = b < 8;
  int nl = t & 63;
  int n = (b & 7) * 64 + nl;
  int seg = t >> 6;
  const float* W = isq ? inW : Wr;
  int ldW = isq ? 1536 : 512;
  float acc = 0.f;
  const float* Wp = W + (size_t)(kb * 64 + seg * 16) * ldW + n;
#pragma unroll
  for (int k = 0; k < 16; k++) acc += xv[seg * 16 + k] * Wp[(size_t)k * ldW];
  red[seg][nl] = acc;
  __syncthreads();
  if (t < 64) {
    part[(size_t)kb * 1024 + (isq ? 0 : 512) + (b & 7) * 64 + t] =
        red[0][t] + red[1][t] + red[2][t] + red[3][t];
  }
}

// reduce merged q/xr partials: n<512 -> qrow (+inb), else xrrow (+br)
__global__ void reduce_qxr(const float* __restrict__ part,
                           const float* __restrict__ inb,
                           const float* __restrict__ br,
                           float* __restrict__ qrow, float* __restrict__ xrrow) {
  int n = blockIdx.x * 256 + threadIdx.x;
  float s = n < 512 ? inb[n] : br[n - 512];
  for (int k = 0; k < 8; k++) s += part[(size_t)k * 1024 + n];
  if (n < 512) qrow[n] = s;
  else xrrow[n - 512] = s;
}

__global__ void row_reduce(const float* __restrict__ part, int KB, int N,
                           const float* __restrict__ bias,
                           float* __restrict__ out, int act) {
  int n = blockIdx.x * 256 + threadIdx.x;
  if (n >= N) return;
  float s = bias[n];
  for (int k = 0; k < KB; k++) s += part[(size_t)k * N + n];
  if (act) s = gelu_f(s);
  out[n] = s;
}

// GAT at node cni, xl from COMPACT buffer (edge p -> row 256+p), fused LN(n1)
__global__ __launch_bounds__(512) void gat_l2(
    const float* __restrict__ xlc, const float* __restrict__ xrrow,
    const int* __restrict__ cni,
    const float* __restrict__ eattr, const float* __restrict__ easum,
    const float* __restrict__ We, const float* __restrict__ att,
    const float* __restrict__ bias, const int* __restrict__ cnt,
    const int* __restrict__ elist,
    const float* __restrict__ n1g, const float* __restrict__ n1b,
    float* __restrict__ local_row) {
  int i = cni[0];
  int tid = threadIdx.x;
  int h = tid >> 6, c = tid & 63;
  int m_cnt = cnt[i];
  if (m_cnt > ECAP) m_cnt = ECAP;
  const float inv_e = 1.f / (float)EDGES;
  float we0 = We[tid], we1 = We[512 + tid];
  float attv = att[tid];
  float xrv = xrrow[tid];
  float ea_m0 = easum[0] * inv_e, ea_m1 = easum[1] * inv_e;
  __shared__ float logits[NHEAD][ECAP];
  __shared__ float sh[8];
  const int* el = elist + (size_t)i * ECAP;
  for (int e = 0; e < m_cnt; e++) {
    int eid = el[e];
    float a0, a1;
    if (eid < EDGES) { a0 = eattr[2 * eid]; a1 = eattr[2 * eid + 1]; }
    else { a0 = ea_m0; a1 = ea_m1; }
    float mval = xlc[(size_t)(256 + e) * 512 + tid] + xrv + a0 * we0 + a1 * we1;
    mval = mval > 0.f ? mval : 0.2f * mval;
    float lg = wave_sum(mval * attv);
    if (c == 0) logits[h][e] = lg;
  }
  float mx = -1e30f;
  for (int e = c; e < m_cnt; e += 64) mx = fmaxf(mx, logits[h][e]);
  mx = wave_max(mx);
  float den = 0.f;
  for (int e = c; e < m_cnt; e += 64) den += expf(logits[h][e] - mx);
  den = wave_sum(den) + 1e-16f;
  float acc = 0.f;
  for (int e = 0; e < m_cnt; e++) {
    float alpha = expf(logits[h][e] - mx) / den;
    acc += alpha * xlc[(size_t)(256 + e) * 512 + tid];
  }
  float v = acc + bias[tid];
  float mu = blk_sum(v, sh) * (1.f / 512.f);
  float d = v - mu;
  float var = blk_sum(d * d, sh) * (1.f / 512.f);
  local_row[tid] = d * rsqrtf(var + 1e-5f) * n1g[tid] + n1b[tid];
}

// fused MHA for row cni: one block per head, 256 thr (thread = key)
__global__ __launch_bounds__(256) void mha_row(const float* __restrict__ qrow,
                                               const float* __restrict__ kv,
                                               float* __restrict__ attO_row) {
  __shared__ float q[64];
  __shared__ float p[SG];
  __shared__ float sh[8];
  __shared__ float red[4][64];
  int h = blockIdx.x, t = threadIdx.x;
  if (t < 64) q[t] = qrow[h * 64 + t];
  __syncthreads();
  const float* kr = kv + (size_t)t * 1024 + h * 64;
  float s = 0.f;
#pragma unroll 8
  for (int c2 = 0; c2 < 64; c2++) s += q[c2] * kr[c2];
  s *= 0.125f;
  float m = blk_max(s, sh);
  float e = __expf(s - m);
  p[t] = e;
  float den = blk_sum(e, sh);
  int c = t & 63, seg = t >> 6;
  float o = 0.f;
  for (int j = seg * 64; j < seg * 64 + 64; j++)
    o += p[j] * kv[(size_t)j * 1024 + 512 + h * 64 + c];
  red[seg][c] = o;
  __syncthreads();
  if (t < 64)
    attO_row[h * 64 + t] = (red[0][t] + red[1][t] + red[2][t] + red[3][t]) / den;
}

__global__ __launch_bounds__(512) void comb_l2(const float* __restrict__ part, int KB,
                                               const float* __restrict__ bias,
                                               const float* __restrict__ local_row,
                                               const float* __restrict__ ap, int l,
                                               const float* __restrict__ g,
                                               const float* __restrict__ b,
                                               float* __restrict__ comb_row) {
  __shared__ float sh[8];
  int t = threadIdx.x;
  float v = bias[t];
  for (int k = 0; k < KB; k++) v += part[(size_t)k * 512 + t];
  float mu = blk_sum(v, sh) * (1.f / 512.f);
  float d = v - mu;
  float var = blk_sum(d * d, sh) * (1.f / 512.f);
  float o = d * rsqrtf(var + 1e-5f) * g[t] + b[t];
  float a = 1.f / (1.f + expf(-ap[l]));
  comb_row[t] = a * local_row[t] + (1.f - a) * o;
}

__global__ __launch_bounds__(512) void final_l2(const float* __restrict__ part, int KB,
                                                const float* __restrict__ bias,
                                                const float* __restrict__ comb_row,
                                                const float* __restrict__ g,
                                                const float* __restrict__ b,
                                                float* __restrict__ hrow) {
  __shared__ float sh[8];
  int t = threadIdx.x;
  float v = bias[t] + comb_row[t];
  for (int k = 0; k < KB; k++) v += part[(size_t)k * 512 + t];
  float mu = blk_sum(v, sh) * (1.f / 512.f);
  float d = v - mu;
  float var = blk_sum(d * d, sh) * (1.f / 512.f);
  hrow[t] = d * rsqrtf(var + 1e-5f) * g[t] + b[t];
}

// head finish: reduce W1 partials + b1 -> LN -> gelu -> z; logits; softmax
__global__ __launch_bounds__(512) void head_finish(
    const float* __restrict__ part, int KB,
    const float* __restrict__ b1,
    const float* __restrict__ g, const float* __restrict__ bt,
    const float* __restrict__ W2, const float* __restrict__ b2,
    float* __restrict__ out) {
  __shared__ float sh[8];
  __shared__ float lg[ACT_N];
  int t = threadIdx.x;
  float v = b1[t];
  for (int k = 0; k < KB; k++) v += part[(size_t)k * 512 + t];
  float mu = blk_sum(v, sh) * (1.f / 512.f);
  float d = v - mu;
  float var = blk_sum(d * d, sh) * (1.f / 512.f);
  float z = gelu_f(d * rsqrtf(var + 1e-5f) * g[t] + bt[t]);
  for (int a = 0; a < ACT_N; a++) {
    float s = blk_sum(z * W2[t * ACT_N + a], sh);
    if (t == 0) lg[a] = s + b2[a];
  }
  __syncthreads();
  if (t == 0) {
    float m2 = lg[0];
    for (int a = 1; a < ACT_N; a++) m2 = fmaxf(m2, lg[a]);
    float den = 0.f;
    float ex[ACT_N];
    for (int a = 0; a < ACT_N; a++) { ex[a] = expf(lg[a] - m2); den += ex[a]; }
    for (int a = 0; a < ACT_N; a++) {
      out[a] = lg[a];
      out[ACT_N + a] = ex[a] / den;
    }
  }
}

extern "C" void kernel_launch(void* const* d_in, const int* in_sizes, int n_in,
                              void* d_out, int out_size, void* d_ws, size_t ws_size,
                              hipStream_t stream) {
  const float* x        = (const float*)d_in[0];
  const float* eattr    = (const float*)d_in[1];
  const float* rwse_W   = (const float*)d_in[2];
  const float* rwse_b   = (const float*)d_in[3];
  const float* rwse_g   = (const float*)d_in[4];
  const float* rwse_bt  = (const float*)d_in[5];
  const float* np_W     = (const float*)d_in[6];
  const float* np_b     = (const float*)d_in[7];
  const float* np_g     = (const float*)d_in[8];
  const float* np_bt    = (const float*)d_in[9];
  const float* gat_Wl   = (const float*)d_in[10];
  const float* gat_bl   = (const float*)d_in[11];
  const float* gat_Wr   = (const float*)d_in[12];
  const float* gat_br   = (const float*)d_in[13];
  const float* gat_We   = (const float*)d_in[14];
  const float* gat_att  = (const float*)d_in[15];
  const float* gat_bias = (const float*)d_in[16];
  const float* n1_g = (const float*)d_in[17];
  const float* n1_b = (const float*)d_in[18];
  const float* mha_inW  = (const float*)d_in[19];
  const float* mha_inb  = (const float*)d_in[20];
  const float* mha_outW = (const float*)d_in[21];
  const float* mha_outb = (const float*)d_in[22];
  const float* alpha_p  = (const float*)d_in[23];
  const float* n2_g = (const float*)d_in[24];
  const float* n2_b = (const float*)d_in[25];
  const float* ffn_W1 = (const float*)d_in[26];
  const float* ffn_b1 = (const float*)d_in[27];
  const float* ffn_W2 = (const float*)d_in[28];
  const float* ffn_b2 = (const float*)d_in[29];
  const float* n3_g = (const float*)d_in[30];
  const float* n3_b = (const float*)d_in[31];
  const float* ah_W1 = (const float*)d_in[32];
  const float* ah_b1 = (const float*)d_in[33];
  const float* ah_g  = (const float*)d_in[34];
  const float* ah_bt = (const float*)d_in[35];
  const float* ah_W2 = (const float*)d_in[36];
  const float* ah_b2 = (const float*)d_in[37];
  const int* edge_index = (const int*)d_in[38];
  const int* cni        = (const int*)d_in[39];
  (void)in_sizes; (void)n_in; (void)out_size; (void)ws_size;

  char* wsp = (char*)d_ws;
  size_t off = 0;
  auto alloc = [&](size_t bytes) -> char* {
    char* p = wsp + off;
    off += (bytes + 255) & ~(size_t)255;
    return p;
  };
  const size_t NNb = (size_t)NODES * NODES * 4;
  char* arena = alloc(3 * NNb);
  float* P2 = (float*)arena;
  float* P3 = (float*)(arena + NNb);
  float* P4 = (float*)(arena + 2 * NNb);
  u16* Axh = (u16*)arena;
  u16* Axl = (u16*)(arena + 17301504);
  float* hbig = (float*)arena;
  float* partC = (float*)(arena + 22020096);
  const u64 SEG_NP = 2162688ull;
  const u64 SEG_L0 = 3670016ull;
  const u64 L1_OFF = SEG_NP + SEG_L0;
  const u64 KV1_OFF = L1_OFF + 262144ull;
  const u64 PTOT = KV1_OFF + 524288ull;
  u16* Bh = (u16*)alloc(PTOT * 2);
  u16* Bl = (u16*)alloc(PTOT * 2);
  float* partNP = (float*)alloc((size_t)6 * NODES * 512 * 4);  // SK6, 25 MB
  float* rwse = (float*)alloc((size_t)NODES * 8 * 4);
  u16* h1h = (u16*)alloc((size_t)NODES * 512 * 2);
  u16* h1l = (u16*)alloc((size_t)NODES * 512 * 2);
  u16* attOh = (u16*)alloc((size_t)NODES * 512 * 2);
  u16* attOl = (u16*)alloc((size_t)NODES * 512 * 2);
  u16* combh = (u16*)alloc((size_t)NC * 512 * 2);
  u16* combl = (u16*)alloc((size_t)NC * 512 * 2);
  u16* ffmh = (u16*)alloc((size_t)NC * 2048 * 2);
  u16* ffml = (u16*)alloc((size_t)NC * 2048 * 2);
  u16* h1ch = (u16*)alloc((size_t)NC * 512 * 2);
  u16* h1cl = (u16*)alloc((size_t)NC * 512 * 2);
  float* h1c  = (float*)alloc((size_t)NC * 512 * 4);
  float* gout = (float*)alloc((size_t)NC * 512 * 4);     // l0 local; l1 xl
  float* comb = (float*)alloc((size_t)NC * 512 * 4);
  float* kvbuf = (float*)alloc((size_t)256 * 1024 * 4);
  float* cb   = (float*)alloc((size_t)QS * 4);
  float* rows = (float*)alloc(4096 * 4);
  float* pv1 = (float*)alloc((size_t)32 * 2048 * 4);
  // zero-init region: bits | scnt | cnt | easum (one memset)
  char* zbase = alloc((size_t)NODES * 64 * 4 + NODES * 4 + NODES * 4 + 256);
  u32* bits  = (u32*)zbase;
  int* scnt  = (int*)(zbase + (size_t)NODES * 64 * 4);
  int* cnt   = (int*)(zbase + (size_t)NODES * 64 * 4 + NODES * 4);
  float* easum = (float*)(zbase + (size_t)NODES * 64 * 4 + NODES * 8);
  size_t zbytes = (size_t)NODES * 64 * 4 + NODES * 8 + 256;
  int* slist = (int*)alloc((size_t)NODES * SCAP * 4);
  int* elist = (int*)alloc((size_t)NODES * ECAP * 4);
  int* rmap  = (int*)alloc((size_t)NC * 4);
  float* pbuf  = (float*)alloc((size_t)8 * NODES * 4 * 4);
  float* qrow = rows, *xrrow = rows + 512, *local_row = rows + 1024;
  float* attO_row = rows + 1536, *comb_row = rows + 2560;
  float* midrow = rows + 3072 - 1024;  // reuse region [2048..4096) carefully:
  // comb_row at 2560..3071; place midrow separately:
  float* midrow2 = (float*)alloc(2048 * 4);
  float* hrow = rows + 3584;

  // ---- graph build (single memset + merged kernel) ----
  hipMemsetAsync(zbase, 0, zbytes, stream);
  build_graph<<<(EDGES + NODES + 255) / 256, 256, 0, stream>>>(edge_index, bits,
                                                               scnt, slist, cnt,
                                                               elist);
  ea_reduce<<<64, 256, 0, stream>>>(eattr, easum);
  build_rowmap<<<2, 256, 0, stream>>>(cni, cnt, elist, edge_index, rmap);

  // ---- RWSE sparse path ----
  spmm_sq<<<NODES, 256, 0, stream>>>(scnt, slist, P2, rwse);
  spmm_gather<<<NODES, 256, 0, stream>>>(scnt, slist, P2, P3, rwse, 2);
  spmm_gather<<<NODES, 256, 0, stream>>>(scnt, slist, P3, P4, rwse, 3);
  diag_tiled<<<dim3(NODES / 64, 8), 256, 0, stream>>>(P2, P3, P4, pbuf);
  diag_reduce<<<NODES / 256, 256, 0, stream>>>(pbuf, bits, scnt, rwse);
  conv_split<<<NODES * DIN / 8 / 256, 256, 0, stream>>>(x, Axh, Axl,
                                                        NODES * DIN / 8, DIN, 4224, 0);
  rwse_proj<<<NODES, 128, 0, stream>>>(rwse, rwse_W, rwse_b, rwse_g, rwse_bt,
                                       Axh, Axl);

  // ---- pack weights ----
  PackArgs pa;
  u64 uc = 0;
  int si = 0;
  auto seg = [&](const float* src, int K, int N, int stride, u64 offElems,
                 int gnTot, int ntOff) {
    pa.src[si] = src; pa.offU[si] = offElems / 8; pa.cumU[si] = uc;
    pa.N[si] = N; pa.srcStride[si] = stride; pa.gnTot[si] = gnTot;
    pa.ntOff[si] = ntOff;
    uc += (u64)K * N / 8; si++;
  };
  seg(np_W, 4224, 512, 512, 0, 8, 0);
  seg(gat_Wl, 512, 512, 512, SEG_NP, 40, 0);
  seg(gat_Wr, 512, 512, 512, SEG_NP, 40, 8);
  seg(mha_inW, 512, 1536, 1536, SEG_NP, 40, 16);
  seg(mha_outW, 512, 512, 512, SEG_NP + 1310720, 8, 0);
  seg(ffn_W1, 512, 2048, 2048, SEG_NP + 1572864, 32, 0);
  seg(ffn_W2, 2048, 512, 512, SEG_NP + 2621440, 8, 0);
  seg(gat_Wl + 512 * 512, 512, 512, 512, L1_OFF, 8, 0);
  seg(mha_inW + 512 * 1536 + 512, 512, 1024, 1536, KV1_OFF, 16, 0);
  for (int s2 = si; s2 <= 13; s2++) pa.cumU[s2] = uc;
  pack_all<<<2048, 256, 0, stream>>>(pa, Bh, Bl);
  build_cbias<<<(QS + 255) / 256, 256, 0, stream>>>(gat_bl, gat_br, mha_inb, cb);

  // ---- np projection: SK6 ----
  gemm_s<<<dim3(256, 6), 256, 0, stream>>>(Axh, Axl, 4224, Bh, Bl,
                                           nullptr, nullptr, nullptr, nullptr,
                                           NODES, 4224, 512, 0, 704, partNP,
                                           nullptr);
  ln512<<<NODES, 256, 0, stream>>>(partNP, 6, NODES, np_b, nullptr, nullptr,
                                   nullptr, 0, np_g, np_bt, nullptr, h1h, h1l, 1);

  // ================= layer 0 (outputs pruned to NC compact rows) ===========
  {
    const u64 lb = SEG_NP;
    gemm_s<<<dim3(1280), 256, 0, stream>>>(h1h, h1l, 512, Bh + lb, Bl + lb,
                                           hbig, nullptr, nullptr, cb,
                                           NODES, 512, QS, 0, 512, nullptr,
                                           nullptr);
    gat_kernel<<<NC, 512, 0, stream>>>(hbig, rmap, eattr, easum, gat_We, gat_att,
                                       gat_bias, cnt, elist, edge_index,
                                       n1_g, n1_b, gout);
    mha_mfma<<<BG * NHEAD * 4, 256, 0, stream>>>(hbig + 1024, attOh, attOl);
    gemm_s<<<dim3(64, 2), 256, 0, stream>>>(attOh, attOl, 512, Bh + lb + 1310720,
                                            Bl + lb + 1310720, nullptr, nullptr,
                                            nullptr, nullptr, NC, 512, 512, 0, 256,
                                            partC, rmap);
    ln512<<<NC, 256, 0, stream>>>(partC, 2, NC, mha_outb, nullptr, gout, alpha_p,
                                  0, n2_g, n2_b, comb, combh, combl, 0);
    gemm_s<<<dim3(256), 256, 0, stream>>>(combh, combl, 512, Bh + lb + 1572864,
                                          Bl + lb + 1572864, nullptr, ffmh, ffml,
                                          ffn_b1, NC, 512, 2048, 1, 512, nullptr,
                                          nullptr);
    gemm_s<<<dim3(64, 4), 256, 0, stream>>>(ffmh, ffml, 2048, Bh + lb + 2621440,
                                            Bl + lb + 2621440, nullptr, nullptr,
                                            nullptr, nullptr, NC, 2048, 512, 0,
                                            512, partC, nullptr);
    ln512<<<NC, 256, 0, stream>>>(partC, 4, NC, ffn_b2, comb, nullptr, nullptr, 0,
                                  n3_g, n3_b, h1c, h1ch, h1cl, 0);
  }

  // ================= layer 1 (row cni; inputs from compact h1c) ============
  {
    float* xlc = gout;
    gemm_s<<<dim3(64), 256, 0, stream>>>(h1ch, h1cl, 512, Bh + L1_OFF, Bl + L1_OFF,
                                         xlc, nullptr, nullptr, gat_bl + 512,
                                         NC, 512, 512, 0, 512, nullptr, nullptr);
    gemm_s<<<dim3(64), 256, 0, stream>>>(h1ch, h1cl, 512, Bh + KV1_OFF, Bl + KV1_OFF,
                                         kvbuf, nullptr, nullptr,
                                         mha_inb + 1536 + 512, 256, 512, 1024, 0,
                                         512, nullptr, nullptr);
    gemv_qxr<<<dim3(16, 8), 256, 0, stream>>>(h1c, cni, mha_inW + 512 * 1536,
                                              gat_Wr + 512 * 512, pv1);
    reduce_qxr<<<4, 256, 0, stream>>>(pv1, mha_inb + 1536, gat_br + 512, qrow,
                                      xrrow);
    gat_l2<<<1, 512, 0, stream>>>(xlc, xrrow, cni, eattr, easum, gat_We + 1024,
                                  gat_att + 512, gat_bias + 512, cnt, elist,
                                  n1_g + 512, n1_b + 512, local_row);
    mha_row<<<8, 256, 0, stream>>>(qrow, kvbuf, attO_row);
    gemv_part<<<dim3(8, 8), 256, 0, stream>>>(attO_row, nullptr, 0, 0,
                                              mha_outW + 512 * 512, 512, 512, pv1);
    comb_l2<<<1, 512, 0, stream>>>(pv1, 8, mha_outb + 512, local_row, alpha_p, 1,
                                   n2_g + 512, n2_b + 512, comb_row);
    gemv_part<<<dim3(32, 8), 256, 0, stream>>>(comb_row, nullptr, 0, 0,
                                               ffn_W1 + (size_t)512 * 2048, 2048,
                                               2048, pv1);
    row_reduce<<<8, 256, 0, stream>>>(pv1, 8, 2048, ffn_b1 + 2048, midrow2, 1);
    gemv_part<<<dim3(8, 32), 256, 0, stream>>>(midrow2, nullptr, 0, 0,
                                               ffn_W2 + (size_t)2048 * 512, 512,
                                               512, pv1);
    final_l2<<<1, 512, 0, stream>>>(pv1, 32, ffn_b2 + 512, comb_row, n3_g + 512,
                                    n3_b + 512, hrow);
  }

  // ---- action head ----
  gemv_part<<<dim3(8, 8), 256, 0, stream>>>(hrow, nullptr, 0, 0, ah_W1, 512, 512,
                                            pv1);
  head_finish<<<1, 512, 0, stream>>>(pv1, 8, ah_b1, ah_g, ah_bt, ah_W2, ah_b2,
                                     (float*)d_out);
  (void)midrow;
}

// Round 13
// 357.812 us; speedup vs baseline: 2.0666x; 1.1200x over previous
//
#include <hip/hip_runtime.h>
#include <math.h>

constexpr int NODES = 2048;
constexpr int BG = 8;
constexpr int SG = 256;
constexpr int DIN = 4096;
constexpr int NHEAD = 8;
constexpr int EDGES = 32768;
constexpr int ACT_N = 5;
constexpr int H4C = 128;
constexpr int ECAP = 192;   // per-dst edge list capacity (GAT)
constexpr int SCAP = 96;    // per-src dedup'd neighbor capacity (RWSE)
constexpr int QS = 2560;    // merged hidden stride: [xl 512 | xr 512 | qkv 1536]
constexpr int NC = 512;     // compact row count (256 graph + 192 nbrs + pad)
constexpr int XK = 1536;    // merged l1 stride: [xl1 512 | K 512 | V 512]

typedef unsigned short u16;
typedef unsigned int u32;
typedef unsigned long long u64;
typedef short short8 __attribute__((ext_vector_type(8)));
typedef float f32x4 __attribute__((ext_vector_type(4)));

__device__ __forceinline__ float wave_sum(float v) {
#pragma unroll
  for (int o = 32; o; o >>= 1) v += __shfl_xor(v, o);
  return v;
}
__device__ __forceinline__ float wave_max(float v) {
#pragma unroll
  for (int o = 32; o; o >>= 1) v = fmaxf(v, __shfl_xor(v, o));
  return v;
}
__device__ __forceinline__ float blk_sum(float v, float* sh) {
  v = wave_sum(v);
  int nw = blockDim.x >> 6;
  __syncthreads();
  if ((threadIdx.x & 63) == 0) sh[threadIdx.x >> 6] = v;
  __syncthreads();
  float s = 0.f;
  for (int k = 0; k < nw; k++) s += sh[k];
  return s;
}
__device__ __forceinline__ float blk_max(float v, float* sh) {
  v = wave_max(v);
  int nw = blockDim.x >> 6;
  __syncthreads();
  if ((threadIdx.x & 63) == 0) sh[threadIdx.x >> 6] = v;
  __syncthreads();
  float m = sh[0];
  for (int k = 1; k < nw; k++) m = fmaxf(m, sh[k]);
  return m;
}
__device__ __forceinline__ float gelu_f(float x) {
  return 0.5f * x * (1.f + erff(x * 0.70710678118654752f));
}
__device__ __forceinline__ u16 f2bf(float x) {  // round-to-nearest-even bf16
  u32 u = __float_as_uint(x);
  return (u16)((u + 0x7FFFu + ((u >> 16) & 1u)) >> 16);
}
__device__ __forceinline__ float bf2f(u16 h) { return __uint_as_float(((u32)h) << 16); }
__device__ __forceinline__ void split2(float v, u16* ph, u16* pl) {
  u16 h = f2bf(v);
  *ph = h;
  *pl = f2bf(v - bf2f(h));
}

// ============ graph build (CSR + GAT lists + edge-attr sums, merged) =======
__global__ void build_graph(const int* __restrict__ ei, const float* __restrict__ ea,
                            u32* __restrict__ bits,
                            int* __restrict__ scnt, int* __restrict__ slist,
                            int* __restrict__ cnt, int* __restrict__ elist,
                            float* __restrict__ sums) {
  int e = blockIdx.x * 256 + threadIdx.x;
  float s0 = 0.f, s1 = 0.f;
  if (e < EDGES) {
    int s = ei[e], d = ei[EDGES + e];
    u32 m = 1u << (d & 31);
    u32 old = atomicOr(&bits[s * 64 + (d >> 5)], m);
    if (!(old & m)) {
      int p = atomicAdd(&scnt[s], 1);
      if (p < SCAP) slist[s * SCAP + p] = d;
    }
    int p2 = atomicAdd(&cnt[d], 1);
    if (p2 < ECAP) elist[(size_t)d * ECAP + p2] = e;
    s0 = ea[2 * e];
    s1 = ea[2 * e + 1];
  } else if (e < EDGES + NODES) {
    int d = e - EDGES;
    int p = atomicAdd(&cnt[d], 1);
    if (p < ECAP) elist[(size_t)d * ECAP + p] = e;
  }
  s0 = wave_sum(s0);
  s1 = wave_sum(s1);
  if ((threadIdx.x & 63) == 0 && (s0 != 0.f || s1 != 0.f)) {
    atomicAdd(&sums[0], s0);
    atomicAdd(&sums[1], s1);
  }
}

// rowmap + cb (l0 merged bias) + cbX (l1 merged bias), one kernel
__global__ void small_setup(const int* __restrict__ cni, const int* __restrict__ cnt,
                            const int* __restrict__ elist, const int* __restrict__ ei,
                            int* __restrict__ rowmap,
                            const float* __restrict__ bl0, const float* __restrict__ br0,
                            const float* __restrict__ inb0, float* __restrict__ cb,
                            const float* __restrict__ bl1, const float* __restrict__ inb1,
                            float* __restrict__ cbX) {
  int t = blockIdx.x * 256 + threadIdx.x;
  if (t < NC) {
    int i = cni[0];
    if (t < 256) {
      rowmap[t] = ((i >> 8) << 8) + t;
    } else {
      int p = t - 256;
      int m = min(cnt[i], ECAP);
      int v = 0;
      if (p < m) {
        int eid = elist[(size_t)i * ECAP + p];
        v = eid < EDGES ? ei[eid] : i;
      }
      rowmap[t] = v;
    }
  } else if (t < NC + QS) {
    int i = t - NC;
    cb[i] = i < 512 ? bl0[i] : (i < 1024 ? br0[i - 512] : inb0[i - 1024]);
  } else if (t < NC + QS + XK) {
    int i = t - NC - QS;
    cbX[i] = i < 512 ? bl1[i] : inb1[i];  // inb1 = mha_inb+1536; KV bias = inb1[512..1535]
  }
}

// ================= RWSE (sparse path) =================
__global__ __launch_bounds__(256) void spmm_sq(const int* __restrict__ scnt,
                                               const int* __restrict__ slist,
                                               float* __restrict__ P2,
                                               float* __restrict__ rwse) {
  int i = blockIdx.x, t = threadIdx.x;
  __shared__ float row[NODES];
  for (int c = t; c < NODES; c += 256) row[c] = 0.f;
  __syncthreads();
  int di = min(scnt[i], SCAP);
  float wi = di > 0 ? 1.f / (float)di : 0.f;
  for (int jj = 0; jj < di; jj++) {
    int j = slist[i * SCAP + jj];
    int dj = min(scnt[j], SCAP);
    if (dj == 0) continue;
    float w = wi / (float)dj;
    for (int kk = t; kk < dj; kk += 256) atomicAdd(&row[slist[j * SCAP + kk]], w);
  }
  __syncthreads();
  for (int c = t; c < NODES; c += 256) {
    float v = row[c];
    P2[(size_t)i * NODES + c] = v;
    if (c == i) rwse[(size_t)i * 8 + 1] = v;
  }
}

__global__ __launch_bounds__(256) void spmm_gather(const int* __restrict__ scnt,
                                                   const int* __restrict__ slist,
                                                   const float* __restrict__ P,
                                                   float* __restrict__ Q,
                                                   float* __restrict__ rwse, int col) {
  int i = blockIdx.x, t = threadIdx.x;
  __shared__ int nb[SCAP];
  int di = min(scnt[i], SCAP);
  for (int c = t; c < di; c += 256) nb[c] = slist[i * SCAP + c];
  __syncthreads();
  float wi = di > 0 ? 1.f / (float)di : 0.f;
  for (int c = t; c < NODES; c += 256) {
    float s = 0.f;
    for (int jj = 0; jj < di; jj++) s += P[(size_t)nb[jj] * NODES + c];
    float v = s * wi;
    Q[(size_t)i * NODES + c] = v;
    if (c == i) rwse[(size_t)i * 8 + col] = v;
  }
}

__global__ __launch_bounds__(256) void diag_tiled(const float* __restrict__ P2,
                                                  const float* __restrict__ P3,
                                                  const float* __restrict__ P4,
                                                  float* __restrict__ pbuf) {
  __shared__ float r2[64][65], r3[64][65], r4[64][65], c3[64][65], c4[64][65];
  __shared__ float red[4][4][64];
  int t = threadIdx.x;
  int i0 = blockIdx.x * 64;
  int js = blockIdx.y;
  int lo = t & 63, hi = t >> 6;
  float d5 = 0, d6 = 0, d7 = 0, d8 = 0;
  for (int jc = 0; jc < 4; jc++) {
    int j0 = js * 256 + jc * 64;
    __syncthreads();
#pragma unroll
    for (int r = 0; r < 16; r++) {
      int a = hi * 16 + r;
      r2[a][lo] = P2[(size_t)(i0 + a) * NODES + j0 + lo];
      r3[a][lo] = P3[(size_t)(i0 + a) * NODES + j0 + lo];
      r4[a][lo] = P4[(size_t)(i0 + a) * NODES + j0 + lo];
      c3[a][lo] = P3[(size_t)(j0 + a) * NODES + i0 + lo];
      c4[a][lo] = P4[(size_t)(j0 + a) * NODES + i0 + lo];
    }
    __syncthreads();
#pragma unroll
    for (int r = 0; r < 16; r++) {
      int jj = hi * 16 + r;
      float p3c = c3[jj][lo], p4c = c4[jj][lo];
      d5 += r2[lo][jj] * p3c;
      d6 += r3[lo][jj] * p3c;
      d7 += r3[lo][jj] * p4c;
      d8 += r4[lo][jj] * p4c;
    }
  }
  red[0][hi][lo] = d5; red[1][hi][lo] = d6; red[2][hi][lo] = d7; red[3][hi][lo] = d8;
  __syncthreads();
  if (hi == 0) {
    int i = i0 + lo;
#pragma unroll
    for (int v = 0; v < 4; v++) {
      float s = red[v][0][lo] + red[v][1][lo] + red[v][2][lo] + red[v][3][lo];
      pbuf[((size_t)js * NODES + i) * 4 + v] = s;
    }
  }
}

__global__ void diag_reduce(const float* __restrict__ pbuf,
                            const u32* __restrict__ bits,
                            const int* __restrict__ scnt,
                            float* __restrict__ rwse) {
  int i = blockIdx.x * 256 + threadIdx.x;
  if (i >= NODES) return;
  int deg = min(scnt[i], SCAP);
  int self = (bits[i * 64 + (i >> 5)] >> (i & 31)) & 1;
  rwse[(size_t)i * 8 + 0] = (self && deg > 0) ? 1.f / (float)deg : 0.f;
#pragma unroll
  for (int v = 0; v < 4; v++) {
    float s = 0.f;
    for (int js = 0; js < 8; js++) s += pbuf[((size_t)js * NODES + i) * 4 + v];
    rwse[(size_t)i * 8 + 4 + v] = s;
  }
}

// ================= fp32 -> split-bf16 helpers =================
__device__ __forceinline__ void splitA8(const float* __restrict__ p, short8& h8,
                                        short8& l8) {
  float4 v0 = *(const float4*)p;
  float4 v1 = *(const float4*)(p + 4);
  float v[8] = {v0.x, v0.y, v0.z, v0.w, v1.x, v1.y, v1.z, v1.w};
#pragma unroll
  for (int i = 0; i < 8; i++) {
    u16 h = f2bf(v[i]);
    h8[i] = (short)h;
    l8[i] = (short)f2bf(v[i] - bf2f(h));
  }
}

// ====== weight packing + x-panel split (merged); x seg marked gnTot < 0 =====
struct PackArgs {
  const float* src[13];
  u64 offU[13];
  u64 cumU[14];
  int N[13];
  int srcStride[13];
  int gnTot[13];
  int ntOff[13];
};

__global__ __launch_bounds__(256) void pack_all(PackArgs pa, u16* __restrict__ Bh,
                                                u16* __restrict__ Bl,
                                                u16* __restrict__ Axh,
                                                u16* __restrict__ Axl) {
  u64 total = pa.cumU[13];
  for (u64 u = (u64)blockIdx.x * 256 + threadIdx.x; u < total;
       u += (u64)gridDim.x * 256) {
    int s = 0;
    while (u >= pa.cumU[s + 1]) s++;
    u64 ur = u - pa.cumU[s];
    if (pa.gnTot[s] < 0) {
      // x panel: linear split, src [NODES][4096] -> A-panel [NODES][4224] @ col 0
      int m = (int)(ur >> 9);
      int k = (int)((ur & 511) << 3);
      short8 h8, l8;
      splitA8(pa.src[s] + (size_t)m * 4096 + k, h8, l8);
      size_t o = (size_t)m * 4224 + k;
      *(short8*)(Axh + o) = h8;
      *(short8*)(Axl + o) = l8;
      continue;
    }
    int lr = (int)(ur & 15);
    int g = (int)((ur >> 4) & 3);
    int ks = (int)((ur >> 6) & 1);
    int j = (int)((ur >> 7) & 3);
    u64 rest = ur >> 9;
    int Nseg = pa.N[s] >> 6;
    int nt = (int)(rest % (u32)Nseg);
    int ktile = (int)(rest / (u32)Nseg);
    int k0 = (ktile << 6) | (ks << 5) | (g << 3);
    int n = (nt << 6) | (j << 4) | lr;
    const float* src = pa.src[s];
    int stride = pa.srcStride[s];
    u64 fiU = pa.offU[s] +
              ((((u64)ktile * pa.gnTot[s] + pa.ntOff[s] + nt) * 8 + j * 2 + ks) * 64 +
               g * 16 + lr);
    short8 h8, l8;
#pragma unroll
    for (int e = 0; e < 8; e++) {
      float v = src[(size_t)(k0 + e) * stride + n];
      u16 h = f2bf(v);
      h8[e] = (short)h;
      l8[e] = (short)f2bf(v - bf2f(h));
    }
    *((short8*)Bh + fiU) = h8;
    *((short8*)Bl + fiU) = l8;
  }
}

// ========== split-bf16 MFMA GEMM, pre-split u16 A, split-K, row gather =====
__global__ __launch_bounds__(256) void gemm_s(
    const u16* __restrict__ Ahg, const u16* __restrict__ Alg, int lda,
    const u16* __restrict__ Bh, const u16* __restrict__ Bl,
    float* __restrict__ C, u16* __restrict__ Ch, u16* __restrict__ Cl,
    const float* __restrict__ bias,
    int M, int K, int N, int act, int Kslice, float* __restrict__ part,
    const int* __restrict__ rowmap) {
  __shared__ __align__(16) u16 LA[2][4096];
  __shared__ __align__(16) u16 LB[2][4096];
  int gn = N >> 6;
  int nwg = (M >> 6) * gn;
  int q = nwg >> 3;
  int flat = blockIdx.x;
  int virt = (flat & 7) * q + (flat >> 3);     // bijective XCD-contiguous remap
  int bm = (virt / gn) << 6, bn = (virt % gn) << 6;
  int kb = blockIdx.y;
  int kstart = kb * Kslice;
  int kend = min(K, kstart + Kslice);
  int t = threadIdx.x;
  int lane = t & 63, w = t >> 6;
  int wm = (w >> 1) << 5, wn = (w & 1) << 5;
  int r0 = t >> 3, r1 = r0 + 32;
  int c8 = (t & 7) << 3;
  int ks_s = (t >> 2) & 1, g_s = t & 3;
  int slotA = (((r0 & 15) + (g_s << 4)) ^ (g_s | (ks_s << 2)));
  int da0 = ((((r0 >> 4) << 1) + ks_s) << 9) + (slotA << 3);
  int da1 = ((((r1 >> 4) << 1) + ks_s) << 9) + (slotA << 3);
  int db0 = t * 8, db1 = (t + 256) * 8;
  size_t btile = ((size_t)(kstart >> 6) * gn + (bn >> 6)) * 4096;
  size_t bstep = (size_t)gn * 4096;

  int rrow0 = bm + r0, rrow1 = bm + r1;
  if (rowmap) { rrow0 = rowmap[rrow0]; rrow1 = rowmap[rrow1]; }
  size_t aoff0 = (size_t)rrow0 * lda + c8;
  size_t aoff1 = (size_t)rrow1 * lda + c8;

  short8 pah0, pal0, pah1, pal1, pbh0, pbl0, pbh1, pbl1;
  pah0 = *(const short8*)(Ahg + aoff0 + kstart);
  pal0 = *(const short8*)(Alg + aoff0 + kstart);
  pah1 = *(const short8*)(Ahg + aoff1 + kstart);
  pal1 = *(const short8*)(Alg + aoff1 + kstart);
  pbh0 = *(const short8*)(Bh + btile + db0);
  pbl0 = *(const short8*)(Bl + btile + db0);
  pbh1 = *(const short8*)(Bh + btile + db1);
  pbl1 = *(const short8*)(Bl + btile + db1);

  f32x4 acc[2][2] = {};
  int lr = lane & 15, lg = lane >> 4;
  int rboff = lane << 3;

  for (int kt = kstart; kt < kend; kt += 64) {
    __syncthreads();
    *(short8*)&LA[0][da0] = pah0;
    *(short8*)&LA[1][da0] = pal0;
    *(short8*)&LA[0][da1] = pah1;
    *(short8*)&LA[1][da1] = pal1;
    *(short8*)&LB[0][db0] = pbh0;
    *(short8*)&LB[1][db0] = pbl0;
    *(short8*)&LB[0][db1] = pbh1;
    *(short8*)&LB[1][db1] = pbl1;
    __syncthreads();
    if (kt + 64 < kend) {
      btile += bstep;
      int kn = kt + 64;
      pah0 = *(const short8*)(Ahg + aoff0 + kn);
      pal0 = *(const short8*)(Alg + aoff0 + kn);
      pah1 = *(const short8*)(Ahg + aoff1 + kn);
      pal1 = *(const short8*)(Alg + aoff1 + kn);
      pbh0 = *(const short8*)(Bh + btile + db0);
      pbl0 = *(const short8*)(Bl + btile + db0);
      pbh1 = *(const short8*)(Bh + btile + db1);
      pbl1 = *(const short8*)(Bl + btile + db1);
    }
#pragma unroll
    for (int ks = 0; ks < 2; ks++) {
      short8 ah[2], al[2], bh[2], bl[2];
      int slr = ((lr + (lg << 4)) ^ (lg | (ks << 2))) << 3;
#pragma unroll
      for (int i = 0; i < 2; i++) {
        int ba = ((((wm >> 4) + i) * 2 + ks) << 9) + slr;
        ah[i] = *(const short8*)&LA[0][ba];
        al[i] = *(const short8*)&LA[1][ba];
        int bb = ((((wn >> 4) + i) * 2 + ks) << 9) + rboff;
        bh[i] = *(const short8*)&LB[0][bb];
        bl[i] = *(const short8*)&LB[1][bb];
      }
#pragma unroll
      for (int i = 0; i < 2; i++)
#pragma unroll
        for (int j = 0; j < 2; j++) {
          acc[i][j] = __builtin_amdgcn_mfma_f32_16x16x32_bf16(ah[i], bh[j], acc[i][j], 0, 0, 0);
          acc[i][j] = __builtin_amdgcn_mfma_f32_16x16x32_bf16(ah[i], bl[j], acc[i][j], 0, 0, 0);
          acc[i][j] = __builtin_amdgcn_mfma_f32_16x16x32_bf16(al[i], bh[j], acc[i][j], 0, 0, 0);
        }
    }
  }
  int row0 = (lane >> 4) * 4;
  if (part) {
    size_t pbase = (size_t)kb * (size_t)M * N;
#pragma unroll
    for (int i = 0; i < 2; i++)
#pragma unroll
      for (int j = 0; j < 2; j++) {
        int n = bn + wn + j * 16 + lr;
#pragma unroll
        for (int r = 0; r < 4; r++) {
          int m = bm + wm + i * 16 + row0 + r;
          part[pbase + (size_t)m * N + n] = acc[i][j][r];
        }
      }
    return;
  }
#pragma unroll
  for (int i = 0; i < 2; i++)
#pragma unroll
    for (int j = 0; j < 2; j++) {
      int n = bn + wn + j * 16 + lr;
      float bv = bias ? bias[n] : 0.f;
#pragma unroll
      for (int r = 0; r < 4; r++) {
        int m = bm + wm + i * 16 + row0 + r;
        float v = acc[i][j][r] + bv;
        if (act) v = gelu_f(v);
        size_t o = (size_t)m * N + n;
        if (Ch) {
          split2(v, Ch + o, Cl + o);
          if (C) C[o] = v;
        } else {
          C[o] = v;
        }
      }
    }
}

// ================= small fused kernels =================
__global__ __launch_bounds__(128) void rwse_proj(const float* __restrict__ rwse,
                                                 const float* __restrict__ W,
                                                 const float* __restrict__ bb,
                                                 const float* __restrict__ g,
                                                 const float* __restrict__ bt,
                                                 u16* __restrict__ Axh,
                                                 u16* __restrict__ Axl) {
  int i = blockIdx.x, j = threadIdx.x;
  float s = bb[j];
#pragma unroll
  for (int k = 0; k < 8; k++) s += rwse[(size_t)i * 8 + k] * W[k * H4C + j];
  __shared__ float sh[8];
  float sum = blk_sum(s, sh);
  float mu = sum * (1.f / 128.f);
  float d = s - mu;
  float var = blk_sum(d * d, sh) * (1.f / 128.f);
  float val = gelu_f(d * rsqrtf(var + 1e-5f) * g[j] + bt[j]);
  size_t o = (size_t)i * 4224 + 4096 + j;
  split2(val, Axh + o, Axl + o);
}

__global__ __launch_bounds__(256) void ln512(const float* __restrict__ x, int sk,
                                             int M,
                                             const float* __restrict__ gbias,
                                             const float* __restrict__ res,
                                             const float* __restrict__ mix,
                                             const float* __restrict__ ap, int l,
                                             const float* __restrict__ g,
                                             const float* __restrict__ b,
                                             float* __restrict__ y,
                                             u16* __restrict__ yh,
                                             u16* __restrict__ yl, int do_gelu) {
  const size_t MN = (size_t)M * 512;
  int i = blockIdx.x, t = threadIdx.x;
  size_t base = (size_t)i * 512;
  float v0 = x[base + t], v1 = x[base + 256 + t];
  for (int s = 1; s < sk; s++) {
    v0 += x[(size_t)s * MN + base + t];
    v1 += x[(size_t)s * MN + base + 256 + t];
  }
  if (gbias) { v0 += gbias[t]; v1 += gbias[t + 256]; }
  if (res) { v0 += res[base + t]; v1 += res[base + 256 + t]; }
  __shared__ float sh[8];
  float s = blk_sum(v0 + v1, sh);
  float mu = s * (1.f / 512.f);
  float d0 = v0 - mu, d1 = v1 - mu;
  float var = blk_sum(d0 * d0 + d1 * d1, sh) * (1.f / 512.f);
  float rstd = rsqrtf(var + 1e-5f);
  float o0 = d0 * rstd * g[t] + b[t];
  float o1 = d1 * rstd * g[t + 256] + b[t + 256];
  if (do_gelu) { o0 = gelu_f(o0); o1 = gelu_f(o1); }
  if (mix) {
    float a = 1.f / (1.f + expf(-ap[l]));
    o0 = a * mix[base + t] + (1.f - a) * o0;
    o1 = a * mix[base + 256 + t] + (1.f - a) * o1;
  }
  if (y) { y[base + t] = o0; y[base + 256 + t] = o1; }
  if (yh) {
    split2(o0, yh + base + t, yl + base + t);
    split2(o1, yh + base + 256 + t, yl + base + 256 + t);
  }
}

// layer-0 GAT at rowmap'd dst nodes, fused LN(n1)
__global__ __launch_bounds__(512) void gat_kernel(
    const float* __restrict__ hb, const int* __restrict__ rowmap,
    const float* __restrict__ eattr, const float* __restrict__ easum,
    const float* __restrict__ We, const float* __restrict__ att,
    const float* __restrict__ bias, const int* __restrict__ cnt,
    const int* __restrict__ elist, const int* __restrict__ ei,
    const float* __restrict__ n1g, const float* __restrict__ n1b,
    float* __restrict__ out) {
  int i = rowmap[blockIdx.x];
  int tid = threadIdx.x;
  int h = tid >> 6, c = tid & 63;
  int m_cnt = cnt[i];
  if (m_cnt > ECAP) m_cnt = ECAP;
  const float inv_e = 1.f / (float)EDGES;
  float we0 = We[tid], we1 = We[512 + tid];
  float attv = att[tid];
  float xrv = hb[(size_t)i * QS + 512 + tid];
  float ea_m0 = easum[0] * inv_e, ea_m1 = easum[1] * inv_e;
  __shared__ float logits[NHEAD][ECAP];
  __shared__ float sh[8];
  const int* el = elist + (size_t)i * ECAP;
  for (int e = 0; e < m_cnt; e++) {
    int eid = el[e];
    int s;
    float a0, a1;
    if (eid < EDGES) { s = ei[eid]; a0 = eattr[2 * eid]; a1 = eattr[2 * eid + 1]; }
    else { s = i; a0 = ea_m0; a1 = ea_m1; }
    float mval = hb[(size_t)s * QS + tid] + xrv + a0 * we0 + a1 * we1;
    mval = mval > 0.f ? mval : 0.2f * mval;
    float lg = wave_sum(mval * attv);
    if (c == 0) logits[h][e] = lg;
  }
  float mx = -1e30f;
  for (int e = c; e < m_cnt; e += 64) mx = fmaxf(mx, logits[h][e]);
  mx = wave_max(mx);
  float den = 0.f;
  for (int e = c; e < m_cnt; e += 64) den += expf(logits[h][e] - mx);
  den = wave_sum(den) + 1e-16f;
  float acc = 0.f;
  for (int e = 0; e < m_cnt; e++) {
    int eid = el[e];
    int s = eid < EDGES ? ei[eid] : i;
    float alpha = expf(logits[h][e] - mx) / den;
    acc += alpha * hb[(size_t)s * QS + tid];
  }
  float v = acc + bias[tid];
  float mu = blk_sum(v, sh) * (1.f / 512.f);
  float d = v - mu;
  float var = blk_sum(d * d, sh) * (1.f / 512.f);
  out[(size_t)blockIdx.x * 512 + tid] = d * rsqrtf(var + 1e-5f) * n1g[tid] + n1b[tid];
}

// ======= MFMA block-diag MHA (layer 0); outputs split u16 =======
__global__ __launch_bounds__(256) void mha_mfma(const float* __restrict__ qkv,
                                                u16* __restrict__ attOh,
                                                u16* __restrict__ attOl) {
  __shared__ __align__(16) u16 Ksh[2][256][72];
  __shared__ __align__(16) u16 Vt[2][64][264];
  int bid = blockIdx.x;
  int qq = bid & 3;
  int h = (bid >> 2) & 7;
  int b = bid >> 5;
  int t = threadIdx.x;
  int lane = t & 63, w = t >> 6;
  int lr = lane & 15, g = lane >> 4, kk = g * 8;
  size_t rowbase = (size_t)(b * SG) * QS;
  const float* Kbase = qkv + rowbase + 512 + h * 64;
  const float* Vbase = qkv + rowbase + 1024 + h * 64;
  for (int idx = t; idx < SG * 64; idx += 256) {
    int j = idx >> 6, c = idx & 63;
    float kv = Kbase[(size_t)j * QS + c];
    u16 khh = f2bf(kv);
    Ksh[0][j][c] = khh;
    Ksh[1][j][c] = f2bf(kv - bf2f(khh));
    float vv = Vbase[(size_t)j * QS + c];
    u16 vhh = f2bf(vv);
    Vt[0][c][j] = vhh;
    Vt[1][c][j] = f2bf(vv - bf2f(vhh));
  }
  const float* Qrow = qkv + rowbase + (size_t)(qq * 64 + w * 16 + lr) * QS + h * 64;
  short8 qh[2], ql[2];
#pragma unroll
  for (int kt = 0; kt < 2; kt++) {
    float qv[8];
    *(float4*)&qv[0] = *(const float4*)&Qrow[kt * 32 + kk];
    *(float4*)&qv[4] = *(const float4*)&Qrow[kt * 32 + kk + 4];
#pragma unroll
    for (int i = 0; i < 8; i++) {
      u16 hh = f2bf(qv[i]);
      qh[kt][i] = hh;
      ql[kt][i] = f2bf(qv[i] - bf2f(hh));
    }
  }
  __syncthreads();
  f32x4 S[16];
#pragma unroll
  for (int j = 0; j < 16; j++) {
    f32x4 acc = {};
#pragma unroll
    for (int kt = 0; kt < 2; kt++) {
      short8 bh = *(const short8*)&Ksh[0][j * 16 + lr][kt * 32 + kk];
      short8 bl = *(const short8*)&Ksh[1][j * 16 + lr][kt * 32 + kk];
      acc = __builtin_amdgcn_mfma_f32_16x16x32_bf16(qh[kt], bh, acc, 0, 0, 0);
      acc = __builtin_amdgcn_mfma_f32_16x16x32_bf16(qh[kt], bl, acc, 0, 0, 0);
      acc = __builtin_amdgcn_mfma_f32_16x16x32_bf16(ql[kt], bh, acc, 0, 0, 0);
    }
    S[j] = acc;
  }
  float mx[4], inv[4];
#pragma unroll
  for (int r = 0; r < 4; r++) {
    float m = S[0][r];
#pragma unroll
    for (int j = 1; j < 16; j++) m = fmaxf(m, S[j][r]);
#pragma unroll
    for (int oo = 1; oo < 16; oo <<= 1) m = fmaxf(m, __shfl_xor(m, oo));
    mx[r] = m;
    float d = 0.f;
#pragma unroll
    for (int j = 0; j < 16; j++) d += __expf((S[j][r] - m) * 0.125f);
#pragma unroll
    for (int oo = 1; oo < 16; oo <<= 1) d += __shfl_xor(d, oo);
    inv[r] = 1.f / d;
  }
  __syncthreads();
  u16* Pb = &Ksh[0][0][0];
  int row0 = w * 16 + g * 4;
#pragma unroll
  for (int j = 0; j < 16; j++) {
    int key = j * 16 + lr;
#pragma unroll
    for (int r = 0; r < 4; r++) {
      float p = __expf((S[j][r] - mx[r]) * 0.125f) * inv[r];
      u16 hh = f2bf(p);
      Pb[(row0 + r) * 264 + key] = hh;
      Pb[16896 + (row0 + r) * 264 + key] = f2bf(p - bf2f(hh));
    }
  }
  __syncthreads();
  f32x4 Oacc[4] = {};
#pragma unroll
  for (int kt = 0; kt < 8; kt++) {
    short8 pah = *(const short8*)&Pb[(w * 16 + lr) * 264 + kt * 32 + kk];
    short8 pal = *(const short8*)&Pb[16896 + (w * 16 + lr) * 264 + kt * 32 + kk];
#pragma unroll
    for (int nf = 0; nf < 4; nf++) {
      short8 vh = *(const short8*)&Vt[0][nf * 16 + lr][kt * 32 + kk];
      short8 vl = *(const short8*)&Vt[1][nf * 16 + lr][kt * 32 + kk];
      Oacc[nf] = __builtin_amdgcn_mfma_f32_16x16x32_bf16(pah, vh, Oacc[nf], 0, 0, 0);
      Oacc[nf] = __builtin_amdgcn_mfma_f32_16x16x32_bf16(pah, vl, Oacc[nf], 0, 0, 0);
      Oacc[nf] = __builtin_amdgcn_mfma_f32_16x16x32_bf16(pal, vh, Oacc[nf], 0, 0, 0);
    }
  }
  size_t obase = (size_t)(b * SG + qq * 64 + w * 16 + g * 4) * 512 + h * 64;
#pragma unroll
  for (int nf = 0; nf < 4; nf++)
#pragma unroll
    for (int r = 0; r < 4; r++) {
      size_t o = obase + (size_t)r * 512 + nf * 16 + lr;
      split2(Oacc[nf][r], attOh + o, attOl + o);
    }
}

// ================= layer-2 pruned path (row cni only) =================
__global__ __launch_bounds__(256) void gemv_part(
    const float* __restrict__ inrow, const int* __restrict__ cni, int rowMask,
    int rowStride, const float* __restrict__ W, int ldW, int N,
    float* __restrict__ part) {
  __shared__ float xv[64];
  __shared__ float red[4][64];
  int t = threadIdx.x;
  int kb = blockIdx.y;
  const float* xr = inrow + (cni ? (size_t)(cni[0] & rowMask) * rowStride : 0) + kb * 64;
  if (t < 64) xv[t] = xr[t];
  __syncthreads();
  int nl = t & 63;
  int n = blockIdx.x * 64 + nl;
  int seg = t >> 6;
  float acc = 0.f;
  const float* Wp = W + (size_t)(kb * 64 + seg * 16) * ldW + n;
#pragma unroll
  for (int k = 0; k < 16; k++) acc += xv[seg * 16 + k] * Wp[(size_t)k * ldW];
  red[seg][nl] = acc;
  __syncthreads();
  if (t < 64) {
    part[(size_t)kb * N + blockIdx.x * 64 + t] =
        red[0][t] + red[1][t] + red[2][t] + red[3][t];
  }
}

// merged q/xr GEMV (unchanged from r12)
__global__ __launch_bounds__(256) void gemv_qxr(
    const float* __restrict__ h1c, const int* __restrict__ cni,
    const float* __restrict__ inW, const float* __restrict__ Wr,
    float* __restrict__ part) {
  __shared__ float xv[64];
  __shared__ float red[4][64];
  int t = threadIdx.x;
  int kb = blockIdx.y;
  const float* xr = h1c + (size_t)(cni[0] & 255) * 512 + kb * 64;
  if (t < 64) xv[t] = xr[t];
  __syncthreads();
  int b = blockIdx.x;
  int isq = b < 8;
  int nl = t & 63;
  int n = (b & 7) * 64 + nl;
  int seg = t >> 6;
  const float* W = isq ? inW : Wr;
  int ldW = isq ? 1536 : 512;
  float acc = 0.f;
  const float* Wp = W + (size_t)(kb * 64 + seg * 16) * ldW + n;
#pragma unroll
  for (int k = 0; k < 16; k++) acc += xv[seg * 16 + k] * Wp[(size_t)k * ldW];
  red[seg][nl] = acc;
  __syncthreads();
  if (t < 64) {
    part[(size_t)kb * 1024 + (isq ? 0 : 512) + (b & 7) * 64 + t] =
        red[0][t] + red[1][t] + red[2][t] + red[3][t];
  }
}

// merged l2 attention: block 0 = GAT@cni (+LN n1, inline xr reduce),
// blocks 1..8 = per-head MHA (inline q reduce). xkc stride XK.
__global__ __launch_bounds__(512) void l2_attn(
    const float* __restrict__ xkc, const float* __restrict__ pvqxr,
    const int* __restrict__ cni,
    const float* __restrict__ eattr, const float* __restrict__ easum,
    const float* __restrict__ We, const float* __restrict__ att,
    const float* __restrict__ bias, const int* __restrict__ cnt,
    const int* __restrict__ elist,
    const float* __restrict__ n1g, const float* __restrict__ n1b,
    const float* __restrict__ inbq, const float* __restrict__ br,
    float* __restrict__ local_row, float* __restrict__ attO_row) {
  __shared__ float logits[NHEAD][ECAP];
  __shared__ float sh[8];
  __shared__ float q[64];
  __shared__ float p[SG];
  __shared__ float red[8][64];
  if (blockIdx.x == 0) {
    int i = cni[0];
    int tid = threadIdx.x;
    int h = tid >> 6, c = tid & 63;
    int m_cnt = min(cnt[i], ECAP);
    const float inv_e = 1.f / (float)EDGES;
    float we0 = We[tid], we1 = We[512 + tid];
    float attv = att[tid];
    float xrv = br[tid];
    for (int k = 0; k < 8; k++) xrv += pvqxr[(size_t)k * 1024 + 512 + tid];
    float ea_m0 = easum[0] * inv_e, ea_m1 = easum[1] * inv_e;
    const int* el = elist + (size_t)i * ECAP;
    for (int e = 0; e < m_cnt; e++) {
      int eid = el[e];
      float a0, a1;
      if (eid < EDGES) { a0 = eattr[2 * eid]; a1 = eattr[2 * eid + 1]; }
      else { a0 = ea_m0; a1 = ea_m1; }
      float mval = xkc[(size_t)(256 + e) * XK + tid] + xrv + a0 * we0 + a1 * we1;
      mval = mval > 0.f ? mval : 0.2f * mval;
      float lg = wave_sum(mval * attv);
      if (c == 0) logits[h][e] = lg;
    }
    float mx = -1e30f;
    for (int e = c; e < m_cnt; e += 64) mx = fmaxf(mx, logits[h][e]);
    mx = wave_max(mx);
    float den = 0.f;
    for (int e = c; e < m_cnt; e += 64) den += expf(logits[h][e] - mx);
    den = wave_sum(den) + 1e-16f;
    float acc = 0.f;
    for (int e = 0; e < m_cnt; e++) {
      float alpha = expf(logits[h][e] - mx) / den;
      acc += alpha * xkc[(size_t)(256 + e) * XK + tid];
    }
    float v = acc + bias[tid];
    float mu = blk_sum(v, sh) * (1.f / 512.f);
    float d = v - mu;
    float var = blk_sum(d * d, sh) * (1.f / 512.f);
    local_row[tid] = d * rsqrtf(var + 1e-5f) * n1g[tid] + n1b[tid];
  } else {
    int h = blockIdx.x - 1;
    int t = threadIdx.x;
    if (t < 64) {
      float qq = inbq[h * 64 + t];
      for (int k = 0; k < 8; k++) qq += pvqxr[(size_t)k * 1024 + h * 64 + t];
      q[t] = qq;
    }
    __syncthreads();
    float s = -1e30f;
    if (t < SG) {
      const float* kr = xkc + (size_t)t * XK + 512 + h * 64;
      float acc = 0.f;
#pragma unroll 8
      for (int c2 = 0; c2 < 64; c2++) acc += q[c2] * kr[c2];
      s = acc * 0.125f;
    }
    float m = blk_max(s, sh);
    float e2 = (t < SG) ? __expf(s - m) : 0.f;
    if (t < SG) p[t] = e2;
    float den = blk_sum(e2, sh);
    __syncthreads();
    int c = t & 63, seg = t >> 6;
    float o = 0.f;
    for (int j = seg * 32; j < seg * 32 + 32; j++)
      o += p[j] * xkc[(size_t)j * XK + 1024 + h * 64 + c];
    red[seg][c] = o;
    __syncthreads();
    if (t < 64) {
      float tot = 0.f;
      for (int k = 0; k < 8; k++) tot += red[k][t];
      attO_row[h * 64 + t] = tot / den;
    }
  }
}

// W1 GEMV with comb (out-proj reduce + LN(n2) + mix) computed inline
__global__ __launch_bounds__(256) void gemv_comb(
    const float* __restrict__ pvout, const float* __restrict__ outb,
    const float* __restrict__ local_row, const float* __restrict__ ap,
    const float* __restrict__ n2g, const float* __restrict__ n2b,
    const float* __restrict__ W, float* __restrict__ comb_out,
    float* __restrict__ part) {
  __shared__ float combs[512];
  __shared__ float sh[8];
  __shared__ float red[4][64];
  int t = threadIdx.x;
  float v0 = outb[t], v1 = outb[t + 256];
  for (int k = 0; k < 8; k++) {
    v0 += pvout[(size_t)k * 512 + t];
    v1 += pvout[(size_t)k * 512 + 256 + t];
  }
  float ssum = blk_sum(v0 + v1, sh);
  float mu = ssum * (1.f / 512.f);
  float d0 = v0 - mu, d1 = v1 - mu;
  float var = blk_sum(d0 * d0 + d1 * d1, sh) * (1.f / 512.f);
  float rstd = rsqrtf(var + 1e-5f);
  float o0 = d0 * rstd * n2g[t] + n2b[t];
  float o1 = d1 * rstd * n2g[t + 256] + n2b[t + 256];
  float a = 1.f / (1.f + expf(-ap[1]));
  combs[t] = a * local_row[t] + (1.f - a) * o0;
  combs[t + 256] = a * local_row[t + 256] + (1.f - a) * o1;
  __syncthreads();
  if (blockIdx.x == 0 && blockIdx.y == 0) {
    comb_out[t] = combs[t];
    comb_out[t + 256] = combs[t + 256];
  }
  int kb = blockIdx.y;
  int nl = t & 63, seg = t >> 6;
  int n = blockIdx.x * 64 + nl;
  float acc = 0.f;
  const float* Wp = W + (size_t)(kb * 64 + seg * 16) * 2048 + n;
#pragma unroll
  for (int k = 0; k < 16; k++) acc += combs[kb * 64 + seg * 16 + k] * Wp[(size_t)k * 2048];
  red[seg][nl] = acc;
  __syncthreads();
  if (t < 64)
    part[(size_t)kb * 2048 + blockIdx.x * 64 + t] =
        red[0][t] + red[1][t] + red[2][t] + red[3][t];
}

// W2 GEMV with W1-partials reduce + bias + gelu inline
__global__ __launch_bounds__(256) void gemv_mid(
    const float* __restrict__ pvW1, const float* __restrict__ b1,
    const float* __restrict__ W, float* __restrict__ part) {
  __shared__ float xv[64];
  __shared__ float red[4][64];
  int t = threadIdx.x;
  int kb = blockIdx.y;  // 0..31
  if (t < 64) {
    float s = b1[kb * 64 + t];
    for (int k = 0; k < 8; k++) s += pvW1[(size_t)k * 2048 + kb * 64 + t];
    xv[t] = gelu_f(s);
  }
  __syncthreads();
  int nl = t & 63, seg = t >> 6;
  int n = blockIdx.x * 64 + nl;
  float acc = 0.f;
  const float* Wp = W + (size_t)(kb * 64 + seg * 16) * 512 + n;
#pragma unroll
  for (int k = 0; k < 16; k++) acc += xv[seg * 16 + k] * Wp[(size_t)k * 512];
  red[seg][nl] = acc;
  __syncthreads();
  if (t < 64)
    part[(size_t)kb * 512 + blockIdx.x * 64 + t] =
        red[0][t] + red[1][t] + red[2][t] + red[3][t];
}

// head W1 GEMV with final LN(n3) (W2-partials reduce + residual) inline
__global__ __launch_bounds__(256) void gemv_head(
    const float* __restrict__ pvW2, const float* __restrict__ b2,
    const float* __restrict__ comb_row,
    const float* __restrict__ n3g, const float* __restrict__ n3b,
    const float* __restrict__ W, float* __restrict__ part) {
  __shared__ float hr[512];
  __shared__ float sh[8];
  __shared__ float red[4][64];
  int t = threadIdx.x;
  float v0 = b2[t] + comb_row[t], v1 = b2[t + 256] + comb_row[t + 256];
  for (int k = 0; k < 32; k++) {
    v0 += pvW2[(size_t)k * 512 + t];
    v1 += pvW2[(size_t)k * 512 + 256 + t];
  }
  float ssum = blk_sum(v0 + v1, sh);
  float mu = ssum * (1.f / 512.f);
  float d0 = v0 - mu, d1 = v1 - mu;
  float var = blk_sum(d0 * d0 + d1 * d1, sh) * (1.f / 512.f);
  float rstd = rsqrtf(var + 1e-5f);
  hr[t] = d0 * rstd * n3g[t] + n3b[t];
  hr[t + 256] = d1 * rstd * n3g[t + 256] + n3b[t + 256];
  __syncthreads();
  int kb = blockIdx.y;
  int nl = t & 63, seg = t >> 6;
  int n = blockIdx.x * 64 + nl;
  float acc = 0.f;
  const float* Wp = W + (size_t)(kb * 64 + seg * 16) * 512 + n;
#pragma unroll
  for (int k = 0; k < 16; k++) acc += hr[kb * 64 + seg * 16 + k] * Wp[(size_t)k * 512];
  red[seg][nl] = acc;
  __syncthreads();
  if (t < 64)
    part[(size_t)kb * 512 + blockIdx.x * 64 + t] =
        red[0][t] + red[1][t] + red[2][t] + red[3][t];
}

// head finish: reduce W1 partials + b1 -> LN -> gelu -> z; logits; softmax
__global__ __launch_bounds__(512) void head_finish(
    const float* __restrict__ part, int KB,
    const float* __restrict__ b1,
    const float* __restrict__ g, const float* __restrict__ bt,
    const float* __restrict__ W2, const float* __restrict__ b2,
    float* __restrict__ out) {
  __shared__ float sh[8];
  __shared__ float lg[ACT_N];
  int t = threadIdx.x;
  float v = b1[t];
  for (int k = 0; k < KB; k++) v += part[(size_t)k * 512 + t];
  float mu = blk_sum(v, sh) * (1.f / 512.f);
  float d = v - mu;
  float var = blk_sum(d * d, sh) * (1.f / 512.f);
  float z = gelu_f(d * rsqrtf(var + 1e-5f) * g[t] + bt[t]);
  for (int a = 0; a < ACT_N; a++) {
    float s = blk_sum(z * W2[t * ACT_N + a], sh);
    if (t == 0) lg[a] = s + b2[a];
  }
  __syncthreads();
  if (t == 0) {
    float m2 = lg[0];
    for (int a = 1; a < ACT_N; a++) m2 = fmaxf(m2, lg[a]);
    float den = 0.f;
    float ex[ACT_N];
    for (int a = 0; a < ACT_N; a++) { ex[a] = expf(lg[a] - m2); den += ex[a]; }
    for (int a = 0; a < ACT_N; a++) {
      out[a] = lg[a];
      out[ACT_N + a] = ex[a] / den;
    }
  }
}

extern "C" void kernel_launch(void* const* d_in, const int* in_sizes, int n_in,
                              void* d_out, int out_size, void* d_ws, size_t ws_size,
                              hipStream_t stream) {
  const float* x        = (const float*)d_in[0];
  const float* eattr    = (const float*)d_in[1];
  const float* rwse_W   = (const float*)d_in[2];
  const float* rwse_b   = (const float*)d_in[3];
  const float* rwse_g   = (const float*)d_in[4];
  const float* rwse_bt  = (const float*)d_in[5];
  const float* np_W     = (const float*)d_in[6];
  const float* np_b     = (const float*)d_in[7];
  const float* np_g     = (const float*)d_in[8];
  const float* np_bt    = (const float*)d_in[9];
  const float* gat_Wl   = (const float*)d_in[10];
  const float* gat_bl   = (const float*)d_in[11];
  const float* gat_Wr   = (const float*)d_in[12];
  const float* gat_br   = (const float*)d_in[13];
  const float* gat_We   = (const float*)d_in[14];
  const float* gat_att  = (const float*)d_in[15];
  const float* gat_bias = (const float*)d_in[16];
  const float* n1_g = (const float*)d_in[17];
  const float* n1_b = (const float*)d_in[18];
  const float* mha_inW  = (const float*)d_in[19];
  const float* mha_inb  = (const float*)d_in[20];
  const float* mha_outW = (const float*)d_in[21];
  const float* mha_outb = (const float*)d_in[22];
  const float* alpha_p  = (const float*)d_in[23];
  const float* n2_g = (const float*)d_in[24];
  const float* n2_b = (const float*)d_in[25];
  const float* ffn_W1 = (const float*)d_in[26];
  const float* ffn_b1 = (const float*)d_in[27];
  const float* ffn_W2 = (const float*)d_in[28];
  const float* ffn_b2 = (const float*)d_in[29];
  const float* n3_g = (const float*)d_in[30];
  const float* n3_b = (const float*)d_in[31];
  const float* ah_W1 = (const float*)d_in[32];
  const float* ah_b1 = (const float*)d_in[33];
  const float* ah_g  = (const float*)d_in[34];
  const float* ah_bt = (const float*)d_in[35];
  const float* ah_W2 = (const float*)d_in[36];
  const float* ah_b2 = (const float*)d_in[37];
  const int* edge_index = (const int*)d_in[38];
  const int* cni        = (const int*)d_in[39];
  (void)in_sizes; (void)n_in; (void)out_size; (void)ws_size;

  char* wsp = (char*)d_ws;
  size_t off = 0;
  auto alloc = [&](size_t bytes) -> char* {
    char* p = wsp + off;
    off += (bytes + 255) & ~(size_t)255;
    return p;
  };
  const size_t NNb = (size_t)NODES * NODES * 4;
  char* arena = alloc(3 * NNb);
  float* P2 = (float*)arena;
  float* P3 = (float*)(arena + NNb);
  float* P4 = (float*)(arena + 2 * NNb);
  u16* Axh = (u16*)arena;
  u16* Axl = (u16*)(arena + 17301504);
  float* hbig = (float*)arena;
  float* partC = (float*)(arena + 22020096);
  const u64 SEG_NP = 2162688ull;
  const u64 SEG_L0 = 3670016ull;
  const u64 L1_OFF = SEG_NP + SEG_L0;      // merged [Wl1|K1|V1], gnTot 24
  const u64 PTOT = L1_OFF + 786432ull;
  u16* Bh = (u16*)alloc(PTOT * 2);
  u16* Bl = (u16*)alloc(PTOT * 2);
  float* partNP = (float*)alloc((size_t)6 * NODES * 512 * 4);  // SK6
  float* rwse = (float*)alloc((size_t)NODES * 8 * 4);
  u16* h1h = (u16*)alloc((size_t)NODES * 512 * 2);
  u16* h1l = (u16*)alloc((size_t)NODES * 512 * 2);
  u16* attOh = (u16*)alloc((size_t)NODES * 512 * 2);
  u16* attOl = (u16*)alloc((size_t)NODES * 512 * 2);
  u16* combh = (u16*)alloc((size_t)NC * 512 * 2);
  u16* combl = (u16*)alloc((size_t)NC * 512 * 2);
  u16* ffmh = (u16*)alloc((size_t)NC * 2048 * 2);
  u16* ffml = (u16*)alloc((size_t)NC * 2048 * 2);
  u16* h1ch = (u16*)alloc((size_t)NC * 512 * 2);
  u16* h1cl = (u16*)alloc((size_t)NC * 512 * 2);
  float* h1c  = (float*)alloc((size_t)NC * 512 * 4);
  float* gout = (float*)alloc((size_t)NC * 512 * 4);
  float* comb = (float*)alloc((size_t)NC * 512 * 4);
  float* xkc  = (float*)alloc((size_t)NC * XK * 4);
  float* cb   = (float*)alloc((size_t)QS * 4);
  float* cbX  = (float*)alloc((size_t)XK * 4);
  float* rows = (float*)alloc(4096 * 4);
  float* pvqxr = (float*)alloc((size_t)8 * 1024 * 4);
  float* pvout = (float*)alloc((size_t)8 * 512 * 4);
  float* pvW1  = (float*)alloc((size_t)8 * 2048 * 4);
  float* pvW2  = (float*)alloc((size_t)32 * 512 * 4);
  float* pvhd  = (float*)alloc((size_t)8 * 512 * 4);
  char* zbase = alloc((size_t)NODES * 64 * 4 + NODES * 4 + NODES * 4 + 256);
  u32* bits  = (u32*)zbase;
  int* scnt  = (int*)(zbase + (size_t)NODES * 64 * 4);
  int* cnt   = (int*)(zbase + (size_t)NODES * 64 * 4 + NODES * 4);
  float* easum = (float*)(zbase + (size_t)NODES * 64 * 4 + NODES * 8);
  size_t zbytes = (size_t)NODES * 64 * 4 + NODES * 8 + 256;
  int* slist = (int*)alloc((size_t)NODES * SCAP * 4);
  int* elist = (int*)alloc((size_t)NODES * ECAP * 4);
  int* rmap  = (int*)alloc((size_t)NC * 4);
  float* pbuf  = (float*)alloc((size_t)8 * NODES * 4 * 4);
  float* local_row = rows + 1024;
  float* attO_row = rows + 1536;
  float* comb_row = rows + 2560;

  // ---- graph build (1 memset + merged kernel) ----
  hipMemsetAsync(zbase, 0, zbytes, stream);
  build_graph<<<(EDGES + NODES + 255) / 256, 256, 0, stream>>>(
      edge_index, eattr, bits, scnt, slist, cnt, elist, easum);
  small_setup<<<(NC + QS + XK + 255) / 256, 256, 0, stream>>>(
      cni, cnt, elist, edge_index, rmap, gat_bl, gat_br, mha_inb, cb,
      gat_bl + 512, mha_inb + 1536, cbX);

  // ---- RWSE sparse path ----
  spmm_sq<<<NODES, 256, 0, stream>>>(scnt, slist, P2, rwse);
  spmm_gather<<<NODES, 256, 0, stream>>>(scnt, slist, P2, P3, rwse, 2);
  spmm_gather<<<NODES, 256, 0, stream>>>(scnt, slist, P3, P4, rwse, 3);
  diag_tiled<<<dim3(NODES / 64, 8), 256, 0, stream>>>(P2, P3, P4, pbuf);
  diag_reduce<<<NODES / 256, 256, 0, stream>>>(pbuf, bits, scnt, rwse);

  // ---- pack weights + split x (merged; arena-as-P now dead) ----
  PackArgs pa;
  u64 uc = 0;
  int si = 0;
  auto seg = [&](const float* src, int K, int N, int stride, u64 offElems,
                 int gnTot, int ntOff) {
    pa.src[si] = src; pa.offU[si] = offElems / 8; pa.cumU[si] = uc;
    pa.N[si] = N; pa.srcStride[si] = stride; pa.gnTot[si] = gnTot;
    pa.ntOff[si] = ntOff;
    uc += (u64)K * N / 8; si++;
  };
  seg(np_W, 4224, 512, 512, 0, 8, 0);
  seg(gat_Wl, 512, 512, 512, SEG_NP, 40, 0);
  seg(gat_Wr, 512, 512, 512, SEG_NP, 40, 8);
  seg(mha_inW, 512, 1536, 1536, SEG_NP, 40, 16);
  seg(mha_outW, 512, 512, 512, SEG_NP + 1310720, 8, 0);
  seg(ffn_W1, 512, 2048, 2048, SEG_NP + 1572864, 32, 0);
  seg(ffn_W2, 2048, 512, 512, SEG_NP + 2621440, 8, 0);
  seg(gat_Wl + 512 * 512, 512, 512, 512, L1_OFF, 24, 0);
  seg(mha_inW + 512 * 1536 + 512, 512, 1024, 1536, L1_OFF, 24, 8);
  seg(x, NODES, 4096, 4096, 0, -1, 0);          // sentinel: split into A-panel
  for (int s2 = si; s2 <= 13; s2++) pa.cumU[s2] = uc;
  pack_all<<<4096, 256, 0, stream>>>(pa, Bh, Bl, Axh, Axl);
  rwse_proj<<<NODES, 128, 0, stream>>>(rwse, rwse_W, rwse_b, rwse_g, rwse_bt,
                                       Axh, Axl);

  // ---- np projection: SK6 ----
  gemm_s<<<dim3(256, 6), 256, 0, stream>>>(Axh, Axl, 4224, Bh, Bl,
                                           nullptr, nullptr, nullptr, nullptr,
                                           NODES, 4224, 512, 0, 704, partNP,
                                           nullptr);
  ln512<<<NODES, 256, 0, stream>>>(partNP, 6, NODES, np_b, nullptr, nullptr,
                                   nullptr, 0, np_g, np_bt, nullptr, h1h, h1l, 1);

  // ================= layer 0 (outputs pruned to NC compact rows) ===========
  {
    const u64 lb = SEG_NP;
    gemm_s<<<dim3(1280), 256, 0, stream>>>(h1h, h1l, 512, Bh + lb, Bl + lb,
                                           hbig, nullptr, nullptr, cb,
                                           NODES, 512, QS, 0, 512, nullptr,
                                           nullptr);
    gat_kernel<<<NC, 512, 0, stream>>>(hbig, rmap, eattr, easum, gat_We, gat_att,
                                       gat_bias, cnt, elist, edge_index,
                                       n1_g, n1_b, gout);
    mha_mfma<<<BG * NHEAD * 4, 256, 0, stream>>>(hbig + 1024, attOh, attOl);
    gemm_s<<<dim3(64, 2), 256, 0, stream>>>(attOh, attOl, 512, Bh + lb + 1310720,
                                            Bl + lb + 1310720, nullptr, nullptr,
                                            nullptr, nullptr, NC, 512, 512, 0, 256,
                                            partC, rmap);
    ln512<<<NC, 256, 0, stream>>>(partC, 2, NC, mha_outb, nullptr, gout, alpha_p,
                                  0, n2_g, n2_b, comb, combh, combl, 0);
    gemm_s<<<dim3(256), 256, 0, stream>>>(combh, combl, 512, Bh + lb + 1572864,
                                          Bl + lb + 1572864, nullptr, ffmh, ffml,
                                          ffn_b1, NC, 512, 2048, 1, 512, nullptr,
                                          nullptr);
    gemm_s<<<dim3(64, 4), 256, 0, stream>>>(ffmh, ffml, 2048, Bh + lb + 2621440,
                                            Bl + lb + 2621440, nullptr, nullptr,
                                            nullptr, nullptr, NC, 2048, 512, 0,
                                            512, partC, nullptr);
    ln512<<<NC, 256, 0, stream>>>(partC, 4, NC, ffn_b2, comb, nullptr, nullptr, 0,
                                  n3_g, n3_b, h1c, h1ch, h1cl, 0);
  }

  // ================= layer 1 (row cni; inputs from compact h1c) ============
  {
    // merged [xl1 | K | V] GEMM (xkc[NC][1536]; KV consumed for rows 0..255)
    gemm_s<<<dim3(192), 256, 0, stream>>>(h1ch, h1cl, 512, Bh + L1_OFF,
                                          Bl + L1_OFF, xkc, nullptr, nullptr,
                                          cbX, NC, 512, XK, 0, 512, nullptr,
                                          nullptr);
    gemv_qxr<<<dim3(16, 8), 256, 0, stream>>>(h1c, cni, mha_inW + 512 * 1536,
                                              gat_Wr + 512 * 512, pvqxr);
    l2_attn<<<9, 512, 0, stream>>>(xkc, pvqxr, cni, eattr, easum, gat_We + 1024,
                                   gat_att + 512, gat_bias + 512, cnt, elist,
                                   n1_g + 512, n1_b + 512, mha_inb + 1536,
                                   gat_br + 512, local_row, attO_row);
    gemv_part<<<dim3(8, 8), 256, 0, stream>>>(attO_row, nullptr, 0, 0,
                                              mha_outW + 512 * 512, 512, 512,
                                              pvout);
    gemv_comb<<<dim3(32, 8), 256, 0, stream>>>(pvout, mha_outb + 512, local_row,
                                               alpha_p, n2_g + 512, n2_b + 512,
                                               ffn_W1 + (size_t)512 * 2048,
                                               comb_row, pvW1);
    gemv_mid<<<dim3(8, 32), 256, 0, stream>>>(pvW1, ffn_b1 + 2048,
                                              ffn_W2 + (size_t)2048 * 512, pvW2);
    gemv_head<<<dim3(8, 8), 256, 0, stream>>>(pvW2, ffn_b2 + 512, comb_row,
                                              n3_g + 512, n3_b + 512, ah_W1,
                                              pvhd);
    head_finish<<<1, 512, 0, stream>>>(pvhd, 8, ah_b1, ah_g, ah_bt, ah_W2, ah_b2,
                                       (float*)d_out);
  }
}

// Round 14
// 332.073 us; speedup vs baseline: 2.2268x; 1.0775x over previous
//
#include <hip/hip_runtime.h>
#include <math.h>

constexpr int NODES = 2048;
constexpr int BG = 8;
constexpr int SG = 256;
constexpr int DIN = 4096;
constexpr int NHEAD = 8;
constexpr int EDGES = 32768;
constexpr int ACT_N = 5;
constexpr int H4C = 128;
constexpr int ECAP = 192;   // per-dst edge list capacity (GAT)
constexpr int SCAP = 96;    // per-src dedup'd neighbor capacity (RWSE)
constexpr int QS = 2560;    // merged hidden stride: [xl 512 | xr 512 | qkv 1536]
constexpr int NC = 512;     // compact row count (256 graph + 192 nbrs + pad)
constexpr int XK = 1536;    // merged l1 stride: [xl1 512 | K 512 | V 512]
constexpr int GR = 8;       // rows per spmm_gather2 block

typedef unsigned short u16;
typedef unsigned int u32;
typedef unsigned long long u64;
typedef short short8 __attribute__((ext_vector_type(8)));
typedef float f32x4 __attribute__((ext_vector_type(4)));

__device__ __forceinline__ float wave_sum(float v) {
#pragma unroll
  for (int o = 32; o; o >>= 1) v += __shfl_xor(v, o);
  return v;
}
__device__ __forceinline__ float wave_max(float v) {
#pragma unroll
  for (int o = 32; o; o >>= 1) v = fmaxf(v, __shfl_xor(v, o));
  return v;
}
__device__ __forceinline__ float blk_sum(float v, float* sh) {
  v = wave_sum(v);
  int nw = blockDim.x >> 6;
  __syncthreads();
  if ((threadIdx.x & 63) == 0) sh[threadIdx.x >> 6] = v;
  __syncthreads();
  float s = 0.f;
  for (int k = 0; k < nw; k++) s += sh[k];
  return s;
}
__device__ __forceinline__ float blk_max(float v, float* sh) {
  v = wave_max(v);
  int nw = blockDim.x >> 6;
  __syncthreads();
  if ((threadIdx.x & 63) == 0) sh[threadIdx.x >> 6] = v;
  __syncthreads();
  float m = sh[0];
  for (int k = 1; k < nw; k++) m = fmaxf(m, sh[k]);
  return m;
}
__device__ __forceinline__ float gelu_f(float x) {
  return 0.5f * x * (1.f + erff(x * 0.70710678118654752f));
}
__device__ __forceinline__ u16 f2bf(float x) {  // round-to-nearest-even bf16
  u32 u = __float_as_uint(x);
  return (u16)((u + 0x7FFFu + ((u >> 16) & 1u)) >> 16);
}
__device__ __forceinline__ float bf2f(u16 h) { return __uint_as_float(((u32)h) << 16); }
__device__ __forceinline__ void split2(float v, u16* ph, u16* pl) {
  u16 h = f2bf(v);
  *ph = h;
  *pl = f2bf(v - bf2f(h));
}

// ============ graph build (CSR + GAT lists + edge-attr sums, merged) =======
__global__ void build_graph(const int* __restrict__ ei, const float* __restrict__ ea,
                            u32* __restrict__ bits,
                            int* __restrict__ scnt, int* __restrict__ slist,
                            int* __restrict__ cnt, int* __restrict__ elist,
                            float* __restrict__ sums) {
  int e = blockIdx.x * 256 + threadIdx.x;
  float s0 = 0.f, s1 = 0.f;
  if (e < EDGES) {
    int s = ei[e], d = ei[EDGES + e];
    u32 m = 1u << (d & 31);
    u32 old = atomicOr(&bits[s * 64 + (d >> 5)], m);
    if (!(old & m)) {
      int p = atomicAdd(&scnt[s], 1);
      if (p < SCAP) slist[s * SCAP + p] = d;
    }
    int p2 = atomicAdd(&cnt[d], 1);
    if (p2 < ECAP) elist[(size_t)d * ECAP + p2] = e;
    s0 = ea[2 * e];
    s1 = ea[2 * e + 1];
  } else if (e < EDGES + NODES) {
    int d = e - EDGES;
    int p = atomicAdd(&cnt[d], 1);
    if (p < ECAP) elist[(size_t)d * ECAP + p] = e;
  }
  s0 = wave_sum(s0);
  s1 = wave_sum(s1);
  if ((threadIdx.x & 63) == 0 && (s0 != 0.f || s1 != 0.f)) {
    atomicAdd(&sums[0], s0);
    atomicAdd(&sums[1], s1);
  }
}

// rowmap + cb (l0 merged bias) + cbX (l1 merged bias), one kernel
__global__ void small_setup(const int* __restrict__ cni, const int* __restrict__ cnt,
                            const int* __restrict__ elist, const int* __restrict__ ei,
                            int* __restrict__ rowmap,
                            const float* __restrict__ bl0, const float* __restrict__ br0,
                            const float* __restrict__ inb0, float* __restrict__ cb,
                            const float* __restrict__ bl1, const float* __restrict__ inb1,
                            float* __restrict__ cbX) {
  int t = blockIdx.x * 256 + threadIdx.x;
  if (t < NC) {
    int i = cni[0];
    if (t < 256) {
      rowmap[t] = ((i >> 8) << 8) + t;
    } else {
      int p = t - 256;
      int m = min(cnt[i], ECAP);
      int v = 0;
      if (p < m) {
        int eid = elist[(size_t)i * ECAP + p];
        v = eid < EDGES ? ei[eid] : i;
      }
      rowmap[t] = v;
    }
  } else if (t < NC + QS) {
    int i = t - NC;
    cb[i] = i < 512 ? bl0[i] : (i < 1024 ? br0[i - 512] : inb0[i - 1024]);
  } else if (t < NC + QS + XK) {
    int i = t - NC - QS;
    cbX[i] = i < 512 ? bl1[i] : inb1[i];
  }
}

// ================= RWSE (sparse path) =================
__global__ __launch_bounds__(256) void spmm_sq(const int* __restrict__ scnt,
                                               const int* __restrict__ slist,
                                               float* __restrict__ P2,
                                               float* __restrict__ rwse) {
  int i = blockIdx.x, t = threadIdx.x;
  __shared__ float row[NODES];
  for (int c = t; c < NODES; c += 256) row[c] = 0.f;
  __syncthreads();
  int di = min(scnt[i], SCAP);
  float wi = di > 0 ? 1.f / (float)di : 0.f;
  for (int jj = 0; jj < di; jj++) {
    int j = slist[i * SCAP + jj];
    int dj = min(scnt[j], SCAP);
    if (dj == 0) continue;
    float w = wi / (float)dj;
    for (int kk = t; kk < dj; kk += 256) atomicAdd(&row[slist[j * SCAP + kk]], w);
  }
  __syncthreads();
  for (int c = t; c < NODES; c += 256) {
    float v = row[c];
    P2[(size_t)i * NODES + c] = v;
    if (c == i) rwse[(size_t)i * 8 + 1] = v;
  }
}

// col-tiled Q = T @ P: grid 2048 = (256 row-groups x 8 col-blocks),
// colg = blk&7 -> XCD round-robin gives per-XCD 2MB col-slab L2 residency.
__global__ __launch_bounds__(256) void spmm_gather2(const int* __restrict__ scnt,
                                                    const int* __restrict__ slist,
                                                    const float* __restrict__ P,
                                                    float* __restrict__ Q,
                                                    float* __restrict__ rwse,
                                                    int col) {
  int flat = blockIdx.x;
  int colg = flat & 7;
  int rowg = flat >> 3;
  int cbase = colg << 8;
  int t = threadIdx.x;
  __shared__ int nb[GR][SCAP];
  __shared__ int dcount[GR];
  for (int r = 0; r < GR; r++) {
    int i = rowg * GR + r;
    int di = min(scnt[i], SCAP);
    if (t == 0) dcount[r] = di;
    for (int c = t; c < di; c += 256) nb[r][c] = slist[i * SCAP + c];
  }
  __syncthreads();
  int gc = cbase + t;
  for (int r = 0; r < GR; r++) {
    int i = rowg * GR + r;
    int di = dcount[r];
    float wi = di > 0 ? 1.f / (float)di : 0.f;
    float s = 0.f;
    for (int j = 0; j < di; j++) s += P[(size_t)nb[r][j] * NODES + gc];
    float v = s * wi;
    Q[(size_t)i * NODES + gc] = v;
    if (gc == i) rwse[(size_t)i * 8 + col] = v;
  }
}

__global__ __launch_bounds__(256) void diag_tiled(const float* __restrict__ P2,
                                                  const float* __restrict__ P3,
                                                  const float* __restrict__ P4,
                                                  float* __restrict__ pbuf) {
  __shared__ float r2[64][65], r3[64][65], r4[64][65], c3[64][65], c4[64][65];
  __shared__ float red[4][4][64];
  int t = threadIdx.x;
  int i0 = blockIdx.x * 64;
  int js = blockIdx.y;
  int lo = t & 63, hi = t >> 6;
  float d5 = 0, d6 = 0, d7 = 0, d8 = 0;
  for (int jc = 0; jc < 4; jc++) {
    int j0 = js * 256 + jc * 64;
    __syncthreads();
#pragma unroll
    for (int r = 0; r < 16; r++) {
      int a = hi * 16 + r;
      r2[a][lo] = P2[(size_t)(i0 + a) * NODES + j0 + lo];
      r3[a][lo] = P3[(size_t)(i0 + a) * NODES + j0 + lo];
      r4[a][lo] = P4[(size_t)(i0 + a) * NODES + j0 + lo];
      c3[a][lo] = P3[(size_t)(j0 + a) * NODES + i0 + lo];
      c4[a][lo] = P4[(size_t)(j0 + a) * NODES + i0 + lo];
    }
    __syncthreads();
#pragma unroll
    for (int r = 0; r < 16; r++) {
      int jj = hi * 16 + r;
      float p3c = c3[jj][lo], p4c = c4[jj][lo];
      d5 += r2[lo][jj] * p3c;
      d6 += r3[lo][jj] * p3c;
      d7 += r3[lo][jj] * p4c;
      d8 += r4[lo][jj] * p4c;
    }
  }
  red[0][hi][lo] = d5; red[1][hi][lo] = d6; red[2][hi][lo] = d7; red[3][hi][lo] = d8;
  __syncthreads();
  if (hi == 0) {
    int i = i0 + lo;
#pragma unroll
    for (int v = 0; v < 4; v++) {
      float s = red[v][0][lo] + red[v][1][lo] + red[v][2][lo] + red[v][3][lo];
      pbuf[((size_t)js * NODES + i) * 4 + v] = s;
    }
  }
}

__global__ void diag_reduce(const float* __restrict__ pbuf,
                            const u32* __restrict__ bits,
                            const int* __restrict__ scnt,
                            float* __restrict__ rwse) {
  int i = blockIdx.x * 256 + threadIdx.x;
  if (i >= NODES) return;
  int deg = min(scnt[i], SCAP);
  int self = (bits[i * 64 + (i >> 5)] >> (i & 31)) & 1;
  rwse[(size_t)i * 8 + 0] = (self && deg > 0) ? 1.f / (float)deg : 0.f;
#pragma unroll
  for (int v = 0; v < 4; v++) {
    float s = 0.f;
    for (int js = 0; js < 8; js++) s += pbuf[((size_t)js * NODES + i) * 4 + v];
    rwse[(size_t)i * 8 + 4 + v] = s;
  }
}

// ================= fp32 -> split-bf16 helpers =================
__device__ __forceinline__ void splitA8(const float* __restrict__ p, short8& h8,
                                        short8& l8) {
  float4 v0 = *(const float4*)p;
  float4 v1 = *(const float4*)(p + 4);
  float v[8] = {v0.x, v0.y, v0.z, v0.w, v1.x, v1.y, v1.z, v1.w};
#pragma unroll
  for (int i = 0; i < 8; i++) {
    u16 h = f2bf(v[i]);
    h8[i] = (short)h;
    l8[i] = (short)f2bf(v[i] - bf2f(h));
  }
}

// ====== weight packing + x-panel split (merged); x seg marked gnTot < 0 =====
struct PackArgs {
  const float* src[13];
  u64 offU[13];
  u64 cumU[14];
  int N[13];
  int srcStride[13];
  int gnTot[13];
  int ntOff[13];
};

__global__ __launch_bounds__(256) void pack_all(PackArgs pa, u16* __restrict__ Bh,
                                                u16* __restrict__ Bl,
                                                u16* __restrict__ Axh,
                                                u16* __restrict__ Axl) {
  u64 total = pa.cumU[13];
  for (u64 u = (u64)blockIdx.x * 256 + threadIdx.x; u < total;
       u += (u64)gridDim.x * 256) {
    int s = 0;
    while (u >= pa.cumU[s + 1]) s++;
    u64 ur = u - pa.cumU[s];
    if (pa.gnTot[s] < 0) {
      int m = (int)(ur >> 9);
      int k = (int)((ur & 511) << 3);
      short8 h8, l8;
      splitA8(pa.src[s] + (size_t)m * 4096 + k, h8, l8);
      size_t o = (size_t)m * 4224 + k;
      *(short8*)(Axh + o) = h8;
      *(short8*)(Axl + o) = l8;
      continue;
    }
    int lr = (int)(ur & 15);
    int g = (int)((ur >> 4) & 3);
    int ks = (int)((ur >> 6) & 1);
    int j = (int)((ur >> 7) & 3);
    u64 rest = ur >> 9;
    int Nseg = pa.N[s] >> 6;
    int nt = (int)(rest % (u32)Nseg);
    int ktile = (int)(rest / (u32)Nseg);
    int k0 = (ktile << 6) | (ks << 5) | (g << 3);
    int n = (nt << 6) | (j << 4) | lr;
    const float* src = pa.src[s];
    int stride = pa.srcStride[s];
    u64 fiU = pa.offU[s] +
              ((((u64)ktile * pa.gnTot[s] + pa.ntOff[s] + nt) * 8 + j * 2 + ks) * 64 +
               g * 16 + lr);
    short8 h8, l8;
#pragma unroll
    for (int e = 0; e < 8; e++) {
      float v = src[(size_t)(k0 + e) * stride + n];
      u16 h = f2bf(v);
      h8[e] = (short)h;
      l8[e] = (short)f2bf(v - bf2f(h));
    }
    *((short8*)Bh + fiU) = h8;
    *((short8*)Bl + fiU) = l8;
  }
}

// ========== split-bf16 MFMA GEMM, pre-split u16 A, split-K, row gather =====
__global__ __launch_bounds__(256) void gemm_s(
    const u16* __restrict__ Ahg, const u16* __restrict__ Alg, int lda,
    const u16* __restrict__ Bh, const u16* __restrict__ Bl,
    float* __restrict__ C, u16* __restrict__ Ch, u16* __restrict__ Cl,
    const float* __restrict__ bias,
    int M, int K, int N, int act, int Kslice, float* __restrict__ part,
    const int* __restrict__ rowmap) {
  __shared__ __align__(16) u16 LA[2][4096];
  __shared__ __align__(16) u16 LB[2][4096];
  int gn = N >> 6;
  int nwg = (M >> 6) * gn;
  int q = nwg >> 3;
  int flat = blockIdx.x;
  int virt = (flat & 7) * q + (flat >> 3);     // bijective XCD-contiguous remap
  int bm = (virt / gn) << 6, bn = (virt % gn) << 6;
  int kb = blockIdx.y;
  int kstart = kb * Kslice;
  int kend = min(K, kstart + Kslice);
  int t = threadIdx.x;
  int lane = t & 63, w = t >> 6;
  int wm = (w >> 1) << 5, wn = (w & 1) << 5;
  int r0 = t >> 3, r1 = r0 + 32;
  int c8 = (t & 7) << 3;
  int ks_s = (t >> 2) & 1, g_s = t & 3;
  int slotA = (((r0 & 15) + (g_s << 4)) ^ (g_s | (ks_s << 2)));
  int da0 = ((((r0 >> 4) << 1) + ks_s) << 9) + (slotA << 3);
  int da1 = ((((r1 >> 4) << 1) + ks_s) << 9) + (slotA << 3);
  int db0 = t * 8, db1 = (t + 256) * 8;
  size_t btile = ((size_t)(kstart >> 6) * gn + (bn >> 6)) * 4096;
  size_t bstep = (size_t)gn * 4096;

  int rrow0 = bm + r0, rrow1 = bm + r1;
  if (rowmap) { rrow0 = rowmap[rrow0]; rrow1 = rowmap[rrow1]; }
  size_t aoff0 = (size_t)rrow0 * lda + c8;
  size_t aoff1 = (size_t)rrow1 * lda + c8;

  short8 pah0, pal0, pah1, pal1, pbh0, pbl0, pbh1, pbl1;
  pah0 = *(const short8*)(Ahg + aoff0 + kstart);
  pal0 = *(const short8*)(Alg + aoff0 + kstart);
  pah1 = *(const short8*)(Ahg + aoff1 + kstart);
  pal1 = *(const short8*)(Alg + aoff1 + kstart);
  pbh0 = *(const short8*)(Bh + btile + db0);
  pbl0 = *(const short8*)(Bl + btile + db0);
  pbh1 = *(const short8*)(Bh + btile + db1);
  pbl1 = *(const short8*)(Bl + btile + db1);

  f32x4 acc[2][2] = {};
  int lr = lane & 15, lg = lane >> 4;
  int rboff = lane << 3;

  for (int kt = kstart; kt < kend; kt += 64) {
    __syncthreads();
    *(short8*)&LA[0][da0] = pah0;
    *(short8*)&LA[1][da0] = pal0;
    *(short8*)&LA[0][da1] = pah1;
    *(short8*)&LA[1][da1] = pal1;
    *(short8*)&LB[0][db0] = pbh0;
    *(short8*)&LB[1][db0] = pbl0;
    *(short8*)&LB[0][db1] = pbh1;
    *(short8*)&LB[1][db1] = pbl1;
    __syncthreads();
    if (kt + 64 < kend) {
      btile += bstep;
      int kn = kt + 64;
      pah0 = *(const short8*)(Ahg + aoff0 + kn);
      pal0 = *(const short8*)(Alg + aoff0 + kn);
      pah1 = *(const short8*)(Ahg + aoff1 + kn);
      pal1 = *(const short8*)(Alg + aoff1 + kn);
      pbh0 = *(const short8*)(Bh + btile + db0);
      pbl0 = *(const short8*)(Bl + btile + db0);
      pbh1 = *(const short8*)(Bh + btile + db1);
      pbl1 = *(const short8*)(Bl + btile + db1);
    }
#pragma unroll
    for (int ks = 0; ks < 2; ks++) {
      short8 ah[2], al[2], bh[2], bl[2];
      int slr = ((lr + (lg << 4)) ^ (lg | (ks << 2))) << 3;
#pragma unroll
      for (int i = 0; i < 2; i++) {
        int ba = ((((wm >> 4) + i) * 2 + ks) << 9) + slr;
        ah[i] = *(const short8*)&LA[0][ba];
        al[i] = *(const short8*)&LA[1][ba];
        int bb = ((((wn >> 4) + i) * 2 + ks) << 9) + rboff;
        bh[i] = *(const short8*)&LB[0][bb];
        bl[i] = *(const short8*)&LB[1][bb];
      }
#pragma unroll
      for (int i = 0; i < 2; i++)
#pragma unroll
        for (int j = 0; j < 2; j++) {
          acc[i][j] = __builtin_amdgcn_mfma_f32_16x16x32_bf16(ah[i], bh[j], acc[i][j], 0, 0, 0);
          acc[i][j] = __builtin_amdgcn_mfma_f32_16x16x32_bf16(ah[i], bl[j], acc[i][j], 0, 0, 0);
          acc[i][j] = __builtin_amdgcn_mfma_f32_16x16x32_bf16(al[i], bh[j], acc[i][j], 0, 0, 0);
        }
    }
  }
  int row0 = (lane >> 4) * 4;
  if (part) {
    size_t pbase = (size_t)kb * (size_t)M * N;
#pragma unroll
    for (int i = 0; i < 2; i++)
#pragma unroll
      for (int j = 0; j < 2; j++) {
        int n = bn + wn + j * 16 + lr;
#pragma unroll
        for (int r = 0; r < 4; r++) {
          int m = bm + wm + i * 16 + row0 + r;
          part[pbase + (size_t)m * N + n] = acc[i][j][r];
        }
      }
    return;
  }
#pragma unroll
  for (int i = 0; i < 2; i++)
#pragma unroll
    for (int j = 0; j < 2; j++) {
      int n = bn + wn + j * 16 + lr;
      float bv = bias ? bias[n] : 0.f;
#pragma unroll
      for (int r = 0; r < 4; r++) {
        int m = bm + wm + i * 16 + row0 + r;
        float v = acc[i][j][r] + bv;
        if (act) v = gelu_f(v);
        size_t o = (size_t)m * N + n;
        if (Ch) {
          split2(v, Ch + o, Cl + o);
          if (C) C[o] = v;
        } else {
          C[o] = v;
        }
      }
    }
}

// ================= small fused kernels =================
__global__ __launch_bounds__(128) void rwse_proj(const float* __restrict__ rwse,
                                                 const float* __restrict__ W,
                                                 const float* __restrict__ bb,
                                                 const float* __restrict__ g,
                                                 const float* __restrict__ bt,
                                                 u16* __restrict__ Axh,
                                                 u16* __restrict__ Axl) {
  int i = blockIdx.x, j = threadIdx.x;
  float s = bb[j];
#pragma unroll
  for (int k = 0; k < 8; k++) s += rwse[(size_t)i * 8 + k] * W[k * H4C + j];
  __shared__ float sh[8];
  float sum = blk_sum(s, sh);
  float mu = sum * (1.f / 128.f);
  float d = s - mu;
  float var = blk_sum(d * d, sh) * (1.f / 128.f);
  float val = gelu_f(d * rsqrtf(var + 1e-5f) * g[j] + bt[j]);
  size_t o = (size_t)i * 4224 + 4096 + j;
  split2(val, Axh + o, Axl + o);
}

__global__ __launch_bounds__(256) void ln512(const float* __restrict__ x, int sk,
                                             int M,
                                             const float* __restrict__ gbias,
                                             const float* __restrict__ res,
                                             const float* __restrict__ mix,
                                             const float* __restrict__ ap, int l,
                                             const float* __restrict__ g,
                                             const float* __restrict__ b,
                                             float* __restrict__ y,
                                             u16* __restrict__ yh,
                                             u16* __restrict__ yl, int do_gelu) {
  const size_t MN = (size_t)M * 512;
  int i = blockIdx.x, t = threadIdx.x;
  size_t base = (size_t)i * 512;
  float v0 = x[base + t], v1 = x[base + 256 + t];
  for (int s = 1; s < sk; s++) {
    v0 += x[(size_t)s * MN + base + t];
    v1 += x[(size_t)s * MN + base + 256 + t];
  }
  if (gbias) { v0 += gbias[t]; v1 += gbias[t + 256]; }
  if (res) { v0 += res[base + t]; v1 += res[base + 256 + t]; }
  __shared__ float sh[8];
  float s = blk_sum(v0 + v1, sh);
  float mu = s * (1.f / 512.f);
  float d0 = v0 - mu, d1 = v1 - mu;
  float var = blk_sum(d0 * d0 + d1 * d1, sh) * (1.f / 512.f);
  float rstd = rsqrtf(var + 1e-5f);
  float o0 = d0 * rstd * g[t] + b[t];
  float o1 = d1 * rstd * g[t + 256] + b[t + 256];
  if (do_gelu) { o0 = gelu_f(o0); o1 = gelu_f(o1); }
  if (mix) {
    float a = 1.f / (1.f + expf(-ap[l]));
    o0 = a * mix[base + t] + (1.f - a) * o0;
    o1 = a * mix[base + 256 + t] + (1.f - a) * o1;
  }
  if (y) { y[base + t] = o0; y[base + 256 + t] = o1; }
  if (yh) {
    split2(o0, yh + base + t, yl + base + t);
    split2(o1, yh + base + 256 + t, yl + base + 256 + t);
  }
}

// layer-0 GAT at rowmap'd dst nodes, fused LN(n1)
__global__ __launch_bounds__(512) void gat_kernel(
    const float* __restrict__ hb, const int* __restrict__ rowmap,
    const float* __restrict__ eattr, const float* __restrict__ easum,
    const float* __restrict__ We, const float* __restrict__ att,
    const float* __restrict__ bias, const int* __restrict__ cnt,
    const int* __restrict__ elist, const int* __restrict__ ei,
    const float* __restrict__ n1g, const float* __restrict__ n1b,
    float* __restrict__ out) {
  int i = rowmap[blockIdx.x];
  int tid = threadIdx.x;
  int h = tid >> 6, c = tid & 63;
  int m_cnt = cnt[i];
  if (m_cnt > ECAP) m_cnt = ECAP;
  const float inv_e = 1.f / (float)EDGES;
  float we0 = We[tid], we1 = We[512 + tid];
  float attv = att[tid];
  float xrv = hb[(size_t)i * QS + 512 + tid];
  float ea_m0 = easum[0] * inv_e, ea_m1 = easum[1] * inv_e;
  __shared__ float logits[NHEAD][ECAP];
  __shared__ float sh[8];
  const int* el = elist + (size_t)i * ECAP;
  for (int e = 0; e < m_cnt; e++) {
    int eid = el[e];
    int s;
    float a0, a1;
    if (eid < EDGES) { s = ei[eid]; a0 = eattr[2 * eid]; a1 = eattr[2 * eid + 1]; }
    else { s = i; a0 = ea_m0; a1 = ea_m1; }
    float mval = hb[(size_t)s * QS + tid] + xrv + a0 * we0 + a1 * we1;
    mval = mval > 0.f ? mval : 0.2f * mval;
    float lg = wave_sum(mval * attv);
    if (c == 0) logits[h][e] = lg;
  }
  float mx = -1e30f;
  for (int e = c; e < m_cnt; e += 64) mx = fmaxf(mx, logits[h][e]);
  mx = wave_max(mx);
  float den = 0.f;
  for (int e = c; e < m_cnt; e += 64) den += expf(logits[h][e] - mx);
  den = wave_sum(den) + 1e-16f;
  float acc = 0.f;
  for (int e = 0; e < m_cnt; e++) {
    int eid = el[e];
    int s = eid < EDGES ? ei[eid] : i;
    float alpha = expf(logits[h][e] - mx) / den;
    acc += alpha * hb[(size_t)s * QS + tid];
  }
  float v = acc + bias[tid];
  float mu = blk_sum(v, sh) * (1.f / 512.f);
  float d = v - mu;
  float var = blk_sum(d * d, sh) * (1.f / 512.f);
  out[(size_t)blockIdx.x * 512 + tid] = d * rsqrtf(var + 1e-5f) * n1g[tid] + n1b[tid];
}

// ======= MFMA block-diag MHA (layer 0); outputs split u16 =======
__global__ __launch_bounds__(256) void mha_mfma(const float* __restrict__ qkv,
                                                u16* __restrict__ attOh,
                                                u16* __restrict__ attOl) {
  __shared__ __align__(16) u16 Ksh[2][256][72];
  __shared__ __align__(16) u16 Vt[2][64][264];
  int bid = blockIdx.x;
  int qq = bid & 3;
  int h = (bid >> 2) & 7;
  int b = bid >> 5;
  int t = threadIdx.x;
  int lane = t & 63, w = t >> 6;
  int lr = lane & 15, g = lane >> 4, kk = g * 8;
  size_t rowbase = (size_t)(b * SG) * QS;
  const float* Kbase = qkv + rowbase + 512 + h * 64;
  const float* Vbase = qkv + rowbase + 1024 + h * 64;
  for (int idx = t; idx < SG * 64; idx += 256) {
    int j = idx >> 6, c = idx & 63;
    float kv = Kbase[(size_t)j * QS + c];
    u16 khh = f2bf(kv);
    Ksh[0][j][c] = khh;
    Ksh[1][j][c] = f2bf(kv - bf2f(khh));
    float vv = Vbase[(size_t)j * QS + c];
    u16 vhh = f2bf(vv);
    Vt[0][c][j] = vhh;
    Vt[1][c][j] = f2bf(vv - bf2f(vhh));
  }
  const float* Qrow = qkv + rowbase + (size_t)(qq * 64 + w * 16 + lr) * QS + h * 64;
  short8 qh[2], ql[2];
#pragma unroll
  for (int kt = 0; kt < 2; kt++) {
    float qv[8];
    *(float4*)&qv[0] = *(const float4*)&Qrow[kt * 32 + kk];
    *(float4*)&qv[4] = *(const float4*)&Qrow[kt * 32 + kk + 4];
#pragma unroll
    for (int i = 0; i < 8; i++) {
      u16 hh = f2bf(qv[i]);
      qh[kt][i] = hh;
      ql[kt][i] = f2bf(qv[i] - bf2f(hh));
    }
  }
  __syncthreads();
  f32x4 S[16];
#pragma unroll
  for (int j = 0; j < 16; j++) {
    f32x4 acc = {};
#pragma unroll
    for (int kt = 0; kt < 2; kt++) {
      short8 bh = *(const short8*)&Ksh[0][j * 16 + lr][kt * 32 + kk];
      short8 bl = *(const short8*)&Ksh[1][j * 16 + lr][kt * 32 + kk];
      acc = __builtin_amdgcn_mfma_f32_16x16x32_bf16(qh[kt], bh, acc, 0, 0, 0);
      acc = __builtin_amdgcn_mfma_f32_16x16x32_bf16(qh[kt], bl, acc, 0, 0, 0);
      acc = __builtin_amdgcn_mfma_f32_16x16x32_bf16(ql[kt], bh, acc, 0, 0, 0);
    }
    S[j] = acc;
  }
  float mx[4], inv[4];
#pragma unroll
  for (int r = 0; r < 4; r++) {
    float m = S[0][r];
#pragma unroll
    for (int j = 1; j < 16; j++) m = fmaxf(m, S[j][r]);
#pragma unroll
    for (int oo = 1; oo < 16; oo <<= 1) m = fmaxf(m, __shfl_xor(m, oo));
    mx[r] = m;
    float d = 0.f;
#pragma unroll
    for (int j = 0; j < 16; j++) d += __expf((S[j][r] - m) * 0.125f);
#pragma unroll
    for (int oo = 1; oo < 16; oo <<= 1) d += __shfl_xor(d, oo);
    inv[r] = 1.f / d;
  }
  __syncthreads();
  u16* Pb = &Ksh[0][0][0];
  int row0 = w * 16 + g * 4;
#pragma unroll
  for (int j = 0; j < 16; j++) {
    int key = j * 16 + lr;
#pragma unroll
    for (int r = 0; r < 4; r++) {
      float p = __expf((S[j][r] - mx[r]) * 0.125f) * inv[r];
      u16 hh = f2bf(p);
      Pb[(row0 + r) * 264 + key] = hh;
      Pb[16896 + (row0 + r) * 264 + key] = f2bf(p - bf2f(hh));
    }
  }
  __syncthreads();
  f32x4 Oacc[4] = {};
#pragma unroll
  for (int kt = 0; kt < 8; kt++) {
    short8 pah = *(const short8*)&Pb[(w * 16 + lr) * 264 + kt * 32 + kk];
    short8 pal = *(const short8*)&Pb[16896 + (w * 16 + lr) * 264 + kt * 32 + kk];
#pragma unroll
    for (int nf = 0; nf < 4; nf++) {
      short8 vh = *(const short8*)&Vt[0][nf * 16 + lr][kt * 32 + kk];
      short8 vl = *(const short8*)&Vt[1][nf * 16 + lr][kt * 32 + kk];
      Oacc[nf] = __builtin_amdgcn_mfma_f32_16x16x32_bf16(pah, vh, Oacc[nf], 0, 0, 0);
      Oacc[nf] = __builtin_amdgcn_mfma_f32_16x16x32_bf16(pah, vl, Oacc[nf], 0, 0, 0);
      Oacc[nf] = __builtin_amdgcn_mfma_f32_16x16x32_bf16(pal, vh, Oacc[nf], 0, 0, 0);
    }
  }
  size_t obase = (size_t)(b * SG + qq * 64 + w * 16 + g * 4) * 512 + h * 64;
#pragma unroll
  for (int nf = 0; nf < 4; nf++)
#pragma unroll
    for (int r = 0; r < 4; r++) {
      size_t o = obase + (size_t)r * 512 + nf * 16 + lr;
      split2(Oacc[nf][r], attOh + o, attOl + o);
    }
}

// ================= layer-2 pruned path (row cni only) =================
__global__ __launch_bounds__(256) void gemv_part(
    const float* __restrict__ inrow, const int* __restrict__ cni, int rowMask,
    int rowStride, const float* __restrict__ W, int ldW, int N,
    float* __restrict__ part) {
  __shared__ float xv[64];
  __shared__ float red[4][64];
  int t = threadIdx.x;
  int kb = blockIdx.y;
  const float* xr = inrow + (cni ? (size_t)(cni[0] & rowMask) * rowStride : 0) + kb * 64;
  if (t < 64) xv[t] = xr[t];
  __syncthreads();
  int nl = t & 63;
  int n = blockIdx.x * 64 + nl;
  int seg = t >> 6;
  float acc = 0.f;
  const float* Wp = W + (size_t)(kb * 64 + seg * 16) * ldW + n;
#pragma unroll
  for (int k = 0; k < 16; k++) acc += xv[seg * 16 + k] * Wp[(size_t)k * ldW];
  red[seg][nl] = acc;
  __syncthreads();
  if (t < 64) {
    part[(size_t)kb * N + blockIdx.x * 64 + t] =
        red[0][t] + red[1][t] + red[2][t] + red[3][t];
  }
}

__global__ __launch_bounds__(256) void gemv_qxr(
    const float* __restrict__ h1c, const int* __restrict__ cni,
    const float* __restrict__ inW, const float* __restrict__ Wr,
    float* __restrict__ part) {
  __shared__ float xv[64];
  __shared__ float red[4][64];
  int t = threadIdx.x;
  int kb = blockIdx.y;
  const float* xr = h1c + (size_t)(cni[0] & 255) * 512 + kb * 64;
  if (t < 64) xv[t] = xr[t];
  __syncthreads();
  int b = blockIdx.x;
  int isq = b < 8;
  int nl = t & 63;
  int n = (b & 7) * 64 + nl;
  int seg = t >> 6;
  const float* W = isq ? inW : Wr;
  int ldW = isq ? 1536 : 512;
  float acc = 0.f;
  const float* Wp = W + (size_t)(kb * 64 + seg * 16) * ldW + n;
#pragma unroll
  for (int k = 0; k < 16; k++) acc += xv[seg * 16 + k] * Wp[(size_t)k * ldW];
  red[seg][nl] = acc;
  __syncthreads();
  if (t < 64) {
    part[(size_t)kb * 1024 + (isq ? 0 : 512) + (b & 7) * 64 + t] =
        red[0][t] + red[1][t] + red[2][t] + red[3][t];
  }
}

// merged l2 attention: block 0 = GAT@cni (+LN n1), blocks 1..8 = per-head MHA
__global__ __launch_bounds__(512) void l2_attn(
    const float* __restrict__ xkc, const float* __restrict__ pvqxr,
    const int* __restrict__ cni,
    const float* __restrict__ eattr, const float* __restrict__ easum,
    const float* __restrict__ We, const float* __restrict__ att,
    const float* __restrict__ bias, const int* __restrict__ cnt,
    const int* __restrict__ elist,
    const float* __restrict__ n1g, const float* __restrict__ n1b,
    const float* __restrict__ inbq, const float* __restrict__ br,
    float* __restrict__ local_row, float* __restrict__ attO_row) {
  __shared__ float logits[NHEAD][ECAP];
  __shared__ float sh[8];
  __shared__ float q[64];
  __shared__ float p[SG];
  __shared__ float red[8][64];
  if (blockIdx.x == 0) {
    int i = cni[0];
    int tid = threadIdx.x;
    int h = tid >> 6, c = tid & 63;
    int m_cnt = min(cnt[i], ECAP);
    const float inv_e = 1.f / (float)EDGES;
    float we0 = We[tid], we1 = We[512 + tid];
    float attv = att[tid];
    float xrv = br[tid];
    for (int k = 0; k < 8; k++) xrv += pvqxr[(size_t)k * 1024 + 512 + tid];
    float ea_m0 = easum[0] * inv_e, ea_m1 = easum[1] * inv_e;
    const int* el = elist + (size_t)i * ECAP;
    for (int e = 0; e < m_cnt; e++) {
      int eid = el[e];
      float a0, a1;
      if (eid < EDGES) { a0 = eattr[2 * eid]; a1 = eattr[2 * eid + 1]; }
      else { a0 = ea_m0; a1 = ea_m1; }
      float mval = xkc[(size_t)(256 + e) * XK + tid] + xrv + a0 * we0 + a1 * we1;
      mval = mval > 0.f ? mval : 0.2f * mval;
      float lg = wave_sum(mval * attv);
      if (c == 0) logits[h][e] = lg;
    }
    float mx = -1e30f;
    for (int e = c; e < m_cnt; e += 64) mx = fmaxf(mx, logits[h][e]);
    mx = wave_max(mx);
    float den = 0.f;
    for (int e = c; e < m_cnt; e += 64) den += expf(logits[h][e] - mx);
    den = wave_sum(den) + 1e-16f;
    float acc = 0.f;
    for (int e = 0; e < m_cnt; e++) {
      float alpha = expf(logits[h][e] - mx) / den;
      acc += alpha * xkc[(size_t)(256 + e) * XK + tid];
    }
    float v = acc + bias[tid];
    float mu = blk_sum(v, sh) * (1.f / 512.f);
    float d = v - mu;
    float var = blk_sum(d * d, sh) * (1.f / 512.f);
    local_row[tid] = d * rsqrtf(var + 1e-5f) * n1g[tid] + n1b[tid];
  } else {
    int h = blockIdx.x - 1;
    int t = threadIdx.x;
    if (t < 64) {
      float qq = inbq[h * 64 + t];
      for (int k = 0; k < 8; k++) qq += pvqxr[(size_t)k * 1024 + h * 64 + t];
      q[t] = qq;
    }
    __syncthreads();
    float s = -1e30f;
    if (t < SG) {
      const float* kr = xkc + (size_t)t * XK + 512 + h * 64;
      float acc = 0.f;
#pragma unroll 8
      for (int c2 = 0; c2 < 64; c2++) acc += q[c2] * kr[c2];
      s = acc * 0.125f;
    }
    float m = blk_max(s, sh);
    float e2 = (t < SG) ? __expf(s - m) : 0.f;
    if (t < SG) p[t] = e2;
    float den = blk_sum(e2, sh);
    __syncthreads();
    int c = t & 63, seg = t >> 6;
    float o = 0.f;
    for (int j = seg * 32; j < seg * 32 + 32; j++)
      o += p[j] * xkc[(size_t)j * XK + 1024 + h * 64 + c];
    red[seg][c] = o;
    __syncthreads();
    if (t < 64) {
      float tot = 0.f;
      for (int k = 0; k < 8; k++) tot += red[k][t];
      attO_row[h * 64 + t] = tot / den;
    }
  }
}

// W1 GEMV with comb (out-proj reduce + LN(n2) + mix) computed inline
__global__ __launch_bounds__(256) void gemv_comb(
    const float* __restrict__ pvout, const float* __restrict__ outb,
    const float* __restrict__ local_row, const float* __restrict__ ap,
    const float* __restrict__ n2g, const float* __restrict__ n2b,
    const float* __restrict__ W, float* __restrict__ comb_out,
    float* __restrict__ part) {
  __shared__ float combs[512];
  __shared__ float sh[8];
  __shared__ float red[4][64];
  int t = threadIdx.x;
  float v0 = outb[t], v1 = outb[t + 256];
  for (int k = 0; k < 8; k++) {
    v0 += pvout[(size_t)k * 512 + t];
    v1 += pvout[(size_t)k * 512 + 256 + t];
  }
  float ssum = blk_sum(v0 + v1, sh);
  float mu = ssum * (1.f / 512.f);
  float d0 = v0 - mu, d1 = v1 - mu;
  float var = blk_sum(d0 * d0 + d1 * d1, sh) * (1.f / 512.f);
  float rstd = rsqrtf(var + 1e-5f);
  float o0 = d0 * rstd * n2g[t] + n2b[t];
  float o1 = d1 * rstd * n2g[t + 256] + n2b[t + 256];
  float a = 1.f / (1.f + expf(-ap[1]));
  combs[t] = a * local_row[t] + (1.f - a) * o0;
  combs[t + 256] = a * local_row[t + 256] + (1.f - a) * o1;
  __syncthreads();
  if (blockIdx.x == 0 && blockIdx.y == 0) {
    comb_out[t] = combs[t];
    comb_out[t + 256] = combs[t + 256];
  }
  int kb = blockIdx.y;
  int nl = t & 63, seg = t >> 6;
  int n = blockIdx.x * 64 + nl;
  float acc = 0.f;
  const float* Wp = W + (size_t)(kb * 64 + seg * 16) * 2048 + n;
#pragma unroll
  for (int k = 0; k < 16; k++) acc += combs[kb * 64 + seg * 16 + k] * Wp[(size_t)k * 2048];
  red[seg][nl] = acc;
  __syncthreads();
  if (t < 64)
    part[(size_t)kb * 2048 + blockIdx.x * 64 + t] =
        red[0][t] + red[1][t] + red[2][t] + red[3][t];
}

// W2 GEMV with W1-partials reduce + bias + gelu inline
__global__ __launch_bounds__(256) void gemv_mid(
    const float* __restrict__ pvW1, const float* __restrict__ b1,
    const float* __restrict__ W, float* __restrict__ part) {
  __shared__ float xv[64];
  __shared__ float red[4][64];
  int t = threadIdx.x;
  int kb = blockIdx.y;  // 0..31
  if (t < 64) {
    float s = b1[kb * 64 + t];
    for (int k = 0; k < 8; k++) s += pvW1[(size_t)k * 2048 + kb * 64 + t];
    xv[t] = gelu_f(s);
  }
  __syncthreads();
  int nl = t & 63, seg = t >> 6;
  int n = blockIdx.x * 64 + nl;
  float acc = 0.f;
  const float* Wp = W + (size_t)(kb * 64 + seg * 16) * 512 + n;
#pragma unroll
  for (int k = 0; k < 16; k++) acc += xv[seg * 16 + k] * Wp[(size_t)k * 512];
  red[seg][nl] = acc;
  __syncthreads();
  if (t < 64)
    part[(size_t)kb * 512 + blockIdx.x * 64 + t] =
        red[0][t] + red[1][t] + red[2][t] + red[3][t];
}

// head W1 GEMV with final LN(n3) (W2-partials reduce + residual) inline
__global__ __launch_bounds__(256) void gemv_head(
    const float* __restrict__ pvW2, const float* __restrict__ b2,
    const float* __restrict__ comb_row,
    const float* __restrict__ n3g, const float* __restrict__ n3b,
    const float* __restrict__ W, float* __restrict__ part) {
  __shared__ float hr[512];
  __shared__ float sh[8];
  __shared__ float red[4][64];
  int t = threadIdx.x;
  float v0 = b2[t] + comb_row[t], v1 = b2[t + 256] + comb_row[t + 256];
  for (int k = 0; k < 32; k++) {
    v0 += pvW2[(size_t)k * 512 + t];
    v1 += pvW2[(size_t)k * 512 + 256 + t];
  }
  float ssum = blk_sum(v0 + v1, sh);
  float mu = ssum * (1.f / 512.f);
  float d0 = v0 - mu, d1 = v1 - mu;
  float var = blk_sum(d0 * d0 + d1 * d1, sh) * (1.f / 512.f);
  float rstd = rsqrtf(var + 1e-5f);
  hr[t] = d0 * rstd * n3g[t] + n3b[t];
  hr[t + 256] = d1 * rstd * n3g[t + 256] + n3b[t + 256];
  __syncthreads();
  int kb = blockIdx.y;
  int nl = t & 63, seg = t >> 6;
  int n = blockIdx.x * 64 + nl;
  float acc = 0.f;
  const float* Wp = W + (size_t)(kb * 64 + seg * 16) * 512 + n;
#pragma unroll
  for (int k = 0; k < 16; k++) acc += hr[kb * 64 + seg * 16 + k] * Wp[(size_t)k * 512];
  red[seg][nl] = acc;
  __syncthreads();
  if (t < 64)
    part[(size_t)kb * 512 + blockIdx.x * 64 + t] =
        red[0][t] + red[1][t] + red[2][t] + red[3][t];
}

// head finish
__global__ __launch_bounds__(512) void head_finish(
    const float* __restrict__ part, int KB,
    const float* __restrict__ b1,
    const float* __restrict__ g, const float* __restrict__ bt,
    const float* __restrict__ W2, const float* __restrict__ b2,
    float* __restrict__ out) {
  __shared__ float sh[8];
  __shared__ float lg[ACT_N];
  int t = threadIdx.x;
  float v = b1[t];
  for (int k = 0; k < KB; k++) v += part[(size_t)k * 512 + t];
  float mu = blk_sum(v, sh) * (1.f / 512.f);
  float d = v - mu;
  float var = blk_sum(d * d, sh) * (1.f / 512.f);
  float z = gelu_f(d * rsqrtf(var + 1e-5f) * g[t] + bt[t]);
  for (int a = 0; a < ACT_N; a++) {
    float s = blk_sum(z * W2[t * ACT_N + a], sh);
    if (t == 0) lg[a] = s + b2[a];
  }
  __syncthreads();
  if (t == 0) {
    float m2 = lg[0];
    for (int a = 1; a < ACT_N; a++) m2 = fmaxf(m2, lg[a]);
    float den = 0.f;
    float ex[ACT_N];
    for (int a = 0; a < ACT_N; a++) { ex[a] = expf(lg[a] - m2); den += ex[a]; }
    for (int a = 0; a < ACT_N; a++) {
      out[a] = lg[a];
      out[ACT_N + a] = ex[a] / den;
    }
  }
}

extern "C" void kernel_launch(void* const* d_in, const int* in_sizes, int n_in,
                              void* d_out, int out_size, void* d_ws, size_t ws_size,
                              hipStream_t stream) {
  const float* x        = (const float*)d_in[0];
  const float* eattr    = (const float*)d_in[1];
  const float* rwse_W   = (const float*)d_in[2];
  const float* rwse_b   = (const float*)d_in[3];
  const float* rwse_g   = (const float*)d_in[4];
  const float* rwse_bt  = (const float*)d_in[5];
  const float* np_W     = (const float*)d_in[6];
  const float* np_b     = (const float*)d_in[7];
  const float* np_g     = (const float*)d_in[8];
  const float* np_bt    = (const float*)d_in[9];
  const float* gat_Wl   = (const float*)d_in[10];
  const float* gat_bl   = (const float*)d_in[11];
  const float* gat_Wr   = (const float*)d_in[12];
  const float* gat_br   = (const float*)d_in[13];
  const float* gat_We   = (const float*)d_in[14];
  const float* gat_att  = (const float*)d_in[15];
  const float* gat_bias = (const float*)d_in[16];
  const float* n1_g = (const float*)d_in[17];
  const float* n1_b = (const float*)d_in[18];
  const float* mha_inW  = (const float*)d_in[19];
  const float* mha_inb  = (const float*)d_in[20];
  const float* mha_outW = (const float*)d_in[21];
  const float* mha_outb = (const float*)d_in[22];
  const float* alpha_p  = (const float*)d_in[23];
  const float* n2_g = (const float*)d_in[24];
  const float* n2_b = (const float*)d_in[25];
  const float* ffn_W1 = (const float*)d_in[26];
  const float* ffn_b1 = (const float*)d_in[27];
  const float* ffn_W2 = (const float*)d_in[28];
  const float* ffn_b2 = (const float*)d_in[29];
  const float* n3_g = (const float*)d_in[30];
  const float* n3_b = (const float*)d_in[31];
  const float* ah_W1 = (const float*)d_in[32];
  const float* ah_b1 = (const float*)d_in[33];
  const float* ah_g  = (const float*)d_in[34];
  const float* ah_bt = (const float*)d_in[35];
  const float* ah_W2 = (const float*)d_in[36];
  const float* ah_b2 = (const float*)d_in[37];
  const int* edge_index = (const int*)d_in[38];
  const int* cni        = (const int*)d_in[39];
  (void)in_sizes; (void)n_in; (void)out_size; (void)ws_size;

  char* wsp = (char*)d_ws;
  size_t off = 0;
  auto alloc = [&](size_t bytes) -> char* {
    char* p = wsp + off;
    off += (bytes + 255) & ~(size_t)255;
    return p;
  };
  const size_t NNb = (size_t)NODES * NODES * 4;
  char* arena = alloc(3 * NNb);
  float* P2 = (float*)arena;
  float* P3 = (float*)(arena + NNb);
  float* P4 = (float*)(arena + 2 * NNb);
  u16* Axh = (u16*)arena;
  u16* Axl = (u16*)(arena + 17301504);
  float* hbig = (float*)arena;
  float* partC = (float*)(arena + 22020096);
  const u64 SEG_NP = 2162688ull;
  const u64 SEG_L0 = 3670016ull;
  const u64 L1_OFF = SEG_NP + SEG_L0;
  const u64 PTOT = L1_OFF + 786432ull;
  u16* Bh = (u16*)alloc(PTOT * 2);
  u16* Bl = (u16*)alloc(PTOT * 2);
  float* partNP = (float*)alloc((size_t)6 * NODES * 512 * 4);
  float* rwse = (float*)alloc((size_t)NODES * 8 * 4);
  u16* h1h = (u16*)alloc((size_t)NODES * 512 * 2);
  u16* h1l = (u16*)alloc((size_t)NODES * 512 * 2);
  u16* attOh = (u16*)alloc((size_t)NODES * 512 * 2);
  u16* attOl = (u16*)alloc((size_t)NODES * 512 * 2);
  u16* combh = (u16*)alloc((size_t)NC * 512 * 2);
  u16* combl = (u16*)alloc((size_t)NC * 512 * 2);
  u16* ffmh = (u16*)alloc((size_t)NC * 2048 * 2);
  u16* ffml = (u16*)alloc((size_t)NC * 2048 * 2);
  u16* h1ch = (u16*)alloc((size_t)NC * 512 * 2);
  u16* h1cl = (u16*)alloc((size_t)NC * 512 * 2);
  float* h1c  = (float*)alloc((size_t)NC * 512 * 4);
  float* gout = (float*)alloc((size_t)NC * 512 * 4);
  float* comb = (float*)alloc((size_t)NC * 512 * 4);
  float* xkc  = (float*)alloc((size_t)NC * XK * 4);
  float* cb   = (float*)alloc((size_t)QS * 4);
  float* cbX  = (float*)alloc((size_t)XK * 4);
  float* rows = (float*)alloc(4096 * 4);
  float* pvqxr = (float*)alloc((size_t)8 * 1024 * 4);
  float* pvout = (float*)alloc((size_t)8 * 512 * 4);
  float* pvW1  = (float*)alloc((size_t)8 * 2048 * 4);
  float* pvW2  = (float*)alloc((size_t)32 * 512 * 4);
  float* pvhd  = (float*)alloc((size_t)8 * 512 * 4);
  char* zbase = alloc((size_t)NODES * 64 * 4 + NODES * 4 + NODES * 4 + 256);
  u32* bits  = (u32*)zbase;
  int* scnt  = (int*)(zbase + (size_t)NODES * 64 * 4);
  int* cnt   = (int*)(zbase + (size_t)NODES * 64 * 4 + NODES * 4);
  float* easum = (float*)(zbase + (size_t)NODES * 64 * 4 + NODES * 8);
  size_t zbytes = (size_t)NODES * 64 * 4 + NODES * 8 + 256;
  int* slist = (int*)alloc((size_t)NODES * SCAP * 4);
  int* elist = (int*)alloc((size_t)NODES * ECAP * 4);
  int* rmap  = (int*)alloc((size_t)NC * 4);
  float* pbuf  = (float*)alloc((size_t)8 * NODES * 4 * 4);
  float* local_row = rows + 1024;
  float* attO_row = rows + 1536;
  float* comb_row = rows + 2560;

  // ---- graph build (1 memset + merged kernel) ----
  hipMemsetAsync(zbase, 0, zbytes, stream);
  build_graph<<<(EDGES + NODES + 255) / 256, 256, 0, stream>>>(
      edge_index, eattr, bits, scnt, slist, cnt, elist, easum);
  small_setup<<<(NC + QS + XK + 255) / 256, 256, 0, stream>>>(
      cni, cnt, elist, edge_index, rmap, gat_bl, gat_br, mha_inb, cb,
      gat_bl + 512, mha_inb + 1536, cbX);

  // ---- RWSE sparse path (col-tiled gathers) ----
  spmm_sq<<<NODES, 256, 0, stream>>>(scnt, slist, P2, rwse);
  spmm_gather2<<<NODES, 256, 0, stream>>>(scnt, slist, P2, P3, rwse, 2);
  spmm_gather2<<<NODES, 256, 0, stream>>>(scnt, slist, P3, P4, rwse, 3);
  diag_tiled<<<dim3(NODES / 64, 8), 256, 0, stream>>>(P2, P3, P4, pbuf);
  diag_reduce<<<NODES / 256, 256, 0, stream>>>(pbuf, bits, scnt, rwse);

  // ---- pack weights + split x (merged) ----
  PackArgs pa;
  u64 uc = 0;
  int si = 0;
  auto seg = [&](const float* src, int K, int N, int stride, u64 offElems,
                 int gnTot, int ntOff) {
    pa.src[si] = src; pa.offU[si] = offElems / 8; pa.cumU[si] = uc;
    pa.N[si] = N; pa.srcStride[si] = stride; pa.gnTot[si] = gnTot;
    pa.ntOff[si] = ntOff;
    uc += (u64)K * N / 8; si++;
  };
  seg(np_W, 4224, 512, 512, 0, 8, 0);
  seg(gat_Wl, 512, 512, 512, SEG_NP, 40, 0);
  seg(gat_Wr, 512, 512, 512, SEG_NP, 40, 8);
  seg(mha_inW, 512, 1536, 1536, SEG_NP, 40, 16);
  seg(mha_outW, 512, 512, 512, SEG_NP + 1310720, 8, 0);
  seg(ffn_W1, 512, 2048, 2048, SEG_NP + 1572864, 32, 0);
  seg(ffn_W2, 2048, 512, 512, SEG_NP + 2621440, 8, 0);
  seg(gat_Wl + 512 * 512, 512, 512, 512, L1_OFF, 24, 0);
  seg(mha_inW + 512 * 1536 + 512, 512, 1024, 1536, L1_OFF, 24, 8);
  seg(x, NODES, 4096, 4096, 0, -1, 0);
  for (int s2 = si; s2 <= 13; s2++) pa.cumU[s2] = uc;
  pack_all<<<4096, 256, 0, stream>>>(pa, Bh, Bl, Axh, Axl);
  rwse_proj<<<NODES, 128, 0, stream>>>(rwse, rwse_W, rwse_b, rwse_g, rwse_bt,
                                       Axh, Axl);

  // ---- np projection: SK6 ----
  gemm_s<<<dim3(256, 6), 256, 0, stream>>>(Axh, Axl, 4224, Bh, Bl,
                                           nullptr, nullptr, nullptr, nullptr,
                                           NODES, 4224, 512, 0, 704, partNP,
                                           nullptr);
  ln512<<<NODES, 256, 0, stream>>>(partNP, 6, NODES, np_b, nullptr, nullptr,
                                   nullptr, 0, np_g, np_bt, nullptr, h1h, h1l, 1);

  // ================= layer 0 (outputs pruned to NC compact rows) ===========
  {
    const u64 lb = SEG_NP;
    gemm_s<<<dim3(1280), 256, 0, stream>>>(h1h, h1l, 512, Bh + lb, Bl + lb,
                                           hbig, nullptr, nullptr, cb,
                                           NODES, 512, QS, 0, 512, nullptr,
                                           nullptr);
    gat_kernel<<<NC, 512, 0, stream>>>(hbig, rmap, eattr, easum, gat_We, gat_att,
                                       gat_bias, cnt, elist, edge_index,
                                       n1_g, n1_b, gout);
    mha_mfma<<<BG * NHEAD * 4, 256, 0, stream>>>(hbig + 1024, attOh, attOl);
    gemm_s<<<dim3(64, 2), 256, 0, stream>>>(attOh, attOl, 512, Bh + lb + 1310720,
                                            Bl + lb + 1310720, nullptr, nullptr,
                                            nullptr, nullptr, NC, 512, 512, 0, 256,
                                            partC, rmap);
    ln512<<<NC, 256, 0, stream>>>(partC, 2, NC, mha_outb, nullptr, gout, alpha_p,
                                  0, n2_g, n2_b, comb, combh, combl, 0);
    gemm_s<<<dim3(256), 256, 0, stream>>>(combh, combl, 512, Bh + lb + 1572864,
                                          Bl + lb + 1572864, nullptr, ffmh, ffml,
                                          ffn_b1, NC, 512, 2048, 1, 512, nullptr,
                                          nullptr);
    gemm_s<<<dim3(64, 4), 256, 0, stream>>>(ffmh, ffml, 2048, Bh + lb + 2621440,
                                            Bl + lb + 2621440, nullptr, nullptr,
                                            nullptr, nullptr, NC, 2048, 512, 0,
                                            512, partC, nullptr);
    ln512<<<NC, 256, 0, stream>>>(partC, 4, NC, ffn_b2, comb, nullptr, nullptr, 0,
                                  n3_g, n3_b, h1c, h1ch, h1cl, 0);
  }

  // ================= layer 1 (row cni; inputs from compact h1c) ============
  {
    gemm_s<<<dim3(192), 256, 0, stream>>>(h1ch, h1cl, 512, Bh + L1_OFF,
                                          Bl + L1_OFF, xkc, nullptr, nullptr,
                                          cbX, NC, 512, XK, 0, 512, nullptr,
                                          nullptr);
    gemv_qxr<<<dim3(16, 8), 256, 0, stream>>>(h1c, cni, mha_inW + 512 * 1536,
                                              gat_Wr + 512 * 512, pvqxr);
    l2_attn<<<9, 512, 0, stream>>>(xkc, pvqxr, cni, eattr, easum, gat_We + 1024,
                                   gat_att + 512, gat_bias + 512, cnt, elist,
                                   n1_g + 512, n1_b + 512, mha_inb + 1536,
                                   gat_br + 512, local_row, attO_row);
    gemv_part<<<dim3(8, 8), 256, 0, stream>>>(attO_row, nullptr, 0, 0,
                                              mha_outW + 512 * 512, 512, 512,
                                              pvout);
    gemv_comb<<<dim3(32, 8), 256, 0, stream>>>(pvout, mha_outb + 512, local_row,
                                               alpha_p, n2_g + 512, n2_b + 512,
                                               ffn_W1 + (size_t)512 * 2048,
                                               comb_row, pvW1);
    gemv_mid<<<dim3(8, 32), 256, 0, stream>>>(pvW1, ffn_b1 + 2048,
                                              ffn_W2 + (size_t)2048 * 512, pvW2);
    gemv_head<<<dim3(8, 8), 256, 0, stream>>>(pvW2, ffn_b2 + 512, comb_row,
                                              n3_g + 512, n3_b + 512, ah_W1,
                                              pvhd);
    head_finish<<<1, 512, 0, stream>>>(pvhd, 8, ah_b1, ah_g, ah_bt, ah_W2, ah_b2,
                                       (float*)d_out);
  }
}